// Round 12
// baseline (853.387 us; speedup 1.0000x reference)
//
#include <hip/hip_runtime.h>
#include <math.h>

constexpr int N = 512;
constexpr int D = 16;
constexpr int E = 12;

// ---- workspace layout (float offsets) ----
constexpr size_t OFF_A     = 0;                            // E*N*N  A -> trail -> iK
constexpr size_t OFF_IK    = OFF_A    + (size_t)E*N*N;     // E*N*N  W = L^{-1}
constexpr size_t OFF_XS    = OFF_IK   + (size_t)E*N*N;     // N*D
constexpr size_t OFF_INP   = OFF_XS   + (size_t)N*D;       // N*D
constexpr size_t OFF_YN    = OFF_INP  + (size_t)N*D;       // E*N
constexpr size_t OFF_BETA  = OFF_YN   + (size_t)E*N;       // E*N
constexpr size_t OFF_KVEC  = OFF_BETA + (size_t)E*N;       // E*N
constexpr size_t OFF_LB    = OFF_KVEC + (size_t)E*N;       // E*N
constexpr size_t OFF_TIL   = OFF_LB   + (size_t)E*N;       // E*N*D
constexpr size_t OFF_U     = OFF_TIL  + (size_t)E*N*D;     // E*E*N
constexpr size_t OFF_V     = OFF_U    + (size_t)E*E*N;     // E*E*N
constexpr size_t OFF_Q     = OFF_V    + (size_t)E*E*N;     // E*E*D*D
constexpr size_t OFF_BINV  = OFF_Q    + (size_t)E*E*D*D;   // E*D*D
constexpr size_t OFF_C     = OFF_BINV + (size_t)E*D*D;     // E
constexpr size_t OFF_ISDR  = OFF_C    + E;                 // E*E
constexpr size_t OFF_SPART = OFF_ISDR + E*E;               // E*E*8
constexpr size_t OFF_TPART = OFF_SPART+ (size_t)E*E*8;     // E*8
constexpr size_t OFF_XMEAN = OFF_TPART+ (size_t)E*8;       // D
constexpr size_t OFF_XSTD  = OFF_XMEAN+ D;                 // D
constexpr size_t OFF_YMEAN = OFF_XSTD + D;                 // E
constexpr size_t OFF_YSTD  = OFF_YMEAN+ E;                 // E
constexpr size_t OFF_SSM   = OFF_YSTD + E;                 // D*D
constexpr size_t OFF_P     = OFF_SSM  + D*D;               // E*1792*64  (L panels, compact)
constexpr size_t OFF_T     = OFF_P    + (size_t)E*1792*64; // E*65536    (D&C scratch)

__device__ __forceinline__ int prow(int k) { return k*(480 - 32*k); }  // row offset of panel k

// ======== fast 64x64 Cholesky: column-split registers, 1 barrier/step, no spill ========
__device__ __forceinline__ void fact64(float a[16], float (*cb)[64], float* invd, int lane, int wv) {
    #pragma unroll
    for (int k = 0; k < 64; ++k) {
        const int kg = k >> 4, kj = k & 15;
        if (wv == kg) {
            float dkk = __shfl(a[kj], k);
            float dv = sqrtf(dkk);
            float iv = 1.0f / dv;
            float sc = a[kj] * iv;
            if (lane == k)      { a[kj] = dv; invd[k] = iv; }
            else if (lane > k)  a[kj] = sc;
            cb[k & 1][lane] = (lane > k) ? a[kj] : 0.0f;
        }
        __syncthreads();
        float lrk = cb[k & 1][lane];
        #pragma unroll
        for (int j = 0; j < 16; ++j)
            a[j] = fmaf(-lrk, cb[k & 1][wv*16 + j], a[j]);
    }
}

// ======== barrier-free triangular inverse: thread c owns column c ========
__device__ __forceinline__ void tinv64(const float (*Lsh)[65], float (*Xsh)[65],
                                       const float* invd, int tid) {
    if (tid < 64) {
        const int c = tid;
        for (int r = 0; r < c; ++r) Xsh[r][c] = 0.0f;
        for (int r = c; r < 64; ++r) {
            float a0 = (r == c) ? 1.0f : 0.0f, a1 = 0.0f;
            int k = c;
            for (; k + 1 < r; k += 2) {
                a0 = fmaf(-Lsh[r][k],   Xsh[k][c],   a0);
                a1 = fmaf(-Lsh[r][k+1], Xsh[k+1][c], a1);
            }
            if (k < r) a0 = fmaf(-Lsh[r][k], Xsh[k][c], a0);
            Xsh[r][c] = (a0 + a1) * invd[r];
        }
    }
    __syncthreads();
}

// ---------- 1. standardization ----------
__global__ __launch_bounds__(512) void k_prep(const float* __restrict__ X, const float* __restrict__ Y,
                                              const float* __restrict__ m, const float* __restrict__ s,
                                              float* __restrict__ ws) {
    int tid = threadIdx.x;
    int lane = tid & 63, wave = tid >> 6;
    __shared__ float meanX[D], stdX[D], meanY[E], stdY[E], mmsh[D];

    for (int col = wave; col < D + E; col += 8) {
        float s1 = 0.f, s2 = 0.f;
        if (col < D) {
            #pragma unroll
            for (int i = 0; i < 8; ++i) { float v = X[(i*64 + lane)*D + col]; s1 += v; s2 += v*v; }
        } else {
            int e = col - D;
            #pragma unroll
            for (int i = 0; i < 8; ++i) { float v = Y[(i*64 + lane)*E + e]; s1 += v; s2 += v*v; }
        }
        #pragma unroll
        for (int off = 32; off > 0; off >>= 1) { s1 += __shfl_xor(s1, off); s2 += __shfl_xor(s2, off); }
        if (lane == 0) {
            float mean = s1 * (1.0f/N);
            float var  = (s2 - (float)N*mean*mean) * (1.0f/(N-1));
            float sd   = sqrtf(var);
            if (col < D) { meanX[col] = mean; stdX[col] = sd; }
            else         { meanY[col-D] = mean; stdY[col-D] = sd; }
        }
    }
    __syncthreads();
    if (tid < D) {
        mmsh[tid] = (m[tid] - meanX[tid]) / stdX[tid];
        ws[OFF_XMEAN + tid] = meanX[tid];
        ws[OFF_XSTD  + tid] = stdX[tid];
    }
    if (tid < E) { ws[OFF_YMEAN + tid] = meanY[tid]; ws[OFF_YSTD + tid] = stdY[tid]; }
    __syncthreads();
    int n = tid;
    #pragma unroll
    for (int d = 0; d < D; ++d) {
        float xs = (X[n*D + d] - meanX[d]) / stdX[d];
        ws[OFF_XS  + n*D + d] = xs;
        ws[OFF_INP + n*D + d] = xs - mmsh[d];
    }
    #pragma unroll
    for (int e = 0; e < E; ++e)
        ws[OFF_YN + e*N + n] = (Y[n*E + e] - meanY[e]) / stdY[e];
    if (tid < D*D) {
        int i = tid / D, j = tid % D;
        ws[OFF_SSM + tid] = s[tid] / (stdX[i] * stdX[j]);
    }
}

// ---------- 2. A = K + noise I  +  appended B/R inverse blocks ----------
__global__ __launch_bounds__(256) void k_buildA(float* __restrict__ ws, const float* __restrict__ ls,
                                                const float* __restrict__ os, const float* __restrict__ noise) {
    int bid = blockIdx.x;
    int tid = threadIdx.x;
    if (bid < E*64) {
        int e  = bid >> 6;
        int t  = bid & 63;
        int bn = t >> 3, bm = t & 7;
        __shared__ float xn[64][17], xm[64][17];
        __shared__ float il2[16];
        for (int idx = tid; idx < 1024; idx += 256) {
            int r = idx >> 4, d0 = idx & 15;
            xn[r][d0] = ws[OFF_XS + (size_t)(bn*64 + r)*D + d0];
            xm[r][d0] = ws[OFF_XS + (size_t)(bm*64 + r)*D + d0];
        }
        if (tid < 16) { float l = ls[e*D + tid]; il2[tid] = 1.0f/(l*l); }
        __syncthreads();
        int tx = tid & 15, ty = tid >> 4;
        float osv = os[e], nsv = noise[e];
        float acc[4][4] = {};
        #pragma unroll
        for (int d = 0; d < 16; ++d) {
            float il = il2[d];
            float an[4], am[4];
            #pragma unroll
            for (int q = 0; q < 4; ++q) { an[q] = xn[ty + q*16][d]; am[q] = xm[tx + q*16][d]; }
            #pragma unroll
            for (int q = 0; q < 4; ++q)
                #pragma unroll
                for (int w = 0; w < 4; ++w) { float df = an[q] - am[w]; acc[q][w] = fmaf(df*df, il, acc[q][w]); }
        }
        float* A = ws + OFF_A + (size_t)e*N*N;
        #pragma unroll
        for (int q = 0; q < 4; ++q)
            #pragma unroll
            for (int w = 0; w < 4; ++w) {
                int nr = bn*64 + ty + q*16, mc = bm*64 + tx + w*16;
                float v = osv * __expf(-0.5f * acc[q][w]);
                if (nr == mc) v += nsv;
                A[(size_t)nr*N + mc] = v;
            }
        return;
    }
    int bidx = bid - E*64;
    int i = tid >> 4, j = tid & 15;
    if (bidx < E) {
        int e = bidx;
        __shared__ float Bm[16][17], BInv[16][17];
        float li = ls[e*D + i], lj = ls[e*D + j];
        Bm[i][j] = ws[OFF_SSM + i*D + j] / (li*lj) + ((i==j) ? 1.f : 0.f);
        BInv[i][j] = (i==j) ? 1.f : 0.f;
        __syncthreads();
        float det = 1.f;
        for (int k = 0; k < D; ++k) {
            float p   = Bm[k][k];
            float fik = Bm[i][k];
            float bkj = Bm[k][j];
            float ikj = BInv[k][j];
            __syncthreads();
            det *= p;
            if (i == k) { Bm[k][j] = bkj/p; BInv[k][j] = ikj/p; }
            else        { float f = fik/p; Bm[i][j] -= f*bkj; BInv[i][j] -= f*ikj; }
            __syncthreads();
        }
        ws[OFF_BINV + ((size_t)e*D + i)*D + j] = BInv[i][j];
        if (tid == 0) ws[OFF_C + e] = os[e] / sqrtf(det);
    } else {
        int pair = bidx - E;
        int a = pair / E, b = pair % E;
        __shared__ float Rm[16][17], RInv[16][17], ssl[16][17];
        float la = ls[a*D + j], lb2 = ls[b*D + j];
        float rj = 1.f/(la*la) + 1.f/(lb2*lb2);
        float ssv = ws[OFF_SSM + i*D + j];
        ssl[i][j] = ssv;
        Rm[i][j] = ssv * rj + ((i==j) ? 1.f : 0.f);
        RInv[i][j] = (i==j) ? 1.f : 0.f;
        __syncthreads();
        float det = 1.f;
        for (int k = 0; k < D; ++k) {
            float p   = Rm[k][k];
            float fik = Rm[i][k];
            float rkj = Rm[k][j];
            float ikj = RInv[k][j];
            __syncthreads();
            det *= p;
            if (i == k) { Rm[k][j] = rkj/p; RInv[k][j] = ikj/p; }
            else        { float f = fik/p; Rm[i][j] -= f*rkj; RInv[i][j] -= f*ikj; }
            __syncthreads();
        }
        float q = 0.f;
        #pragma unroll
        for (int k2 = 0; k2 < D; ++k2) q += RInv[i][k2] * ssl[k2][j];
        ws[OFF_Q + ((size_t)pair*D + i)*D + j] = 0.5f * q;
        if (tid == 0) ws[OFF_ISDR + pair] = 1.f / sqrtf(det);
    }
}

// ---------- 3a. first diag: fast factor + barrier-free inverse ----------
__global__ __launch_bounds__(256) void k_diag64(float* __restrict__ ws, int k0) {
    int e = blockIdx.x;
    int tid = threadIdx.x;
    int lane = tid & 63, wv = tid >> 6;
    const float* A = ws + OFF_A + (size_t)e*N*N;
    float* W = ws + OFF_IK + (size_t)e*N*N;
    __shared__ float Lsh[64][65], Xsh[64][65];
    __shared__ float cb[2][64];
    __shared__ float invd[64];
    float a[16];
    #pragma unroll
    for (int j = 0; j < 16; ++j)
        a[j] = A[(size_t)(k0 + wv*16 + j)*N + k0 + lane];
    __syncthreads();
    fact64(a, cb, invd, lane, wv);
    #pragma unroll
    for (int j = 0; j < 16; ++j) Lsh[lane][wv*16 + j] = a[j];
    __syncthreads();
    tinv64(Lsh, Xsh, invd, tid);
    for (int idx = tid; idx < 4096; idx += 256) {
        int r = idx >> 6, c = idx & 63;
        W[(size_t)(k0 + r)*N + k0 + c] = Xsh[r][c];
    }
}

// ---------- 3b. panel TRSM as GEMM: P <- P * W_kk^T (writes A + compact OFF_P) ----------
__global__ __launch_bounds__(256) void k_panelmul(float* __restrict__ ws, int k0) {
    int kk = k0 >> 6;
    int nb = (N - k0 - 64) >> 6;
    int e  = blockIdx.x / nb;
    int bi = blockIdx.x % nb;
    float* A = ws + OFF_A + (size_t)e*N*N;
    const float* W = ws + OFF_IK + (size_t)e*N*N;
    int r0 = k0 + 64 + bi*64;
    __shared__ float Ps[64][65], Wsh[64][65];
    int tid = threadIdx.x;
    for (int idx = tid; idx < 4096; idx += 256) {
        int r = idx >> 6, c2 = idx & 63;
        Ps[r][c2]  = A[(size_t)(r0 + r)*N + k0 + c2];
        Wsh[r][c2] = W[(size_t)(k0 + r)*N + k0 + c2];
    }
    __syncthreads();
    int tx = tid & 15, ty = tid >> 4;
    float acc[4][4] = {};
    #pragma unroll 8
    for (int j = 0; j < 64; ++j) {
        float pr[4], wr[4];
        #pragma unroll
        for (int q = 0; q < 4; ++q) { pr[q] = Ps[ty*4+q][j]; wr[q] = Wsh[tx*4+q][j]; }
        #pragma unroll
        for (int q = 0; q < 4; ++q)
            #pragma unroll
            for (int w = 0; w < 4; ++w) acc[q][w] = fmaf(pr[q], wr[w], acc[q][w]);
    }
    float* Pp = ws + OFF_P + ((size_t)e*1792 + prow(kk) + (size_t)bi*64)*64;
    #pragma unroll
    for (int q = 0; q < 4; ++q)
        #pragma unroll
        for (int w = 0; w < 4; ++w) {
            A[(size_t)(r0 + ty*4 + q)*N + k0 + tx*4 + w] = acc[q][w];
            Pp[(size_t)(ty*4 + q)*64 + tx*4 + w] = acc[q][w];
        }
}

// ---------- 3c. trailing SYRK + fused fast next-diag on (0,0) ----------
__global__ __launch_bounds__(256) void k_traild(float* __restrict__ ws, int k0) {
    int t0 = k0 + 64;
    int nb = (N - t0) >> 6;
    int ntiles = (nb*(nb+1)) >> 1;
    int e = blockIdx.x / ntiles;
    int t = blockIdx.x % ntiles;
    int bj = 0; while (t >= nb - bj) { t -= nb - bj; ++bj; }
    int bi = bj + t;
    bool same = (bi == bj);
    bool isdiag0 = (bi == 0) && (bj == 0);
    float* A = ws + OFF_A + (size_t)e*N*N;
    __shared__ float Sr[64][65], Sc[64][65];
    __shared__ float cb[2][64];
    __shared__ float invd[64];
    int tid = threadIdx.x;
    int tx = tid & 15, ty = tid >> 4;
    for (int idx = tid; idx < 4096; idx += 256) {
        int r = idx >> 6, c = idx & 63;
        Sr[r][c] = A[(size_t)(t0 + bi*64 + r)*N + k0 + c];
        if (!same) Sc[r][c] = A[(size_t)(t0 + bj*64 + r)*N + k0 + c];
    }
    __syncthreads();
    float acc[4][4] = {};
    if (same) {
        #pragma unroll 8
        for (int p = 0; p < 64; ++p) {
            float ar[4], ac[4];
            #pragma unroll
            for (int q = 0; q < 4; ++q) { ar[q] = Sr[ty*4+q][p]; ac[q] = Sr[tx*4+q][p]; }
            #pragma unroll
            for (int q = 0; q < 4; ++q)
                #pragma unroll
                for (int w = 0; w < 4; ++w) acc[q][w] = fmaf(ar[q], ac[w], acc[q][w]);
        }
    } else {
        #pragma unroll 8
        for (int p = 0; p < 64; ++p) {
            float ar[4], ac[4];
            #pragma unroll
            for (int q = 0; q < 4; ++q) { ar[q] = Sr[ty*4+q][p]; ac[q] = Sc[tx*4+q][p]; }
            #pragma unroll
            for (int q = 0; q < 4; ++q)
                #pragma unroll
                for (int w = 0; w < 4; ++w) acc[q][w] = fmaf(ar[q], ac[w], acc[q][w]);
        }
    }
    float* Out = A + (size_t)(t0 + bi*64)*N + (t0 + bj*64);
    if (!isdiag0) {
        #pragma unroll
        for (int q = 0; q < 4; ++q)
            #pragma unroll
            for (int w = 0; w < 4; ++w)
                Out[(size_t)(ty*4+q)*N + tx*4+w] -= acc[q][w];
        return;
    }
    // ---- fused: updated (t0,t0) tile -> fast factor + barrier-free invert -> W diag ----
    __syncthreads();
    #pragma unroll
    for (int q = 0; q < 4; ++q)
        #pragma unroll
        for (int w = 0; w < 4; ++w)
            Sc[ty*4+q][tx*4+w] = Out[(size_t)(ty*4+q)*N + tx*4+w] - acc[q][w];
    __syncthreads();
    int lane = tid & 63, wv = tid >> 6;
    float a[16];
    #pragma unroll
    for (int j = 0; j < 16; ++j) a[j] = Sc[lane][wv*16 + j];   // tile symmetric
    __syncthreads();
    fact64(a, cb, invd, lane, wv);
    #pragma unroll
    for (int j = 0; j < 16; ++j) Sc[lane][wv*16 + j] = a[j];   // Sc becomes Lsh
    __syncthreads();
    tinv64(Sc, Sr, invd, tid);                                 // Sr becomes Xsh
    float* W = ws + OFF_IK + (size_t)e*N*N;
    for (int idx = tid; idx < 4096; idx += 256) {
        int r = idx >> 6, c = idx & 63;
        W[(size_t)(t0 + r)*N + t0 + c] = Sr[r][c];
    }
}

// ---------- 3d. D&C triangular inverse: level 1 fused (H=1): W21 = -W22 L21 W11 ----------
__global__ __launch_bounds__(256) void k_dc1(float* __restrict__ ws) {
    int e = blockIdx.x >> 2, p = blockIdx.x & 3;
    float* W = ws + OFF_IK + (size_t)e*N*N;
    const float* Lt = ws + OFF_P + ((size_t)e*1792 + prow(2*p))*64;   // L_{2p+1,2p}
    __shared__ float Sa[64][65], Sb[64][65], T[64][65];
    int tid = threadIdx.x;
    int tx = tid & 15, ty = tid >> 4;
    for (int idx = tid; idx < 4096; idx += 256) {
        int r = idx >> 6, c = idx & 63;
        Sa[r][c] = Lt[(size_t)r*64 + c];
        Sb[r][c] = W[(size_t)(2*p*64 + r)*N + 2*p*64 + c];            // W11
    }
    __syncthreads();
    float acc[4][4] = {};
    #pragma unroll 8
    for (int pp = 0; pp < 64; ++pp) {
        float ar[4], bc[4];
        #pragma unroll
        for (int q = 0; q < 4; ++q) { ar[q] = Sa[ty*4+q][pp]; bc[q] = Sb[pp][tx*4+q]; }
        #pragma unroll
        for (int q = 0; q < 4; ++q)
            #pragma unroll
            for (int w = 0; w < 4; ++w) acc[q][w] = fmaf(ar[q], bc[w], acc[q][w]);
    }
    #pragma unroll
    for (int q = 0; q < 4; ++q)
        #pragma unroll
        for (int w = 0; w < 4; ++w) T[ty*4+q][tx*4+w] = acc[q][w];
    for (int idx = tid; idx < 4096; idx += 256) {
        int r = idx >> 6, c = idx & 63;
        Sa[r][c] = W[(size_t)((2*p+1)*64 + r)*N + (2*p+1)*64 + c];    // W22
    }
    __syncthreads();
    float o[4][4] = {};
    #pragma unroll 8
    for (int pp = 0; pp < 64; ++pp) {
        float ar[4], bc[4];
        #pragma unroll
        for (int q = 0; q < 4; ++q) { ar[q] = Sa[ty*4+q][pp]; bc[q] = T[pp][tx*4+q]; }
        #pragma unroll
        for (int q = 0; q < 4; ++q)
            #pragma unroll
            for (int w = 0; w < 4; ++w) o[q][w] = fmaf(ar[q], bc[w], o[q][w]);
    }
    #pragma unroll
    for (int q = 0; q < 4; ++q)
        #pragma unroll
        for (int w = 0; w < 4; ++w)
            W[(size_t)((2*p+1)*64 + ty*4 + q)*N + 2*p*64 + tx*4 + w] = -o[q][w];
}

// ---------- 3e. D&C: T = L21 * W11 (levels H=2,4) ----------
__global__ __launch_bounds__(256) void k_dcT(float* __restrict__ ws, int H) {
    int per_e = 4*H;
    int e = blockIdx.x / per_e;
    int rem = blockIdx.x % per_e;
    int p  = rem / (H*H);
    int tt = rem % (H*H);
    int ti = tt / H, tj = tt % H;
    int C0 = 2*p*H;
    int I  = C0 + H + ti;
    const float* W = ws + OFF_IK + (size_t)e*N*N;
    float* Tt = ws + OFF_T + (size_t)e*65536 + (size_t)(p*H*H + ti*H + tj)*4096;
    __shared__ float Sa[64][65], Sb[64][65];
    int tid = threadIdx.x;
    int tx = tid & 15, ty = tid >> 4;
    float acc[4][4] = {};
    for (int k = tj; k < H; ++k) {
        int K = C0 + k;
        const float* Lt = ws + OFF_P + ((size_t)e*1792 + prow(K) + (size_t)(I - K - 1)*64)*64;
        __syncthreads();
        for (int idx = tid; idx < 4096; idx += 256) {
            int r = idx >> 6, c = idx & 63;
            Sa[r][c] = Lt[(size_t)r*64 + c];
            Sb[r][c] = W[(size_t)(K*64 + r)*N + (C0 + tj)*64 + c];
        }
        __syncthreads();
        #pragma unroll 8
        for (int pp = 0; pp < 64; ++pp) {
            float ar[4], bc[4];
            #pragma unroll
            for (int q = 0; q < 4; ++q) { ar[q] = Sa[ty*4+q][pp]; bc[q] = Sb[pp][tx*4+q]; }
            #pragma unroll
            for (int q = 0; q < 4; ++q)
                #pragma unroll
                for (int w = 0; w < 4; ++w) acc[q][w] = fmaf(ar[q], bc[w], acc[q][w]);
        }
    }
    #pragma unroll
    for (int q = 0; q < 4; ++q)
        #pragma unroll
        for (int w = 0; w < 4; ++w)
            Tt[(size_t)(ty*4+q)*64 + tx*4 + w] = acc[q][w];
}

// ---------- 3f. D&C: W21 = -W22 * T ----------
__global__ __launch_bounds__(256) void k_dcW(float* __restrict__ ws, int H) {
    int per_e = 4*H;
    int e = blockIdx.x / per_e;
    int rem = blockIdx.x % per_e;
    int p  = rem / (H*H);
    int tt = rem % (H*H);
    int ti = tt / H, tj = tt % H;
    int C0 = 2*p*H, R0 = C0 + H;
    float* W = ws + OFF_IK + (size_t)e*N*N;
    const float* Tbase = ws + OFF_T + (size_t)e*65536 + (size_t)(p*H*H)*4096;
    __shared__ float Sa[64][65], Sb[64][65];
    int tid = threadIdx.x;
    int tx = tid & 15, ty = tid >> 4;
    float acc[4][4] = {};
    for (int tk = 0; tk <= ti; ++tk) {
        const float* Tt = Tbase + (size_t)(tk*H + tj)*4096;
        __syncthreads();
        for (int idx = tid; idx < 4096; idx += 256) {
            int r = idx >> 6, c = idx & 63;
            Sa[r][c] = W[(size_t)((R0 + ti)*64 + r)*N + (R0 + tk)*64 + c];
            Sb[r][c] = Tt[(size_t)r*64 + c];
        }
        __syncthreads();
        #pragma unroll 8
        for (int pp = 0; pp < 64; ++pp) {
            float ar[4], bc[4];
            #pragma unroll
            for (int q = 0; q < 4; ++q) { ar[q] = Sa[ty*4+q][pp]; bc[q] = Sb[pp][tx*4+q]; }
            #pragma unroll
            for (int q = 0; q < 4; ++q)
                #pragma unroll
                for (int w = 0; w < 4; ++w) acc[q][w] = fmaf(ar[q], bc[w], acc[q][w]);
        }
    }
    #pragma unroll
    for (int q = 0; q < 4; ++q)
        #pragma unroll
        for (int w = 0; w < 4; ++w)
            W[(size_t)((R0 + ti)*64 + ty*4 + q)*N + (C0 + tj)*64 + tx*4 + w] = -acc[q][w];
}

// ---------- 3g. iK = W^T W (into OFF_A, full symmetric) ----------
__global__ __launch_bounds__(256) void k_syrk(float* __restrict__ ws) {
    int e = blockIdx.x / 36;
    int t = blockIdx.x % 36;
    int bj = 0; while (t >= 8 - bj) { t -= 8 - bj; ++bj; }
    int bi = bj + t;
    const float* W = ws + OFF_IK + (size_t)e*N*N;
    float*      IK = ws + OFF_A  + (size_t)e*N*N;
    __shared__ float Sa[64][65], Sb[64][65];
    int tid = threadIdx.x;
    int tx = tid & 15, ty = tid >> 4;
    float acc[4][4] = {};
    for (int p = bi; p < 8; ++p) {
        __syncthreads();
        for (int idx = tid; idx < 4096; idx += 256) {
            int r = idx >> 6, cc = idx & 63;
            Sa[r][cc] = W[(size_t)(p*64+r)*N + bi*64+cc];
            Sb[r][cc] = W[(size_t)(p*64+r)*N + bj*64+cc];
        }
        __syncthreads();
        #pragma unroll 8
        for (int pr2 = 0; pr2 < 64; ++pr2) {
            float ar[4], ac[4];
            #pragma unroll
            for (int q = 0; q < 4; ++q) { ar[q] = Sa[pr2][ty*4+q]; ac[q] = Sb[pr2][tx*4+q]; }
            #pragma unroll
            for (int q = 0; q < 4; ++q)
                #pragma unroll
                for (int w = 0; w < 4; ++w) acc[q][w] = fmaf(ar[q], ac[w], acc[q][w]);
        }
    }
    #pragma unroll
    for (int q = 0; q < 4; ++q)
        #pragma unroll
        for (int w = 0; w < 4; ++w) {
            int r = bi*64 + ty*4 + q, c = bj*64 + tx*4 + w;
            IK[(size_t)r*N + c] = acc[q][w];
            IK[(size_t)c*N + r] = acc[q][w];
        }
}

// ---------- 3h. beta = iK @ Yn ----------
__global__ __launch_bounds__(256) void k_beta(float* __restrict__ ws) {
    int e = blockIdx.x >> 2, qtr = blockIdx.x & 3;
    int tid = threadIdx.x;
    int half = tid >> 7;
    int nl = tid & 127;
    int n = qtr*128 + nl;
    __shared__ float yn[N];
    __shared__ float part[2][128];
    for (int i = tid; i < N; i += 256) yn[i] = ws[OFF_YN + (size_t)e*N + i];
    __syncthreads();
    const float* IK = ws + OFF_A + (size_t)e*N*N;
    int m0 = half*256;
    float a0 = 0.f, a1 = 0.f, a2 = 0.f, a3 = 0.f;
    for (int mm = m0; mm < m0 + 256; mm += 4) {
        a0 = fmaf(IK[(size_t)mm*N + n],     yn[mm],   a0);
        a1 = fmaf(IK[(size_t)(mm+1)*N + n], yn[mm+1], a1);
        a2 = fmaf(IK[(size_t)(mm+2)*N + n], yn[mm+2], a2);
        a3 = fmaf(IK[(size_t)(mm+3)*N + n], yn[mm+3], a3);
    }
    part[half][nl] = (a0 + a1) + (a2 + a3);
    __syncthreads();
    if (tid < 128)
        ws[OFF_BETA + e*N + qtr*128 + tid] = part[0][tid] + part[1][tid];
}

// ---------- 5. per (e,n): iN, t, lb, tiL, kvec ----------
__global__ __launch_bounds__(256) void k_point(float* __restrict__ ws, const float* __restrict__ ls,
                                               const float* __restrict__ os) {
    int t = blockIdx.x*256 + threadIdx.x;
    int e = t >> 9, n = t & 511;
    float iN[D], tt[D], l[D];
    #pragma unroll
    for (int d = 0; d < D; ++d) { l[d] = ls[e*D + d]; iN[d] = ws[OFF_INP + n*D + d] / l[d]; }
    #pragma unroll
    for (int d = 0; d < D; ++d) {
        float acc = 0.f;
        #pragma unroll
        for (int j = 0; j < D; ++j) acc += ws[OFF_BINV + ((size_t)e*D + d)*D + j] * iN[j];
        tt[d] = acc;
    }
    float siNt = 0.f, siN2 = 0.f;
    #pragma unroll
    for (int d = 0; d < D; ++d) { siNt += iN[d]*tt[d]; siN2 += iN[d]*iN[d]; }
    float lbv = __expf(-0.5f * siNt) * ws[OFF_BETA + e*N + n];
    ws[OFF_LB + e*N + n] = lbv;
    #pragma unroll
    for (int d = 0; d < D; ++d) ws[OFF_TIL + ((size_t)e*N + n)*D + d] = tt[d] / l[d];
    ws[OFF_KVEC + e*N + n] = logf(os[e]) - 0.5f * siN2;
}

// ---------- 6. U/V = kvec + quadratic forms per (pair, n) ----------
__global__ __launch_bounds__(256) void k_xs(float* __restrict__ ws, const float* __restrict__ ls) {
    int t = blockIdx.x*256 + threadIdx.x;
    int pair = t / N, n = t % N;
    int a = pair / E, b = pair % E;
    int tid = threadIdx.x;
    __shared__ float Qs[16][17];
    __shared__ float i2a[16], i2b[16];
    Qs[tid >> 4][tid & 15] = ws[OFF_Q + (size_t)pair*D*D + tid];
    if (tid < 16) { float l = ls[a*D + tid]; i2a[tid] = 1.0f/(l*l); }
    else if (tid < 32) { int d = tid-16; float l = ls[b*D + d]; i2b[d] = 1.0f/(l*l); }
    __syncthreads();
    float x1[D], x2[D];
    #pragma unroll
    for (int d = 0; d < D; ++d) {
        float ip = ws[OFF_INP + n*D + d];
        x1[d] = ip * i2a[d];
        x2[d] = ip * i2b[d];
    }
    float xs1 = 0.f, xs2 = 0.f;
    #pragma unroll
    for (int j = 0; j < D; ++j) {
        float t1 = 0.f, t2 = 0.f;
        #pragma unroll
        for (int i = 0; i < D; ++i) { t1 = fmaf(x1[i], Qs[i][j], t1); t2 = fmaf(x2[i], Qs[i][j], t2); }
        xs1 = fmaf(t1, x1[j], xs1);
        xs2 = fmaf(t2, x2[j], xs2);
    }
    ws[OFF_U + (size_t)pair*N + n] = ws[OFF_KVEC + a*N + n] + xs1;
    ws[OFF_V + (size_t)pair*N + n] = ws[OFF_KVEC + b*N + n] + xs2;
}

// ---------- 7. big cross-term: d-major LDS, reg-cached A-side, LDS-staged iK tile ----------
__global__ __launch_bounds__(256) void k_S(float* __restrict__ ws, const float* __restrict__ ls) {
    int bid = blockIdx.x;
    int pair = bid >> 3, ntile = bid & 7;
    int a = pair / E, b = pair % E;
    int tid = threadIdx.x;
    int tx = tid & 15, ty = tid >> 4;
    __shared__ float Qs[16][17];
    __shared__ float i2a[16], i2b[16];
    __shared__ float __align__(16) pool[64*68];     // bufAT | x1qT, later aliased as ikS
    __shared__ float __align__(16) bufBT[16][68];
    __shared__ float u_s[64], v_s[64], ba_s[64], bb_s[64];
    __shared__ float red[256];
    float (*bufAT)[68] = (float(*)[68])pool;
    float (*x1qT)[68]  = (float(*)[68])(pool + 16*68);
    float (*ikS)[68]   = (float(*)[68])pool;        // valid after av4 cached (barrier-protected)
    int n0 = ntile*64;
    Qs[tid >> 4][tid & 15] = ws[OFF_Q + (size_t)pair*D*D + tid];
    if (tid < 16) { float l = ls[a*D + tid]; i2a[tid] = 1.0f/(l*l); }
    else if (tid < 32) { int d = tid-16; float l = ls[b*D + d]; i2b[d] = 1.0f/(l*l); }
    __syncthreads();
    for (int idx = tid; idx < 1024; idx += 256) {
        int r = idx >> 4, d = idx & 15;
        bufAT[d][r] = ws[OFF_INP + (size_t)(n0 + r)*D + d] * i2a[d];
    }
    __syncthreads();
    for (int idx = tid; idx < 1024; idx += 256) {
        int r = idx >> 4, j = idx & 15;
        float s = 0.f;
        #pragma unroll
        for (int i = 0; i < 16; ++i) s = fmaf(bufAT[i][r], Qs[i][j], s);
        x1qT[j][r] = s;
    }
    if (tid < 64) {
        u_s[tid]  = ws[OFF_U + (size_t)pair*N + n0 + tid];
        ba_s[tid] = ws[OFF_BETA + a*N + n0 + tid];
    }
    __syncthreads();
    float4 av4[16];
    #pragma unroll
    for (int d = 0; d < 16; ++d) av4[d] = *(const float4*)&x1qT[d][ty*4];
    float uq[4], baq[4];
    #pragma unroll
    for (int q = 0; q < 4; ++q) { uq[q] = u_s[ty*4+q]; baq[q] = ba_s[ty*4+q]; }

    float sacc = 0.f, tacc = 0.f;
    for (int mt = 0; mt < 8; ++mt) {
        __syncthreads();   // protects bufBT reuse AND pool->ikS aliasing after av4 cached
        for (int idx = tid; idx < 1024; idx += 256) {
            int r = idx >> 4, d = idx & 15;
            bufBT[d][r] = ws[OFF_INP + (size_t)(mt*64 + r)*D + d] * i2b[d];
        }
        if (a == b) {
            const float* IKt = ws + OFF_A + ((size_t)a*N + n0)*N + mt*64;
            for (int idx = tid; idx < 4096; idx += 256) {
                int r = idx >> 6, c = idx & 63;
                ikS[r][c] = IKt[(size_t)r*N + c];     // coalesced 256B rows
            }
        }
        if (tid < 64) {
            v_s[tid]  = ws[OFF_V + (size_t)pair*N + mt*64 + tid];
            bb_s[tid] = ws[OFF_BETA + b*N + mt*64 + tid];
        }
        __syncthreads();
        float dacc[4][4] = {};
        #pragma unroll
        for (int d = 0; d < 16; ++d) {
            float4 bv = *(const float4*)&bufBT[d][tx*4];
            float4 av = av4[d];
            dacc[0][0] = fmaf(av.x, bv.x, dacc[0][0]); dacc[0][1] = fmaf(av.x, bv.y, dacc[0][1]);
            dacc[0][2] = fmaf(av.x, bv.z, dacc[0][2]); dacc[0][3] = fmaf(av.x, bv.w, dacc[0][3]);
            dacc[1][0] = fmaf(av.y, bv.x, dacc[1][0]); dacc[1][1] = fmaf(av.y, bv.y, dacc[1][1]);
            dacc[1][2] = fmaf(av.y, bv.z, dacc[1][2]); dacc[1][3] = fmaf(av.y, bv.w, dacc[1][3]);
            dacc[2][0] = fmaf(av.z, bv.x, dacc[2][0]); dacc[2][1] = fmaf(av.z, bv.y, dacc[2][1]);
            dacc[2][2] = fmaf(av.z, bv.z, dacc[2][2]); dacc[2][3] = fmaf(av.z, bv.w, dacc[2][3]);
            dacc[3][0] = fmaf(av.w, bv.x, dacc[3][0]); dacc[3][1] = fmaf(av.w, bv.y, dacc[3][1]);
            dacc[3][2] = fmaf(av.w, bv.z, dacc[3][2]); dacc[3][3] = fmaf(av.w, bv.w, dacc[3][3]);
        }
        #pragma unroll
        for (int q = 0; q < 4; ++q) {
            #pragma unroll
            for (int w = 0; w < 4; ++w) {
                float Lv = __expf(2.f*dacc[q][w] + uq[q] + v_s[tx*4+w]);
                sacc = fmaf(baq[q] * bb_s[tx*4+w], Lv, sacc);
                if (a == b)
                    tacc = fmaf(ikS[ty*4+q][tx*4+w], Lv, tacc);
            }
        }
    }
    red[tid] = sacc; __syncthreads();
    for (int o = 128; o > 0; o >>= 1) { if (tid < o) red[tid] += red[tid+o]; __syncthreads(); }
    if (tid == 0) ws[OFF_SPART + bid] = red[0];
    if (a == b) {
        __syncthreads();
        red[tid] = tacc; __syncthreads();
        for (int o = 128; o > 0; o >>= 1) { if (tid < o) red[tid] += red[tid+o]; __syncthreads(); }
        if (tid == 0) ws[OFF_TPART + a*8 + ntile] = red[0];
    }
}

// ---------- 8. finalize ----------
__global__ __launch_bounds__(256) void k_final(float* __restrict__ ws, const float* __restrict__ s,
                                               const float* __restrict__ os, float* __restrict__ out) {
    int tid = threadIdx.x;
    __shared__ float Msh[E], Vsh[E][D], cov[D][E+1];
    __shared__ float Sm[16][17], Si[16][17];
    __shared__ float vred[16][17];

    {
        int wv = tid >> 6, lane = tid & 63;
        for (int e = wv; e < E; e += 4) {
            float sum = 0.f;
            #pragma unroll
            for (int i = 0; i < 8; ++i) sum += ws[OFF_LB + e*N + i*64 + lane];
            #pragma unroll
            for (int off = 32; off > 0; off >>= 1) sum += __shfl_xor(sum, off);
            if (lane == 0) Msh[e] = ws[OFF_C + e] * sum;
        }
    }
    for (int e = 0; e < E; ++e) {
        int d = tid & 15, sl = tid >> 4;
        float acc = 0.f;
        for (int i = 0; i < 32; ++i) {
            int n = sl*32 + i;
            acc = fmaf(ws[OFF_TIL + ((size_t)e*N + n)*D + d], ws[OFF_LB + e*N + n], acc);
        }
        vred[sl][d] = acc;
        __syncthreads();
        if (tid < 16) {
            float sum = 0.f;
            #pragma unroll
            for (int s2 = 0; s2 < 16; ++s2) sum += vred[s2][tid];
            Vsh[e][tid] = ws[OFF_C + e] * sum;
        }
        __syncthreads();
    }

    if (tid < E*E) {
        int a = tid / E, bb = tid % E;
        float acc = 0.f;
        for (int q = 0; q < 8; ++q) acc += ws[OFF_SPART + (size_t)tid*8 + q];
        if (a == bb) {
            float tr = 0.f;
            for (int q = 0; q < 8; ++q) tr += ws[OFF_TPART + a*8 + q];
            acc -= tr;
        }
        acc *= ws[OFF_ISDR + tid];
        if (a == bb) acc += os[a];
        float v = acc - Msh[a]*Msh[bb];
        v *= ws[OFF_YSTD + a] * ws[OFF_YSTD + bb];
        out[E + tid] = v;
    }
    if (tid < E) out[tid] = Msh[tid]*ws[OFF_YSTD + tid] + ws[OFF_YMEAN + tid];

    if (tid < D*E) {
        int d = tid / E, e = tid % E;
        float acc = 0.f;
        for (int k = 0; k < D; ++k) acc += ws[OFF_SSM + d*D + k] * Vsh[e][k];
        cov[d][e] = acc * ws[OFF_XSTD + d] * ws[OFF_YSTD + e];
    }
    int i = tid >> 4, j = tid & 15;
    Sm[i][j] = s[i*D + j];
    Si[i][j] = (i==j) ? 1.f : 0.f;
    __syncthreads();
    for (int k = 0; k < D; ++k) {
        float p   = Sm[k][k];
        float fik = Sm[i][k];
        float skj = Sm[k][j];
        float ikj = Si[k][j];
        __syncthreads();
        if (i == k) { Sm[k][j] = skj/p; Si[k][j] = ikj/p; }
        else        { float f = fik/p; Sm[i][j] -= f*skj; Si[i][j] -= f*ikj; }
        __syncthreads();
    }
    if (tid < D*E) {
        int d = tid / E, e = tid % E;
        float acc = 0.f;
        for (int k = 0; k < D; ++k) acc += Si[d][k] * cov[k][e];
        out[E + E*E + d*E + e] = acc;
    }
}

extern "C" void kernel_launch(void* const* d_in, const int* in_sizes, int n_in,
                              void* d_out, int out_size, void* d_ws, size_t ws_size,
                              hipStream_t stream) {
    const float* X     = (const float*)d_in[0];
    const float* Y     = (const float*)d_in[1];
    const float* m     = (const float*)d_in[2];
    const float* s     = (const float*)d_in[3];
    const float* ls    = (const float*)d_in[4];
    const float* os    = (const float*)d_in[5];
    const float* noise = (const float*)d_in[6];
    float* ws  = (float*)d_ws;
    float* out = (float*)d_out;

    k_prep   <<<1,              512, 0, stream>>>(X, Y, m, s, ws);
    k_buildA <<<E*64 + E + E*E, 256, 0, stream>>>(ws, ls, os, noise);
    k_diag64 <<<E,              256, 0, stream>>>(ws, 0);
    for (int kk = 0; kk < 7; ++kk) {
        int k0 = kk*64;
        int nb = 7 - kk;
        k_panelmul<<<E*nb,          256, 0, stream>>>(ws, k0);
        k_traild  <<<E*nb*(nb+1)/2, 256, 0, stream>>>(ws, k0);
    }
    k_dc1 <<<E*4,  256, 0, stream>>>(ws);
    k_dcT <<<E*8,  256, 0, stream>>>(ws, 2);
    k_dcW <<<E*8,  256, 0, stream>>>(ws, 2);
    k_dcT <<<E*16, 256, 0, stream>>>(ws, 4);
    k_dcW <<<E*16, 256, 0, stream>>>(ws, 4);
    k_syrk    <<<E*36,       256, 0, stream>>>(ws);
    k_beta    <<<E*4,        256, 0, stream>>>(ws);
    k_point   <<<E*N/256,    256, 0, stream>>>(ws, ls, os);
    k_xs      <<<E*E*N/256,  256, 0, stream>>>(ws, ls);
    k_S       <<<E*E*8,      256, 0, stream>>>(ws, ls);
    k_final   <<<1,          256, 0, stream>>>(ws, s, os, out);
}

// Round 13
// 823.870 us; speedup vs baseline: 1.0358x; 1.0358x over previous
//
#include <hip/hip_runtime.h>
#include <math.h>

constexpr int N = 512;
constexpr int D = 16;
constexpr int E = 12;

// ---- workspace layout (float offsets) ----
constexpr size_t OFF_A     = 0;                            // E*N*N  A -> trail -> iK
constexpr size_t OFF_IK    = OFF_A    + (size_t)E*N*N;     // E*N*N  W = L^{-1}
constexpr size_t OFF_XS    = OFF_IK   + (size_t)E*N*N;     // N*D
constexpr size_t OFF_INP   = OFF_XS   + (size_t)N*D;       // N*D
constexpr size_t OFF_YN    = OFF_INP  + (size_t)N*D;       // E*N
constexpr size_t OFF_BETA  = OFF_YN   + (size_t)E*N;       // E*N
constexpr size_t OFF_KVEC  = OFF_BETA + (size_t)E*N;       // E*N
constexpr size_t OFF_LB    = OFF_KVEC + (size_t)E*N;       // E*N
constexpr size_t OFF_TIL   = OFF_LB   + (size_t)E*N;       // E*N*D
constexpr size_t OFF_U     = OFF_TIL  + (size_t)E*N*D;     // E*E*N
constexpr size_t OFF_V     = OFF_U    + (size_t)E*E*N;     // E*E*N
constexpr size_t OFF_Q     = OFF_V    + (size_t)E*E*N;     // E*E*D*D
constexpr size_t OFF_BINV  = OFF_Q    + (size_t)E*E*D*D;   // E*D*D
constexpr size_t OFF_C     = OFF_BINV + (size_t)E*D*D;     // E
constexpr size_t OFF_ISDR  = OFF_C    + E;                 // E*E
constexpr size_t OFF_SPART = OFF_ISDR + E*E;               // E*E*8
constexpr size_t OFF_TPART = OFF_SPART+ (size_t)E*E*8;     // E*8
constexpr size_t OFF_XMEAN = OFF_TPART+ (size_t)E*8;       // D
constexpr size_t OFF_XSTD  = OFF_XMEAN+ D;                 // D
constexpr size_t OFF_YMEAN = OFF_XSTD + D;                 // E
constexpr size_t OFF_YSTD  = OFF_YMEAN+ E;                 // E
constexpr size_t OFF_SSM   = OFF_YSTD + E;                 // D*D
constexpr size_t OFF_P     = OFF_SSM  + D*D;               // E*1792*64  (L panels, compact)
constexpr size_t OFF_T     = OFF_P    + (size_t)E*1792*64; // E*65536    (D&C scratch)

__device__ __forceinline__ int prow(int k) { return k*(480 - 32*k); }  // row offset of panel k

// ======== fast 64x64 Cholesky: column-split registers, 1 barrier/step, no spill ========
__device__ __forceinline__ void fact64(float a[16], float (*cb)[64], float* invd, int lane, int wv) {
    #pragma unroll
    for (int k = 0; k < 64; ++k) {
        const int kg = k >> 4, kj = k & 15;
        if (wv == kg) {
            float dkk = __shfl(a[kj], k);
            float dv = sqrtf(dkk);
            float iv = 1.0f / dv;
            float sc = a[kj] * iv;
            if (lane == k)      { a[kj] = dv; invd[k] = iv; }
            else if (lane > k)  a[kj] = sc;
            cb[k & 1][lane] = (lane > k) ? a[kj] : 0.0f;
        }
        __syncthreads();
        float lrk = cb[k & 1][lane];
        #pragma unroll
        for (int j = 0; j < 16; ++j)
            a[j] = fmaf(-lrk, cb[k & 1][wv*16 + j], a[j]);
    }
}

// ======== barrier-free triangular inverse: thread c owns column c ========
__device__ __forceinline__ void tinv64(const float (*Lsh)[65], float (*Xsh)[65],
                                       const float* invd, int tid) {
    if (tid < 64) {
        const int c = tid;
        for (int r = 0; r < c; ++r) Xsh[r][c] = 0.0f;
        for (int r = c; r < 64; ++r) {
            float a0 = (r == c) ? 1.0f : 0.0f, a1 = 0.0f;
            int k = c;
            for (; k + 1 < r; k += 2) {
                a0 = fmaf(-Lsh[r][k],   Xsh[k][c],   a0);
                a1 = fmaf(-Lsh[r][k+1], Xsh[k+1][c], a1);
            }
            if (k < r) a0 = fmaf(-Lsh[r][k], Xsh[k][c], a0);
            Xsh[r][c] = (a0 + a1) * invd[r];
        }
    }
    __syncthreads();
}

// ---------- 1. standardization ----------
__global__ __launch_bounds__(512) void k_prep(const float* __restrict__ X, const float* __restrict__ Y,
                                              const float* __restrict__ m, const float* __restrict__ s,
                                              float* __restrict__ ws) {
    int tid = threadIdx.x;
    int lane = tid & 63, wave = tid >> 6;
    __shared__ float meanX[D], stdX[D], meanY[E], stdY[E], mmsh[D];

    for (int col = wave; col < D + E; col += 8) {
        float s1 = 0.f, s2 = 0.f;
        if (col < D) {
            #pragma unroll
            for (int i = 0; i < 8; ++i) { float v = X[(i*64 + lane)*D + col]; s1 += v; s2 += v*v; }
        } else {
            int e = col - D;
            #pragma unroll
            for (int i = 0; i < 8; ++i) { float v = Y[(i*64 + lane)*E + e]; s1 += v; s2 += v*v; }
        }
        #pragma unroll
        for (int off = 32; off > 0; off >>= 1) { s1 += __shfl_xor(s1, off); s2 += __shfl_xor(s2, off); }
        if (lane == 0) {
            float mean = s1 * (1.0f/N);
            float var  = (s2 - (float)N*mean*mean) * (1.0f/(N-1));
            float sd   = sqrtf(var);
            if (col < D) { meanX[col] = mean; stdX[col] = sd; }
            else         { meanY[col-D] = mean; stdY[col-D] = sd; }
        }
    }
    __syncthreads();
    if (tid < D) {
        mmsh[tid] = (m[tid] - meanX[tid]) / stdX[tid];
        ws[OFF_XMEAN + tid] = meanX[tid];
        ws[OFF_XSTD  + tid] = stdX[tid];
    }
    if (tid < E) { ws[OFF_YMEAN + tid] = meanY[tid]; ws[OFF_YSTD + tid] = stdY[tid]; }
    __syncthreads();
    int n = tid;
    #pragma unroll
    for (int d = 0; d < D; ++d) {
        float xs = (X[n*D + d] - meanX[d]) / stdX[d];
        ws[OFF_XS  + n*D + d] = xs;
        ws[OFF_INP + n*D + d] = xs - mmsh[d];
    }
    #pragma unroll
    for (int e = 0; e < E; ++e)
        ws[OFF_YN + e*N + n] = (Y[n*E + e] - meanY[e]) / stdY[e];
    if (tid < D*D) {
        int i = tid / D, j = tid % D;
        ws[OFF_SSM + tid] = s[tid] / (stdX[i] * stdX[j]);
    }
}

// ---------- 2. A = K + noise I  +  appended B/R inverse blocks ----------
__global__ __launch_bounds__(256) void k_buildA(float* __restrict__ ws, const float* __restrict__ ls,
                                                const float* __restrict__ os, const float* __restrict__ noise) {
    int bid = blockIdx.x;
    int tid = threadIdx.x;
    if (bid < E*64) {
        int e  = bid >> 6;
        int t  = bid & 63;
        int bn = t >> 3, bm = t & 7;
        __shared__ float xn[64][17], xm[64][17];
        __shared__ float il2[16];
        for (int idx = tid; idx < 1024; idx += 256) {
            int r = idx >> 4, d0 = idx & 15;
            xn[r][d0] = ws[OFF_XS + (size_t)(bn*64 + r)*D + d0];
            xm[r][d0] = ws[OFF_XS + (size_t)(bm*64 + r)*D + d0];
        }
        if (tid < 16) { float l = ls[e*D + tid]; il2[tid] = 1.0f/(l*l); }
        __syncthreads();
        int tx = tid & 15, ty = tid >> 4;
        float osv = os[e], nsv = noise[e];
        float acc[4][4] = {};
        #pragma unroll
        for (int d = 0; d < 16; ++d) {
            float il = il2[d];
            float an[4], am[4];
            #pragma unroll
            for (int q = 0; q < 4; ++q) { an[q] = xn[ty + q*16][d]; am[q] = xm[tx + q*16][d]; }
            #pragma unroll
            for (int q = 0; q < 4; ++q)
                #pragma unroll
                for (int w = 0; w < 4; ++w) { float df = an[q] - am[w]; acc[q][w] = fmaf(df*df, il, acc[q][w]); }
        }
        float* A = ws + OFF_A + (size_t)e*N*N;
        #pragma unroll
        for (int q = 0; q < 4; ++q)
            #pragma unroll
            for (int w = 0; w < 4; ++w) {
                int nr = bn*64 + ty + q*16, mc = bm*64 + tx + w*16;
                float v = osv * __expf(-0.5f * acc[q][w]);
                if (nr == mc) v += nsv;
                A[(size_t)nr*N + mc] = v;
            }
        return;
    }
    int bidx = bid - E*64;
    int i = tid >> 4, j = tid & 15;
    if (bidx < E) {
        int e = bidx;
        __shared__ float Bm[16][17], BInv[16][17];
        float li = ls[e*D + i], lj = ls[e*D + j];
        Bm[i][j] = ws[OFF_SSM + i*D + j] / (li*lj) + ((i==j) ? 1.f : 0.f);
        BInv[i][j] = (i==j) ? 1.f : 0.f;
        __syncthreads();
        float det = 1.f;
        for (int k = 0; k < D; ++k) {
            float p   = Bm[k][k];
            float fik = Bm[i][k];
            float bkj = Bm[k][j];
            float ikj = BInv[k][j];
            __syncthreads();
            det *= p;
            if (i == k) { Bm[k][j] = bkj/p; BInv[k][j] = ikj/p; }
            else        { float f = fik/p; Bm[i][j] -= f*bkj; BInv[i][j] -= f*ikj; }
            __syncthreads();
        }
        ws[OFF_BINV + ((size_t)e*D + i)*D + j] = BInv[i][j];
        if (tid == 0) ws[OFF_C + e] = os[e] / sqrtf(det);
    } else {
        int pair = bidx - E;
        int a = pair / E, b = pair % E;
        __shared__ float Rm[16][17], RInv[16][17], ssl[16][17];
        float la = ls[a*D + j], lb2 = ls[b*D + j];
        float rj = 1.f/(la*la) + 1.f/(lb2*lb2);
        float ssv = ws[OFF_SSM + i*D + j];
        ssl[i][j] = ssv;
        Rm[i][j] = ssv * rj + ((i==j) ? 1.f : 0.f);
        RInv[i][j] = (i==j) ? 1.f : 0.f;
        __syncthreads();
        float det = 1.f;
        for (int k = 0; k < D; ++k) {
            float p   = Rm[k][k];
            float fik = Rm[i][k];
            float rkj = Rm[k][j];
            float ikj = RInv[k][j];
            __syncthreads();
            det *= p;
            if (i == k) { Rm[k][j] = rkj/p; RInv[k][j] = ikj/p; }
            else        { float f = fik/p; Rm[i][j] -= f*rkj; RInv[i][j] -= f*ikj; }
            __syncthreads();
        }
        float q = 0.f;
        #pragma unroll
        for (int k2 = 0; k2 < D; ++k2) q += RInv[i][k2] * ssl[k2][j];
        ws[OFF_Q + ((size_t)pair*D + i)*D + j] = 0.5f * q;
        if (tid == 0) ws[OFF_ISDR + pair] = 1.f / sqrtf(det);
    }
}

// ---------- 3a. first diag: fast factor + barrier-free inverse ----------
__global__ __launch_bounds__(256) void k_diag64(float* __restrict__ ws, int k0) {
    int e = blockIdx.x;
    int tid = threadIdx.x;
    int lane = tid & 63, wv = tid >> 6;
    const float* A = ws + OFF_A + (size_t)e*N*N;
    float* W = ws + OFF_IK + (size_t)e*N*N;
    __shared__ float Lsh[64][65], Xsh[64][65];
    __shared__ float cb[2][64];
    __shared__ float invd[64];
    float a[16];
    #pragma unroll
    for (int j = 0; j < 16; ++j)
        a[j] = A[(size_t)(k0 + wv*16 + j)*N + k0 + lane];
    __syncthreads();
    fact64(a, cb, invd, lane, wv);
    #pragma unroll
    for (int j = 0; j < 16; ++j) Lsh[lane][wv*16 + j] = a[j];
    __syncthreads();
    tinv64(Lsh, Xsh, invd, tid);
    for (int idx = tid; idx < 4096; idx += 256) {
        int r = idx >> 6, c = idx & 63;
        W[(size_t)(k0 + r)*N + k0 + c] = Xsh[r][c];
    }
}

// ---------- 3b. panel TRSM as GEMM: P <- P * W_kk^T (writes A + compact OFF_P) ----------
__global__ __launch_bounds__(256) void k_panelmul(float* __restrict__ ws, int k0) {
    int kk = k0 >> 6;
    int nb = (N - k0 - 64) >> 6;
    int e  = blockIdx.x / nb;
    int bi = blockIdx.x % nb;
    float* A = ws + OFF_A + (size_t)e*N*N;
    const float* W = ws + OFF_IK + (size_t)e*N*N;
    int r0 = k0 + 64 + bi*64;
    __shared__ float Ps[64][65], Wsh[64][65];
    int tid = threadIdx.x;
    for (int idx = tid; idx < 4096; idx += 256) {
        int r = idx >> 6, c2 = idx & 63;
        Ps[r][c2]  = A[(size_t)(r0 + r)*N + k0 + c2];
        Wsh[r][c2] = W[(size_t)(k0 + r)*N + k0 + c2];
    }
    __syncthreads();
    int tx = tid & 15, ty = tid >> 4;
    float acc[4][4] = {};
    #pragma unroll 8
    for (int j = 0; j < 64; ++j) {
        float pr[4], wr[4];
        #pragma unroll
        for (int q = 0; q < 4; ++q) { pr[q] = Ps[ty*4+q][j]; wr[q] = Wsh[tx*4+q][j]; }
        #pragma unroll
        for (int q = 0; q < 4; ++q)
            #pragma unroll
            for (int w = 0; w < 4; ++w) acc[q][w] = fmaf(pr[q], wr[w], acc[q][w]);
    }
    float* Pp = ws + OFF_P + ((size_t)e*1792 + prow(kk) + (size_t)bi*64)*64;
    #pragma unroll
    for (int q = 0; q < 4; ++q)
        #pragma unroll
        for (int w = 0; w < 4; ++w) {
            A[(size_t)(r0 + ty*4 + q)*N + k0 + tx*4 + w] = acc[q][w];
            Pp[(size_t)(ty*4 + q)*64 + tx*4 + w] = acc[q][w];
        }
}

// ---------- 3c. trailing SYRK + fused fast next-diag on (0,0) ----------
__global__ __launch_bounds__(256) void k_traild(float* __restrict__ ws, int k0) {
    int t0 = k0 + 64;
    int nb = (N - t0) >> 6;
    int ntiles = (nb*(nb+1)) >> 1;
    int e = blockIdx.x / ntiles;
    int t = blockIdx.x % ntiles;
    int bj = 0; while (t >= nb - bj) { t -= nb - bj; ++bj; }
    int bi = bj + t;
    bool same = (bi == bj);
    bool isdiag0 = (bi == 0) && (bj == 0);
    float* A = ws + OFF_A + (size_t)e*N*N;
    __shared__ float Sr[64][65], Sc[64][65];
    __shared__ float cb[2][64];
    __shared__ float invd[64];
    int tid = threadIdx.x;
    int tx = tid & 15, ty = tid >> 4;
    for (int idx = tid; idx < 4096; idx += 256) {
        int r = idx >> 6, c = idx & 63;
        Sr[r][c] = A[(size_t)(t0 + bi*64 + r)*N + k0 + c];
        if (!same) Sc[r][c] = A[(size_t)(t0 + bj*64 + r)*N + k0 + c];
    }
    __syncthreads();
    float acc[4][4] = {};
    if (same) {
        #pragma unroll 8
        for (int p = 0; p < 64; ++p) {
            float ar[4], ac[4];
            #pragma unroll
            for (int q = 0; q < 4; ++q) { ar[q] = Sr[ty*4+q][p]; ac[q] = Sr[tx*4+q][p]; }
            #pragma unroll
            for (int q = 0; q < 4; ++q)
                #pragma unroll
                for (int w = 0; w < 4; ++w) acc[q][w] = fmaf(ar[q], ac[w], acc[q][w]);
        }
    } else {
        #pragma unroll 8
        for (int p = 0; p < 64; ++p) {
            float ar[4], ac[4];
            #pragma unroll
            for (int q = 0; q < 4; ++q) { ar[q] = Sr[ty*4+q][p]; ac[q] = Sc[tx*4+q][p]; }
            #pragma unroll
            for (int q = 0; q < 4; ++q)
                #pragma unroll
                for (int w = 0; w < 4; ++w) acc[q][w] = fmaf(ar[q], ac[w], acc[q][w]);
        }
    }
    float* Out = A + (size_t)(t0 + bi*64)*N + (t0 + bj*64);
    if (!isdiag0) {
        #pragma unroll
        for (int q = 0; q < 4; ++q)
            #pragma unroll
            for (int w = 0; w < 4; ++w)
                Out[(size_t)(ty*4+q)*N + tx*4+w] -= acc[q][w];
        return;
    }
    __syncthreads();
    #pragma unroll
    for (int q = 0; q < 4; ++q)
        #pragma unroll
        for (int w = 0; w < 4; ++w)
            Sc[ty*4+q][tx*4+w] = Out[(size_t)(ty*4+q)*N + tx*4+w] - acc[q][w];
    __syncthreads();
    int lane = tid & 63, wv = tid >> 6;
    float a[16];
    #pragma unroll
    for (int j = 0; j < 16; ++j) a[j] = Sc[lane][wv*16 + j];   // tile symmetric
    __syncthreads();
    fact64(a, cb, invd, lane, wv);
    #pragma unroll
    for (int j = 0; j < 16; ++j) Sc[lane][wv*16 + j] = a[j];   // Sc becomes Lsh
    __syncthreads();
    tinv64(Sc, Sr, invd, tid);                                 // Sr becomes Xsh
    float* W = ws + OFF_IK + (size_t)e*N*N;
    for (int idx = tid; idx < 4096; idx += 256) {
        int r = idx >> 6, c = idx & 63;
        W[(size_t)(t0 + r)*N + t0 + c] = Sr[r][c];
    }
}

// ---------- 3d. D&C level 1 (H=1): W21 = -W22 L21 W11 ----------
__global__ __launch_bounds__(256) void k_dc1(float* __restrict__ ws) {
    int e = blockIdx.x >> 2, p = blockIdx.x & 3;
    float* W = ws + OFF_IK + (size_t)e*N*N;
    const float* Lt = ws + OFF_P + ((size_t)e*1792 + prow(2*p))*64;
    __shared__ float Sa[64][65], Sb[64][65], T[64][65];
    int tid = threadIdx.x;
    int tx = tid & 15, ty = tid >> 4;
    for (int idx = tid; idx < 4096; idx += 256) {
        int r = idx >> 6, c = idx & 63;
        Sa[r][c] = Lt[(size_t)r*64 + c];
        Sb[r][c] = W[(size_t)(2*p*64 + r)*N + 2*p*64 + c];
    }
    __syncthreads();
    float acc[4][4] = {};
    #pragma unroll 8
    for (int pp = 0; pp < 64; ++pp) {
        float ar[4], bc[4];
        #pragma unroll
        for (int q = 0; q < 4; ++q) { ar[q] = Sa[ty*4+q][pp]; bc[q] = Sb[pp][tx*4+q]; }
        #pragma unroll
        for (int q = 0; q < 4; ++q)
            #pragma unroll
            for (int w = 0; w < 4; ++w) acc[q][w] = fmaf(ar[q], bc[w], acc[q][w]);
    }
    #pragma unroll
    for (int q = 0; q < 4; ++q)
        #pragma unroll
        for (int w = 0; w < 4; ++w) T[ty*4+q][tx*4+w] = acc[q][w];
    for (int idx = tid; idx < 4096; idx += 256) {
        int r = idx >> 6, c = idx & 63;
        Sa[r][c] = W[(size_t)((2*p+1)*64 + r)*N + (2*p+1)*64 + c];
    }
    __syncthreads();
    float o[4][4] = {};
    #pragma unroll 8
    for (int pp = 0; pp < 64; ++pp) {
        float ar[4], bc[4];
        #pragma unroll
        for (int q = 0; q < 4; ++q) { ar[q] = Sa[ty*4+q][pp]; bc[q] = T[pp][tx*4+q]; }
        #pragma unroll
        for (int q = 0; q < 4; ++q)
            #pragma unroll
            for (int w = 0; w < 4; ++w) o[q][w] = fmaf(ar[q], bc[w], o[q][w]);
    }
    #pragma unroll
    for (int q = 0; q < 4; ++q)
        #pragma unroll
        for (int w = 0; w < 4; ++w)
            W[(size_t)((2*p+1)*64 + ty*4 + q)*N + 2*p*64 + tx*4 + w] = -o[q][w];
}

// ---------- 3e. D&C: T = L21 * W11 (levels H=2,4) ----------
__global__ __launch_bounds__(256) void k_dcT(float* __restrict__ ws, int H) {
    int per_e = 4*H;
    int e = blockIdx.x / per_e;
    int rem = blockIdx.x % per_e;
    int p  = rem / (H*H);
    int tt = rem % (H*H);
    int ti = tt / H, tj = tt % H;
    int C0 = 2*p*H;
    int I  = C0 + H + ti;
    const float* W = ws + OFF_IK + (size_t)e*N*N;
    float* Tt = ws + OFF_T + (size_t)e*65536 + (size_t)(p*H*H + ti*H + tj)*4096;
    __shared__ float Sa[64][65], Sb[64][65];
    int tid = threadIdx.x;
    int tx = tid & 15, ty = tid >> 4;
    float acc[4][4] = {};
    for (int k = tj; k < H; ++k) {
        int K = C0 + k;
        const float* Lt = ws + OFF_P + ((size_t)e*1792 + prow(K) + (size_t)(I - K - 1)*64)*64;
        __syncthreads();
        for (int idx = tid; idx < 4096; idx += 256) {
            int r = idx >> 6, c = idx & 63;
            Sa[r][c] = Lt[(size_t)r*64 + c];
            Sb[r][c] = W[(size_t)(K*64 + r)*N + (C0 + tj)*64 + c];
        }
        __syncthreads();
        #pragma unroll 8
        for (int pp = 0; pp < 64; ++pp) {
            float ar[4], bc[4];
            #pragma unroll
            for (int q = 0; q < 4; ++q) { ar[q] = Sa[ty*4+q][pp]; bc[q] = Sb[pp][tx*4+q]; }
            #pragma unroll
            for (int q = 0; q < 4; ++q)
                #pragma unroll
                for (int w = 0; w < 4; ++w) acc[q][w] = fmaf(ar[q], bc[w], acc[q][w]);
        }
    }
    #pragma unroll
    for (int q = 0; q < 4; ++q)
        #pragma unroll
        for (int w = 0; w < 4; ++w)
            Tt[(size_t)(ty*4+q)*64 + tx*4 + w] = acc[q][w];
}

// ---------- 3f. D&C: W21 = -W22 * T ----------
__global__ __launch_bounds__(256) void k_dcW(float* __restrict__ ws, int H) {
    int per_e = 4*H;
    int e = blockIdx.x / per_e;
    int rem = blockIdx.x % per_e;
    int p  = rem / (H*H);
    int tt = rem % (H*H);
    int ti = tt / H, tj = tt % H;
    int C0 = 2*p*H, R0 = C0 + H;
    float* W = ws + OFF_IK + (size_t)e*N*N;
    const float* Tbase = ws + OFF_T + (size_t)e*65536 + (size_t)(p*H*H)*4096;
    __shared__ float Sa[64][65], Sb[64][65];
    int tid = threadIdx.x;
    int tx = tid & 15, ty = tid >> 4;
    float acc[4][4] = {};
    for (int tk = 0; tk <= ti; ++tk) {
        const float* Tt = Tbase + (size_t)(tk*H + tj)*4096;
        __syncthreads();
        for (int idx = tid; idx < 4096; idx += 256) {
            int r = idx >> 6, c = idx & 63;
            Sa[r][c] = W[(size_t)((R0 + ti)*64 + r)*N + (R0 + tk)*64 + c];
            Sb[r][c] = Tt[(size_t)r*64 + c];
        }
        __syncthreads();
        #pragma unroll 8
        for (int pp = 0; pp < 64; ++pp) {
            float ar[4], bc[4];
            #pragma unroll
            for (int q = 0; q < 4; ++q) { ar[q] = Sa[ty*4+q][pp]; bc[q] = Sb[pp][tx*4+q]; }
            #pragma unroll
            for (int q = 0; q < 4; ++q)
                #pragma unroll
                for (int w = 0; w < 4; ++w) acc[q][w] = fmaf(ar[q], bc[w], acc[q][w]);
        }
    }
    #pragma unroll
    for (int q = 0; q < 4; ++q)
        #pragma unroll
        for (int w = 0; w < 4; ++w)
            W[(size_t)((R0 + ti)*64 + ty*4 + q)*N + (C0 + tj)*64 + tx*4 + w] = -acc[q][w];
}

// ---------- 3g. iK = W^T W (into OFF_A, full symmetric) ----------
__global__ __launch_bounds__(256) void k_syrk(float* __restrict__ ws) {
    int e = blockIdx.x / 36;
    int t = blockIdx.x % 36;
    int bj = 0; while (t >= 8 - bj) { t -= 8 - bj; ++bj; }
    int bi = bj + t;
    const float* W = ws + OFF_IK + (size_t)e*N*N;
    float*      IK = ws + OFF_A  + (size_t)e*N*N;
    __shared__ float Sa[64][65], Sb[64][65];
    int tid = threadIdx.x;
    int tx = tid & 15, ty = tid >> 4;
    float acc[4][4] = {};
    for (int p = bi; p < 8; ++p) {
        __syncthreads();
        for (int idx = tid; idx < 4096; idx += 256) {
            int r = idx >> 6, cc = idx & 63;
            Sa[r][cc] = W[(size_t)(p*64+r)*N + bi*64+cc];
            Sb[r][cc] = W[(size_t)(p*64+r)*N + bj*64+cc];
        }
        __syncthreads();
        #pragma unroll 8
        for (int pr2 = 0; pr2 < 64; ++pr2) {
            float ar[4], ac[4];
            #pragma unroll
            for (int q = 0; q < 4; ++q) { ar[q] = Sa[pr2][ty*4+q]; ac[q] = Sb[pr2][tx*4+q]; }
            #pragma unroll
            for (int q = 0; q < 4; ++q)
                #pragma unroll
                for (int w = 0; w < 4; ++w) acc[q][w] = fmaf(ar[q], ac[w], acc[q][w]);
        }
    }
    #pragma unroll
    for (int q = 0; q < 4; ++q)
        #pragma unroll
        for (int w = 0; w < 4; ++w) {
            int r = bi*64 + ty*4 + q, c = bj*64 + tx*4 + w;
            IK[(size_t)r*N + c] = acc[q][w];
            IK[(size_t)c*N + r] = acc[q][w];
        }
}

// ---------- 3h. beta = iK @ Yn ----------
__global__ __launch_bounds__(256) void k_beta(float* __restrict__ ws) {
    int e = blockIdx.x >> 2, qtr = blockIdx.x & 3;
    int tid = threadIdx.x;
    int half = tid >> 7;
    int nl = tid & 127;
    int n = qtr*128 + nl;
    __shared__ float yn[N];
    __shared__ float part[2][128];
    for (int i = tid; i < N; i += 256) yn[i] = ws[OFF_YN + (size_t)e*N + i];
    __syncthreads();
    const float* IK = ws + OFF_A + (size_t)e*N*N;
    int m0 = half*256;
    float a0 = 0.f, a1 = 0.f, a2 = 0.f, a3 = 0.f;
    for (int mm = m0; mm < m0 + 256; mm += 4) {
        a0 = fmaf(IK[(size_t)mm*N + n],     yn[mm],   a0);
        a1 = fmaf(IK[(size_t)(mm+1)*N + n], yn[mm+1], a1);
        a2 = fmaf(IK[(size_t)(mm+2)*N + n], yn[mm+2], a2);
        a3 = fmaf(IK[(size_t)(mm+3)*N + n], yn[mm+3], a3);
    }
    part[half][nl] = (a0 + a1) + (a2 + a3);
    __syncthreads();
    if (tid < 128)
        ws[OFF_BETA + e*N + qtr*128 + tid] = part[0][tid] + part[1][tid];
}

// ---------- 5+6 merged: k_point (first E*N/256 blocks) and k_xs (rest) ----------
__global__ __launch_bounds__(256) void k_pxs(float* __restrict__ ws, const float* __restrict__ ls,
                                             const float* __restrict__ os) {
    int tid = threadIdx.x;
    if (blockIdx.x < E*N/256) {
        int t = blockIdx.x*256 + tid;
        int e = t >> 9, n = t & 511;
        float iN[D], tt[D], l[D];
        #pragma unroll
        for (int d = 0; d < D; ++d) { l[d] = ls[e*D + d]; iN[d] = ws[OFF_INP + n*D + d] / l[d]; }
        #pragma unroll
        for (int d = 0; d < D; ++d) {
            float acc = 0.f;
            #pragma unroll
            for (int j = 0; j < D; ++j) acc += ws[OFF_BINV + ((size_t)e*D + d)*D + j] * iN[j];
            tt[d] = acc;
        }
        float siNt = 0.f, siN2 = 0.f;
        #pragma unroll
        for (int d = 0; d < D; ++d) { siNt += iN[d]*tt[d]; siN2 += iN[d]*iN[d]; }
        float lbv = __expf(-0.5f * siNt) * ws[OFF_BETA + e*N + n];
        ws[OFF_LB + e*N + n] = lbv;
        #pragma unroll
        for (int d = 0; d < D; ++d) ws[OFF_TIL + ((size_t)e*N + n)*D + d] = tt[d] / l[d];
        ws[OFF_KVEC + e*N + n] = logf(os[e]) - 0.5f * siN2;
        return;
    }
    // ---- xs part: computes kvec inline (independent of point part) ----
    int t = (blockIdx.x - E*N/256)*256 + tid;
    int pair = t / N, n = t % N;
    int a = pair / E, b = pair % E;
    __shared__ float Qs[16][17];
    __shared__ float i2a[16], i2b[16], la_s[16];
    Qs[tid >> 4][tid & 15] = ws[OFF_Q + (size_t)pair*D*D + tid];
    if (tid < 16) { float l = ls[a*D + tid]; i2a[tid] = 1.0f/(l*l); la_s[tid] = l; }
    else if (tid < 32) { int d = tid-16; float l = ls[b*D + d]; i2b[d] = 1.0f/(l*l); }
    __syncthreads();
    float x1[D], x2[D];
    float siNa = 0.f, siNb = 0.f;
    #pragma unroll
    for (int d = 0; d < D; ++d) {
        float ip = ws[OFF_INP + n*D + d];
        x1[d] = ip * i2a[d];
        x2[d] = ip * i2b[d];
        siNa = fmaf(ip*ip, i2a[d], siNa);
        siNb = fmaf(ip*ip, i2b[d], siNb);
    }
    float xs1 = 0.f, xs2 = 0.f;
    #pragma unroll
    for (int j = 0; j < D; ++j) {
        float t1 = 0.f, t2 = 0.f;
        #pragma unroll
        for (int i = 0; i < D; ++i) { t1 = fmaf(x1[i], Qs[i][j], t1); t2 = fmaf(x2[i], Qs[i][j], t2); }
        xs1 = fmaf(t1, x1[j], xs1);
        xs2 = fmaf(t2, x2[j], xs2);
    }
    float loa = logf(os[a]), lob = logf(os[b]);
    ws[OFF_U + (size_t)pair*N + n] = loa - 0.5f*siNa + xs1;
    ws[OFF_V + (size_t)pair*N + n] = lob - 0.5f*siNb + xs2;
}

// ---------- 7. big cross-term: reg-prefetched B-tile (latency hiding) ----------
__global__ __launch_bounds__(256) void k_S(float* __restrict__ ws, const float* __restrict__ ls) {
    int bid = blockIdx.x;
    int pair = bid >> 3, ntile = bid & 7;
    int a = pair / E, b = pair % E;
    int tid = threadIdx.x;
    int tx = tid & 15, ty = tid >> 4;
    __shared__ float Qs[16][17];
    __shared__ float i2a[16], i2b[16];
    __shared__ float __align__(16) bufAT[16][68];
    __shared__ float __align__(16) x1qT[16][68];
    __shared__ float __align__(16) bufBT[16][68];
    __shared__ float u_s[64], v_s[64], ba_s[64], bb_s[64];
    __shared__ float red[256];
    int n0 = ntile*64;
    Qs[tid >> 4][tid & 15] = ws[OFF_Q + (size_t)pair*D*D + tid];
    if (tid < 16) { float l = ls[a*D + tid]; i2a[tid] = 1.0f/(l*l); }
    else if (tid < 32) { int d = tid-16; float l = ls[b*D + d]; i2b[d] = 1.0f/(l*l); }
    __syncthreads();
    for (int idx = tid; idx < 1024; idx += 256) {
        int r = idx >> 4, d = idx & 15;
        bufAT[d][r] = ws[OFF_INP + (size_t)(n0 + r)*D + d] * i2a[d];
    }
    __syncthreads();
    for (int idx = tid; idx < 1024; idx += 256) {
        int r = idx >> 4, j = idx & 15;
        float s = 0.f;
        #pragma unroll
        for (int i = 0; i < 16; ++i) s = fmaf(bufAT[i][r], Qs[i][j], s);
        x1qT[j][r] = s;
    }
    if (tid < 64) {
        u_s[tid]  = ws[OFF_U + (size_t)pair*N + n0 + tid];
        ba_s[tid] = ws[OFF_BETA + a*N + n0 + tid];
    }
    __syncthreads();
    float4 av4[16];
    #pragma unroll
    for (int d = 0; d < 16; ++d) av4[d] = *(const float4*)&x1qT[d][ty*4];
    float uq[4], baq[4];
    #pragma unroll
    for (int q = 0; q < 4; ++q) { uq[q] = u_s[ty*4+q]; baq[q] = ba_s[ty*4+q]; }

    // prefetch tile 0 into registers
    float pf[4];
    #pragma unroll
    for (int j = 0; j < 4; ++j) {
        int idx = tid + j*256;
        pf[j] = ws[OFF_INP + (size_t)((idx >> 4))*D + (idx & 15)];   // mt=0 rows 0..63
    }
    float vpf = 0.f, bpf = 0.f;
    if (tid < 64) {
        vpf = ws[OFF_V + (size_t)pair*N + tid];
        bpf = ws[OFF_BETA + b*N + tid];
    }

    float sacc = 0.f, tacc = 0.f;
    for (int mt = 0; mt < 8; ++mt) {
        __syncthreads();
        #pragma unroll
        for (int j = 0; j < 4; ++j) {
            int idx = tid + j*256;
            bufBT[idx & 15][idx >> 4] = pf[j] * i2b[idx & 15];
        }
        if (tid < 64) { v_s[tid] = vpf; bb_s[tid] = bpf; }
        // issue prefetch for mt+1 (hidden under compute below)
        if (mt < 7) {
            #pragma unroll
            for (int j = 0; j < 4; ++j) {
                int idx = tid + j*256;
                pf[j] = ws[OFF_INP + (size_t)((mt+1)*64 + (idx >> 4))*D + (idx & 15)];
            }
            if (tid < 64) {
                vpf = ws[OFF_V + (size_t)pair*N + (mt+1)*64 + tid];
                bpf = ws[OFF_BETA + b*N + (mt+1)*64 + tid];
            }
        }
        __syncthreads();
        float dacc[4][4] = {};
        #pragma unroll
        for (int d = 0; d < 16; ++d) {
            float4 bv = *(const float4*)&bufBT[d][tx*4];
            float4 av = av4[d];
            dacc[0][0] = fmaf(av.x, bv.x, dacc[0][0]); dacc[0][1] = fmaf(av.x, bv.y, dacc[0][1]);
            dacc[0][2] = fmaf(av.x, bv.z, dacc[0][2]); dacc[0][3] = fmaf(av.x, bv.w, dacc[0][3]);
            dacc[1][0] = fmaf(av.y, bv.x, dacc[1][0]); dacc[1][1] = fmaf(av.y, bv.y, dacc[1][1]);
            dacc[1][2] = fmaf(av.y, bv.z, dacc[1][2]); dacc[1][3] = fmaf(av.y, bv.w, dacc[1][3]);
            dacc[2][0] = fmaf(av.z, bv.x, dacc[2][0]); dacc[2][1] = fmaf(av.z, bv.y, dacc[2][1]);
            dacc[2][2] = fmaf(av.z, bv.z, dacc[2][2]); dacc[2][3] = fmaf(av.z, bv.w, dacc[2][3]);
            dacc[3][0] = fmaf(av.w, bv.x, dacc[3][0]); dacc[3][1] = fmaf(av.w, bv.y, dacc[3][1]);
            dacc[3][2] = fmaf(av.w, bv.z, dacc[3][2]); dacc[3][3] = fmaf(av.w, bv.w, dacc[3][3]);
        }
        #pragma unroll
        for (int q = 0; q < 4; ++q) {
            #pragma unroll
            for (int w = 0; w < 4; ++w) {
                float Lv = __expf(2.f*dacc[q][w] + uq[q] + v_s[tx*4+w]);
                sacc = fmaf(baq[q] * bb_s[tx*4+w], Lv, sacc);
                if (a == b) {
                    float ik = ws[OFF_A + ((size_t)a*N + n0 + ty*4 + q)*N + mt*64 + tx*4 + w];
                    tacc = fmaf(ik, Lv, tacc);
                }
            }
        }
    }
    red[tid] = sacc; __syncthreads();
    for (int o = 128; o > 0; o >>= 1) { if (tid < o) red[tid] += red[tid+o]; __syncthreads(); }
    if (tid == 0) ws[OFF_SPART + bid] = red[0];
    if (a == b) {
        __syncthreads();
        red[tid] = tacc; __syncthreads();
        for (int o = 128; o > 0; o >>= 1) { if (tid < o) red[tid] += red[tid+o]; __syncthreads(); }
        if (tid == 0) ws[OFF_TPART + a*8 + ntile] = red[0];
    }
}

// ---------- 8. finalize ----------
__global__ __launch_bounds__(256) void k_final(float* __restrict__ ws, const float* __restrict__ s,
                                               const float* __restrict__ os, float* __restrict__ out) {
    int tid = threadIdx.x;
    __shared__ float Msh[E], Vsh[E][D], cov[D][E+1];
    __shared__ float Sm[16][17], Si[16][17];
    __shared__ float vred[16][17];

    {
        int wv = tid >> 6, lane = tid & 63;
        for (int e = wv; e < E; e += 4) {
            float sum = 0.f;
            #pragma unroll
            for (int i = 0; i < 8; ++i) sum += ws[OFF_LB + e*N + i*64 + lane];
            #pragma unroll
            for (int off = 32; off > 0; off >>= 1) sum += __shfl_xor(sum, off);
            if (lane == 0) Msh[e] = ws[OFF_C + e] * sum;
        }
    }
    for (int e = 0; e < E; ++e) {
        int d = tid & 15, sl = tid >> 4;
        float acc = 0.f;
        for (int i = 0; i < 32; ++i) {
            int n = sl*32 + i;
            acc = fmaf(ws[OFF_TIL + ((size_t)e*N + n)*D + d], ws[OFF_LB + e*N + n], acc);
        }
        vred[sl][d] = acc;
        __syncthreads();
        if (tid < 16) {
            float sum = 0.f;
            #pragma unroll
            for (int s2 = 0; s2 < 16; ++s2) sum += vred[s2][tid];
            Vsh[e][tid] = ws[OFF_C + e] * sum;
        }
        __syncthreads();
    }

    if (tid < E*E) {
        int a = tid / E, bb = tid % E;
        float acc = 0.f;
        for (int q = 0; q < 8; ++q) acc += ws[OFF_SPART + (size_t)tid*8 + q];
        if (a == bb) {
            float tr = 0.f;
            for (int q = 0; q < 8; ++q) tr += ws[OFF_TPART + a*8 + q];
            acc -= tr;
        }
        acc *= ws[OFF_ISDR + tid];
        if (a == bb) acc += os[a];
        float v = acc - Msh[a]*Msh[bb];
        v *= ws[OFF_YSTD + a] * ws[OFF_YSTD + bb];
        out[E + tid] = v;
    }
    if (tid < E) out[tid] = Msh[tid]*ws[OFF_YSTD + tid] + ws[OFF_YMEAN + tid];

    if (tid < D*E) {
        int d = tid / E, e = tid % E;
        float acc = 0.f;
        for (int k = 0; k < D; ++k) acc += ws[OFF_SSM + d*D + k] * Vsh[e][k];
        cov[d][e] = acc * ws[OFF_XSTD + d] * ws[OFF_YSTD + e];
    }
    int i = tid >> 4, j = tid & 15;
    Sm[i][j] = s[i*D + j];
    Si[i][j] = (i==j) ? 1.f : 0.f;
    __syncthreads();
    for (int k = 0; k < D; ++k) {
        float p   = Sm[k][k];
        float fik = Sm[i][k];
        float skj = Sm[k][j];
        float ikj = Si[k][j];
        __syncthreads();
        if (i == k) { Sm[k][j] = skj/p; Si[k][j] = ikj/p; }
        else        { float f = fik/p; Sm[i][j] -= f*skj; Si[i][j] -= f*ikj; }
        __syncthreads();
    }
    if (tid < D*E) {
        int d = tid / E, e = tid % E;
        float acc = 0.f;
        for (int k = 0; k < D; ++k) acc += Si[d][k] * cov[k][e];
        out[E + E*E + d*E + e] = acc;
    }
}

extern "C" void kernel_launch(void* const* d_in, const int* in_sizes, int n_in,
                              void* d_out, int out_size, void* d_ws, size_t ws_size,
                              hipStream_t stream) {
    const float* X     = (const float*)d_in[0];
    const float* Y     = (const float*)d_in[1];
    const float* m     = (const float*)d_in[2];
    const float* s     = (const float*)d_in[3];
    const float* ls    = (const float*)d_in[4];
    const float* os    = (const float*)d_in[5];
    const float* noise = (const float*)d_in[6];
    float* ws  = (float*)d_ws;
    float* out = (float*)d_out;

    k_prep   <<<1,              512, 0, stream>>>(X, Y, m, s, ws);
    k_buildA <<<E*64 + E + E*E, 256, 0, stream>>>(ws, ls, os, noise);
    k_diag64 <<<E,              256, 0, stream>>>(ws, 0);
    for (int kk = 0; kk < 7; ++kk) {
        int k0 = kk*64;
        int nb = 7 - kk;
        k_panelmul<<<E*nb,          256, 0, stream>>>(ws, k0);
        k_traild  <<<E*nb*(nb+1)/2, 256, 0, stream>>>(ws, k0);
    }
    k_dc1 <<<E*4,  256, 0, stream>>>(ws);
    k_dcT <<<E*8,  256, 0, stream>>>(ws, 2);
    k_dcW <<<E*8,  256, 0, stream>>>(ws, 2);
    k_dcT <<<E*16, 256, 0, stream>>>(ws, 4);
    k_dcW <<<E*16, 256, 0, stream>>>(ws, 4);
    k_syrk <<<E*36,               256, 0, stream>>>(ws);
    k_beta <<<E*4,                256, 0, stream>>>(ws);
    k_pxs  <<<E*N/256 + E*E*N/256,256, 0, stream>>>(ws, ls, os);
    k_S    <<<E*E*8,              256, 0, stream>>>(ws, ls);
    k_final<<<1,                  256, 0, stream>>>(ws, s, os, out);
}

// Round 14
// 803.824 us; speedup vs baseline: 1.0617x; 1.0249x over previous
//
#include <hip/hip_runtime.h>
#include <math.h>

constexpr int N = 512;
constexpr int D = 16;
constexpr int E = 12;

// ---- workspace layout (float offsets) ----
constexpr size_t OFF_A     = 0;                            // E*N*N  A -> trail -> iK
constexpr size_t OFF_IK    = OFF_A    + (size_t)E*N*N;     // E*N*N  W = L^{-1}
constexpr size_t OFF_XS    = OFF_IK   + (size_t)E*N*N;     // N*D
constexpr size_t OFF_INP   = OFF_XS   + (size_t)N*D;       // N*D
constexpr size_t OFF_YN    = OFF_INP  + (size_t)N*D;       // E*N
constexpr size_t OFF_BETA  = OFF_YN   + (size_t)E*N;       // E*N
constexpr size_t OFF_KVEC  = OFF_BETA + (size_t)E*N;       // E*N
constexpr size_t OFF_LB    = OFF_KVEC + (size_t)E*N;       // E*N
constexpr size_t OFF_TIL   = OFF_LB   + (size_t)E*N;       // E*N*D
constexpr size_t OFF_U     = OFF_TIL  + (size_t)E*N*D;     // E*E*N
constexpr size_t OFF_V     = OFF_U    + (size_t)E*E*N;     // E*E*N
constexpr size_t OFF_Q     = OFF_V    + (size_t)E*E*N;     // E*E*D*D
constexpr size_t OFF_BINV  = OFF_Q    + (size_t)E*E*D*D;   // E*D*D
constexpr size_t OFF_C     = OFF_BINV + (size_t)E*D*D;     // E
constexpr size_t OFF_ISDR  = OFF_C    + E;                 // E*E
constexpr size_t OFF_SPART = OFF_ISDR + E*E;               // E*E*8
constexpr size_t OFF_TPART = OFF_SPART+ (size_t)E*E*8;     // E*8
constexpr size_t OFF_XMEAN = OFF_TPART+ (size_t)E*8;       // D
constexpr size_t OFF_XSTD  = OFF_XMEAN+ D;                 // D
constexpr size_t OFF_YMEAN = OFF_XSTD + D;                 // E
constexpr size_t OFF_YSTD  = OFF_YMEAN+ E;                 // E
constexpr size_t OFF_SSM   = OFF_YSTD + E;                 // D*D
constexpr size_t OFF_P     = OFF_SSM  + D*D;               // E*1792*64  (L panels, compact)
constexpr size_t OFF_T     = OFF_P    + (size_t)E*1792*64; // E*65536    (D&C scratch)

__device__ __forceinline__ int prow(int k) { return k*(480 - 32*k); }  // row offset of panel k

// ======== fast 64x64 Cholesky: column-split registers, 1 barrier/step, no spill ========
__device__ __forceinline__ void fact64(float a[16], float (*cb)[64], float* invd, int lane, int wv) {
    #pragma unroll
    for (int k = 0; k < 64; ++k) {
        const int kg = k >> 4, kj = k & 15;
        if (wv == kg) {
            float dkk = __shfl(a[kj], k);
            float dv = sqrtf(dkk);
            float iv = 1.0f / dv;
            float sc = a[kj] * iv;
            if (lane == k)      { a[kj] = dv; invd[k] = iv; }
            else if (lane > k)  a[kj] = sc;
            cb[k & 1][lane] = (lane > k) ? a[kj] : 0.0f;
        }
        __syncthreads();
        float lrk = cb[k & 1][lane];
        #pragma unroll
        for (int j = 0; j < 16; ++j)
            a[j] = fmaf(-lrk, cb[k & 1][wv*16 + j], a[j]);
    }
}

// ======== barrier-free triangular inverse: thread c owns column c ========
__device__ __forceinline__ void tinv64(const float (*Lsh)[65], float (*Xsh)[65],
                                       const float* invd, int tid) {
    if (tid < 64) {
        const int c = tid;
        for (int r = 0; r < c; ++r) Xsh[r][c] = 0.0f;
        for (int r = c; r < 64; ++r) {
            float a0 = (r == c) ? 1.0f : 0.0f, a1 = 0.0f;
            int k = c;
            for (; k + 1 < r; k += 2) {
                a0 = fmaf(-Lsh[r][k],   Xsh[k][c],   a0);
                a1 = fmaf(-Lsh[r][k+1], Xsh[k+1][c], a1);
            }
            if (k < r) a0 = fmaf(-Lsh[r][k], Xsh[k][c], a0);
            Xsh[r][c] = (a0 + a1) * invd[r];
        }
    }
    __syncthreads();
}

// ---------- 1. standardization ----------
__global__ __launch_bounds__(512) void k_prep(const float* __restrict__ X, const float* __restrict__ Y,
                                              const float* __restrict__ m, const float* __restrict__ s,
                                              float* __restrict__ ws) {
    int tid = threadIdx.x;
    int lane = tid & 63, wave = tid >> 6;
    __shared__ float meanX[D], stdX[D], meanY[E], stdY[E], mmsh[D];

    for (int col = wave; col < D + E; col += 8) {
        float s1 = 0.f, s2 = 0.f;
        if (col < D) {
            #pragma unroll
            for (int i = 0; i < 8; ++i) { float v = X[(i*64 + lane)*D + col]; s1 += v; s2 += v*v; }
        } else {
            int e = col - D;
            #pragma unroll
            for (int i = 0; i < 8; ++i) { float v = Y[(i*64 + lane)*E + e]; s1 += v; s2 += v*v; }
        }
        #pragma unroll
        for (int off = 32; off > 0; off >>= 1) { s1 += __shfl_xor(s1, off); s2 += __shfl_xor(s2, off); }
        if (lane == 0) {
            float mean = s1 * (1.0f/N);
            float var  = (s2 - (float)N*mean*mean) * (1.0f/(N-1));
            float sd   = sqrtf(var);
            if (col < D) { meanX[col] = mean; stdX[col] = sd; }
            else         { meanY[col-D] = mean; stdY[col-D] = sd; }
        }
    }
    __syncthreads();
    if (tid < D) {
        mmsh[tid] = (m[tid] - meanX[tid]) / stdX[tid];
        ws[OFF_XMEAN + tid] = meanX[tid];
        ws[OFF_XSTD  + tid] = stdX[tid];
    }
    if (tid < E) { ws[OFF_YMEAN + tid] = meanY[tid]; ws[OFF_YSTD + tid] = stdY[tid]; }
    __syncthreads();
    int n = tid;
    #pragma unroll
    for (int d = 0; d < D; ++d) {
        float xs = (X[n*D + d] - meanX[d]) / stdX[d];
        ws[OFF_XS  + n*D + d] = xs;
        ws[OFF_INP + n*D + d] = xs - mmsh[d];
    }
    #pragma unroll
    for (int e = 0; e < E; ++e)
        ws[OFF_YN + e*N + n] = (Y[n*E + e] - meanY[e]) / stdY[e];
    if (tid < D*D) {
        int i = tid / D, j = tid % D;
        ws[OFF_SSM + tid] = s[tid] / (stdX[i] * stdX[j]);
    }
}

// ---------- 2. A = K + noise I  +  appended B/R inverse blocks ----------
__global__ __launch_bounds__(256) void k_buildA(float* __restrict__ ws, const float* __restrict__ ls,
                                                const float* __restrict__ os, const float* __restrict__ noise) {
    int bid = blockIdx.x;
    int tid = threadIdx.x;
    if (bid < E*64) {
        int e  = bid >> 6;
        int t  = bid & 63;
        int bn = t >> 3, bm = t & 7;
        __shared__ float xn[64][17], xm[64][17];
        __shared__ float il2[16];
        for (int idx = tid; idx < 1024; idx += 256) {
            int r = idx >> 4, d0 = idx & 15;
            xn[r][d0] = ws[OFF_XS + (size_t)(bn*64 + r)*D + d0];
            xm[r][d0] = ws[OFF_XS + (size_t)(bm*64 + r)*D + d0];
        }
        if (tid < 16) { float l = ls[e*D + tid]; il2[tid] = 1.0f/(l*l); }
        __syncthreads();
        int tx = tid & 15, ty = tid >> 4;
        float osv = os[e], nsv = noise[e];
        float acc[4][4] = {};
        #pragma unroll
        for (int d = 0; d < 16; ++d) {
            float il = il2[d];
            float an[4], am[4];
            #pragma unroll
            for (int q = 0; q < 4; ++q) { an[q] = xn[ty + q*16][d]; am[q] = xm[tx + q*16][d]; }
            #pragma unroll
            for (int q = 0; q < 4; ++q)
                #pragma unroll
                for (int w = 0; w < 4; ++w) { float df = an[q] - am[w]; acc[q][w] = fmaf(df*df, il, acc[q][w]); }
        }
        float* A = ws + OFF_A + (size_t)e*N*N;
        #pragma unroll
        for (int q = 0; q < 4; ++q)
            #pragma unroll
            for (int w = 0; w < 4; ++w) {
                int nr = bn*64 + ty + q*16, mc = bm*64 + tx + w*16;
                float v = osv * __expf(-0.5f * acc[q][w]);
                if (nr == mc) v += nsv;
                A[(size_t)nr*N + mc] = v;
            }
        return;
    }
    int bidx = bid - E*64;
    int i = tid >> 4, j = tid & 15;
    if (bidx < E) {
        int e = bidx;
        __shared__ float Bm[16][17], BInv[16][17];
        float li = ls[e*D + i], lj = ls[e*D + j];
        Bm[i][j] = ws[OFF_SSM + i*D + j] / (li*lj) + ((i==j) ? 1.f : 0.f);
        BInv[i][j] = (i==j) ? 1.f : 0.f;
        __syncthreads();
        float det = 1.f;
        for (int k = 0; k < D; ++k) {
            float p   = Bm[k][k];
            float fik = Bm[i][k];
            float bkj = Bm[k][j];
            float ikj = BInv[k][j];
            __syncthreads();
            det *= p;
            if (i == k) { Bm[k][j] = bkj/p; BInv[k][j] = ikj/p; }
            else        { float f = fik/p; Bm[i][j] -= f*bkj; BInv[i][j] -= f*ikj; }
            __syncthreads();
        }
        ws[OFF_BINV + ((size_t)e*D + i)*D + j] = BInv[i][j];
        if (tid == 0) ws[OFF_C + e] = os[e] / sqrtf(det);
    } else {
        int pair = bidx - E;
        int a = pair / E, b = pair % E;
        __shared__ float Rm[16][17], RInv[16][17], ssl[16][17];
        float la = ls[a*D + j], lb2 = ls[b*D + j];
        float rj = 1.f/(la*la) + 1.f/(lb2*lb2);
        float ssv = ws[OFF_SSM + i*D + j];
        ssl[i][j] = ssv;
        Rm[i][j] = ssv * rj + ((i==j) ? 1.f : 0.f);
        RInv[i][j] = (i==j) ? 1.f : 0.f;
        __syncthreads();
        float det = 1.f;
        for (int k = 0; k < D; ++k) {
            float p   = Rm[k][k];
            float fik = Rm[i][k];
            float rkj = Rm[k][j];
            float ikj = RInv[k][j];
            __syncthreads();
            det *= p;
            if (i == k) { Rm[k][j] = rkj/p; RInv[k][j] = ikj/p; }
            else        { float f = fik/p; Rm[i][j] -= f*rkj; RInv[i][j] -= f*ikj; }
            __syncthreads();
        }
        float q = 0.f;
        #pragma unroll
        for (int k2 = 0; k2 < D; ++k2) q += RInv[i][k2] * ssl[k2][j];
        ws[OFF_Q + ((size_t)pair*D + i)*D + j] = 0.5f * q;
        if (tid == 0) ws[OFF_ISDR + pair] = 1.f / sqrtf(det);
    }
}

// ---------- 3a. first diag: fast factor + barrier-free inverse ----------
__global__ __launch_bounds__(256) void k_diag64(float* __restrict__ ws, int k0) {
    int e = blockIdx.x;
    int tid = threadIdx.x;
    int lane = tid & 63, wv = tid >> 6;
    const float* A = ws + OFF_A + (size_t)e*N*N;
    float* W = ws + OFF_IK + (size_t)e*N*N;
    __shared__ float Lsh[64][65], Xsh[64][65];
    __shared__ float cb[2][64];
    __shared__ float invd[64];
    float a[16];
    #pragma unroll
    for (int j = 0; j < 16; ++j)
        a[j] = A[(size_t)(k0 + wv*16 + j)*N + k0 + lane];
    __syncthreads();
    fact64(a, cb, invd, lane, wv);
    #pragma unroll
    for (int j = 0; j < 16; ++j) Lsh[lane][wv*16 + j] = a[j];
    __syncthreads();
    tinv64(Lsh, Xsh, invd, tid);
    for (int idx = tid; idx < 4096; idx += 256) {
        int r = idx >> 6, c = idx & 63;
        W[(size_t)(k0 + r)*N + k0 + c] = Xsh[r][c];
    }
}

// ---------- 3b. panel TRSM as GEMM: P <- P * W_kk^T (writes A + compact OFF_P) ----------
__global__ __launch_bounds__(256) void k_panelmul(float* __restrict__ ws, int k0) {
    int kk = k0 >> 6;
    int nb = (N - k0 - 64) >> 6;
    int e  = blockIdx.x / nb;
    int bi = blockIdx.x % nb;
    float* A = ws + OFF_A + (size_t)e*N*N;
    const float* W = ws + OFF_IK + (size_t)e*N*N;
    int r0 = k0 + 64 + bi*64;
    __shared__ float Ps[64][65], Wsh[64][65];
    int tid = threadIdx.x;
    for (int idx = tid; idx < 4096; idx += 256) {
        int r = idx >> 6, c2 = idx & 63;
        Ps[r][c2]  = A[(size_t)(r0 + r)*N + k0 + c2];
        Wsh[r][c2] = W[(size_t)(k0 + r)*N + k0 + c2];
    }
    __syncthreads();
    int tx = tid & 15, ty = tid >> 4;
    float acc[4][4] = {};
    #pragma unroll 8
    for (int j = 0; j < 64; ++j) {
        float pr[4], wr[4];
        #pragma unroll
        for (int q = 0; q < 4; ++q) { pr[q] = Ps[ty*4+q][j]; wr[q] = Wsh[tx*4+q][j]; }
        #pragma unroll
        for (int q = 0; q < 4; ++q)
            #pragma unroll
            for (int w = 0; w < 4; ++w) acc[q][w] = fmaf(pr[q], wr[w], acc[q][w]);
    }
    float* Pp = ws + OFF_P + ((size_t)e*1792 + prow(kk) + (size_t)bi*64)*64;
    #pragma unroll
    for (int q = 0; q < 4; ++q)
        #pragma unroll
        for (int w = 0; w < 4; ++w) {
            A[(size_t)(r0 + ty*4 + q)*N + k0 + tx*4 + w] = acc[q][w];
            Pp[(size_t)(ty*4 + q)*64 + tx*4 + w] = acc[q][w];
        }
}

// ---------- 3c. trailing SYRK + fused fast next-diag on (0,0) ----------
__global__ __launch_bounds__(256) void k_traild(float* __restrict__ ws, int k0) {
    int t0 = k0 + 64;
    int nb = (N - t0) >> 6;
    int ntiles = (nb*(nb+1)) >> 1;
    int e = blockIdx.x / ntiles;
    int t = blockIdx.x % ntiles;
    int bj = 0; while (t >= nb - bj) { t -= nb - bj; ++bj; }
    int bi = bj + t;
    bool same = (bi == bj);
    bool isdiag0 = (bi == 0) && (bj == 0);
    float* A = ws + OFF_A + (size_t)e*N*N;
    __shared__ float Sr[64][65], Sc[64][65];
    __shared__ float cb[2][64];
    __shared__ float invd[64];
    int tid = threadIdx.x;
    int tx = tid & 15, ty = tid >> 4;
    for (int idx = tid; idx < 4096; idx += 256) {
        int r = idx >> 6, c = idx & 63;
        Sr[r][c] = A[(size_t)(t0 + bi*64 + r)*N + k0 + c];
        if (!same) Sc[r][c] = A[(size_t)(t0 + bj*64 + r)*N + k0 + c];
    }
    __syncthreads();
    float acc[4][4] = {};
    if (same) {
        #pragma unroll 8
        for (int p = 0; p < 64; ++p) {
            float ar[4], ac[4];
            #pragma unroll
            for (int q = 0; q < 4; ++q) { ar[q] = Sr[ty*4+q][p]; ac[q] = Sr[tx*4+q][p]; }
            #pragma unroll
            for (int q = 0; q < 4; ++q)
                #pragma unroll
                for (int w = 0; w < 4; ++w) acc[q][w] = fmaf(ar[q], ac[w], acc[q][w]);
        }
    } else {
        #pragma unroll 8
        for (int p = 0; p < 64; ++p) {
            float ar[4], ac[4];
            #pragma unroll
            for (int q = 0; q < 4; ++q) { ar[q] = Sr[ty*4+q][p]; ac[q] = Sc[tx*4+q][p]; }
            #pragma unroll
            for (int q = 0; q < 4; ++q)
                #pragma unroll
                for (int w = 0; w < 4; ++w) acc[q][w] = fmaf(ar[q], ac[w], acc[q][w]);
        }
    }
    float* Out = A + (size_t)(t0 + bi*64)*N + (t0 + bj*64);
    if (!isdiag0) {
        #pragma unroll
        for (int q = 0; q < 4; ++q)
            #pragma unroll
            for (int w = 0; w < 4; ++w)
                Out[(size_t)(ty*4+q)*N + tx*4+w] -= acc[q][w];
        return;
    }
    __syncthreads();
    #pragma unroll
    for (int q = 0; q < 4; ++q)
        #pragma unroll
        for (int w = 0; w < 4; ++w)
            Sc[ty*4+q][tx*4+w] = Out[(size_t)(ty*4+q)*N + tx*4+w] - acc[q][w];
    __syncthreads();
    int lane = tid & 63, wv = tid >> 6;
    float a[16];
    #pragma unroll
    for (int j = 0; j < 16; ++j) a[j] = Sc[lane][wv*16 + j];   // tile symmetric
    __syncthreads();
    fact64(a, cb, invd, lane, wv);
    #pragma unroll
    for (int j = 0; j < 16; ++j) Sc[lane][wv*16 + j] = a[j];   // Sc becomes Lsh
    __syncthreads();
    tinv64(Sc, Sr, invd, tid);                                 // Sr becomes Xsh
    float* W = ws + OFF_IK + (size_t)e*N*N;
    for (int idx = tid; idx < 4096; idx += 256) {
        int r = idx >> 6, c = idx & 63;
        W[(size_t)(t0 + r)*N + t0 + c] = Sr[r][c];
    }
}

// ---------- 3d. D&C level 1 (H=1): W21 = -W22 L21 W11 ----------
__global__ __launch_bounds__(256) void k_dc1(float* __restrict__ ws) {
    int e = blockIdx.x >> 2, p = blockIdx.x & 3;
    float* W = ws + OFF_IK + (size_t)e*N*N;
    const float* Lt = ws + OFF_P + ((size_t)e*1792 + prow(2*p))*64;
    __shared__ float Sa[64][65], Sb[64][65], T[64][65];
    int tid = threadIdx.x;
    int tx = tid & 15, ty = tid >> 4;
    for (int idx = tid; idx < 4096; idx += 256) {
        int r = idx >> 6, c = idx & 63;
        Sa[r][c] = Lt[(size_t)r*64 + c];
        Sb[r][c] = W[(size_t)(2*p*64 + r)*N + 2*p*64 + c];
    }
    __syncthreads();
    float acc[4][4] = {};
    #pragma unroll 8
    for (int pp = 0; pp < 64; ++pp) {
        float ar[4], bc[4];
        #pragma unroll
        for (int q = 0; q < 4; ++q) { ar[q] = Sa[ty*4+q][pp]; bc[q] = Sb[pp][tx*4+q]; }
        #pragma unroll
        for (int q = 0; q < 4; ++q)
            #pragma unroll
            for (int w = 0; w < 4; ++w) acc[q][w] = fmaf(ar[q], bc[w], acc[q][w]);
    }
    #pragma unroll
    for (int q = 0; q < 4; ++q)
        #pragma unroll
        for (int w = 0; w < 4; ++w) T[ty*4+q][tx*4+w] = acc[q][w];
    for (int idx = tid; idx < 4096; idx += 256) {
        int r = idx >> 6, c = idx & 63;
        Sa[r][c] = W[(size_t)((2*p+1)*64 + r)*N + (2*p+1)*64 + c];
    }
    __syncthreads();
    float o[4][4] = {};
    #pragma unroll 8
    for (int pp = 0; pp < 64; ++pp) {
        float ar[4], bc[4];
        #pragma unroll
        for (int q = 0; q < 4; ++q) { ar[q] = Sa[ty*4+q][pp]; bc[q] = T[pp][tx*4+q]; }
        #pragma unroll
        for (int q = 0; q < 4; ++q)
            #pragma unroll
            for (int w = 0; w < 4; ++w) o[q][w] = fmaf(ar[q], bc[w], o[q][w]);
    }
    #pragma unroll
    for (int q = 0; q < 4; ++q)
        #pragma unroll
        for (int w = 0; w < 4; ++w)
            W[(size_t)((2*p+1)*64 + ty*4 + q)*N + 2*p*64 + tx*4 + w] = -o[q][w];
}

// ---------- 3e. D&C: T = L21 * W11 (levels H=2,4) ----------
__global__ __launch_bounds__(256) void k_dcT(float* __restrict__ ws, int H) {
    int per_e = 4*H;
    int e = blockIdx.x / per_e;
    int rem = blockIdx.x % per_e;
    int p  = rem / (H*H);
    int tt = rem % (H*H);
    int ti = tt / H, tj = tt % H;
    int C0 = 2*p*H;
    int I  = C0 + H + ti;
    const float* W = ws + OFF_IK + (size_t)e*N*N;
    float* Tt = ws + OFF_T + (size_t)e*65536 + (size_t)(p*H*H + ti*H + tj)*4096;
    __shared__ float Sa[64][65], Sb[64][65];
    int tid = threadIdx.x;
    int tx = tid & 15, ty = tid >> 4;
    float acc[4][4] = {};
    for (int k = tj; k < H; ++k) {
        int K = C0 + k;
        const float* Lt = ws + OFF_P + ((size_t)e*1792 + prow(K) + (size_t)(I - K - 1)*64)*64;
        __syncthreads();
        for (int idx = tid; idx < 4096; idx += 256) {
            int r = idx >> 6, c = idx & 63;
            Sa[r][c] = Lt[(size_t)r*64 + c];
            Sb[r][c] = W[(size_t)(K*64 + r)*N + (C0 + tj)*64 + c];
        }
        __syncthreads();
        #pragma unroll 8
        for (int pp = 0; pp < 64; ++pp) {
            float ar[4], bc[4];
            #pragma unroll
            for (int q = 0; q < 4; ++q) { ar[q] = Sa[ty*4+q][pp]; bc[q] = Sb[pp][tx*4+q]; }
            #pragma unroll
            for (int q = 0; q < 4; ++q)
                #pragma unroll
                for (int w = 0; w < 4; ++w) acc[q][w] = fmaf(ar[q], bc[w], acc[q][w]);
        }
    }
    #pragma unroll
    for (int q = 0; q < 4; ++q)
        #pragma unroll
        for (int w = 0; w < 4; ++w)
            Tt[(size_t)(ty*4+q)*64 + tx*4 + w] = acc[q][w];
}

// ---------- 3f. D&C: W21 = -W22 * T ----------
__global__ __launch_bounds__(256) void k_dcW(float* __restrict__ ws, int H) {
    int per_e = 4*H;
    int e = blockIdx.x / per_e;
    int rem = blockIdx.x % per_e;
    int p  = rem / (H*H);
    int tt = rem % (H*H);
    int ti = tt / H, tj = tt % H;
    int C0 = 2*p*H, R0 = C0 + H;
    float* W = ws + OFF_IK + (size_t)e*N*N;
    const float* Tbase = ws + OFF_T + (size_t)e*65536 + (size_t)(p*H*H)*4096;
    __shared__ float Sa[64][65], Sb[64][65];
    int tid = threadIdx.x;
    int tx = tid & 15, ty = tid >> 4;
    float acc[4][4] = {};
    for (int tk = 0; tk <= ti; ++tk) {
        const float* Tt = Tbase + (size_t)(tk*H + tj)*4096;
        __syncthreads();
        for (int idx = tid; idx < 4096; idx += 256) {
            int r = idx >> 6, c = idx & 63;
            Sa[r][c] = W[(size_t)((R0 + ti)*64 + r)*N + (R0 + tk)*64 + c];
            Sb[r][c] = Tt[(size_t)r*64 + c];
        }
        __syncthreads();
        #pragma unroll 8
        for (int pp = 0; pp < 64; ++pp) {
            float ar[4], bc[4];
            #pragma unroll
            for (int q = 0; q < 4; ++q) { ar[q] = Sa[ty*4+q][pp]; bc[q] = Sb[pp][tx*4+q]; }
            #pragma unroll
            for (int q = 0; q < 4; ++q)
                #pragma unroll
                for (int w = 0; w < 4; ++w) acc[q][w] = fmaf(ar[q], bc[w], acc[q][w]);
        }
    }
    #pragma unroll
    for (int q = 0; q < 4; ++q)
        #pragma unroll
        for (int w = 0; w < 4; ++w)
            W[(size_t)((R0 + ti)*64 + ty*4 + q)*N + (C0 + tj)*64 + tx*4 + w] = -acc[q][w];
}

// ---------- 3g. iK = W^T W (into OFF_A, full symmetric) — reg-prefetched p-loop ----------
__global__ __launch_bounds__(256) void k_syrk(float* __restrict__ ws) {
    int e = blockIdx.x / 36;
    int t = blockIdx.x % 36;
    int bj = 0; while (t >= 8 - bj) { t -= 8 - bj; ++bj; }
    int bi = bj + t;
    bool same = (bi == bj);
    const float* W = ws + OFF_IK + (size_t)e*N*N;
    float*      IK = ws + OFF_A  + (size_t)e*N*N;
    __shared__ float Sa[64][65], Sb[64][65];
    int tid = threadIdx.x;
    int tx = tid & 15, ty = tid >> 4;
    int lr = tid >> 6, lc4 = (tid & 63);            // not used; keep simple idx mapping below
    (void)lr; (void)lc4;

    // prefetch p = bi into registers (16 elems/thread per tile)
    float pa[16], pb[16];
    #pragma unroll
    for (int j = 0; j < 16; ++j) {
        int idx = tid + j*256;
        int r = idx >> 6, c = idx & 63;
        pa[j] = W[(size_t)(bi*64 + r)*N + bi*64 + c];
        if (!same) pb[j] = W[(size_t)(bi*64 + r)*N + bj*64 + c];
    }

    float acc[4][4] = {};
    for (int p = bi; p < 8; ++p) {
        __syncthreads();
        #pragma unroll
        for (int j = 0; j < 16; ++j) {
            int idx = tid + j*256;
            int r = idx >> 6, c = idx & 63;
            Sa[r][c] = pa[j];
            if (!same) Sb[r][c] = pb[j];
        }
        // prefetch p+1 while computing p
        if (p < 7) {
            #pragma unroll
            for (int j = 0; j < 16; ++j) {
                int idx = tid + j*256;
                int r = idx >> 6, c = idx & 63;
                pa[j] = W[(size_t)((p+1)*64 + r)*N + bi*64 + c];
                if (!same) pb[j] = W[(size_t)((p+1)*64 + r)*N + bj*64 + c];
            }
        }
        __syncthreads();
        if (same) {
            #pragma unroll 8
            for (int pr2 = 0; pr2 < 64; ++pr2) {
                float ar[4], ac[4];
                #pragma unroll
                for (int q = 0; q < 4; ++q) { ar[q] = Sa[pr2][ty*4+q]; ac[q] = Sa[pr2][tx*4+q]; }
                #pragma unroll
                for (int q = 0; q < 4; ++q)
                    #pragma unroll
                    for (int w = 0; w < 4; ++w) acc[q][w] = fmaf(ar[q], ac[w], acc[q][w]);
            }
        } else {
            #pragma unroll 8
            for (int pr2 = 0; pr2 < 64; ++pr2) {
                float ar[4], ac[4];
                #pragma unroll
                for (int q = 0; q < 4; ++q) { ar[q] = Sa[pr2][ty*4+q]; ac[q] = Sb[pr2][tx*4+q]; }
                #pragma unroll
                for (int q = 0; q < 4; ++q)
                    #pragma unroll
                    for (int w = 0; w < 4; ++w) acc[q][w] = fmaf(ar[q], ac[w], acc[q][w]);
            }
        }
    }
    #pragma unroll
    for (int q = 0; q < 4; ++q)
        #pragma unroll
        for (int w = 0; w < 4; ++w) {
            int r = bi*64 + ty*4 + q, c = bj*64 + tx*4 + w;
            IK[(size_t)r*N + c] = acc[q][w];
            IK[(size_t)c*N + r] = acc[q][w];
        }
}

// ---------- 3h. beta = iK @ Yn ----------
__global__ __launch_bounds__(256) void k_beta(float* __restrict__ ws) {
    int e = blockIdx.x >> 2, qtr = blockIdx.x & 3;
    int tid = threadIdx.x;
    int half = tid >> 7;
    int nl = tid & 127;
    int n = qtr*128 + nl;
    __shared__ float yn[N];
    __shared__ float part[2][128];
    for (int i = tid; i < N; i += 256) yn[i] = ws[OFF_YN + (size_t)e*N + i];
    __syncthreads();
    const float* IK = ws + OFF_A + (size_t)e*N*N;
    int m0 = half*256;
    float a0 = 0.f, a1 = 0.f, a2 = 0.f, a3 = 0.f;
    for (int mm = m0; mm < m0 + 256; mm += 4) {
        a0 = fmaf(IK[(size_t)mm*N + n],     yn[mm],   a0);
        a1 = fmaf(IK[(size_t)(mm+1)*N + n], yn[mm+1], a1);
        a2 = fmaf(IK[(size_t)(mm+2)*N + n], yn[mm+2], a2);
        a3 = fmaf(IK[(size_t)(mm+3)*N + n], yn[mm+3], a3);
    }
    part[half][nl] = (a0 + a1) + (a2 + a3);
    __syncthreads();
    if (tid < 128)
        ws[OFF_BETA + e*N + qtr*128 + tid] = part[0][tid] + part[1][tid];
}

// ---------- 5+6 merged: k_point (first E*N/256 blocks) and k_xs (rest) ----------
__global__ __launch_bounds__(256) void k_pxs(float* __restrict__ ws, const float* __restrict__ ls,
                                             const float* __restrict__ os) {
    int tid = threadIdx.x;
    if (blockIdx.x < E*N/256) {
        int t = blockIdx.x*256 + tid;
        int e = t >> 9, n = t & 511;
        float iN[D], tt[D], l[D];
        #pragma unroll
        for (int d = 0; d < D; ++d) { l[d] = ls[e*D + d]; iN[d] = ws[OFF_INP + n*D + d] / l[d]; }
        #pragma unroll
        for (int d = 0; d < D; ++d) {
            float acc = 0.f;
            #pragma unroll
            for (int j = 0; j < D; ++j) acc += ws[OFF_BINV + ((size_t)e*D + d)*D + j] * iN[j];
            tt[d] = acc;
        }
        float siNt = 0.f, siN2 = 0.f;
        #pragma unroll
        for (int d = 0; d < D; ++d) { siNt += iN[d]*tt[d]; siN2 += iN[d]*iN[d]; }
        float lbv = __expf(-0.5f * siNt) * ws[OFF_BETA + e*N + n];
        ws[OFF_LB + e*N + n] = lbv;
        #pragma unroll
        for (int d = 0; d < D; ++d) ws[OFF_TIL + ((size_t)e*N + n)*D + d] = tt[d] / l[d];
        ws[OFF_KVEC + e*N + n] = logf(os[e]) - 0.5f * siN2;
        return;
    }
    int t = (blockIdx.x - E*N/256)*256 + tid;
    int pair = t / N, n = t % N;
    int a = pair / E, b = pair % E;
    __shared__ float Qs[16][17];
    __shared__ float i2a[16], i2b[16];
    Qs[tid >> 4][tid & 15] = ws[OFF_Q + (size_t)pair*D*D + tid];
    if (tid < 16) { float l = ls[a*D + tid]; i2a[tid] = 1.0f/(l*l); }
    else if (tid < 32) { int d = tid-16; float l = ls[b*D + d]; i2b[d] = 1.0f/(l*l); }
    __syncthreads();
    float x1[D], x2[D];
    float siNa = 0.f, siNb = 0.f;
    #pragma unroll
    for (int d = 0; d < D; ++d) {
        float ip = ws[OFF_INP + n*D + d];
        x1[d] = ip * i2a[d];
        x2[d] = ip * i2b[d];
        siNa = fmaf(ip*ip, i2a[d], siNa);
        siNb = fmaf(ip*ip, i2b[d], siNb);
    }
    float xs1 = 0.f, xs2 = 0.f;
    #pragma unroll
    for (int j = 0; j < D; ++j) {
        float t1 = 0.f, t2 = 0.f;
        #pragma unroll
        for (int i = 0; i < D; ++i) { t1 = fmaf(x1[i], Qs[i][j], t1); t2 = fmaf(x2[i], Qs[i][j], t2); }
        xs1 = fmaf(t1, x1[j], xs1);
        xs2 = fmaf(t2, x2[j], xs2);
    }
    float loa = logf(os[a]), lob = logf(os[b]);
    ws[OFF_U + (size_t)pair*N + n] = loa - 0.5f*siNa + xs1;
    ws[OFF_V + (size_t)pair*N + n] = lob - 0.5f*siNb + xs2;
}

// ---------- 7. big cross-term: reg-prefetched B-tile (latency hiding) ----------
__global__ __launch_bounds__(256) void k_S(float* __restrict__ ws, const float* __restrict__ ls) {
    int bid = blockIdx.x;
    int pair = bid >> 3, ntile = bid & 7;
    int a = pair / E, b = pair % E;
    int tid = threadIdx.x;
    int tx = tid & 15, ty = tid >> 4;
    __shared__ float Qs[16][17];
    __shared__ float i2a[16], i2b[16];
    __shared__ float __align__(16) bufAT[16][68];
    __shared__ float __align__(16) x1qT[16][68];
    __shared__ float __align__(16) bufBT[16][68];
    __shared__ float u_s[64], v_s[64], ba_s[64], bb_s[64];
    __shared__ float red[256];
    int n0 = ntile*64;
    Qs[tid >> 4][tid & 15] = ws[OFF_Q + (size_t)pair*D*D + tid];
    if (tid < 16) { float l = ls[a*D + tid]; i2a[tid] = 1.0f/(l*l); }
    else if (tid < 32) { int d = tid-16; float l = ls[b*D + d]; i2b[d] = 1.0f/(l*l); }
    __syncthreads();
    for (int idx = tid; idx < 1024; idx += 256) {
        int r = idx >> 4, d = idx & 15;
        bufAT[d][r] = ws[OFF_INP + (size_t)(n0 + r)*D + d] * i2a[d];
    }
    __syncthreads();
    for (int idx = tid; idx < 1024; idx += 256) {
        int r = idx >> 4, j = idx & 15;
        float s = 0.f;
        #pragma unroll
        for (int i = 0; i < 16; ++i) s = fmaf(bufAT[i][r], Qs[i][j], s);
        x1qT[j][r] = s;
    }
    if (tid < 64) {
        u_s[tid]  = ws[OFF_U + (size_t)pair*N + n0 + tid];
        ba_s[tid] = ws[OFF_BETA + a*N + n0 + tid];
    }
    __syncthreads();
    float4 av4[16];
    #pragma unroll
    for (int d = 0; d < 16; ++d) av4[d] = *(const float4*)&x1qT[d][ty*4];
    float uq[4], baq[4];
    #pragma unroll
    for (int q = 0; q < 4; ++q) { uq[q] = u_s[ty*4+q]; baq[q] = ba_s[ty*4+q]; }

    float pf[4];
    #pragma unroll
    for (int j = 0; j < 4; ++j) {
        int idx = tid + j*256;
        pf[j] = ws[OFF_INP + (size_t)((idx >> 4))*D + (idx & 15)];
    }
    float vpf = 0.f, bpf = 0.f;
    if (tid < 64) {
        vpf = ws[OFF_V + (size_t)pair*N + tid];
        bpf = ws[OFF_BETA + b*N + tid];
    }

    float sacc = 0.f, tacc = 0.f;
    for (int mt = 0; mt < 8; ++mt) {
        __syncthreads();
        #pragma unroll
        for (int j = 0; j < 4; ++j) {
            int idx = tid + j*256;
            bufBT[idx & 15][idx >> 4] = pf[j] * i2b[idx & 15];
        }
        if (tid < 64) { v_s[tid] = vpf; bb_s[tid] = bpf; }
        if (mt < 7) {
            #pragma unroll
            for (int j = 0; j < 4; ++j) {
                int idx = tid + j*256;
                pf[j] = ws[OFF_INP + (size_t)((mt+1)*64 + (idx >> 4))*D + (idx & 15)];
            }
            if (tid < 64) {
                vpf = ws[OFF_V + (size_t)pair*N + (mt+1)*64 + tid];
                bpf = ws[OFF_BETA + b*N + (mt+1)*64 + tid];
            }
        }
        __syncthreads();
        float dacc[4][4] = {};
        #pragma unroll
        for (int d = 0; d < 16; ++d) {
            float4 bv = *(const float4*)&bufBT[d][tx*4];
            float4 av = av4[d];
            dacc[0][0] = fmaf(av.x, bv.x, dacc[0][0]); dacc[0][1] = fmaf(av.x, bv.y, dacc[0][1]);
            dacc[0][2] = fmaf(av.x, bv.z, dacc[0][2]); dacc[0][3] = fmaf(av.x, bv.w, dacc[0][3]);
            dacc[1][0] = fmaf(av.y, bv.x, dacc[1][0]); dacc[1][1] = fmaf(av.y, bv.y, dacc[1][1]);
            dacc[1][2] = fmaf(av.y, bv.z, dacc[1][2]); dacc[1][3] = fmaf(av.y, bv.w, dacc[1][3]);
            dacc[2][0] = fmaf(av.z, bv.x, dacc[2][0]); dacc[2][1] = fmaf(av.z, bv.y, dacc[2][1]);
            dacc[2][2] = fmaf(av.z, bv.z, dacc[2][2]); dacc[2][3] = fmaf(av.z, bv.w, dacc[2][3]);
            dacc[3][0] = fmaf(av.w, bv.x, dacc[3][0]); dacc[3][1] = fmaf(av.w, bv.y, dacc[3][1]);
            dacc[3][2] = fmaf(av.w, bv.z, dacc[3][2]); dacc[3][3] = fmaf(av.w, bv.w, dacc[3][3]);
        }
        #pragma unroll
        for (int q = 0; q < 4; ++q) {
            #pragma unroll
            for (int w = 0; w < 4; ++w) {
                float Lv = __expf(2.f*dacc[q][w] + uq[q] + v_s[tx*4+w]);
                sacc = fmaf(baq[q] * bb_s[tx*4+w], Lv, sacc);
                if (a == b) {
                    float ik = ws[OFF_A + ((size_t)a*N + n0 + ty*4 + q)*N + mt*64 + tx*4 + w];
                    tacc = fmaf(ik, Lv, tacc);
                }
            }
        }
    }
    red[tid] = sacc; __syncthreads();
    for (int o = 128; o > 0; o >>= 1) { if (tid < o) red[tid] += red[tid+o]; __syncthreads(); }
    if (tid == 0) ws[OFF_SPART + bid] = red[0];
    if (a == b) {
        __syncthreads();
        red[tid] = tacc; __syncthreads();
        for (int o = 128; o > 0; o >>= 1) { if (tid < o) red[tid] += red[tid+o]; __syncthreads(); }
        if (tid == 0) ws[OFF_TPART + a*8 + ntile] = red[0];
    }
}

// ---------- 8. finalize ----------
__global__ __launch_bounds__(256) void k_final(float* __restrict__ ws, const float* __restrict__ s,
                                               const float* __restrict__ os, float* __restrict__ out) {
    int tid = threadIdx.x;
    __shared__ float Msh[E], Vsh[E][D], cov[D][E+1];
    __shared__ float Sm[16][17], Si[16][17];
    __shared__ float vred[16][17];

    {
        int wv = tid >> 6, lane = tid & 63;
        for (int e = wv; e < E; e += 4) {
            float sum = 0.f;
            #pragma unroll
            for (int i = 0; i < 8; ++i) sum += ws[OFF_LB + e*N + i*64 + lane];
            #pragma unroll
            for (int off = 32; off > 0; off >>= 1) sum += __shfl_xor(sum, off);
            if (lane == 0) Msh[e] = ws[OFF_C + e] * sum;
        }
    }
    for (int e = 0; e < E; ++e) {
        int d = tid & 15, sl = tid >> 4;
        float acc = 0.f;
        for (int i = 0; i < 32; ++i) {
            int n = sl*32 + i;
            acc = fmaf(ws[OFF_TIL + ((size_t)e*N + n)*D + d], ws[OFF_LB + e*N + n], acc);
        }
        vred[sl][d] = acc;
        __syncthreads();
        if (tid < 16) {
            float sum = 0.f;
            #pragma unroll
            for (int s2 = 0; s2 < 16; ++s2) sum += vred[s2][tid];
            Vsh[e][tid] = ws[OFF_C + e] * sum;
        }
        __syncthreads();
    }

    if (tid < E*E) {
        int a = tid / E, bb = tid % E;
        float acc = 0.f;
        for (int q = 0; q < 8; ++q) acc += ws[OFF_SPART + (size_t)tid*8 + q];
        if (a == bb) {
            float tr = 0.f;
            for (int q = 0; q < 8; ++q) tr += ws[OFF_TPART + a*8 + q];
            acc -= tr;
        }
        acc *= ws[OFF_ISDR + tid];
        if (a == bb) acc += os[a];
        float v = acc - Msh[a]*Msh[bb];
        v *= ws[OFF_YSTD + a] * ws[OFF_YSTD + bb];
        out[E + tid] = v;
    }
    if (tid < E) out[tid] = Msh[tid]*ws[OFF_YSTD + tid] + ws[OFF_YMEAN + tid];

    if (tid < D*E) {
        int d = tid / E, e = tid % E;
        float acc = 0.f;
        for (int k = 0; k < D; ++k) acc += ws[OFF_SSM + d*D + k] * Vsh[e][k];
        cov[d][e] = acc * ws[OFF_XSTD + d] * ws[OFF_YSTD + e];
    }
    int i = tid >> 4, j = tid & 15;
    Sm[i][j] = s[i*D + j];
    Si[i][j] = (i==j) ? 1.f : 0.f;
    __syncthreads();
    for (int k = 0; k < D; ++k) {
        float p   = Sm[k][k];
        float fik = Sm[i][k];
        float skj = Sm[k][j];
        float ikj = Si[k][j];
        __syncthreads();
        if (i == k) { Sm[k][j] = skj/p; Si[k][j] = ikj/p; }
        else        { float f = fik/p; Sm[i][j] -= f*skj; Si[i][j] -= f*ikj; }
        __syncthreads();
    }
    if (tid < D*E) {
        int d = tid / E, e = tid % E;
        float acc = 0.f;
        for (int k = 0; k < D; ++k) acc += Si[d][k] * cov[k][e];
        out[E + E*E + d*E + e] = acc;
    }
}

extern "C" void kernel_launch(void* const* d_in, const int* in_sizes, int n_in,
                              void* d_out, int out_size, void* d_ws, size_t ws_size,
                              hipStream_t stream) {
    const float* X     = (const float*)d_in[0];
    const float* Y     = (const float*)d_in[1];
    const float* m     = (const float*)d_in[2];
    const float* s     = (const float*)d_in[3];
    const float* ls    = (const float*)d_in[4];
    const float* os    = (const float*)d_in[5];
    const float* noise = (const float*)d_in[6];
    float* ws  = (float*)d_ws;
    float* out = (float*)d_out;

    k_prep   <<<1,              512, 0, stream>>>(X, Y, m, s, ws);
    k_buildA <<<E*64 + E + E*E, 256, 0, stream>>>(ws, ls, os, noise);
    k_diag64 <<<E,              256, 0, stream>>>(ws, 0);
    for (int kk = 0; kk < 7; ++kk) {
        int k0 = kk*64;
        int nb = 7 - kk;
        k_panelmul<<<E*nb,          256, 0, stream>>>(ws, k0);
        k_traild  <<<E*nb*(nb+1)/2, 256, 0, stream>>>(ws, k0);
    }
    k_dc1 <<<E*4,  256, 0, stream>>>(ws);
    k_dcT <<<E*8,  256, 0, stream>>>(ws, 2);
    k_dcW <<<E*8,  256, 0, stream>>>(ws, 2);
    k_dcT <<<E*16, 256, 0, stream>>>(ws, 4);
    k_dcW <<<E*16, 256, 0, stream>>>(ws, 4);
    k_syrk <<<E*36,               256, 0, stream>>>(ws);
    k_beta <<<E*4,                256, 0, stream>>>(ws);
    k_pxs  <<<E*N/256 + E*E*N/256,256, 0, stream>>>(ws, ls, os);
    k_S    <<<E*E*8,              256, 0, stream>>>(ws, ls);
    k_final<<<1,                  256, 0, stream>>>(ws, s, os, out);
}

// Round 15
// 733.647 us; speedup vs baseline: 1.1632x; 1.0957x over previous
//
#include <hip/hip_runtime.h>
#include <math.h>

constexpr int N = 512;
constexpr int D = 16;
constexpr int E = 12;

// ---- workspace layout (float offsets) ----
constexpr size_t OFF_A     = 0;                            // E*N*N  A -> trail -> iK
constexpr size_t OFF_IK    = OFF_A    + (size_t)E*N*N;     // E*N*N  W = L^{-1}
constexpr size_t OFF_XS    = OFF_IK   + (size_t)E*N*N;     // N*D
constexpr size_t OFF_INP   = OFF_XS   + (size_t)N*D;       // N*D
constexpr size_t OFF_YN    = OFF_INP  + (size_t)N*D;       // E*N
constexpr size_t OFF_BETA  = OFF_YN   + (size_t)E*N;       // E*N
constexpr size_t OFF_KVEC  = OFF_BETA + (size_t)E*N;       // E*N
constexpr size_t OFF_LB    = OFF_KVEC + (size_t)E*N;       // E*N
constexpr size_t OFF_TIL   = OFF_LB   + (size_t)E*N;       // E*N*D
constexpr size_t OFF_U     = OFF_TIL  + (size_t)E*N*D;     // E*E*N
constexpr size_t OFF_V     = OFF_U    + (size_t)E*E*N;     // E*E*N
constexpr size_t OFF_Q     = OFF_V    + (size_t)E*E*N;     // E*E*D*D
constexpr size_t OFF_BINV  = OFF_Q    + (size_t)E*E*D*D;   // E*D*D
constexpr size_t OFF_C     = OFF_BINV + (size_t)E*D*D;     // E
constexpr size_t OFF_ISDR  = OFF_C    + E;                 // E*E
constexpr size_t OFF_SPART = OFF_ISDR + E*E;               // E*E*8
constexpr size_t OFF_TPART = OFF_SPART+ (size_t)E*E*8;     // E*8
constexpr size_t OFF_XMEAN = OFF_TPART+ (size_t)E*8;       // D
constexpr size_t OFF_XSTD  = OFF_XMEAN+ D;                 // D
constexpr size_t OFF_YMEAN = OFF_XSTD + D;                 // E
constexpr size_t OFF_YSTD  = OFF_YMEAN+ E;                 // E
constexpr size_t OFF_SSM   = OFF_YSTD + E;                 // D*D
constexpr size_t OFF_P     = OFF_SSM  + D*D;               // E*1792*64  (L panels, compact)
constexpr size_t OFF_T     = OFF_P    + (size_t)E*1792*64; // E*65536    (D&C scratch)

__device__ __forceinline__ int prow(int k) { return k*(480 - 32*k); }  // row offset of panel k

// ======== fast 64x64 Cholesky: column-split registers, 1 barrier/step, no spill ========
__device__ __forceinline__ void fact64(float a[16], float (*cb)[64], float* invd, int lane, int wv) {
    #pragma unroll
    for (int k = 0; k < 64; ++k) {
        const int kg = k >> 4, kj = k & 15;
        if (wv == kg) {
            float dkk = __shfl(a[kj], k);
            float dv = sqrtf(dkk);
            float iv = 1.0f / dv;
            float sc = a[kj] * iv;
            if (lane == k)      { a[kj] = dv; invd[k] = iv; }
            else if (lane > k)  a[kj] = sc;
            cb[k & 1][lane] = (lane > k) ? a[kj] : 0.0f;
        }
        __syncthreads();
        float lrk = cb[k & 1][lane];
        #pragma unroll
        for (int j = 0; j < 16; ++j)
            a[j] = fmaf(-lrk, cb[k & 1][wv*16 + j], a[j]);
    }
}

// ======== barrier-free triangular inverse: thread c owns column c ========
__device__ __forceinline__ void tinv64(const float (*Lsh)[65], float (*Xsh)[65],
                                       const float* invd, int tid) {
    if (tid < 64) {
        const int c = tid;
        for (int r = 0; r < c; ++r) Xsh[r][c] = 0.0f;
        for (int r = c; r < 64; ++r) {
            float a0 = (r == c) ? 1.0f : 0.0f, a1 = 0.0f;
            int k = c;
            for (; k + 1 < r; k += 2) {
                a0 = fmaf(-Lsh[r][k],   Xsh[k][c],   a0);
                a1 = fmaf(-Lsh[r][k+1], Xsh[k+1][c], a1);
            }
            if (k < r) a0 = fmaf(-Lsh[r][k], Xsh[k][c], a0);
            Xsh[r][c] = (a0 + a1) * invd[r];
        }
    }
    __syncthreads();
}

// ======== vectorized 64x64 tile load: global (rowbase + r*N + c) -> LDS [64][65] ========
__device__ __forceinline__ void load_tile4(const float* __restrict__ g, size_t ldg,
                                           float (*S)[65], int tid) {
    #pragma unroll
    for (int j = 0; j < 4; ++j) {
        int idx = tid + j*256;
        int r = idx >> 4, c4 = idx & 15;
        float4 v = *(const float4*)&g[(size_t)r*ldg + c4*4];
        S[r][c4*4+0] = v.x; S[r][c4*4+1] = v.y; S[r][c4*4+2] = v.z; S[r][c4*4+3] = v.w;
    }
}

// ---------- 1. standardization ----------
__global__ __launch_bounds__(512) void k_prep(const float* __restrict__ X, const float* __restrict__ Y,
                                              const float* __restrict__ m, const float* __restrict__ s,
                                              float* __restrict__ ws) {
    int tid = threadIdx.x;
    int lane = tid & 63, wave = tid >> 6;
    __shared__ float meanX[D], stdX[D], meanY[E], stdY[E], mmsh[D];

    for (int col = wave; col < D + E; col += 8) {
        float s1 = 0.f, s2 = 0.f;
        if (col < D) {
            #pragma unroll
            for (int i = 0; i < 8; ++i) { float v = X[(i*64 + lane)*D + col]; s1 += v; s2 += v*v; }
        } else {
            int e = col - D;
            #pragma unroll
            for (int i = 0; i < 8; ++i) { float v = Y[(i*64 + lane)*E + e]; s1 += v; s2 += v*v; }
        }
        #pragma unroll
        for (int off = 32; off > 0; off >>= 1) { s1 += __shfl_xor(s1, off); s2 += __shfl_xor(s2, off); }
        if (lane == 0) {
            float mean = s1 * (1.0f/N);
            float var  = (s2 - (float)N*mean*mean) * (1.0f/(N-1));
            float sd   = sqrtf(var);
            if (col < D) { meanX[col] = mean; stdX[col] = sd; }
            else         { meanY[col-D] = mean; stdY[col-D] = sd; }
        }
    }
    __syncthreads();
    if (tid < D) {
        mmsh[tid] = (m[tid] - meanX[tid]) / stdX[tid];
        ws[OFF_XMEAN + tid] = meanX[tid];
        ws[OFF_XSTD  + tid] = stdX[tid];
    }
    if (tid < E) { ws[OFF_YMEAN + tid] = meanY[tid]; ws[OFF_YSTD + tid] = stdY[tid]; }
    __syncthreads();
    int n = tid;
    #pragma unroll
    for (int d = 0; d < D; ++d) {
        float xs = (X[n*D + d] - meanX[d]) / stdX[d];
        ws[OFF_XS  + n*D + d] = xs;
        ws[OFF_INP + n*D + d] = xs - mmsh[d];
    }
    #pragma unroll
    for (int e = 0; e < E; ++e)
        ws[OFF_YN + e*N + n] = (Y[n*E + e] - meanY[e]) / stdY[e];
    if (tid < D*D) {
        int i = tid / D, j = tid % D;
        ws[OFF_SSM + tid] = s[tid] / (stdX[i] * stdX[j]);
    }
}

// ---------- 2. A = K + noise I  +  appended B/R inverse blocks ----------
__global__ __launch_bounds__(256) void k_buildA(float* __restrict__ ws, const float* __restrict__ ls,
                                                const float* __restrict__ os, const float* __restrict__ noise) {
    int bid = blockIdx.x;
    int tid = threadIdx.x;
    if (bid < E*64) {
        int e  = bid >> 6;
        int t  = bid & 63;
        int bn = t >> 3, bm = t & 7;
        __shared__ float xn[64][17], xm[64][17];
        __shared__ float il2[16];
        for (int idx = tid; idx < 1024; idx += 256) {
            int r = idx >> 4, d0 = idx & 15;
            xn[r][d0] = ws[OFF_XS + (size_t)(bn*64 + r)*D + d0];
            xm[r][d0] = ws[OFF_XS + (size_t)(bm*64 + r)*D + d0];
        }
        if (tid < 16) { float l = ls[e*D + tid]; il2[tid] = 1.0f/(l*l); }
        __syncthreads();
        int tx = tid & 15, ty = tid >> 4;
        float osv = os[e], nsv = noise[e];
        float acc[4][4] = {};
        #pragma unroll
        for (int d = 0; d < 16; ++d) {
            float il = il2[d];
            float an[4], am[4];
            #pragma unroll
            for (int q = 0; q < 4; ++q) { an[q] = xn[ty + q*16][d]; am[q] = xm[tx + q*16][d]; }
            #pragma unroll
            for (int q = 0; q < 4; ++q)
                #pragma unroll
                for (int w = 0; w < 4; ++w) { float df = an[q] - am[w]; acc[q][w] = fmaf(df*df, il, acc[q][w]); }
        }
        float* A = ws + OFF_A + (size_t)e*N*N;
        #pragma unroll
        for (int q = 0; q < 4; ++q)
            #pragma unroll
            for (int w = 0; w < 4; ++w) {
                int nr = bn*64 + ty + q*16, mc = bm*64 + tx + w*16;
                float v = osv * __expf(-0.5f * acc[q][w]);
                if (nr == mc) v += nsv;
                A[(size_t)nr*N + mc] = v;
            }
        return;
    }
    int bidx = bid - E*64;
    int i = tid >> 4, j = tid & 15;
    if (bidx < E) {
        int e = bidx;
        __shared__ float Bm[16][17], BInv[16][17];
        float li = ls[e*D + i], lj = ls[e*D + j];
        Bm[i][j] = ws[OFF_SSM + i*D + j] / (li*lj) + ((i==j) ? 1.f : 0.f);
        BInv[i][j] = (i==j) ? 1.f : 0.f;
        __syncthreads();
        float det = 1.f;
        for (int k = 0; k < D; ++k) {
            float p   = Bm[k][k];
            float fik = Bm[i][k];
            float bkj = Bm[k][j];
            float ikj = BInv[k][j];
            __syncthreads();
            det *= p;
            if (i == k) { Bm[k][j] = bkj/p; BInv[k][j] = ikj/p; }
            else        { float f = fik/p; Bm[i][j] -= f*bkj; BInv[i][j] -= f*ikj; }
            __syncthreads();
        }
        ws[OFF_BINV + ((size_t)e*D + i)*D + j] = BInv[i][j];
        if (tid == 0) ws[OFF_C + e] = os[e] / sqrtf(det);
    } else {
        int pair = bidx - E;
        int a = pair / E, b = pair % E;
        __shared__ float Rm[16][17], RInv[16][17], ssl[16][17];
        float la = ls[a*D + j], lb2 = ls[b*D + j];
        float rj = 1.f/(la*la) + 1.f/(lb2*lb2);
        float ssv = ws[OFF_SSM + i*D + j];
        ssl[i][j] = ssv;
        Rm[i][j] = ssv * rj + ((i==j) ? 1.f : 0.f);
        RInv[i][j] = (i==j) ? 1.f : 0.f;
        __syncthreads();
        float det = 1.f;
        for (int k = 0; k < D; ++k) {
            float p   = Rm[k][k];
            float fik = Rm[i][k];
            float rkj = Rm[k][j];
            float ikj = RInv[k][j];
            __syncthreads();
            det *= p;
            if (i == k) { Rm[k][j] = rkj/p; RInv[k][j] = ikj/p; }
            else        { float f = fik/p; Rm[i][j] -= f*rkj; RInv[i][j] -= f*ikj; }
            __syncthreads();
        }
        float q = 0.f;
        #pragma unroll
        for (int k2 = 0; k2 < D; ++k2) q += RInv[i][k2] * ssl[k2][j];
        ws[OFF_Q + ((size_t)pair*D + i)*D + j] = 0.5f * q;
        if (tid == 0) ws[OFF_ISDR + pair] = 1.f / sqrtf(det);
    }
}

// ---------- 3a. first diag: fast factor + barrier-free inverse ----------
__global__ __launch_bounds__(256) void k_diag64(float* __restrict__ ws, int k0) {
    int e = blockIdx.x;
    int tid = threadIdx.x;
    int lane = tid & 63, wv = tid >> 6;
    const float* A = ws + OFF_A + (size_t)e*N*N;
    float* W = ws + OFF_IK + (size_t)e*N*N;
    __shared__ float Lsh[64][65], Xsh[64][65];
    __shared__ float cb[2][64];
    __shared__ float invd[64];
    float a[16];
    #pragma unroll
    for (int j = 0; j < 16; ++j)
        a[j] = A[(size_t)(k0 + wv*16 + j)*N + k0 + lane];
    __syncthreads();
    fact64(a, cb, invd, lane, wv);
    #pragma unroll
    for (int j = 0; j < 16; ++j) Lsh[lane][wv*16 + j] = a[j];
    __syncthreads();
    tinv64(Lsh, Xsh, invd, tid);
    for (int idx = tid; idx < 4096; idx += 256) {
        int r = idx >> 6, c = idx & 63;
        W[(size_t)(k0 + r)*N + k0 + c] = Xsh[r][c];
    }
}

// ---------- 3b. panel TRSM as GEMM: P <- P * W_kk^T (writes A + compact OFF_P) ----------
__global__ __launch_bounds__(256) void k_panelmul(float* __restrict__ ws, int k0) {
    int kk = k0 >> 6;
    int nb = (N - k0 - 64) >> 6;
    int e  = blockIdx.x / nb;
    int bi = blockIdx.x % nb;
    float* A = ws + OFF_A + (size_t)e*N*N;
    const float* W = ws + OFF_IK + (size_t)e*N*N;
    int r0 = k0 + 64 + bi*64;
    __shared__ float Ps[64][65], Wsh[64][65];
    int tid = threadIdx.x;
    load_tile4(A + (size_t)r0*N + k0, N, Ps, tid);
    load_tile4(W + (size_t)k0*N + k0, N, Wsh, tid);
    __syncthreads();
    int tx = tid & 15, ty = tid >> 4;
    float acc[4][4] = {};
    #pragma unroll 8
    for (int j = 0; j < 64; ++j) {
        float pr[4], wr[4];
        #pragma unroll
        for (int q = 0; q < 4; ++q) { pr[q] = Ps[ty*4+q][j]; wr[q] = Wsh[tx*4+q][j]; }
        #pragma unroll
        for (int q = 0; q < 4; ++q)
            #pragma unroll
            for (int w = 0; w < 4; ++w) acc[q][w] = fmaf(pr[q], wr[w], acc[q][w]);
    }
    float* Pp = ws + OFF_P + ((size_t)e*1792 + prow(kk) + (size_t)bi*64)*64;
    #pragma unroll
    for (int q = 0; q < 4; ++q)
        #pragma unroll
        for (int w = 0; w < 4; ++w) {
            A[(size_t)(r0 + ty*4 + q)*N + k0 + tx*4 + w] = acc[q][w];
            Pp[(size_t)(ty*4 + q)*64 + tx*4 + w] = acc[q][w];
        }
}

// ---------- 3c. trailing SYRK + fused fast next-diag on (0,0) ----------
__global__ __launch_bounds__(256) void k_traild(float* __restrict__ ws, int k0) {
    int t0 = k0 + 64;
    int nb = (N - t0) >> 6;
    int ntiles = (nb*(nb+1)) >> 1;
    int e = blockIdx.x / ntiles;
    int t = blockIdx.x % ntiles;
    int bj = 0; while (t >= nb - bj) { t -= nb - bj; ++bj; }
    int bi = bj + t;
    bool same = (bi == bj);
    bool isdiag0 = (bi == 0) && (bj == 0);
    float* A = ws + OFF_A + (size_t)e*N*N;
    __shared__ float Sr[64][65], Sc[64][65];
    __shared__ float cb[2][64];
    __shared__ float invd[64];
    int tid = threadIdx.x;
    int tx = tid & 15, ty = tid >> 4;
    load_tile4(A + (size_t)(t0 + bi*64)*N + k0, N, Sr, tid);
    if (!same) load_tile4(A + (size_t)(t0 + bj*64)*N + k0, N, Sc, tid);
    __syncthreads();
    float acc[4][4] = {};
    if (same) {
        #pragma unroll 8
        for (int p = 0; p < 64; ++p) {
            float ar[4], ac[4];
            #pragma unroll
            for (int q = 0; q < 4; ++q) { ar[q] = Sr[ty*4+q][p]; ac[q] = Sr[tx*4+q][p]; }
            #pragma unroll
            for (int q = 0; q < 4; ++q)
                #pragma unroll
                for (int w = 0; w < 4; ++w) acc[q][w] = fmaf(ar[q], ac[w], acc[q][w]);
        }
    } else {
        #pragma unroll 8
        for (int p = 0; p < 64; ++p) {
            float ar[4], ac[4];
            #pragma unroll
            for (int q = 0; q < 4; ++q) { ar[q] = Sr[ty*4+q][p]; ac[q] = Sc[tx*4+q][p]; }
            #pragma unroll
            for (int q = 0; q < 4; ++q)
                #pragma unroll
                for (int w = 0; w < 4; ++w) acc[q][w] = fmaf(ar[q], ac[w], acc[q][w]);
        }
    }
    float* Out = A + (size_t)(t0 + bi*64)*N + (t0 + bj*64);
    if (!isdiag0) {
        #pragma unroll
        for (int q = 0; q < 4; ++q)
            #pragma unroll
            for (int w = 0; w < 4; ++w)
                Out[(size_t)(ty*4+q)*N + tx*4+w] -= acc[q][w];
        return;
    }
    __syncthreads();
    #pragma unroll
    for (int q = 0; q < 4; ++q)
        #pragma unroll
        for (int w = 0; w < 4; ++w)
            Sc[ty*4+q][tx*4+w] = Out[(size_t)(ty*4+q)*N + tx*4+w] - acc[q][w];
    __syncthreads();
    int lane = tid & 63, wv = tid >> 6;
    float a[16];
    #pragma unroll
    for (int j = 0; j < 16; ++j) a[j] = Sc[lane][wv*16 + j];   // tile symmetric
    __syncthreads();
    fact64(a, cb, invd, lane, wv);
    #pragma unroll
    for (int j = 0; j < 16; ++j) Sc[lane][wv*16 + j] = a[j];   // Sc becomes Lsh
    __syncthreads();
    tinv64(Sc, Sr, invd, tid);                                 // Sr becomes Xsh
    float* W = ws + OFF_IK + (size_t)e*N*N;
    for (int idx = tid; idx < 4096; idx += 256) {
        int r = idx >> 6, c = idx & 63;
        W[(size_t)(t0 + r)*N + t0 + c] = Sr[r][c];
    }
}

// ---------- 3d. D&C level 1 (H=1): W21 = -W22 L21 W11 ----------
__global__ __launch_bounds__(256) void k_dc1(float* __restrict__ ws) {
    int e = blockIdx.x >> 2, p = blockIdx.x & 3;
    float* W = ws + OFF_IK + (size_t)e*N*N;
    const float* Lt = ws + OFF_P + ((size_t)e*1792 + prow(2*p))*64;
    __shared__ float Sa[64][65], Sb[64][65], T[64][65];
    int tid = threadIdx.x;
    int tx = tid & 15, ty = tid >> 4;
    load_tile4(Lt, 64, Sa, tid);
    load_tile4(W + (size_t)(2*p*64)*N + 2*p*64, N, Sb, tid);
    __syncthreads();
    float acc[4][4] = {};
    #pragma unroll 8
    for (int pp = 0; pp < 64; ++pp) {
        float ar[4], bc[4];
        #pragma unroll
        for (int q = 0; q < 4; ++q) { ar[q] = Sa[ty*4+q][pp]; bc[q] = Sb[pp][tx*4+q]; }
        #pragma unroll
        for (int q = 0; q < 4; ++q)
            #pragma unroll
            for (int w = 0; w < 4; ++w) acc[q][w] = fmaf(ar[q], bc[w], acc[q][w]);
    }
    #pragma unroll
    for (int q = 0; q < 4; ++q)
        #pragma unroll
        for (int w = 0; w < 4; ++w) T[ty*4+q][tx*4+w] = acc[q][w];
    __syncthreads();
    load_tile4(W + (size_t)((2*p+1)*64)*N + (2*p+1)*64, N, Sa, tid);
    __syncthreads();
    float o[4][4] = {};
    #pragma unroll 8
    for (int pp = 0; pp < 64; ++pp) {
        float ar[4], bc[4];
        #pragma unroll
        for (int q = 0; q < 4; ++q) { ar[q] = Sa[ty*4+q][pp]; bc[q] = T[pp][tx*4+q]; }
        #pragma unroll
        for (int q = 0; q < 4; ++q)
            #pragma unroll
            for (int w = 0; w < 4; ++w) o[q][w] = fmaf(ar[q], bc[w], o[q][w]);
    }
    #pragma unroll
    for (int q = 0; q < 4; ++q)
        #pragma unroll
        for (int w = 0; w < 4; ++w)
            W[(size_t)((2*p+1)*64 + ty*4 + q)*N + 2*p*64 + tx*4 + w] = -o[q][w];
}

// ---------- 3e. D&C: T = L21 * W11 (levels H=2,4) ----------
__global__ __launch_bounds__(256) void k_dcT(float* __restrict__ ws, int H) {
    int per_e = 4*H;
    int e = blockIdx.x / per_e;
    int rem = blockIdx.x % per_e;
    int p  = rem / (H*H);
    int tt = rem % (H*H);
    int ti = tt / H, tj = tt % H;
    int C0 = 2*p*H;
    int I  = C0 + H + ti;
    const float* W = ws + OFF_IK + (size_t)e*N*N;
    float* Tt = ws + OFF_T + (size_t)e*65536 + (size_t)(p*H*H + ti*H + tj)*4096;
    __shared__ float Sa[64][65], Sb[64][65];
    int tid = threadIdx.x;
    int tx = tid & 15, ty = tid >> 4;
    float acc[4][4] = {};
    for (int k = tj; k < H; ++k) {
        int K = C0 + k;
        const float* Lt = ws + OFF_P + ((size_t)e*1792 + prow(K) + (size_t)(I - K - 1)*64)*64;
        __syncthreads();
        load_tile4(Lt, 64, Sa, tid);
        load_tile4(W + (size_t)(K*64)*N + (C0 + tj)*64, N, Sb, tid);
        __syncthreads();
        #pragma unroll 8
        for (int pp = 0; pp < 64; ++pp) {
            float ar[4], bc[4];
            #pragma unroll
            for (int q = 0; q < 4; ++q) { ar[q] = Sa[ty*4+q][pp]; bc[q] = Sb[pp][tx*4+q]; }
            #pragma unroll
            for (int q = 0; q < 4; ++q)
                #pragma unroll
                for (int w = 0; w < 4; ++w) acc[q][w] = fmaf(ar[q], bc[w], acc[q][w]);
        }
    }
    #pragma unroll
    for (int q = 0; q < 4; ++q)
        #pragma unroll
        for (int w = 0; w < 4; ++w)
            Tt[(size_t)(ty*4+q)*64 + tx*4 + w] = acc[q][w];
}

// ---------- 3f. D&C: W21 = -W22 * T ----------
__global__ __launch_bounds__(256) void k_dcW(float* __restrict__ ws, int H) {
    int per_e = 4*H;
    int e = blockIdx.x / per_e;
    int rem = blockIdx.x % per_e;
    int p  = rem / (H*H);
    int tt = rem % (H*H);
    int ti = tt / H, tj = tt % H;
    int C0 = 2*p*H, R0 = C0 + H;
    float* W = ws + OFF_IK + (size_t)e*N*N;
    const float* Tbase = ws + OFF_T + (size_t)e*65536 + (size_t)(p*H*H)*4096;
    __shared__ float Sa[64][65], Sb[64][65];
    int tid = threadIdx.x;
    int tx = tid & 15, ty = tid >> 4;
    float acc[4][4] = {};
    for (int tk = 0; tk <= ti; ++tk) {
        const float* Tt = Tbase + (size_t)(tk*H + tj)*4096;
        __syncthreads();
        load_tile4(W + (size_t)((R0 + ti)*64)*N + (R0 + tk)*64, N, Sa, tid);
        load_tile4(Tt, 64, Sb, tid);
        __syncthreads();
        #pragma unroll 8
        for (int pp = 0; pp < 64; ++pp) {
            float ar[4], bc[4];
            #pragma unroll
            for (int q = 0; q < 4; ++q) { ar[q] = Sa[ty*4+q][pp]; bc[q] = Sb[pp][tx*4+q]; }
            #pragma unroll
            for (int q = 0; q < 4; ++q)
                #pragma unroll
                for (int w = 0; w < 4; ++w) acc[q][w] = fmaf(ar[q], bc[w], acc[q][w]);
        }
    }
    #pragma unroll
    for (int q = 0; q < 4; ++q)
        #pragma unroll
        for (int w = 0; w < 4; ++w)
            W[(size_t)((R0 + ti)*64 + ty*4 + q)*N + (C0 + tj)*64 + tx*4 + w] = -acc[q][w];
}

// ---------- 3g. iK = W^T W (into OFF_A, full symmetric) — float4 reg-prefetched ----------
__global__ __launch_bounds__(256) void k_syrk(float* __restrict__ ws) {
    int e = blockIdx.x / 36;
    int t = blockIdx.x % 36;
    int bj = 0; while (t >= 8 - bj) { t -= 8 - bj; ++bj; }
    int bi = bj + t;
    bool same = (bi == bj);
    const float* W = ws + OFF_IK + (size_t)e*N*N;
    float*      IK = ws + OFF_A  + (size_t)e*N*N;
    __shared__ float Sa[64][65], Sb[64][65];
    int tid = threadIdx.x;
    int tx = tid & 15, ty = tid >> 4;
    int pr4 = (tid + 0) >> 4;   // row for this thread's float4 slots
    (void)pr4;

    float4 pa[4], pb[4];
    #pragma unroll
    for (int j = 0; j < 4; ++j) {
        int idx = tid + j*256;
        int r = idx >> 4, c4 = idx & 15;
        pa[j] = *(const float4*)&W[(size_t)(bi*64 + r)*N + bi*64 + c4*4];
        if (!same) pb[j] = *(const float4*)&W[(size_t)(bi*64 + r)*N + bj*64 + c4*4];
    }

    float acc[4][4] = {};
    for (int p = bi; p < 8; ++p) {
        __syncthreads();
        #pragma unroll
        for (int j = 0; j < 4; ++j) {
            int idx = tid + j*256;
            int r = idx >> 4, c4 = idx & 15;
            Sa[r][c4*4+0] = pa[j].x; Sa[r][c4*4+1] = pa[j].y; Sa[r][c4*4+2] = pa[j].z; Sa[r][c4*4+3] = pa[j].w;
            if (!same) { Sb[r][c4*4+0] = pb[j].x; Sb[r][c4*4+1] = pb[j].y; Sb[r][c4*4+2] = pb[j].z; Sb[r][c4*4+3] = pb[j].w; }
        }
        if (p < 7) {
            #pragma unroll
            for (int j = 0; j < 4; ++j) {
                int idx = tid + j*256;
                int r = idx >> 4, c4 = idx & 15;
                pa[j] = *(const float4*)&W[(size_t)((p+1)*64 + r)*N + bi*64 + c4*4];
                if (!same) pb[j] = *(const float4*)&W[(size_t)((p+1)*64 + r)*N + bj*64 + c4*4];
            }
        }
        __syncthreads();
        if (same) {
            #pragma unroll 8
            for (int pr2 = 0; pr2 < 64; ++pr2) {
                float ar[4], ac[4];
                #pragma unroll
                for (int q = 0; q < 4; ++q) { ar[q] = Sa[pr2][ty*4+q]; ac[q] = Sa[pr2][tx*4+q]; }
                #pragma unroll
                for (int q = 0; q < 4; ++q)
                    #pragma unroll
                    for (int w = 0; w < 4; ++w) acc[q][w] = fmaf(ar[q], ac[w], acc[q][w]);
            }
        } else {
            #pragma unroll 8
            for (int pr2 = 0; pr2 < 64; ++pr2) {
                float ar[4], ac[4];
                #pragma unroll
                for (int q = 0; q < 4; ++q) { ar[q] = Sa[pr2][ty*4+q]; ac[q] = Sb[pr2][tx*4+q]; }
                #pragma unroll
                for (int q = 0; q < 4; ++q)
                    #pragma unroll
                    for (int w = 0; w < 4; ++w) acc[q][w] = fmaf(ar[q], ac[w], acc[q][w]);
            }
        }
    }
    #pragma unroll
    for (int q = 0; q < 4; ++q)
        #pragma unroll
        for (int w = 0; w < 4; ++w) {
            int r = bi*64 + ty*4 + q, c = bj*64 + tx*4 + w;
            IK[(size_t)r*N + c] = acc[q][w];
            IK[(size_t)c*N + r] = acc[q][w];
        }
}

// ---------- 3h. beta = iK @ Yn ----------
__global__ __launch_bounds__(256) void k_beta(float* __restrict__ ws) {
    int e = blockIdx.x >> 2, qtr = blockIdx.x & 3;
    int tid = threadIdx.x;
    int half = tid >> 7;
    int nl = tid & 127;
    int n = qtr*128 + nl;
    __shared__ float yn[N];
    __shared__ float part[2][128];
    for (int i = tid; i < N; i += 256) yn[i] = ws[OFF_YN + (size_t)e*N + i];
    __syncthreads();
    const float* IK = ws + OFF_A + (size_t)e*N*N;
    int m0 = half*256;
    float a0 = 0.f, a1 = 0.f, a2 = 0.f, a3 = 0.f;
    for (int mm = m0; mm < m0 + 256; mm += 4) {
        a0 = fmaf(IK[(size_t)mm*N + n],     yn[mm],   a0);
        a1 = fmaf(IK[(size_t)(mm+1)*N + n], yn[mm+1], a1);
        a2 = fmaf(IK[(size_t)(mm+2)*N + n], yn[mm+2], a2);
        a3 = fmaf(IK[(size_t)(mm+3)*N + n], yn[mm+3], a3);
    }
    part[half][nl] = (a0 + a1) + (a2 + a3);
    __syncthreads();
    if (tid < 128)
        ws[OFF_BETA + e*N + qtr*128 + tid] = part[0][tid] + part[1][tid];
}

// ---------- 5+6 merged: k_point (first E*N/256 blocks) and k_xs (rest) ----------
__global__ __launch_bounds__(256) void k_pxs(float* __restrict__ ws, const float* __restrict__ ls,
                                             const float* __restrict__ os) {
    int tid = threadIdx.x;
    if (blockIdx.x < E*N/256) {
        int t = blockIdx.x*256 + tid;
        int e = t >> 9, n = t & 511;
        float iN[D], tt[D], l[D];
        #pragma unroll
        for (int d = 0; d < D; ++d) { l[d] = ls[e*D + d]; iN[d] = ws[OFF_INP + n*D + d] / l[d]; }
        #pragma unroll
        for (int d = 0; d < D; ++d) {
            float acc = 0.f;
            #pragma unroll
            for (int j = 0; j < D; ++j) acc += ws[OFF_BINV + ((size_t)e*D + d)*D + j] * iN[j];
            tt[d] = acc;
        }
        float siNt = 0.f, siN2 = 0.f;
        #pragma unroll
        for (int d = 0; d < D; ++d) { siNt += iN[d]*tt[d]; siN2 += iN[d]*iN[d]; }
        float lbv = __expf(-0.5f * siNt) * ws[OFF_BETA + e*N + n];
        ws[OFF_LB + e*N + n] = lbv;
        #pragma unroll
        for (int d = 0; d < D; ++d) ws[OFF_TIL + ((size_t)e*N + n)*D + d] = tt[d] / l[d];
        ws[OFF_KVEC + e*N + n] = logf(os[e]) - 0.5f * siN2;
        return;
    }
    int t = (blockIdx.x - E*N/256)*256 + tid;
    int pair = t / N, n = t % N;
    int a = pair / E, b = pair % E;
    __shared__ float Qs[16][17];
    __shared__ float i2a[16], i2b[16];
    Qs[tid >> 4][tid & 15] = ws[OFF_Q + (size_t)pair*D*D + tid];
    if (tid < 16) { float l = ls[a*D + tid]; i2a[tid] = 1.0f/(l*l); }
    else if (tid < 32) { int d = tid-16; float l = ls[b*D + d]; i2b[d] = 1.0f/(l*l); }
    __syncthreads();
    float x1[D], x2[D];
    float siNa = 0.f, siNb = 0.f;
    #pragma unroll
    for (int d = 0; d < D; ++d) {
        float ip = ws[OFF_INP + n*D + d];
        x1[d] = ip * i2a[d];
        x2[d] = ip * i2b[d];
        siNa = fmaf(ip*ip, i2a[d], siNa);
        siNb = fmaf(ip*ip, i2b[d], siNb);
    }
    float xs1 = 0.f, xs2 = 0.f;
    #pragma unroll
    for (int j = 0; j < D; ++j) {
        float t1 = 0.f, t2 = 0.f;
        #pragma unroll
        for (int i = 0; i < D; ++i) { t1 = fmaf(x1[i], Qs[i][j], t1); t2 = fmaf(x2[i], Qs[i][j], t2); }
        xs1 = fmaf(t1, x1[j], xs1);
        xs2 = fmaf(t2, x2[j], xs2);
    }
    float loa = logf(os[a]), lob = logf(os[b]);
    ws[OFF_U + (size_t)pair*N + n] = loa - 0.5f*siNa + xs1;
    ws[OFF_V + (size_t)pair*N + n] = lob - 0.5f*siNb + xs2;
}

// ---------- 7. big cross-term: reg-prefetched B-tile + float4 iK read ----------
__global__ __launch_bounds__(256) void k_S(float* __restrict__ ws, const float* __restrict__ ls) {
    int bid = blockIdx.x;
    int pair = bid >> 3, ntile = bid & 7;
    int a = pair / E, b = pair % E;
    int tid = threadIdx.x;
    int tx = tid & 15, ty = tid >> 4;
    __shared__ float Qs[16][17];
    __shared__ float i2a[16], i2b[16];
    __shared__ float __align__(16) bufAT[16][68];
    __shared__ float __align__(16) x1qT[16][68];
    __shared__ float __align__(16) bufBT[16][68];
    __shared__ float u_s[64], v_s[64], ba_s[64], bb_s[64];
    __shared__ float red[256];
    int n0 = ntile*64;
    Qs[tid >> 4][tid & 15] = ws[OFF_Q + (size_t)pair*D*D + tid];
    if (tid < 16) { float l = ls[a*D + tid]; i2a[tid] = 1.0f/(l*l); }
    else if (tid < 32) { int d = tid-16; float l = ls[b*D + d]; i2b[d] = 1.0f/(l*l); }
    __syncthreads();
    for (int idx = tid; idx < 1024; idx += 256) {
        int r = idx >> 4, d = idx & 15;
        bufAT[d][r] = ws[OFF_INP + (size_t)(n0 + r)*D + d] * i2a[d];
    }
    __syncthreads();
    for (int idx = tid; idx < 1024; idx += 256) {
        int r = idx >> 4, j = idx & 15;
        float s = 0.f;
        #pragma unroll
        for (int i = 0; i < 16; ++i) s = fmaf(bufAT[i][r], Qs[i][j], s);
        x1qT[j][r] = s;
    }
    if (tid < 64) {
        u_s[tid]  = ws[OFF_U + (size_t)pair*N + n0 + tid];
        ba_s[tid] = ws[OFF_BETA + a*N + n0 + tid];
    }
    __syncthreads();
    float4 av4[16];
    #pragma unroll
    for (int d = 0; d < 16; ++d) av4[d] = *(const float4*)&x1qT[d][ty*4];
    float uq[4], baq[4];
    #pragma unroll
    for (int q = 0; q < 4; ++q) { uq[q] = u_s[ty*4+q]; baq[q] = ba_s[ty*4+q]; }

    float pf[4];
    #pragma unroll
    for (int j = 0; j < 4; ++j) {
        int idx = tid + j*256;
        pf[j] = ws[OFF_INP + (size_t)((idx >> 4))*D + (idx & 15)];
    }
    float vpf = 0.f, bpf = 0.f;
    if (tid < 64) {
        vpf = ws[OFF_V + (size_t)pair*N + tid];
        bpf = ws[OFF_BETA + b*N + tid];
    }

    float sacc = 0.f, tacc = 0.f;
    for (int mt = 0; mt < 8; ++mt) {
        __syncthreads();
        #pragma unroll
        for (int j = 0; j < 4; ++j) {
            int idx = tid + j*256;
            bufBT[idx & 15][idx >> 4] = pf[j] * i2b[idx & 15];
        }
        if (tid < 64) { v_s[tid] = vpf; bb_s[tid] = bpf; }
        if (mt < 7) {
            #pragma unroll
            for (int j = 0; j < 4; ++j) {
                int idx = tid + j*256;
                pf[j] = ws[OFF_INP + (size_t)((mt+1)*64 + (idx >> 4))*D + (idx & 15)];
            }
            if (tid < 64) {
                vpf = ws[OFF_V + (size_t)pair*N + (mt+1)*64 + tid];
                bpf = ws[OFF_BETA + b*N + (mt+1)*64 + tid];
            }
        }
        __syncthreads();
        float dacc[4][4] = {};
        #pragma unroll
        for (int d = 0; d < 16; ++d) {
            float4 bv = *(const float4*)&bufBT[d][tx*4];
            float4 av = av4[d];
            dacc[0][0] = fmaf(av.x, bv.x, dacc[0][0]); dacc[0][1] = fmaf(av.x, bv.y, dacc[0][1]);
            dacc[0][2] = fmaf(av.x, bv.z, dacc[0][2]); dacc[0][3] = fmaf(av.x, bv.w, dacc[0][3]);
            dacc[1][0] = fmaf(av.y, bv.x, dacc[1][0]); dacc[1][1] = fmaf(av.y, bv.y, dacc[1][1]);
            dacc[1][2] = fmaf(av.y, bv.z, dacc[1][2]); dacc[1][3] = fmaf(av.y, bv.w, dacc[1][3]);
            dacc[2][0] = fmaf(av.z, bv.x, dacc[2][0]); dacc[2][1] = fmaf(av.z, bv.y, dacc[2][1]);
            dacc[2][2] = fmaf(av.z, bv.z, dacc[2][2]); dacc[2][3] = fmaf(av.z, bv.w, dacc[2][3]);
            dacc[3][0] = fmaf(av.w, bv.x, dacc[3][0]); dacc[3][1] = fmaf(av.w, bv.y, dacc[3][1]);
            dacc[3][2] = fmaf(av.w, bv.z, dacc[3][2]); dacc[3][3] = fmaf(av.w, bv.w, dacc[3][3]);
        }
        #pragma unroll
        for (int q = 0; q < 4; ++q) {
            float ikq[4];
            if (a == b)
                *(float4*)ikq = *(const float4*)&ws[OFF_A + ((size_t)a*N + n0 + ty*4 + q)*N + mt*64 + tx*4];
            #pragma unroll
            for (int w = 0; w < 4; ++w) {
                float Lv = __expf(2.f*dacc[q][w] + uq[q] + v_s[tx*4+w]);
                sacc = fmaf(baq[q] * bb_s[tx*4+w], Lv, sacc);
                if (a == b)
                    tacc = fmaf(ikq[w], Lv, tacc);
            }
        }
    }
    red[tid] = sacc; __syncthreads();
    for (int o = 128; o > 0; o >>= 1) { if (tid < o) red[tid] += red[tid+o]; __syncthreads(); }
    if (tid == 0) ws[OFF_SPART + bid] = red[0];
    if (a == b) {
        __syncthreads();
        red[tid] = tacc; __syncthreads();
        for (int o = 128; o > 0; o >>= 1) { if (tid < o) red[tid] += red[tid+o]; __syncthreads(); }
        if (tid == 0) ws[OFF_TPART + a*8 + ntile] = red[0];
    }
}

// ---------- 8. finalize ----------
__global__ __launch_bounds__(256) void k_final(float* __restrict__ ws, const float* __restrict__ s,
                                               const float* __restrict__ os, float* __restrict__ out) {
    int tid = threadIdx.x;
    __shared__ float Msh[E], Vsh[E][D], cov[D][E+1];
    __shared__ float Sm[16][17], Si[16][17];
    __shared__ float vred[16][17];

    {
        int wv = tid >> 6, lane = tid & 63;
        for (int e = wv; e < E; e += 4) {
            float sum = 0.f;
            #pragma unroll
            for (int i = 0; i < 8; ++i) sum += ws[OFF_LB + e*N + i*64 + lane];
            #pragma unroll
            for (int off = 32; off > 0; off >>= 1) sum += __shfl_xor(sum, off);
            if (lane == 0) Msh[e] = ws[OFF_C + e] * sum;
        }
    }
    for (int e = 0; e < E; ++e) {
        int d = tid & 15, sl = tid >> 4;
        float acc = 0.f;
        for (int i = 0; i < 32; ++i) {
            int n = sl*32 + i;
            acc = fmaf(ws[OFF_TIL + ((size_t)e*N + n)*D + d], ws[OFF_LB + e*N + n], acc);
        }
        vred[sl][d] = acc;
        __syncthreads();
        if (tid < 16) {
            float sum = 0.f;
            #pragma unroll
            for (int s2 = 0; s2 < 16; ++s2) sum += vred[s2][tid];
            Vsh[e][tid] = ws[OFF_C + e] * sum;
        }
        __syncthreads();
    }

    if (tid < E*E) {
        int a = tid / E, bb = tid % E;
        float acc = 0.f;
        for (int q = 0; q < 8; ++q) acc += ws[OFF_SPART + (size_t)tid*8 + q];
        if (a == bb) {
            float tr = 0.f;
            for (int q = 0; q < 8; ++q) tr += ws[OFF_TPART + a*8 + q];
            acc -= tr;
        }
        acc *= ws[OFF_ISDR + tid];
        if (a == bb) acc += os[a];
        float v = acc - Msh[a]*Msh[bb];
        v *= ws[OFF_YSTD + a] * ws[OFF_YSTD + bb];
        out[E + tid] = v;
    }
    if (tid < E) out[tid] = Msh[tid]*ws[OFF_YSTD + tid] + ws[OFF_YMEAN + tid];

    if (tid < D*E) {
        int d = tid / E, e = tid % E;
        float acc = 0.f;
        for (int k = 0; k < D; ++k) acc += ws[OFF_SSM + d*D + k] * Vsh[e][k];
        cov[d][e] = acc * ws[OFF_XSTD + d] * ws[OFF_YSTD + e];
    }
    int i = tid >> 4, j = tid & 15;
    Sm[i][j] = s[i*D + j];
    Si[i][j] = (i==j) ? 1.f : 0.f;
    __syncthreads();
    for (int k = 0; k < D; ++k) {
        float p   = Sm[k][k];
        float fik = Sm[i][k];
        float skj = Sm[k][j];
        float ikj = Si[k][j];
        __syncthreads();
        if (i == k) { Sm[k][j] = skj/p; Si[k][j] = ikj/p; }
        else        { float f = fik/p; Sm[i][j] -= f*skj; Si[i][j] -= f*ikj; }
        __syncthreads();
    }
    if (tid < D*E) {
        int d = tid / E, e = tid % E;
        float acc = 0.f;
        for (int k = 0; k < D; ++k) acc += Si[d][k] * cov[k][e];
        out[E + E*E + d*E + e] = acc;
    }
}

extern "C" void kernel_launch(void* const* d_in, const int* in_sizes, int n_in,
                              void* d_out, int out_size, void* d_ws, size_t ws_size,
                              hipStream_t stream) {
    const float* X     = (const float*)d_in[0];
    const float* Y     = (const float*)d_in[1];
    const float* m     = (const float*)d_in[2];
    const float* s     = (const float*)d_in[3];
    const float* ls    = (const float*)d_in[4];
    const float* os    = (const float*)d_in[5];
    const float* noise = (const float*)d_in[6];
    float* ws  = (float*)d_ws;
    float* out = (float*)d_out;

    k_prep   <<<1,              512, 0, stream>>>(X, Y, m, s, ws);
    k_buildA <<<E*64 + E + E*E, 256, 0, stream>>>(ws, ls, os, noise);
    k_diag64 <<<E,              256, 0, stream>>>(ws, 0);
    for (int kk = 0; kk < 7; ++kk) {
        int k0 = kk*64;
        int nb = 7 - kk;
        k_panelmul<<<E*nb,          256, 0, stream>>>(ws, k0);
        k_traild  <<<E*nb*(nb+1)/2, 256, 0, stream>>>(ws, k0);
    }
    k_dc1 <<<E*4,  256, 0, stream>>>(ws);
    k_dcT <<<E*8,  256, 0, stream>>>(ws, 2);
    k_dcW <<<E*8,  256, 0, stream>>>(ws, 2);
    k_dcT <<<E*16, 256, 0, stream>>>(ws, 4);
    k_dcW <<<E*16, 256, 0, stream>>>(ws, 4);
    k_syrk <<<E*36,               256, 0, stream>>>(ws);
    k_beta <<<E*4,                256, 0, stream>>>(ws);
    k_pxs  <<<E*N/256 + E*E*N/256,256, 0, stream>>>(ws, ls, os);
    k_S    <<<E*E*8,              256, 0, stream>>>(ws, ls);
    k_final<<<1,                  256, 0, stream>>>(ws, s, os, out);
}

// Round 16
// 535.052 us; speedup vs baseline: 1.5950x; 1.3712x over previous
//
#include <hip/hip_runtime.h>
#include <math.h>

constexpr int N = 512;
constexpr int D = 16;
constexpr int E = 12;

// ---- workspace layout (float offsets) ----
constexpr size_t OFF_A     = 0;                            // E*N*N  A -> trail -> iK
constexpr size_t OFF_IK    = OFF_A    + (size_t)E*N*N;     // E*N*N  W = L^{-1}
constexpr size_t OFF_XS    = OFF_IK   + (size_t)E*N*N;     // N*D
constexpr size_t OFF_INP   = OFF_XS   + (size_t)N*D;       // N*D
constexpr size_t OFF_YN    = OFF_INP  + (size_t)N*D;       // E*N
constexpr size_t OFF_BETA  = OFF_YN   + (size_t)E*N;       // E*N
constexpr size_t OFF_KVEC  = OFF_BETA + (size_t)E*N;       // E*N
constexpr size_t OFF_LB    = OFF_KVEC + (size_t)E*N;       // E*N
constexpr size_t OFF_TIL   = OFF_LB   + (size_t)E*N;       // E*N*D
constexpr size_t OFF_U     = OFF_TIL  + (size_t)E*N*D;     // E*E*N
constexpr size_t OFF_V     = OFF_U    + (size_t)E*E*N;     // E*E*N
constexpr size_t OFF_Q     = OFF_V    + (size_t)E*E*N;     // E*E*D*D
constexpr size_t OFF_BINV  = OFF_Q    + (size_t)E*E*D*D;   // E*D*D
constexpr size_t OFF_C     = OFF_BINV + (size_t)E*D*D;     // E
constexpr size_t OFF_ISDR  = OFF_C    + E;                 // E*E
constexpr size_t OFF_SPART = OFF_ISDR + E*E;               // E*E*8
constexpr size_t OFF_TPART = OFF_SPART+ (size_t)E*E*8;     // E*8
constexpr size_t OFF_XMEAN = OFF_TPART+ (size_t)E*8;       // D
constexpr size_t OFF_XSTD  = OFF_XMEAN+ D;                 // D
constexpr size_t OFF_YMEAN = OFF_XSTD + D;                 // E
constexpr size_t OFF_YSTD  = OFF_YMEAN+ E;                 // E
constexpr size_t OFF_SSM   = OFF_YSTD + E;                 // D*D
constexpr size_t OFF_P     = OFF_SSM  + D*D;               // E*1792*64  (L panels, compact)
constexpr size_t OFF_T     = OFF_P    + (size_t)E*1792*64; // E*65536    (D&C scratch)

__device__ __forceinline__ int prow(int k) { return k*(480 - 32*k); }  // row offset of panel k

// ======== fast 64x64 Cholesky: column-split registers, 1 barrier/step, no spill ========
__device__ __forceinline__ void fact64(float a[16], float (*cb)[64], float* invd, int lane, int wv) {
    #pragma unroll
    for (int k = 0; k < 64; ++k) {
        const int kg = k >> 4, kj = k & 15;
        if (wv == kg) {
            float dkk = __shfl(a[kj], k);
            float dv = sqrtf(dkk);
            float iv = 1.0f / dv;
            float sc = a[kj] * iv;
            if (lane == k)      { a[kj] = dv; invd[k] = iv; }
            else if (lane > k)  a[kj] = sc;
            cb[k & 1][lane] = (lane > k) ? a[kj] : 0.0f;
        }
        __syncthreads();
        float lrk = cb[k & 1][lane];
        #pragma unroll
        for (int j = 0; j < 16; ++j)
            a[j] = fmaf(-lrk, cb[k & 1][wv*16 + j], a[j]);
    }
}

// ======== blocked in-LDS 64x64 triangular inverse: short critical path ========
// Partition into 16x16 blocks. Step 1: 4 diag blocks inverted in parallel
// (thread t<64: group g=t>>4, column c=t&15; serial depth ~120 fma). Other
// threads zero the strict-upper blocks. Step 2: wavefronts d=1..3 compute
// X_ij = -X_ii (sum_k L_ik X_kj) as pairs of 16x16 GEMMs, all 256 threads.
__device__ __forceinline__ void binv64(const float (*Lsh)[65], float (*Xsh)[65],
                                       const float* invd, float (*Tsh)[16][17], int tid) {
    if (tid < 64) {
        int g = tid >> 4, c = tid & 15;
        int b = g*16;
        for (int r = 0; r < c; ++r) Xsh[b+r][b+c] = 0.f;
        for (int r = c; r < 16; ++r) {
            float acc = (r == c) ? 1.0f : 0.0f;
            for (int k = c; k < r; ++k)
                acc = fmaf(-Lsh[b+r][b+k], Xsh[b+k][b+c], acc);
            Xsh[b+r][b+c] = acc * invd[b+r];
        }
    } else {
        // zero the 6 strict-upper 16x16 blocks (1536 elements, 192 threads)
        const int bis[6] = {0,0,0,1,1,2};
        const int bjs[6] = {1,2,3,2,3,3};
        for (int idx = tid - 64; idx < 1536; idx += 192) {
            int blk = idx >> 8, off = idx & 255;
            Xsh[bis[blk]*16 + (off >> 4)][bjs[blk]*16 + (off & 15)] = 0.f;
        }
    }
    __syncthreads();
    for (int d = 1; d <= 3; ++d) {
        int np = 4 - d;
        for (int idx = tid; idx < np*256; idx += 256) {
            int p = idx >> 8, off = idx & 255;
            int r = off >> 4, c = off & 15;
            int i = p + d, j = p;
            float acc = 0.f;
            for (int k = j; k < i; ++k)
                #pragma unroll
                for (int m = 0; m < 16; ++m)
                    acc = fmaf(Lsh[i*16+r][k*16+m], Xsh[k*16+m][j*16+c], acc);
            Tsh[p][r][c] = acc;
        }
        __syncthreads();
        for (int idx = tid; idx < np*256; idx += 256) {
            int p = idx >> 8, off = idx & 255;
            int r = off >> 4, c = off & 15;
            int i = p + d, j = p;
            float acc = 0.f;
            #pragma unroll
            for (int m = 0; m < 16; ++m)
                acc = fmaf(Xsh[i*16+r][i*16+m], Tsh[p][m][c], acc);
            Xsh[i*16+r][j*16+c] = -acc;
        }
        __syncthreads();
    }
}

// ======== vectorized 64x64 tile load: global (rowbase + r*N + c) -> LDS [64][65] ========
__device__ __forceinline__ void load_tile4(const float* __restrict__ g, size_t ldg,
                                           float (*S)[65], int tid) {
    #pragma unroll
    for (int j = 0; j < 4; ++j) {
        int idx = tid + j*256;
        int r = idx >> 4, c4 = idx & 15;
        float4 v = *(const float4*)&g[(size_t)r*ldg + c4*4];
        S[r][c4*4+0] = v.x; S[r][c4*4+1] = v.y; S[r][c4*4+2] = v.z; S[r][c4*4+3] = v.w;
    }
}

// ---------- 1. standardization ----------
__global__ __launch_bounds__(512) void k_prep(const float* __restrict__ X, const float* __restrict__ Y,
                                              const float* __restrict__ m, const float* __restrict__ s,
                                              float* __restrict__ ws) {
    int tid = threadIdx.x;
    int lane = tid & 63, wave = tid >> 6;
    __shared__ float meanX[D], stdX[D], meanY[E], stdY[E], mmsh[D];

    for (int col = wave; col < D + E; col += 8) {
        float s1 = 0.f, s2 = 0.f;
        if (col < D) {
            #pragma unroll
            for (int i = 0; i < 8; ++i) { float v = X[(i*64 + lane)*D + col]; s1 += v; s2 += v*v; }
        } else {
            int e = col - D;
            #pragma unroll
            for (int i = 0; i < 8; ++i) { float v = Y[(i*64 + lane)*E + e]; s1 += v; s2 += v*v; }
        }
        #pragma unroll
        for (int off = 32; off > 0; off >>= 1) { s1 += __shfl_xor(s1, off); s2 += __shfl_xor(s2, off); }
        if (lane == 0) {
            float mean = s1 * (1.0f/N);
            float var  = (s2 - (float)N*mean*mean) * (1.0f/(N-1));
            float sd   = sqrtf(var);
            if (col < D) { meanX[col] = mean; stdX[col] = sd; }
            else         { meanY[col-D] = mean; stdY[col-D] = sd; }
        }
    }
    __syncthreads();
    if (tid < D) {
        mmsh[tid] = (m[tid] - meanX[tid]) / stdX[tid];
        ws[OFF_XMEAN + tid] = meanX[tid];
        ws[OFF_XSTD  + tid] = stdX[tid];
    }
    if (tid < E) { ws[OFF_YMEAN + tid] = meanY[tid]; ws[OFF_YSTD + tid] = stdY[tid]; }
    __syncthreads();
    int n = tid;
    #pragma unroll
    for (int d = 0; d < D; ++d) {
        float xs = (X[n*D + d] - meanX[d]) / stdX[d];
        ws[OFF_XS  + n*D + d] = xs;
        ws[OFF_INP + n*D + d] = xs - mmsh[d];
    }
    #pragma unroll
    for (int e = 0; e < E; ++e)
        ws[OFF_YN + e*N + n] = (Y[n*E + e] - meanY[e]) / stdY[e];
    if (tid < D*D) {
        int i = tid / D, j = tid % D;
        ws[OFF_SSM + tid] = s[tid] / (stdX[i] * stdX[j]);
    }
}

// ---------- 2. A = K + noise I  +  appended B/R inverse blocks ----------
__global__ __launch_bounds__(256) void k_buildA(float* __restrict__ ws, const float* __restrict__ ls,
                                                const float* __restrict__ os, const float* __restrict__ noise) {
    int bid = blockIdx.x;
    int tid = threadIdx.x;
    if (bid < E*64) {
        int e  = bid >> 6;
        int t  = bid & 63;
        int bn = t >> 3, bm = t & 7;
        __shared__ float xn[64][17], xm[64][17];
        __shared__ float il2[16];
        for (int idx = tid; idx < 1024; idx += 256) {
            int r = idx >> 4, d0 = idx & 15;
            xn[r][d0] = ws[OFF_XS + (size_t)(bn*64 + r)*D + d0];
            xm[r][d0] = ws[OFF_XS + (size_t)(bm*64 + r)*D + d0];
        }
        if (tid < 16) { float l = ls[e*D + tid]; il2[tid] = 1.0f/(l*l); }
        __syncthreads();
        int tx = tid & 15, ty = tid >> 4;
        float osv = os[e], nsv = noise[e];
        float acc[4][4] = {};
        #pragma unroll
        for (int d = 0; d < 16; ++d) {
            float il = il2[d];
            float an[4], am[4];
            #pragma unroll
            for (int q = 0; q < 4; ++q) { an[q] = xn[ty + q*16][d]; am[q] = xm[tx + q*16][d]; }
            #pragma unroll
            for (int q = 0; q < 4; ++q)
                #pragma unroll
                for (int w = 0; w < 4; ++w) { float df = an[q] - am[w]; acc[q][w] = fmaf(df*df, il, acc[q][w]); }
        }
        float* A = ws + OFF_A + (size_t)e*N*N;
        #pragma unroll
        for (int q = 0; q < 4; ++q)
            #pragma unroll
            for (int w = 0; w < 4; ++w) {
                int nr = bn*64 + ty + q*16, mc = bm*64 + tx + w*16;
                float v = osv * __expf(-0.5f * acc[q][w]);
                if (nr == mc) v += nsv;
                A[(size_t)nr*N + mc] = v;
            }
        return;
    }
    int bidx = bid - E*64;
    int i = tid >> 4, j = tid & 15;
    if (bidx < E) {
        int e = bidx;
        __shared__ float Bm[16][17], BInv[16][17];
        float li = ls[e*D + i], lj = ls[e*D + j];
        Bm[i][j] = ws[OFF_SSM + i*D + j] / (li*lj) + ((i==j) ? 1.f : 0.f);
        BInv[i][j] = (i==j) ? 1.f : 0.f;
        __syncthreads();
        float det = 1.f;
        for (int k = 0; k < D; ++k) {
            float p   = Bm[k][k];
            float fik = Bm[i][k];
            float bkj = Bm[k][j];
            float ikj = BInv[k][j];
            __syncthreads();
            det *= p;
            if (i == k) { Bm[k][j] = bkj/p; BInv[k][j] = ikj/p; }
            else        { float f = fik/p; Bm[i][j] -= f*bkj; BInv[i][j] -= f*ikj; }
            __syncthreads();
        }
        ws[OFF_BINV + ((size_t)e*D + i)*D + j] = BInv[i][j];
        if (tid == 0) ws[OFF_C + e] = os[e] / sqrtf(det);
    } else {
        int pair = bidx - E;
        int a = pair / E, b = pair % E;
        __shared__ float Rm[16][17], RInv[16][17], ssl[16][17];
        float la = ls[a*D + j], lb2 = ls[b*D + j];
        float rj = 1.f/(la*la) + 1.f/(lb2*lb2);
        float ssv = ws[OFF_SSM + i*D + j];
        ssl[i][j] = ssv;
        Rm[i][j] = ssv * rj + ((i==j) ? 1.f : 0.f);
        RInv[i][j] = (i==j) ? 1.f : 0.f;
        __syncthreads();
        float det = 1.f;
        for (int k = 0; k < D; ++k) {
            float p   = Rm[k][k];
            float fik = Rm[i][k];
            float rkj = Rm[k][j];
            float ikj = RInv[k][j];
            __syncthreads();
            det *= p;
            if (i == k) { Rm[k][j] = rkj/p; RInv[k][j] = ikj/p; }
            else        { float f = fik/p; Rm[i][j] -= f*rkj; RInv[i][j] -= f*ikj; }
            __syncthreads();
        }
        float q = 0.f;
        #pragma unroll
        for (int k2 = 0; k2 < D; ++k2) q += RInv[i][k2] * ssl[k2][j];
        ws[OFF_Q + ((size_t)pair*D + i)*D + j] = 0.5f * q;
        if (tid == 0) ws[OFF_ISDR + pair] = 1.f / sqrtf(det);
    }
}

// ---------- 3a. first diag: fast factor + blocked inverse ----------
__global__ __launch_bounds__(256) void k_diag64(float* __restrict__ ws, int k0) {
    int e = blockIdx.x;
    int tid = threadIdx.x;
    int lane = tid & 63, wv = tid >> 6;
    const float* A = ws + OFF_A + (size_t)e*N*N;
    float* W = ws + OFF_IK + (size_t)e*N*N;
    __shared__ float Lsh[64][65], Xsh[64][65];
    __shared__ float cb[2][64];
    __shared__ float invd[64];
    __shared__ float Tsh[3][16][17];
    float a[16];
    #pragma unroll
    for (int j = 0; j < 16; ++j)
        a[j] = A[(size_t)(k0 + wv*16 + j)*N + k0 + lane];
    __syncthreads();
    fact64(a, cb, invd, lane, wv);
    #pragma unroll
    for (int j = 0; j < 16; ++j) Lsh[lane][wv*16 + j] = a[j];
    __syncthreads();
    binv64(Lsh, Xsh, invd, Tsh, tid);
    for (int idx = tid; idx < 4096; idx += 256) {
        int r = idx >> 6, c = idx & 63;
        W[(size_t)(k0 + r)*N + k0 + c] = Xsh[r][c];
    }
}

// ---------- 3b. panel TRSM as GEMM: P <- P * W_kk^T (writes A + compact OFF_P) ----------
__global__ __launch_bounds__(256) void k_panelmul(float* __restrict__ ws, int k0) {
    int kk = k0 >> 6;
    int nb = (N - k0 - 64) >> 6;
    int e  = blockIdx.x / nb;
    int bi = blockIdx.x % nb;
    float* A = ws + OFF_A + (size_t)e*N*N;
    const float* W = ws + OFF_IK + (size_t)e*N*N;
    int r0 = k0 + 64 + bi*64;
    __shared__ float Ps[64][65], Wsh[64][65];
    int tid = threadIdx.x;
    load_tile4(A + (size_t)r0*N + k0, N, Ps, tid);
    load_tile4(W + (size_t)k0*N + k0, N, Wsh, tid);
    __syncthreads();
    int tx = tid & 15, ty = tid >> 4;
    float acc[4][4] = {};
    #pragma unroll 8
    for (int j = 0; j < 64; ++j) {
        float pr[4], wr[4];
        #pragma unroll
        for (int q = 0; q < 4; ++q) { pr[q] = Ps[ty*4+q][j]; wr[q] = Wsh[tx*4+q][j]; }
        #pragma unroll
        for (int q = 0; q < 4; ++q)
            #pragma unroll
            for (int w = 0; w < 4; ++w) acc[q][w] = fmaf(pr[q], wr[w], acc[q][w]);
    }
    float* Pp = ws + OFF_P + ((size_t)e*1792 + prow(kk) + (size_t)bi*64)*64;
    #pragma unroll
    for (int q = 0; q < 4; ++q)
        #pragma unroll
        for (int w = 0; w < 4; ++w) {
            A[(size_t)(r0 + ty*4 + q)*N + k0 + tx*4 + w] = acc[q][w];
            Pp[(size_t)(ty*4 + q)*64 + tx*4 + w] = acc[q][w];
        }
}

// ---------- 3c. trailing SYRK + fused fast next-diag on (0,0) ----------
__global__ __launch_bounds__(256) void k_traild(float* __restrict__ ws, int k0) {
    int t0 = k0 + 64;
    int nb = (N - t0) >> 6;
    int ntiles = (nb*(nb+1)) >> 1;
    int e = blockIdx.x / ntiles;
    int t = blockIdx.x % ntiles;
    int bj = 0; while (t >= nb - bj) { t -= nb - bj; ++bj; }
    int bi = bj + t;
    bool same = (bi == bj);
    bool isdiag0 = (bi == 0) && (bj == 0);
    float* A = ws + OFF_A + (size_t)e*N*N;
    __shared__ float Sr[64][65], Sc[64][65];
    __shared__ float cb[2][64];
    __shared__ float invd[64];
    __shared__ float Tsh[3][16][17];
    int tid = threadIdx.x;
    int tx = tid & 15, ty = tid >> 4;
    load_tile4(A + (size_t)(t0 + bi*64)*N + k0, N, Sr, tid);
    if (!same) load_tile4(A + (size_t)(t0 + bj*64)*N + k0, N, Sc, tid);
    __syncthreads();
    float acc[4][4] = {};
    if (same) {
        #pragma unroll 8
        for (int p = 0; p < 64; ++p) {
            float ar[4], ac[4];
            #pragma unroll
            for (int q = 0; q < 4; ++q) { ar[q] = Sr[ty*4+q][p]; ac[q] = Sr[tx*4+q][p]; }
            #pragma unroll
            for (int q = 0; q < 4; ++q)
                #pragma unroll
                for (int w = 0; w < 4; ++w) acc[q][w] = fmaf(ar[q], ac[w], acc[q][w]);
        }
    } else {
        #pragma unroll 8
        for (int p = 0; p < 64; ++p) {
            float ar[4], ac[4];
            #pragma unroll
            for (int q = 0; q < 4; ++q) { ar[q] = Sr[ty*4+q][p]; ac[q] = Sc[tx*4+q][p]; }
            #pragma unroll
            for (int q = 0; q < 4; ++q)
                #pragma unroll
                for (int w = 0; w < 4; ++w) acc[q][w] = fmaf(ar[q], ac[w], acc[q][w]);
        }
    }
    float* Out = A + (size_t)(t0 + bi*64)*N + (t0 + bj*64);
    if (!isdiag0) {
        #pragma unroll
        for (int q = 0; q < 4; ++q)
            #pragma unroll
            for (int w = 0; w < 4; ++w)
                Out[(size_t)(ty*4+q)*N + tx*4+w] -= acc[q][w];
        return;
    }
    __syncthreads();
    #pragma unroll
    for (int q = 0; q < 4; ++q)
        #pragma unroll
        for (int w = 0; w < 4; ++w)
            Sc[ty*4+q][tx*4+w] = Out[(size_t)(ty*4+q)*N + tx*4+w] - acc[q][w];
    __syncthreads();
    int lane = tid & 63, wv = tid >> 6;
    float a[16];
    #pragma unroll
    for (int j = 0; j < 16; ++j) a[j] = Sc[lane][wv*16 + j];   // tile symmetric
    __syncthreads();
    fact64(a, cb, invd, lane, wv);
    #pragma unroll
    for (int j = 0; j < 16; ++j) Sc[lane][wv*16 + j] = a[j];   // Sc becomes Lsh
    __syncthreads();
    binv64(Sc, Sr, invd, Tsh, tid);                            // Sr becomes Xsh
    float* W = ws + OFF_IK + (size_t)e*N*N;
    for (int idx = tid; idx < 4096; idx += 256) {
        int r = idx >> 6, c = idx & 63;
        W[(size_t)(t0 + r)*N + t0 + c] = Sr[r][c];
    }
}

// ---------- 3d. D&C level 1 (H=1): W21 = -W22 L21 W11 ----------
__global__ __launch_bounds__(256) void k_dc1(float* __restrict__ ws) {
    int e = blockIdx.x >> 2, p = blockIdx.x & 3;
    float* W = ws + OFF_IK + (size_t)e*N*N;
    const float* Lt = ws + OFF_P + ((size_t)e*1792 + prow(2*p))*64;
    __shared__ float Sa[64][65], Sb[64][65], T[64][65];
    int tid = threadIdx.x;
    int tx = tid & 15, ty = tid >> 4;
    load_tile4(Lt, 64, Sa, tid);
    load_tile4(W + (size_t)(2*p*64)*N + 2*p*64, N, Sb, tid);
    __syncthreads();
    float acc[4][4] = {};
    #pragma unroll 8
    for (int pp = 0; pp < 64; ++pp) {
        float ar[4], bc[4];
        #pragma unroll
        for (int q = 0; q < 4; ++q) { ar[q] = Sa[ty*4+q][pp]; bc[q] = Sb[pp][tx*4+q]; }
        #pragma unroll
        for (int q = 0; q < 4; ++q)
            #pragma unroll
            for (int w = 0; w < 4; ++w) acc[q][w] = fmaf(ar[q], bc[w], acc[q][w]);
    }
    #pragma unroll
    for (int q = 0; q < 4; ++q)
        #pragma unroll
        for (int w = 0; w < 4; ++w) T[ty*4+q][tx*4+w] = acc[q][w];
    __syncthreads();
    load_tile4(W + (size_t)((2*p+1)*64)*N + (2*p+1)*64, N, Sa, tid);
    __syncthreads();
    float o[4][4] = {};
    #pragma unroll 8
    for (int pp = 0; pp < 64; ++pp) {
        float ar[4], bc[4];
        #pragma unroll
        for (int q = 0; q < 4; ++q) { ar[q] = Sa[ty*4+q][pp]; bc[q] = T[pp][tx*4+q]; }
        #pragma unroll
        for (int q = 0; q < 4; ++q)
            #pragma unroll
            for (int w = 0; w < 4; ++w) o[q][w] = fmaf(ar[q], bc[w], o[q][w]);
    }
    #pragma unroll
    for (int q = 0; q < 4; ++q)
        #pragma unroll
        for (int w = 0; w < 4; ++w)
            W[(size_t)((2*p+1)*64 + ty*4 + q)*N + 2*p*64 + tx*4 + w] = -o[q][w];
}

// ---------- 3e. D&C: T = L21 * W11 (levels H=2,4) ----------
__global__ __launch_bounds__(256) void k_dcT(float* __restrict__ ws, int H) {
    int per_e = 4*H;
    int e = blockIdx.x / per_e;
    int rem = blockIdx.x % per_e;
    int p  = rem / (H*H);
    int tt = rem % (H*H);
    int ti = tt / H, tj = tt % H;
    int C0 = 2*p*H;
    int I  = C0 + H + ti;
    const float* W = ws + OFF_IK + (size_t)e*N*N;
    float* Tt = ws + OFF_T + (size_t)e*65536 + (size_t)(p*H*H + ti*H + tj)*4096;
    __shared__ float Sa[64][65], Sb[64][65];
    int tid = threadIdx.x;
    int tx = tid & 15, ty = tid >> 4;
    float acc[4][4] = {};
    for (int k = tj; k < H; ++k) {
        int K = C0 + k;
        const float* Lt = ws + OFF_P + ((size_t)e*1792 + prow(K) + (size_t)(I - K - 1)*64)*64;
        __syncthreads();
        load_tile4(Lt, 64, Sa, tid);
        load_tile4(W + (size_t)(K*64)*N + (C0 + tj)*64, N, Sb, tid);
        __syncthreads();
        #pragma unroll 8
        for (int pp = 0; pp < 64; ++pp) {
            float ar[4], bc[4];
            #pragma unroll
            for (int q = 0; q < 4; ++q) { ar[q] = Sa[ty*4+q][pp]; bc[q] = Sb[pp][tx*4+q]; }
            #pragma unroll
            for (int q = 0; q < 4; ++q)
                #pragma unroll
                for (int w = 0; w < 4; ++w) acc[q][w] = fmaf(ar[q], bc[w], acc[q][w]);
        }
    }
    #pragma unroll
    for (int q = 0; q < 4; ++q)
        #pragma unroll
        for (int w = 0; w < 4; ++w)
            Tt[(size_t)(ty*4+q)*64 + tx*4 + w] = acc[q][w];
}

// ---------- 3f. D&C: W21 = -W22 * T ----------
__global__ __launch_bounds__(256) void k_dcW(float* __restrict__ ws, int H) {
    int per_e = 4*H;
    int e = blockIdx.x / per_e;
    int rem = blockIdx.x % per_e;
    int p  = rem / (H*H);
    int tt = rem % (H*H);
    int ti = tt / H, tj = tt % H;
    int C0 = 2*p*H, R0 = C0 + H;
    float* W = ws + OFF_IK + (size_t)e*N*N;
    const float* Tbase = ws + OFF_T + (size_t)e*65536 + (size_t)(p*H*H)*4096;
    __shared__ float Sa[64][65], Sb[64][65];
    int tid = threadIdx.x;
    int tx = tid & 15, ty = tid >> 4;
    float acc[4][4] = {};
    for (int tk = 0; tk <= ti; ++tk) {
        const float* Tt = Tbase + (size_t)(tk*H + tj)*4096;
        __syncthreads();
        load_tile4(W + (size_t)((R0 + ti)*64)*N + (R0 + tk)*64, N, Sa, tid);
        load_tile4(Tt, 64, Sb, tid);
        __syncthreads();
        #pragma unroll 8
        for (int pp = 0; pp < 64; ++pp) {
            float ar[4], bc[4];
            #pragma unroll
            for (int q = 0; q < 4; ++q) { ar[q] = Sa[ty*4+q][pp]; bc[q] = Sb[pp][tx*4+q]; }
            #pragma unroll
            for (int q = 0; q < 4; ++q)
                #pragma unroll
                for (int w = 0; w < 4; ++w) acc[q][w] = fmaf(ar[q], bc[w], acc[q][w]);
        }
    }
    #pragma unroll
    for (int q = 0; q < 4; ++q)
        #pragma unroll
        for (int w = 0; w < 4; ++w)
            W[(size_t)((R0 + ti)*64 + ty*4 + q)*N + (C0 + tj)*64 + tx*4 + w] = -acc[q][w];
}

// ---------- 3g. iK = W^T W (into OFF_A, full symmetric) — float4 reg-prefetched ----------
__global__ __launch_bounds__(256) void k_syrk(float* __restrict__ ws) {
    int e = blockIdx.x / 36;
    int t = blockIdx.x % 36;
    int bj = 0; while (t >= 8 - bj) { t -= 8 - bj; ++bj; }
    int bi = bj + t;
    bool same = (bi == bj);
    const float* W = ws + OFF_IK + (size_t)e*N*N;
    float*      IK = ws + OFF_A  + (size_t)e*N*N;
    __shared__ float Sa[64][65], Sb[64][65];
    int tid = threadIdx.x;
    int tx = tid & 15, ty = tid >> 4;

    float4 pa[4], pb[4];
    #pragma unroll
    for (int j = 0; j < 4; ++j) {
        int idx = tid + j*256;
        int r = idx >> 4, c4 = idx & 15;
        pa[j] = *(const float4*)&W[(size_t)(bi*64 + r)*N + bi*64 + c4*4];
        if (!same) pb[j] = *(const float4*)&W[(size_t)(bi*64 + r)*N + bj*64 + c4*4];
    }

    float acc[4][4] = {};
    for (int p = bi; p < 8; ++p) {
        __syncthreads();
        #pragma unroll
        for (int j = 0; j < 4; ++j) {
            int idx = tid + j*256;
            int r = idx >> 4, c4 = idx & 15;
            Sa[r][c4*4+0] = pa[j].x; Sa[r][c4*4+1] = pa[j].y; Sa[r][c4*4+2] = pa[j].z; Sa[r][c4*4+3] = pa[j].w;
            if (!same) { Sb[r][c4*4+0] = pb[j].x; Sb[r][c4*4+1] = pb[j].y; Sb[r][c4*4+2] = pb[j].z; Sb[r][c4*4+3] = pb[j].w; }
        }
        if (p < 7) {
            #pragma unroll
            for (int j = 0; j < 4; ++j) {
                int idx = tid + j*256;
                int r = idx >> 4, c4 = idx & 15;
                pa[j] = *(const float4*)&W[(size_t)((p+1)*64 + r)*N + bi*64 + c4*4];
                if (!same) pb[j] = *(const float4*)&W[(size_t)((p+1)*64 + r)*N + bj*64 + c4*4];
            }
        }
        __syncthreads();
        if (same) {
            #pragma unroll 8
            for (int pr2 = 0; pr2 < 64; ++pr2) {
                float ar[4], ac[4];
                #pragma unroll
                for (int q = 0; q < 4; ++q) { ar[q] = Sa[pr2][ty*4+q]; ac[q] = Sa[pr2][tx*4+q]; }
                #pragma unroll
                for (int q = 0; q < 4; ++q)
                    #pragma unroll
                    for (int w = 0; w < 4; ++w) acc[q][w] = fmaf(ar[q], ac[w], acc[q][w]);
            }
        } else {
            #pragma unroll 8
            for (int pr2 = 0; pr2 < 64; ++pr2) {
                float ar[4], ac[4];
                #pragma unroll
                for (int q = 0; q < 4; ++q) { ar[q] = Sa[pr2][ty*4+q]; ac[q] = Sb[pr2][tx*4+q]; }
                #pragma unroll
                for (int q = 0; q < 4; ++q)
                    #pragma unroll
                    for (int w = 0; w < 4; ++w) acc[q][w] = fmaf(ar[q], ac[w], acc[q][w]);
            }
        }
    }
    #pragma unroll
    for (int q = 0; q < 4; ++q)
        #pragma unroll
        for (int w = 0; w < 4; ++w) {
            int r = bi*64 + ty*4 + q, c = bj*64 + tx*4 + w;
            IK[(size_t)r*N + c] = acc[q][w];
            IK[(size_t)c*N + r] = acc[q][w];
        }
}

// ---------- 3h. beta = iK @ Yn ----------
__global__ __launch_bounds__(256) void k_beta(float* __restrict__ ws) {
    int e = blockIdx.x >> 2, qtr = blockIdx.x & 3;
    int tid = threadIdx.x;
    int half = tid >> 7;
    int nl = tid & 127;
    int n = qtr*128 + nl;
    __shared__ float yn[N];
    __shared__ float part[2][128];
    for (int i = tid; i < N; i += 256) yn[i] = ws[OFF_YN + (size_t)e*N + i];
    __syncthreads();
    const float* IK = ws + OFF_A + (size_t)e*N*N;
    int m0 = half*256;
    float a0 = 0.f, a1 = 0.f, a2 = 0.f, a3 = 0.f;
    for (int mm = m0; mm < m0 + 256; mm += 4) {
        a0 = fmaf(IK[(size_t)mm*N + n],     yn[mm],   a0);
        a1 = fmaf(IK[(size_t)(mm+1)*N + n], yn[mm+1], a1);
        a2 = fmaf(IK[(size_t)(mm+2)*N + n], yn[mm+2], a2);
        a3 = fmaf(IK[(size_t)(mm+3)*N + n], yn[mm+3], a3);
    }
    part[half][nl] = (a0 + a1) + (a2 + a3);
    __syncthreads();
    if (tid < 128)
        ws[OFF_BETA + e*N + qtr*128 + tid] = part[0][tid] + part[1][tid];
}

// ---------- 5+6 merged: k_point (first E*N/256 blocks) and k_xs (rest) ----------
__global__ __launch_bounds__(256) void k_pxs(float* __restrict__ ws, const float* __restrict__ ls,
                                             const float* __restrict__ os) {
    int tid = threadIdx.x;
    if (blockIdx.x < E*N/256) {
        int t = blockIdx.x*256 + tid;
        int e = t >> 9, n = t & 511;
        float iN[D], tt[D], l[D];
        #pragma unroll
        for (int d = 0; d < D; ++d) { l[d] = ls[e*D + d]; iN[d] = ws[OFF_INP + n*D + d] / l[d]; }
        #pragma unroll
        for (int d = 0; d < D; ++d) {
            float acc = 0.f;
            #pragma unroll
            for (int j = 0; j < D; ++j) acc += ws[OFF_BINV + ((size_t)e*D + d)*D + j] * iN[j];
            tt[d] = acc;
        }
        float siNt = 0.f, siN2 = 0.f;
        #pragma unroll
        for (int d = 0; d < D; ++d) { siNt += iN[d]*tt[d]; siN2 += iN[d]*iN[d]; }
        float lbv = __expf(-0.5f * siNt) * ws[OFF_BETA + e*N + n];
        ws[OFF_LB + e*N + n] = lbv;
        #pragma unroll
        for (int d = 0; d < D; ++d) ws[OFF_TIL + ((size_t)e*N + n)*D + d] = tt[d] / l[d];
        ws[OFF_KVEC + e*N + n] = logf(os[e]) - 0.5f * siN2;
        return;
    }
    int t = (blockIdx.x - E*N/256)*256 + tid;
    int pair = t / N, n = t % N;
    int a = pair / E, b = pair % E;
    __shared__ float Qs[16][17];
    __shared__ float i2a[16], i2b[16];
    Qs[tid >> 4][tid & 15] = ws[OFF_Q + (size_t)pair*D*D + tid];
    if (tid < 16) { float l = ls[a*D + tid]; i2a[tid] = 1.0f/(l*l); }
    else if (tid < 32) { int d = tid-16; float l = ls[b*D + d]; i2b[d] = 1.0f/(l*l); }
    __syncthreads();
    float x1[D], x2[D];
    float siNa = 0.f, siNb = 0.f;
    #pragma unroll
    for (int d = 0; d < D; ++d) {
        float ip = ws[OFF_INP + n*D + d];
        x1[d] = ip * i2a[d];
        x2[d] = ip * i2b[d];
        siNa = fmaf(ip*ip, i2a[d], siNa);
        siNb = fmaf(ip*ip, i2b[d], siNb);
    }
    float xs1 = 0.f, xs2 = 0.f;
    #pragma unroll
    for (int j = 0; j < D; ++j) {
        float t1 = 0.f, t2 = 0.f;
        #pragma unroll
        for (int i = 0; i < D; ++i) { t1 = fmaf(x1[i], Qs[i][j], t1); t2 = fmaf(x2[i], Qs[i][j], t2); }
        xs1 = fmaf(t1, x1[j], xs1);
        xs2 = fmaf(t2, x2[j], xs2);
    }
    float loa = logf(os[a]), lob = logf(os[b]);
    ws[OFF_U + (size_t)pair*N + n] = loa - 0.5f*siNa + xs1;
    ws[OFF_V + (size_t)pair*N + n] = lob - 0.5f*siNb + xs2;
}

// ---------- 7. big cross-term: reg-prefetched B-tile + float4 iK read ----------
__global__ __launch_bounds__(256) void k_S(float* __restrict__ ws, const float* __restrict__ ls) {
    int bid = blockIdx.x;
    int pair = bid >> 3, ntile = bid & 7;
    int a = pair / E, b = pair % E;
    int tid = threadIdx.x;
    int tx = tid & 15, ty = tid >> 4;
    __shared__ float Qs[16][17];
    __shared__ float i2a[16], i2b[16];
    __shared__ float __align__(16) bufAT[16][68];
    __shared__ float __align__(16) x1qT[16][68];
    __shared__ float __align__(16) bufBT[16][68];
    __shared__ float u_s[64], v_s[64], ba_s[64], bb_s[64];
    __shared__ float red[256];
    int n0 = ntile*64;
    Qs[tid >> 4][tid & 15] = ws[OFF_Q + (size_t)pair*D*D + tid];
    if (tid < 16) { float l = ls[a*D + tid]; i2a[tid] = 1.0f/(l*l); }
    else if (tid < 32) { int d = tid-16; float l = ls[b*D + d]; i2b[d] = 1.0f/(l*l); }
    __syncthreads();
    for (int idx = tid; idx < 1024; idx += 256) {
        int r = idx >> 4, d = idx & 15;
        bufAT[d][r] = ws[OFF_INP + (size_t)(n0 + r)*D + d] * i2a[d];
    }
    __syncthreads();
    for (int idx = tid; idx < 1024; idx += 256) {
        int r = idx >> 4, j = idx & 15;
        float s = 0.f;
        #pragma unroll
        for (int i = 0; i < 16; ++i) s = fmaf(bufAT[i][r], Qs[i][j], s);
        x1qT[j][r] = s;
    }
    if (tid < 64) {
        u_s[tid]  = ws[OFF_U + (size_t)pair*N + n0 + tid];
        ba_s[tid] = ws[OFF_BETA + a*N + n0 + tid];
    }
    __syncthreads();
    float4 av4[16];
    #pragma unroll
    for (int d = 0; d < 16; ++d) av4[d] = *(const float4*)&x1qT[d][ty*4];
    float uq[4], baq[4];
    #pragma unroll
    for (int q = 0; q < 4; ++q) { uq[q] = u_s[ty*4+q]; baq[q] = ba_s[ty*4+q]; }

    float pf[4];
    #pragma unroll
    for (int j = 0; j < 4; ++j) {
        int idx = tid + j*256;
        pf[j] = ws[OFF_INP + (size_t)((idx >> 4))*D + (idx & 15)];
    }
    float vpf = 0.f, bpf = 0.f;
    if (tid < 64) {
        vpf = ws[OFF_V + (size_t)pair*N + tid];
        bpf = ws[OFF_BETA + b*N + tid];
    }

    float sacc = 0.f, tacc = 0.f;
    for (int mt = 0; mt < 8; ++mt) {
        __syncthreads();
        #pragma unroll
        for (int j = 0; j < 4; ++j) {
            int idx = tid + j*256;
            bufBT[idx & 15][idx >> 4] = pf[j] * i2b[idx & 15];
        }
        if (tid < 64) { v_s[tid] = vpf; bb_s[tid] = bpf; }
        if (mt < 7) {
            #pragma unroll
            for (int j = 0; j < 4; ++j) {
                int idx = tid + j*256;
                pf[j] = ws[OFF_INP + (size_t)((mt+1)*64 + (idx >> 4))*D + (idx & 15)];
            }
            if (tid < 64) {
                vpf = ws[OFF_V + (size_t)pair*N + (mt+1)*64 + tid];
                bpf = ws[OFF_BETA + b*N + (mt+1)*64 + tid];
            }
        }
        __syncthreads();
        float dacc[4][4] = {};
        #pragma unroll
        for (int d = 0; d < 16; ++d) {
            float4 bv = *(const float4*)&bufBT[d][tx*4];
            float4 av = av4[d];
            dacc[0][0] = fmaf(av.x, bv.x, dacc[0][0]); dacc[0][1] = fmaf(av.x, bv.y, dacc[0][1]);
            dacc[0][2] = fmaf(av.x, bv.z, dacc[0][2]); dacc[0][3] = fmaf(av.x, bv.w, dacc[0][3]);
            dacc[1][0] = fmaf(av.y, bv.x, dacc[1][0]); dacc[1][1] = fmaf(av.y, bv.y, dacc[1][1]);
            dacc[1][2] = fmaf(av.y, bv.z, dacc[1][2]); dacc[1][3] = fmaf(av.y, bv.w, dacc[1][3]);
            dacc[2][0] = fmaf(av.z, bv.x, dacc[2][0]); dacc[2][1] = fmaf(av.z, bv.y, dacc[2][1]);
            dacc[2][2] = fmaf(av.z, bv.z, dacc[2][2]); dacc[2][3] = fmaf(av.z, bv.w, dacc[2][3]);
            dacc[3][0] = fmaf(av.w, bv.x, dacc[3][0]); dacc[3][1] = fmaf(av.w, bv.y, dacc[3][1]);
            dacc[3][2] = fmaf(av.w, bv.z, dacc[3][2]); dacc[3][3] = fmaf(av.w, bv.w, dacc[3][3]);
        }
        #pragma unroll
        for (int q = 0; q < 4; ++q) {
            float ikq[4];
            if (a == b)
                *(float4*)ikq = *(const float4*)&ws[OFF_A + ((size_t)a*N + n0 + ty*4 + q)*N + mt*64 + tx*4];
            #pragma unroll
            for (int w = 0; w < 4; ++w) {
                float Lv = __expf(2.f*dacc[q][w] + uq[q] + v_s[tx*4+w]);
                sacc = fmaf(baq[q] * bb_s[tx*4+w], Lv, sacc);
                if (a == b)
                    tacc = fmaf(ikq[w], Lv, tacc);
            }
        }
    }
    red[tid] = sacc; __syncthreads();
    for (int o = 128; o > 0; o >>= 1) { if (tid < o) red[tid] += red[tid+o]; __syncthreads(); }
    if (tid == 0) ws[OFF_SPART + bid] = red[0];
    if (a == b) {
        __syncthreads();
        red[tid] = tacc; __syncthreads();
        for (int o = 128; o > 0; o >>= 1) { if (tid < o) red[tid] += red[tid+o]; __syncthreads(); }
        if (tid == 0) ws[OFF_TPART + a*8 + ntile] = red[0];
    }
}

// ---------- 8. finalize ----------
__global__ __launch_bounds__(256) void k_final(float* __restrict__ ws, const float* __restrict__ s,
                                               const float* __restrict__ os, float* __restrict__ out) {
    int tid = threadIdx.x;
    __shared__ float Msh[E], Vsh[E][D], cov[D][E+1];
    __shared__ float Sm[16][17], Si[16][17];
    __shared__ float vred[16][17];

    {
        int wv = tid >> 6, lane = tid & 63;
        for (int e = wv; e < E; e += 4) {
            float sum = 0.f;
            #pragma unroll
            for (int i = 0; i < 8; ++i) sum += ws[OFF_LB + e*N + i*64 + lane];
            #pragma unroll
            for (int off = 32; off > 0; off >>= 1) sum += __shfl_xor(sum, off);
            if (lane == 0) Msh[e] = ws[OFF_C + e] * sum;
        }
    }
    for (int e = 0; e < E; ++e) {
        int d = tid & 15, sl = tid >> 4;
        float acc = 0.f;
        for (int i = 0; i < 32; ++i) {
            int n = sl*32 + i;
            acc = fmaf(ws[OFF_TIL + ((size_t)e*N + n)*D + d], ws[OFF_LB + e*N + n], acc);
        }
        vred[sl][d] = acc;
        __syncthreads();
        if (tid < 16) {
            float sum = 0.f;
            #pragma unroll
            for (int s2 = 0; s2 < 16; ++s2) sum += vred[s2][tid];
            Vsh[e][tid] = ws[OFF_C + e] * sum;
        }
        __syncthreads();
    }

    if (tid < E*E) {
        int a = tid / E, bb = tid % E;
        float acc = 0.f;
        for (int q = 0; q < 8; ++q) acc += ws[OFF_SPART + (size_t)tid*8 + q];
        if (a == bb) {
            float tr = 0.f;
            for (int q = 0; q < 8; ++q) tr += ws[OFF_TPART + a*8 + q];
            acc -= tr;
        }
        acc *= ws[OFF_ISDR + tid];
        if (a == bb) acc += os[a];
        float v = acc - Msh[a]*Msh[bb];
        v *= ws[OFF_YSTD + a] * ws[OFF_YSTD + bb];
        out[E + tid] = v;
    }
    if (tid < E) out[tid] = Msh[tid]*ws[OFF_YSTD + tid] + ws[OFF_YMEAN + tid];

    if (tid < D*E) {
        int d = tid / E, e = tid % E;
        float acc = 0.f;
        for (int k = 0; k < D; ++k) acc += ws[OFF_SSM + d*D + k] * Vsh[e][k];
        cov[d][e] = acc * ws[OFF_XSTD + d] * ws[OFF_YSTD + e];
    }
    int i = tid >> 4, j = tid & 15;
    Sm[i][j] = s[i*D + j];
    Si[i][j] = (i==j) ? 1.f : 0.f;
    __syncthreads();
    for (int k = 0; k < D; ++k) {
        float p   = Sm[k][k];
        float fik = Sm[i][k];
        float skj = Sm[k][j];
        float ikj = Si[k][j];
        __syncthreads();
        if (i == k) { Sm[k][j] = skj/p; Si[k][j] = ikj/p; }
        else        { float f = fik/p; Sm[i][j] -= f*skj; Si[i][j] -= f*ikj; }
        __syncthreads();
    }
    if (tid < D*E) {
        int d = tid / E, e = tid % E;
        float acc = 0.f;
        for (int k = 0; k < D; ++k) acc += Si[d][k] * cov[k][e];
        out[E + E*E + d*E + e] = acc;
    }
}

extern "C" void kernel_launch(void* const* d_in, const int* in_sizes, int n_in,
                              void* d_out, int out_size, void* d_ws, size_t ws_size,
                              hipStream_t stream) {
    const float* X     = (const float*)d_in[0];
    const float* Y     = (const float*)d_in[1];
    const float* m     = (const float*)d_in[2];
    const float* s     = (const float*)d_in[3];
    const float* ls    = (const float*)d_in[4];
    const float* os    = (const float*)d_in[5];
    const float* noise = (const float*)d_in[6];
    float* ws  = (float*)d_ws;
    float* out = (float*)d_out;

    k_prep   <<<1,              512, 0, stream>>>(X, Y, m, s, ws);
    k_buildA <<<E*64 + E + E*E, 256, 0, stream>>>(ws, ls, os, noise);
    k_diag64 <<<E,              256, 0, stream>>>(ws, 0);
    for (int kk = 0; kk < 7; ++kk) {
        int k0 = kk*64;
        int nb = 7 - kk;
        k_panelmul<<<E*nb,          256, 0, stream>>>(ws, k0);
        k_traild  <<<E*nb*(nb+1)/2, 256, 0, stream>>>(ws, k0);
    }
    k_dc1 <<<E*4,  256, 0, stream>>>(ws);
    k_dcT <<<E*8,  256, 0, stream>>>(ws, 2);
    k_dcW <<<E*8,  256, 0, stream>>>(ws, 2);
    k_dcT <<<E*16, 256, 0, stream>>>(ws, 4);
    k_dcW <<<E*16, 256, 0, stream>>>(ws, 4);
    k_syrk <<<E*36,               256, 0, stream>>>(ws);
    k_beta <<<E*4,                256, 0, stream>>>(ws);
    k_pxs  <<<E*N/256 + E*E*N/256,256, 0, stream>>>(ws, ls, os);
    k_S    <<<E*E*8,              256, 0, stream>>>(ws, ls);
    k_final<<<1,                  256, 0, stream>>>(ws, s, os, out);
}

// Round 17
// 522.417 us; speedup vs baseline: 1.6335x; 1.0242x over previous
//
#include <hip/hip_runtime.h>
#include <math.h>

constexpr int N = 512;
constexpr int D = 16;
constexpr int E = 12;
constexpr int NPAIR = E*(E+1)/2;   // 78 compact pairs (a<=b)

// ---- workspace layout (float offsets) ----
constexpr size_t OFF_A     = 0;                            // E*N*N  A -> trail -> iK
constexpr size_t OFF_IK    = OFF_A    + (size_t)E*N*N;     // E*N*N  W = L^{-1}
constexpr size_t OFF_XS    = OFF_IK   + (size_t)E*N*N;     // N*D
constexpr size_t OFF_INP   = OFF_XS   + (size_t)N*D;       // N*D
constexpr size_t OFF_YN    = OFF_INP  + (size_t)N*D;       // E*N
constexpr size_t OFF_BETA  = OFF_YN   + (size_t)E*N;       // E*N
constexpr size_t OFF_KVEC  = OFF_BETA + (size_t)E*N;       // E*N
constexpr size_t OFF_LB    = OFF_KVEC + (size_t)E*N;       // E*N
constexpr size_t OFF_TIL   = OFF_LB   + (size_t)E*N;       // E*N*D
constexpr size_t OFF_U     = OFF_TIL  + (size_t)E*N*D;     // NPAIR*N (compact)
constexpr size_t OFF_V     = OFF_U    + (size_t)E*E*N;     // NPAIR*N (compact)
constexpr size_t OFF_Q     = OFF_V    + (size_t)E*E*N;     // E*E*D*D
constexpr size_t OFF_BINV  = OFF_Q    + (size_t)E*E*D*D;   // E*D*D
constexpr size_t OFF_C     = OFF_BINV + (size_t)E*D*D;     // E
constexpr size_t OFF_ISDR  = OFF_C    + E;                 // E*E
constexpr size_t OFF_SPART = OFF_ISDR + E*E;               // NPAIR*8
constexpr size_t OFF_TPART = OFF_SPART+ (size_t)E*E*8;     // E*8
constexpr size_t OFF_XMEAN = OFF_TPART+ (size_t)E*8;       // D
constexpr size_t OFF_XSTD  = OFF_XMEAN+ D;                 // D
constexpr size_t OFF_YMEAN = OFF_XSTD + D;                 // E
constexpr size_t OFF_YSTD  = OFF_YMEAN+ E;                 // E
constexpr size_t OFF_SSM   = OFF_YSTD + E;                 // D*D
constexpr size_t OFF_P     = OFF_SSM  + D*D;               // E*1792*64  (L panels, compact)
constexpr size_t OFF_T     = OFF_P    + (size_t)E*1792*64; // E*65536    (D&C scratch)

__device__ __forceinline__ int prow(int k) { return k*(480 - 32*k); }  // row offset of panel k

// compact pair index helpers (a<=b)
__device__ __forceinline__ void pc2ab(int pc, int& a, int& b) {
    int aa = 0, t = pc;
    while (t >= E - aa) { t -= E - aa; ++aa; }
    a = aa; b = aa + t;
}
__device__ __forceinline__ int ab2pc(int a, int b) {       // requires a<=b
    return a*E - (a*(a-1))/2 + (b - a);
}

// ======== fast 64x64 Cholesky: column-split registers, 1 barrier/step, no spill ========
__device__ __forceinline__ void fact64(float a[16], float (*cb)[64], float* invd, int lane, int wv) {
    #pragma unroll
    for (int k = 0; k < 64; ++k) {
        const int kg = k >> 4, kj = k & 15;
        if (wv == kg) {
            float dkk = __shfl(a[kj], k);
            float dv = sqrtf(dkk);
            float iv = 1.0f / dv;
            float sc = a[kj] * iv;
            if (lane == k)      { a[kj] = dv; invd[k] = iv; }
            else if (lane > k)  a[kj] = sc;
            cb[k & 1][lane] = (lane > k) ? a[kj] : 0.0f;
        }
        __syncthreads();
        float lrk = cb[k & 1][lane];
        #pragma unroll
        for (int j = 0; j < 16; ++j)
            a[j] = fmaf(-lrk, cb[k & 1][wv*16 + j], a[j]);
    }
}

// ======== blocked in-LDS 64x64 triangular inverse: short critical path ========
__device__ __forceinline__ void binv64(const float (*Lsh)[65], float (*Xsh)[65],
                                       const float* invd, float (*Tsh)[16][17], int tid) {
    if (tid < 64) {
        int g = tid >> 4, c = tid & 15;
        int b = g*16;
        for (int r = 0; r < c; ++r) Xsh[b+r][b+c] = 0.f;
        for (int r = c; r < 16; ++r) {
            float acc = (r == c) ? 1.0f : 0.0f;
            for (int k = c; k < r; ++k)
                acc = fmaf(-Lsh[b+r][b+k], Xsh[b+k][b+c], acc);
            Xsh[b+r][b+c] = acc * invd[b+r];
        }
    } else {
        const int bis[6] = {0,0,0,1,1,2};
        const int bjs[6] = {1,2,3,2,3,3};
        for (int idx = tid - 64; idx < 1536; idx += 192) {
            int blk = idx >> 8, off = idx & 255;
            Xsh[bis[blk]*16 + (off >> 4)][bjs[blk]*16 + (off & 15)] = 0.f;
        }
    }
    __syncthreads();
    for (int d = 1; d <= 3; ++d) {
        int np = 4 - d;
        for (int idx = tid; idx < np*256; idx += 256) {
            int p = idx >> 8, off = idx & 255;
            int r = off >> 4, c = off & 15;
            int i = p + d, j = p;
            float acc = 0.f;
            for (int k = j; k < i; ++k)
                #pragma unroll
                for (int m = 0; m < 16; ++m)
                    acc = fmaf(Lsh[i*16+r][k*16+m], Xsh[k*16+m][j*16+c], acc);
            Tsh[p][r][c] = acc;
        }
        __syncthreads();
        for (int idx = tid; idx < np*256; idx += 256) {
            int p = idx >> 8, off = idx & 255;
            int r = off >> 4, c = off & 15;
            int i = p + d, j = p;
            float acc = 0.f;
            #pragma unroll
            for (int m = 0; m < 16; ++m)
                acc = fmaf(Xsh[i*16+r][i*16+m], Tsh[p][m][c], acc);
            Xsh[i*16+r][j*16+c] = -acc;
        }
        __syncthreads();
    }
}

// ======== vectorized 64x64 tile load ========
__device__ __forceinline__ void load_tile4(const float* __restrict__ g, size_t ldg,
                                           float (*S)[65], int tid) {
    #pragma unroll
    for (int j = 0; j < 4; ++j) {
        int idx = tid + j*256;
        int r = idx >> 4, c4 = idx & 15;
        float4 v = *(const float4*)&g[(size_t)r*ldg + c4*4];
        S[r][c4*4+0] = v.x; S[r][c4*4+1] = v.y; S[r][c4*4+2] = v.z; S[r][c4*4+3] = v.w;
    }
}

// ---------- 1. standardization ----------
__global__ __launch_bounds__(512) void k_prep(const float* __restrict__ X, const float* __restrict__ Y,
                                              const float* __restrict__ m, const float* __restrict__ s,
                                              float* __restrict__ ws) {
    int tid = threadIdx.x;
    int lane = tid & 63, wave = tid >> 6;
    __shared__ float meanX[D], stdX[D], meanY[E], stdY[E], mmsh[D];

    for (int col = wave; col < D + E; col += 8) {
        float s1 = 0.f, s2 = 0.f;
        if (col < D) {
            #pragma unroll
            for (int i = 0; i < 8; ++i) { float v = X[(i*64 + lane)*D + col]; s1 += v; s2 += v*v; }
        } else {
            int e = col - D;
            #pragma unroll
            for (int i = 0; i < 8; ++i) { float v = Y[(i*64 + lane)*E + e]; s1 += v; s2 += v*v; }
        }
        #pragma unroll
        for (int off = 32; off > 0; off >>= 1) { s1 += __shfl_xor(s1, off); s2 += __shfl_xor(s2, off); }
        if (lane == 0) {
            float mean = s1 * (1.0f/N);
            float var  = (s2 - (float)N*mean*mean) * (1.0f/(N-1));
            float sd   = sqrtf(var);
            if (col < D) { meanX[col] = mean; stdX[col] = sd; }
            else         { meanY[col-D] = mean; stdY[col-D] = sd; }
        }
    }
    __syncthreads();
    if (tid < D) {
        mmsh[tid] = (m[tid] - meanX[tid]) / stdX[tid];
        ws[OFF_XMEAN + tid] = meanX[tid];
        ws[OFF_XSTD  + tid] = stdX[tid];
    }
    if (tid < E) { ws[OFF_YMEAN + tid] = meanY[tid]; ws[OFF_YSTD + tid] = stdY[tid]; }
    __syncthreads();
    int n = tid;
    #pragma unroll
    for (int d = 0; d < D; ++d) {
        float xs = (X[n*D + d] - meanX[d]) / stdX[d];
        ws[OFF_XS  + n*D + d] = xs;
        ws[OFF_INP + n*D + d] = xs - mmsh[d];
    }
    #pragma unroll
    for (int e = 0; e < E; ++e)
        ws[OFF_YN + e*N + n] = (Y[n*E + e] - meanY[e]) / stdY[e];
    if (tid < D*D) {
        int i = tid / D, j = tid % D;
        ws[OFF_SSM + tid] = s[tid] / (stdX[i] * stdX[j]);
    }
}

// ---------- 2. A = K + noise I  +  appended B/R inverse blocks ----------
__global__ __launch_bounds__(256) void k_buildA(float* __restrict__ ws, const float* __restrict__ ls,
                                                const float* __restrict__ os, const float* __restrict__ noise) {
    int bid = blockIdx.x;
    int tid = threadIdx.x;
    if (bid < E*64) {
        int e  = bid >> 6;
        int t  = bid & 63;
        int bn = t >> 3, bm = t & 7;
        __shared__ float xn[64][17], xm[64][17];
        __shared__ float il2[16];
        for (int idx = tid; idx < 1024; idx += 256) {
            int r = idx >> 4, d0 = idx & 15;
            xn[r][d0] = ws[OFF_XS + (size_t)(bn*64 + r)*D + d0];
            xm[r][d0] = ws[OFF_XS + (size_t)(bm*64 + r)*D + d0];
        }
        if (tid < 16) { float l = ls[e*D + tid]; il2[tid] = 1.0f/(l*l); }
        __syncthreads();
        int tx = tid & 15, ty = tid >> 4;
        float osv = os[e], nsv = noise[e];
        float acc[4][4] = {};
        #pragma unroll
        for (int d = 0; d < 16; ++d) {
            float il = il2[d];
            float an[4], am[4];
            #pragma unroll
            for (int q = 0; q < 4; ++q) { an[q] = xn[ty + q*16][d]; am[q] = xm[tx + q*16][d]; }
            #pragma unroll
            for (int q = 0; q < 4; ++q)
                #pragma unroll
                for (int w = 0; w < 4; ++w) { float df = an[q] - am[w]; acc[q][w] = fmaf(df*df, il, acc[q][w]); }
        }
        float* A = ws + OFF_A + (size_t)e*N*N;
        #pragma unroll
        for (int q = 0; q < 4; ++q)
            #pragma unroll
            for (int w = 0; w < 4; ++w) {
                int nr = bn*64 + ty + q*16, mc = bm*64 + tx + w*16;
                float v = osv * __expf(-0.5f * acc[q][w]);
                if (nr == mc) v += nsv;
                A[(size_t)nr*N + mc] = v;
            }
        return;
    }
    int bidx = bid - E*64;
    int i = tid >> 4, j = tid & 15;
    if (bidx < E) {
        int e = bidx;
        __shared__ float Bm[16][17], BInv[16][17];
        float li = ls[e*D + i], lj = ls[e*D + j];
        Bm[i][j] = ws[OFF_SSM + i*D + j] / (li*lj) + ((i==j) ? 1.f : 0.f);
        BInv[i][j] = (i==j) ? 1.f : 0.f;
        __syncthreads();
        float det = 1.f;
        for (int k = 0; k < D; ++k) {
            float p   = Bm[k][k];
            float fik = Bm[i][k];
            float bkj = Bm[k][j];
            float ikj = BInv[k][j];
            __syncthreads();
            det *= p;
            if (i == k) { Bm[k][j] = bkj/p; BInv[k][j] = ikj/p; }
            else        { float f = fik/p; Bm[i][j] -= f*bkj; BInv[i][j] -= f*ikj; }
            __syncthreads();
        }
        ws[OFF_BINV + ((size_t)e*D + i)*D + j] = BInv[i][j];
        if (tid == 0) ws[OFF_C + e] = os[e] / sqrtf(det);
    } else {
        int pair = bidx - E;
        int a = pair / E, b = pair % E;
        __shared__ float Rm[16][17], RInv[16][17], ssl[16][17];
        float la = ls[a*D + j], lb2 = ls[b*D + j];
        float rj = 1.f/(la*la) + 1.f/(lb2*lb2);
        float ssv = ws[OFF_SSM + i*D + j];
        ssl[i][j] = ssv;
        Rm[i][j] = ssv * rj + ((i==j) ? 1.f : 0.f);
        RInv[i][j] = (i==j) ? 1.f : 0.f;
        __syncthreads();
        float det = 1.f;
        for (int k = 0; k < D; ++k) {
            float p   = Rm[k][k];
            float fik = Rm[i][k];
            float rkj = Rm[k][j];
            float ikj = RInv[k][j];
            __syncthreads();
            det *= p;
            if (i == k) { Rm[k][j] = rkj/p; RInv[k][j] = ikj/p; }
            else        { float f = fik/p; Rm[i][j] -= f*rkj; RInv[i][j] -= f*ikj; }
            __syncthreads();
        }
        float q = 0.f;
        #pragma unroll
        for (int k2 = 0; k2 < D; ++k2) q += RInv[i][k2] * ssl[k2][j];
        ws[OFF_Q + ((size_t)pair*D + i)*D + j] = 0.5f * q;
        if (tid == 0) ws[OFF_ISDR + pair] = 1.f / sqrtf(det);
    }
}

// ---------- 3a. first diag: fast factor + blocked inverse ----------
__global__ __launch_bounds__(256) void k_diag64(float* __restrict__ ws, int k0) {
    int e = blockIdx.x;
    int tid = threadIdx.x;
    int lane = tid & 63, wv = tid >> 6;
    const float* A = ws + OFF_A + (size_t)e*N*N;
    float* W = ws + OFF_IK + (size_t)e*N*N;
    __shared__ float Lsh[64][65], Xsh[64][65];
    __shared__ float cb[2][64];
    __shared__ float invd[64];
    __shared__ float Tsh[3][16][17];
    float a[16];
    #pragma unroll
    for (int j = 0; j < 16; ++j)
        a[j] = A[(size_t)(k0 + wv*16 + j)*N + k0 + lane];
    __syncthreads();
    fact64(a, cb, invd, lane, wv);
    #pragma unroll
    for (int j = 0; j < 16; ++j) Lsh[lane][wv*16 + j] = a[j];
    __syncthreads();
    binv64(Lsh, Xsh, invd, Tsh, tid);
    for (int idx = tid; idx < 4096; idx += 256) {
        int r = idx >> 6, c = idx & 63;
        W[(size_t)(k0 + r)*N + k0 + c] = Xsh[r][c];
    }
}

// ---------- 3b. panel TRSM as GEMM: P <- P * W_kk^T (writes A + compact OFF_P) ----------
__global__ __launch_bounds__(256) void k_panelmul(float* __restrict__ ws, int k0) {
    int kk = k0 >> 6;
    int nb = (N - k0 - 64) >> 6;
    int e  = blockIdx.x / nb;
    int bi = blockIdx.x % nb;
    float* A = ws + OFF_A + (size_t)e*N*N;
    const float* W = ws + OFF_IK + (size_t)e*N*N;
    int r0 = k0 + 64 + bi*64;
    __shared__ float Ps[64][65], Wsh[64][65];
    int tid = threadIdx.x;
    load_tile4(A + (size_t)r0*N + k0, N, Ps, tid);
    load_tile4(W + (size_t)k0*N + k0, N, Wsh, tid);
    __syncthreads();
    int tx = tid & 15, ty = tid >> 4;
    float acc[4][4] = {};
    #pragma unroll 8
    for (int j = 0; j < 64; ++j) {
        float pr[4], wr[4];
        #pragma unroll
        for (int q = 0; q < 4; ++q) { pr[q] = Ps[ty*4+q][j]; wr[q] = Wsh[tx*4+q][j]; }
        #pragma unroll
        for (int q = 0; q < 4; ++q)
            #pragma unroll
            for (int w = 0; w < 4; ++w) acc[q][w] = fmaf(pr[q], wr[w], acc[q][w]);
    }
    float* Pp = ws + OFF_P + ((size_t)e*1792 + prow(kk) + (size_t)bi*64)*64;
    #pragma unroll
    for (int q = 0; q < 4; ++q)
        #pragma unroll
        for (int w = 0; w < 4; ++w) {
            A[(size_t)(r0 + ty*4 + q)*N + k0 + tx*4 + w] = acc[q][w];
            Pp[(size_t)(ty*4 + q)*64 + tx*4 + w] = acc[q][w];
        }
}

// ---------- 3c. trailing SYRK + fused fast next-diag on (0,0) ----------
__global__ __launch_bounds__(256) void k_traild(float* __restrict__ ws, int k0) {
    int t0 = k0 + 64;
    int nb = (N - t0) >> 6;
    int ntiles = (nb*(nb+1)) >> 1;
    int e = blockIdx.x / ntiles;
    int t = blockIdx.x % ntiles;
    int bj = 0; while (t >= nb - bj) { t -= nb - bj; ++bj; }
    int bi = bj + t;
    bool same = (bi == bj);
    bool isdiag0 = (bi == 0) && (bj == 0);
    float* A = ws + OFF_A + (size_t)e*N*N;
    __shared__ float Sr[64][65], Sc[64][65];
    __shared__ float cb[2][64];
    __shared__ float invd[64];
    __shared__ float Tsh[3][16][17];
    int tid = threadIdx.x;
    int tx = tid & 15, ty = tid >> 4;
    load_tile4(A + (size_t)(t0 + bi*64)*N + k0, N, Sr, tid);
    if (!same) load_tile4(A + (size_t)(t0 + bj*64)*N + k0, N, Sc, tid);
    __syncthreads();
    float acc[4][4] = {};
    if (same) {
        #pragma unroll 8
        for (int p = 0; p < 64; ++p) {
            float ar[4], ac[4];
            #pragma unroll
            for (int q = 0; q < 4; ++q) { ar[q] = Sr[ty*4+q][p]; ac[q] = Sr[tx*4+q][p]; }
            #pragma unroll
            for (int q = 0; q < 4; ++q)
                #pragma unroll
                for (int w = 0; w < 4; ++w) acc[q][w] = fmaf(ar[q], ac[w], acc[q][w]);
        }
    } else {
        #pragma unroll 8
        for (int p = 0; p < 64; ++p) {
            float ar[4], ac[4];
            #pragma unroll
            for (int q = 0; q < 4; ++q) { ar[q] = Sr[ty*4+q][p]; ac[q] = Sc[tx*4+q][p]; }
            #pragma unroll
            for (int q = 0; q < 4; ++q)
                #pragma unroll
                for (int w = 0; w < 4; ++w) acc[q][w] = fmaf(ar[q], ac[w], acc[q][w]);
        }
    }
    float* Out = A + (size_t)(t0 + bi*64)*N + (t0 + bj*64);
    if (!isdiag0) {
        #pragma unroll
        for (int q = 0; q < 4; ++q)
            #pragma unroll
            for (int w = 0; w < 4; ++w)
                Out[(size_t)(ty*4+q)*N + tx*4+w] -= acc[q][w];
        return;
    }
    __syncthreads();
    #pragma unroll
    for (int q = 0; q < 4; ++q)
        #pragma unroll
        for (int w = 0; w < 4; ++w)
            Sc[ty*4+q][tx*4+w] = Out[(size_t)(ty*4+q)*N + tx*4+w] - acc[q][w];
    __syncthreads();
    int lane = tid & 63, wv = tid >> 6;
    float a[16];
    #pragma unroll
    for (int j = 0; j < 16; ++j) a[j] = Sc[lane][wv*16 + j];   // tile symmetric
    __syncthreads();
    fact64(a, cb, invd, lane, wv);
    #pragma unroll
    for (int j = 0; j < 16; ++j) Sc[lane][wv*16 + j] = a[j];   // Sc becomes Lsh
    __syncthreads();
    binv64(Sc, Sr, invd, Tsh, tid);                            // Sr becomes Xsh
    float* W = ws + OFF_IK + (size_t)e*N*N;
    for (int idx = tid; idx < 4096; idx += 256) {
        int r = idx >> 6, c = idx & 63;
        W[(size_t)(t0 + r)*N + t0 + c] = Sr[r][c];
    }
}

// ---------- 3d. D&C level 1 (H=1): W21 = -W22 L21 W11 ----------
__global__ __launch_bounds__(256) void k_dc1(float* __restrict__ ws) {
    int e = blockIdx.x >> 2, p = blockIdx.x & 3;
    float* W = ws + OFF_IK + (size_t)e*N*N;
    const float* Lt = ws + OFF_P + ((size_t)e*1792 + prow(2*p))*64;
    __shared__ float Sa[64][65], Sb[64][65], T[64][65];
    int tid = threadIdx.x;
    int tx = tid & 15, ty = tid >> 4;
    load_tile4(Lt, 64, Sa, tid);
    load_tile4(W + (size_t)(2*p*64)*N + 2*p*64, N, Sb, tid);
    __syncthreads();
    float acc[4][4] = {};
    #pragma unroll 8
    for (int pp = 0; pp < 64; ++pp) {
        float ar[4], bc[4];
        #pragma unroll
        for (int q = 0; q < 4; ++q) { ar[q] = Sa[ty*4+q][pp]; bc[q] = Sb[pp][tx*4+q]; }
        #pragma unroll
        for (int q = 0; q < 4; ++q)
            #pragma unroll
            for (int w = 0; w < 4; ++w) acc[q][w] = fmaf(ar[q], bc[w], acc[q][w]);
    }
    #pragma unroll
    for (int q = 0; q < 4; ++q)
        #pragma unroll
        for (int w = 0; w < 4; ++w) T[ty*4+q][tx*4+w] = acc[q][w];
    __syncthreads();
    load_tile4(W + (size_t)((2*p+1)*64)*N + (2*p+1)*64, N, Sa, tid);
    __syncthreads();
    float o[4][4] = {};
    #pragma unroll 8
    for (int pp = 0; pp < 64; ++pp) {
        float ar[4], bc[4];
        #pragma unroll
        for (int q = 0; q < 4; ++q) { ar[q] = Sa[ty*4+q][pp]; bc[q] = T[pp][tx*4+q]; }
        #pragma unroll
        for (int q = 0; q < 4; ++q)
            #pragma unroll
            for (int w = 0; w < 4; ++w) o[q][w] = fmaf(ar[q], bc[w], o[q][w]);
    }
    #pragma unroll
    for (int q = 0; q < 4; ++q)
        #pragma unroll
        for (int w = 0; w < 4; ++w)
            W[(size_t)((2*p+1)*64 + ty*4 + q)*N + 2*p*64 + tx*4 + w] = -o[q][w];
}

// ---------- 3e. D&C: T = L21 * W11 (levels H=2,4) ----------
__global__ __launch_bounds__(256) void k_dcT(float* __restrict__ ws, int H) {
    int per_e = 4*H;
    int e = blockIdx.x / per_e;
    int rem = blockIdx.x % per_e;
    int p  = rem / (H*H);
    int tt = rem % (H*H);
    int ti = tt / H, tj = tt % H;
    int C0 = 2*p*H;
    int I  = C0 + H + ti;
    const float* W = ws + OFF_IK + (size_t)e*N*N;
    float* Tt = ws + OFF_T + (size_t)e*65536 + (size_t)(p*H*H + ti*H + tj)*4096;
    __shared__ float Sa[64][65], Sb[64][65];
    int tid = threadIdx.x;
    int tx = tid & 15, ty = tid >> 4;
    float acc[4][4] = {};
    for (int k = tj; k < H; ++k) {
        int K = C0 + k;
        const float* Lt = ws + OFF_P + ((size_t)e*1792 + prow(K) + (size_t)(I - K - 1)*64)*64;
        __syncthreads();
        load_tile4(Lt, 64, Sa, tid);
        load_tile4(W + (size_t)(K*64)*N + (C0 + tj)*64, N, Sb, tid);
        __syncthreads();
        #pragma unroll 8
        for (int pp = 0; pp < 64; ++pp) {
            float ar[4], bc[4];
            #pragma unroll
            for (int q = 0; q < 4; ++q) { ar[q] = Sa[ty*4+q][pp]; bc[q] = Sb[pp][tx*4+q]; }
            #pragma unroll
            for (int q = 0; q < 4; ++q)
                #pragma unroll
                for (int w = 0; w < 4; ++w) acc[q][w] = fmaf(ar[q], bc[w], acc[q][w]);
        }
    }
    #pragma unroll
    for (int q = 0; q < 4; ++q)
        #pragma unroll
        for (int w = 0; w < 4; ++w)
            Tt[(size_t)(ty*4+q)*64 + tx*4 + w] = acc[q][w];
}

// ---------- 3f. D&C: W21 = -W22 * T ----------
__global__ __launch_bounds__(256) void k_dcW(float* __restrict__ ws, int H) {
    int per_e = 4*H;
    int e = blockIdx.x / per_e;
    int rem = blockIdx.x % per_e;
    int p  = rem / (H*H);
    int tt = rem % (H*H);
    int ti = tt / H, tj = tt % H;
    int C0 = 2*p*H, R0 = C0 + H;
    float* W = ws + OFF_IK + (size_t)e*N*N;
    const float* Tbase = ws + OFF_T + (size_t)e*65536 + (size_t)(p*H*H)*4096;
    __shared__ float Sa[64][65], Sb[64][65];
    int tid = threadIdx.x;
    int tx = tid & 15, ty = tid >> 4;
    float acc[4][4] = {};
    for (int tk = 0; tk <= ti; ++tk) {
        const float* Tt = Tbase + (size_t)(tk*H + tj)*4096;
        __syncthreads();
        load_tile4(W + (size_t)((R0 + ti)*64)*N + (R0 + tk)*64, N, Sa, tid);
        load_tile4(Tt, 64, Sb, tid);
        __syncthreads();
        #pragma unroll 8
        for (int pp = 0; pp < 64; ++pp) {
            float ar[4], bc[4];
            #pragma unroll
            for (int q = 0; q < 4; ++q) { ar[q] = Sa[ty*4+q][pp]; bc[q] = Sb[pp][tx*4+q]; }
            #pragma unroll
            for (int q = 0; q < 4; ++q)
                #pragma unroll
                for (int w = 0; w < 4; ++w) acc[q][w] = fmaf(ar[q], bc[w], acc[q][w]);
        }
    }
    #pragma unroll
    for (int q = 0; q < 4; ++q)
        #pragma unroll
        for (int w = 0; w < 4; ++w)
            W[(size_t)((R0 + ti)*64 + ty*4 + q)*N + (C0 + tj)*64 + tx*4 + w] = -acc[q][w];
}

// ---------- 3g. iK = W^T W (into OFF_A, full symmetric) — float4 reg-prefetched ----------
__global__ __launch_bounds__(256) void k_syrk(float* __restrict__ ws) {
    int e = blockIdx.x / 36;
    int t = blockIdx.x % 36;
    int bj = 0; while (t >= 8 - bj) { t -= 8 - bj; ++bj; }
    int bi = bj + t;
    bool same = (bi == bj);
    const float* W = ws + OFF_IK + (size_t)e*N*N;
    float*      IK = ws + OFF_A  + (size_t)e*N*N;
    __shared__ float Sa[64][65], Sb[64][65];
    int tid = threadIdx.x;
    int tx = tid & 15, ty = tid >> 4;

    float4 pa[4], pb[4];
    #pragma unroll
    for (int j = 0; j < 4; ++j) {
        int idx = tid + j*256;
        int r = idx >> 4, c4 = idx & 15;
        pa[j] = *(const float4*)&W[(size_t)(bi*64 + r)*N + bi*64 + c4*4];
        if (!same) pb[j] = *(const float4*)&W[(size_t)(bi*64 + r)*N + bj*64 + c4*4];
    }

    float acc[4][4] = {};
    for (int p = bi; p < 8; ++p) {
        __syncthreads();
        #pragma unroll
        for (int j = 0; j < 4; ++j) {
            int idx = tid + j*256;
            int r = idx >> 4, c4 = idx & 15;
            Sa[r][c4*4+0] = pa[j].x; Sa[r][c4*4+1] = pa[j].y; Sa[r][c4*4+2] = pa[j].z; Sa[r][c4*4+3] = pa[j].w;
            if (!same) { Sb[r][c4*4+0] = pb[j].x; Sb[r][c4*4+1] = pb[j].y; Sb[r][c4*4+2] = pb[j].z; Sb[r][c4*4+3] = pb[j].w; }
        }
        if (p < 7) {
            #pragma unroll
            for (int j = 0; j < 4; ++j) {
                int idx = tid + j*256;
                int r = idx >> 4, c4 = idx & 15;
                pa[j] = *(const float4*)&W[(size_t)((p+1)*64 + r)*N + bi*64 + c4*4];
                if (!same) pb[j] = *(const float4*)&W[(size_t)((p+1)*64 + r)*N + bj*64 + c4*4];
            }
        }
        __syncthreads();
        if (same) {
            #pragma unroll 8
            for (int pr2 = 0; pr2 < 64; ++pr2) {
                float ar[4], ac[4];
                #pragma unroll
                for (int q = 0; q < 4; ++q) { ar[q] = Sa[pr2][ty*4+q]; ac[q] = Sa[pr2][tx*4+q]; }
                #pragma unroll
                for (int q = 0; q < 4; ++q)
                    #pragma unroll
                    for (int w = 0; w < 4; ++w) acc[q][w] = fmaf(ar[q], ac[w], acc[q][w]);
            }
        } else {
            #pragma unroll 8
            for (int pr2 = 0; pr2 < 64; ++pr2) {
                float ar[4], ac[4];
                #pragma unroll
                for (int q = 0; q < 4; ++q) { ar[q] = Sa[pr2][ty*4+q]; ac[q] = Sb[pr2][tx*4+q]; }
                #pragma unroll
                for (int q = 0; q < 4; ++q)
                    #pragma unroll
                    for (int w = 0; w < 4; ++w) acc[q][w] = fmaf(ar[q], ac[w], acc[q][w]);
            }
        }
    }
    #pragma unroll
    for (int q = 0; q < 4; ++q)
        #pragma unroll
        for (int w = 0; w < 4; ++w) {
            int r = bi*64 + ty*4 + q, c = bj*64 + tx*4 + w;
            IK[(size_t)r*N + c] = acc[q][w];
            IK[(size_t)c*N + r] = acc[q][w];
        }
}

// ---------- 3h. beta = iK @ Yn ----------
__global__ __launch_bounds__(256) void k_beta(float* __restrict__ ws) {
    int e = blockIdx.x >> 2, qtr = blockIdx.x & 3;
    int tid = threadIdx.x;
    int half = tid >> 7;
    int nl = tid & 127;
    int n = qtr*128 + nl;
    __shared__ float yn[N];
    __shared__ float part[2][128];
    for (int i = tid; i < N; i += 256) yn[i] = ws[OFF_YN + (size_t)e*N + i];
    __syncthreads();
    const float* IK = ws + OFF_A + (size_t)e*N*N;
    int m0 = half*256;
    float a0 = 0.f, a1 = 0.f, a2 = 0.f, a3 = 0.f;
    for (int mm = m0; mm < m0 + 256; mm += 4) {
        a0 = fmaf(IK[(size_t)mm*N + n],     yn[mm],   a0);
        a1 = fmaf(IK[(size_t)(mm+1)*N + n], yn[mm+1], a1);
        a2 = fmaf(IK[(size_t)(mm+2)*N + n], yn[mm+2], a2);
        a3 = fmaf(IK[(size_t)(mm+3)*N + n], yn[mm+3], a3);
    }
    part[half][nl] = (a0 + a1) + (a2 + a3);
    __syncthreads();
    if (tid < 128)
        ws[OFF_BETA + e*N + qtr*128 + tid] = part[0][tid] + part[1][tid];
}

// ---------- 5+6 merged: k_point (first E*N/256 blocks) and k_xs (compact pairs) ----------
__global__ __launch_bounds__(256) void k_pxs(float* __restrict__ ws, const float* __restrict__ ls,
                                             const float* __restrict__ os) {
    int tid = threadIdx.x;
    if (blockIdx.x < E*N/256) {
        int t = blockIdx.x*256 + tid;
        int e = t >> 9, n = t & 511;
        float iN[D], tt[D], l[D];
        #pragma unroll
        for (int d = 0; d < D; ++d) { l[d] = ls[e*D + d]; iN[d] = ws[OFF_INP + n*D + d] / l[d]; }
        #pragma unroll
        for (int d = 0; d < D; ++d) {
            float acc = 0.f;
            #pragma unroll
            for (int j = 0; j < D; ++j) acc += ws[OFF_BINV + ((size_t)e*D + d)*D + j] * iN[j];
            tt[d] = acc;
        }
        float siNt = 0.f, siN2 = 0.f;
        #pragma unroll
        for (int d = 0; d < D; ++d) { siNt += iN[d]*tt[d]; siN2 += iN[d]*iN[d]; }
        float lbv = __expf(-0.5f * siNt) * ws[OFF_BETA + e*N + n];
        ws[OFF_LB + e*N + n] = lbv;
        #pragma unroll
        for (int d = 0; d < D; ++d) ws[OFF_TIL + ((size_t)e*N + n)*D + d] = tt[d] / l[d];
        ws[OFF_KVEC + e*N + n] = logf(os[e]) - 0.5f * siN2;
        return;
    }
    // ---- xs part: only compact pairs (a<=b) ----
    int t = (blockIdx.x - E*N/256)*256 + tid;
    int pc = t / N, n = t % N;
    int a, b;
    pc2ab(pc, a, b);
    int pairQ = a*E + b;
    __shared__ float Qs[16][17];
    __shared__ float i2a[16], i2b[16];
    Qs[tid >> 4][tid & 15] = ws[OFF_Q + (size_t)pairQ*D*D + tid];
    if (tid < 16) { float l = ls[a*D + tid]; i2a[tid] = 1.0f/(l*l); }
    else if (tid < 32) { int d = tid-16; float l = ls[b*D + d]; i2b[d] = 1.0f/(l*l); }
    __syncthreads();
    float x1[D], x2[D];
    float siNa = 0.f, siNb = 0.f;
    #pragma unroll
    for (int d = 0; d < D; ++d) {
        float ip = ws[OFF_INP + n*D + d];
        x1[d] = ip * i2a[d];
        x2[d] = ip * i2b[d];
        siNa = fmaf(ip*ip, i2a[d], siNa);
        siNb = fmaf(ip*ip, i2b[d], siNb);
    }
    float xs1 = 0.f, xs2 = 0.f;
    #pragma unroll
    for (int j = 0; j < D; ++j) {
        float t1 = 0.f, t2 = 0.f;
        #pragma unroll
        for (int i = 0; i < D; ++i) { t1 = fmaf(x1[i], Qs[i][j], t1); t2 = fmaf(x2[i], Qs[i][j], t2); }
        xs1 = fmaf(t1, x1[j], xs1);
        xs2 = fmaf(t2, x2[j], xs2);
    }
    float loa = logf(os[a]), lob = logf(os[b]);
    ws[OFF_U + (size_t)pc*N + n] = loa - 0.5f*siNa + xs1;
    ws[OFF_V + (size_t)pc*N + n] = lob - 0.5f*siNb + xs2;
}

// ---------- 7. big cross-term: compact pairs (a<=b), reg-prefetched ----------
__global__ __launch_bounds__(256) void k_S(float* __restrict__ ws, const float* __restrict__ ls) {
    int bid = blockIdx.x;            // NPAIR * 8
    int pc = bid >> 3, ntile = bid & 7;
    int a, b;
    pc2ab(pc, a, b);
    int pairQ = a*E + b;
    int tid = threadIdx.x;
    int tx = tid & 15, ty = tid >> 4;
    __shared__ float Qs[16][17];
    __shared__ float i2a[16], i2b[16];
    __shared__ float __align__(16) bufAT[16][68];
    __shared__ float __align__(16) x1qT[16][68];
    __shared__ float __align__(16) bufBT[16][68];
    __shared__ float u_s[64], v_s[64], ba_s[64], bb_s[64];
    __shared__ float red[256];
    int n0 = ntile*64;
    Qs[tid >> 4][tid & 15] = ws[OFF_Q + (size_t)pairQ*D*D + tid];
    if (tid < 16) { float l = ls[a*D + tid]; i2a[tid] = 1.0f/(l*l); }
    else if (tid < 32) { int d = tid-16; float l = ls[b*D + d]; i2b[d] = 1.0f/(l*l); }
    __syncthreads();
    for (int idx = tid; idx < 1024; idx += 256) {
        int r = idx >> 4, d = idx & 15;
        bufAT[d][r] = ws[OFF_INP + (size_t)(n0 + r)*D + d] * i2a[d];
    }
    __syncthreads();
    for (int idx = tid; idx < 1024; idx += 256) {
        int r = idx >> 4, j = idx & 15;
        float s = 0.f;
        #pragma unroll
        for (int i = 0; i < 16; ++i) s = fmaf(bufAT[i][r], Qs[i][j], s);
        x1qT[j][r] = s;
    }
    if (tid < 64) {
        u_s[tid]  = ws[OFF_U + (size_t)pc*N + n0 + tid];
        ba_s[tid] = ws[OFF_BETA + a*N + n0 + tid];
    }
    __syncthreads();
    float4 av4[16];
    #pragma unroll
    for (int d = 0; d < 16; ++d) av4[d] = *(const float4*)&x1qT[d][ty*4];
    float uq[4], baq[4];
    #pragma unroll
    for (int q = 0; q < 4; ++q) { uq[q] = u_s[ty*4+q]; baq[q] = ba_s[ty*4+q]; }

    float pf[4];
    #pragma unroll
    for (int j = 0; j < 4; ++j) {
        int idx = tid + j*256;
        pf[j] = ws[OFF_INP + (size_t)((idx >> 4))*D + (idx & 15)];
    }
    float vpf = 0.f, bpf = 0.f;
    if (tid < 64) {
        vpf = ws[OFF_V + (size_t)pc*N + tid];
        bpf = ws[OFF_BETA + b*N + tid];
    }

    float sacc = 0.f, tacc = 0.f;
    for (int mt = 0; mt < 8; ++mt) {
        __syncthreads();
        #pragma unroll
        for (int j = 0; j < 4; ++j) {
            int idx = tid + j*256;
            bufBT[idx & 15][idx >> 4] = pf[j] * i2b[idx & 15];
        }
        if (tid < 64) { v_s[tid] = vpf; bb_s[tid] = bpf; }
        if (mt < 7) {
            #pragma unroll
            for (int j = 0; j < 4; ++j) {
                int idx = tid + j*256;
                pf[j] = ws[OFF_INP + (size_t)((mt+1)*64 + (idx >> 4))*D + (idx & 15)];
            }
            if (tid < 64) {
                vpf = ws[OFF_V + (size_t)pc*N + (mt+1)*64 + tid];
                bpf = ws[OFF_BETA + b*N + (mt+1)*64 + tid];
            }
        }
        __syncthreads();
        float dacc[4][4] = {};
        #pragma unroll
        for (int d = 0; d < 16; ++d) {
            float4 bv = *(const float4*)&bufBT[d][tx*4];
            float4 av = av4[d];
            dacc[0][0] = fmaf(av.x, bv.x, dacc[0][0]); dacc[0][1] = fmaf(av.x, bv.y, dacc[0][1]);
            dacc[0][2] = fmaf(av.x, bv.z, dacc[0][2]); dacc[0][3] = fmaf(av.x, bv.w, dacc[0][3]);
            dacc[1][0] = fmaf(av.y, bv.x, dacc[1][0]); dacc[1][1] = fmaf(av.y, bv.y, dacc[1][1]);
            dacc[1][2] = fmaf(av.y, bv.z, dacc[1][2]); dacc[1][3] = fmaf(av.y, bv.w, dacc[1][3]);
            dacc[2][0] = fmaf(av.z, bv.x, dacc[2][0]); dacc[2][1] = fmaf(av.z, bv.y, dacc[2][1]);
            dacc[2][2] = fmaf(av.z, bv.z, dacc[2][2]); dacc[2][3] = fmaf(av.z, bv.w, dacc[2][3]);
            dacc[3][0] = fmaf(av.w, bv.x, dacc[3][0]); dacc[3][1] = fmaf(av.w, bv.y, dacc[3][1]);
            dacc[3][2] = fmaf(av.w, bv.z, dacc[3][2]); dacc[3][3] = fmaf(av.w, bv.w, dacc[3][3]);
        }
        #pragma unroll
        for (int q = 0; q < 4; ++q) {
            float ikq[4];
            if (a == b)
                *(float4*)ikq = *(const float4*)&ws[OFF_A + ((size_t)a*N + n0 + ty*4 + q)*N + mt*64 + tx*4];
            #pragma unroll
            for (int w = 0; w < 4; ++w) {
                float Lv = __expf(2.f*dacc[q][w] + uq[q] + v_s[tx*4+w]);
                sacc = fmaf(baq[q] * bb_s[tx*4+w], Lv, sacc);
                if (a == b)
                    tacc = fmaf(ikq[w], Lv, tacc);
            }
        }
    }
    red[tid] = sacc; __syncthreads();
    for (int o = 128; o > 0; o >>= 1) { if (tid < o) red[tid] += red[tid+o]; __syncthreads(); }
    if (tid == 0) ws[OFF_SPART + bid] = red[0];
    if (a == b) {
        __syncthreads();
        red[tid] = tacc; __syncthreads();
        for (int o = 128; o > 0; o >>= 1) { if (tid < o) red[tid] += red[tid+o]; __syncthreads(); }
        if (tid == 0) ws[OFF_TPART + a*8 + ntile] = red[0];
    }
}

// ---------- 8. finalize ----------
__global__ __launch_bounds__(256) void k_final(float* __restrict__ ws, const float* __restrict__ s,
                                               const float* __restrict__ os, float* __restrict__ out) {
    int tid = threadIdx.x;
    __shared__ float Msh[E], Vsh[E][D], cov[D][E+1];
    __shared__ float Sm[16][17], Si[16][17];
    __shared__ float vred[16][17];

    {
        int wv = tid >> 6, lane = tid & 63;
        for (int e = wv; e < E; e += 4) {
            float sum = 0.f;
            #pragma unroll
            for (int i = 0; i < 8; ++i) sum += ws[OFF_LB + e*N + i*64 + lane];
            #pragma unroll
            for (int off = 32; off > 0; off >>= 1) sum += __shfl_xor(sum, off);
            if (lane == 0) Msh[e] = ws[OFF_C + e] * sum;
        }
    }
    for (int e = 0; e < E; ++e) {
        int d = tid & 15, sl = tid >> 4;
        float acc = 0.f;
        for (int i = 0; i < 32; ++i) {
            int n = sl*32 + i;
            acc = fmaf(ws[OFF_TIL + ((size_t)e*N + n)*D + d], ws[OFF_LB + e*N + n], acc);
        }
        vred[sl][d] = acc;
        __syncthreads();
        if (tid < 16) {
            float sum = 0.f;
            #pragma unroll
            for (int s2 = 0; s2 < 16; ++s2) sum += vred[s2][tid];
            Vsh[e][tid] = ws[OFF_C + e] * sum;
        }
        __syncthreads();
    }

    if (tid < E*E) {
        int a = tid / E, bb = tid % E;
        int amin = (a < bb) ? a : bb;
        int amax = (a < bb) ? bb : a;
        int pc = amin*E - (amin*(amin-1))/2 + (amax - amin);
        float acc = 0.f;
        for (int q = 0; q < 8; ++q) acc += ws[OFF_SPART + (size_t)pc*8 + q];
        if (a == bb) {
            float tr = 0.f;
            for (int q = 0; q < 8; ++q) tr += ws[OFF_TPART + a*8 + q];
            acc -= tr;
        }
        acc *= ws[OFF_ISDR + tid];
        if (a == bb) acc += os[a];
        float v = acc - Msh[a]*Msh[bb];
        v *= ws[OFF_YSTD + a] * ws[OFF_YSTD + bb];
        out[E + tid] = v;
    }
    if (tid < E) out[tid] = Msh[tid]*ws[OFF_YSTD + tid] + ws[OFF_YMEAN + tid];

    if (tid < D*E) {
        int d = tid / E, e = tid % E;
        float acc = 0.f;
        for (int k = 0; k < D; ++k) acc += ws[OFF_SSM + d*D + k] * Vsh[e][k];
        cov[d][e] = acc * ws[OFF_XSTD + d] * ws[OFF_YSTD + e];
    }
    int i = tid >> 4, j = tid & 15;
    Sm[i][j] = s[i*D + j];
    Si[i][j] = (i==j) ? 1.f : 0.f;
    __syncthreads();
    for (int k = 0; k < D; ++k) {
        float p   = Sm[k][k];
        float fik = Sm[i][k];
        float skj = Sm[k][j];
        float ikj = Si[k][j];
        __syncthreads();
        if (i == k) { Sm[k][j] = skj/p; Si[k][j] = ikj/p; }
        else        { float f = fik/p; Sm[i][j] -= f*skj; Si[i][j] -= f*ikj; }
        __syncthreads();
    }
    if (tid < D*E) {
        int d = tid / E, e = tid % E;
        float acc = 0.f;
        for (int k = 0; k < D; ++k) acc += Si[d][k] * cov[k][e];
        out[E + E*E + d*E + e] = acc;
    }
}

extern "C" void kernel_launch(void* const* d_in, const int* in_sizes, int n_in,
                              void* d_out, int out_size, void* d_ws, size_t ws_size,
                              hipStream_t stream) {
    const float* X     = (const float*)d_in[0];
    const float* Y     = (const float*)d_in[1];
    const float* m     = (const float*)d_in[2];
    const float* s     = (const float*)d_in[3];
    const float* ls    = (const float*)d_in[4];
    const float* os    = (const float*)d_in[5];
    const float* noise = (const float*)d_in[6];
    float* ws  = (float*)d_ws;
    float* out = (float*)d_out;

    k_prep   <<<1,              512, 0, stream>>>(X, Y, m, s, ws);
    k_buildA <<<E*64 + E + E*E, 256, 0, stream>>>(ws, ls, os, noise);
    k_diag64 <<<E,              256, 0, stream>>>(ws, 0);
    for (int kk = 0; kk < 7; ++kk) {
        int k0 = kk*64;
        int nb = 7 - kk;
        k_panelmul<<<E*nb,          256, 0, stream>>>(ws, k0);
        k_traild  <<<E*nb*(nb+1)/2, 256, 0, stream>>>(ws, k0);
    }
    k_dc1 <<<E*4,  256, 0, stream>>>(ws);
    k_dcT <<<E*8,  256, 0, stream>>>(ws, 2);
    k_dcW <<<E*8,  256, 0, stream>>>(ws, 2);
    k_dcT <<<E*16, 256, 0, stream>>>(ws, 4);
    k_dcW <<<E*16, 256, 0, stream>>>(ws, 4);
    k_syrk <<<E*36,                   256, 0, stream>>>(ws);
    k_beta <<<E*4,                    256, 0, stream>>>(ws);
    k_pxs  <<<E*N/256 + NPAIR*N/256,  256, 0, stream>>>(ws, ls, os);
    k_S    <<<NPAIR*8,                256, 0, stream>>>(ws, ls);
    k_final<<<1,                      256, 0, stream>>>(ws, s, os, out);
}

// Round 18
// 517.309 us; speedup vs baseline: 1.6497x; 1.0099x over previous
//
#include <hip/hip_runtime.h>
#include <math.h>

constexpr int N = 512;
constexpr int D = 16;
constexpr int E = 12;
constexpr int NPAIR = E*(E+1)/2;   // 78 compact pairs (a<=b)

// ---- workspace layout (float offsets) ----
constexpr size_t OFF_A     = 0;                            // E*N*N  A -> trail -> iK
constexpr size_t OFF_IK    = OFF_A    + (size_t)E*N*N;     // E*N*N  W = L^{-1}
constexpr size_t OFF_XS    = OFF_IK   + (size_t)E*N*N;     // N*D
constexpr size_t OFF_INP   = OFF_XS   + (size_t)N*D;       // N*D
constexpr size_t OFF_YN    = OFF_INP  + (size_t)N*D;       // E*N
constexpr size_t OFF_BETA  = OFF_YN   + (size_t)E*N;       // E*N
constexpr size_t OFF_KVEC  = OFF_BETA + (size_t)E*N;       // E*N (unused)
constexpr size_t OFF_LB    = OFF_KVEC + (size_t)E*N;       // E*N
constexpr size_t OFF_TIL   = OFF_LB   + (size_t)E*N;       // E*N*D
constexpr size_t OFF_U     = OFF_TIL  + (size_t)E*N*D;     // NPAIR*N (compact)
constexpr size_t OFF_V     = OFF_U    + (size_t)E*E*N;     // NPAIR*N (compact)
constexpr size_t OFF_Q     = OFF_V    + (size_t)E*E*N;     // E*E*D*D
constexpr size_t OFF_BINV  = OFF_Q    + (size_t)E*E*D*D;   // E*D*D
constexpr size_t OFF_C     = OFF_BINV + (size_t)E*D*D;     // E
constexpr size_t OFF_ISDR  = OFF_C    + E;                 // E*E
constexpr size_t OFF_SPART = OFF_ISDR + E*E;               // NPAIR*8
constexpr size_t OFF_TPART = OFF_SPART+ (size_t)E*E*8;     // E*8
constexpr size_t OFF_XMEAN = OFF_TPART+ (size_t)E*8;       // D
constexpr size_t OFF_XSTD  = OFF_XMEAN+ D;                 // D
constexpr size_t OFF_YMEAN = OFF_XSTD + D;                 // E
constexpr size_t OFF_YSTD  = OFF_YMEAN+ E;                 // E
constexpr size_t OFF_SSM   = OFF_YSTD + E;                 // D*D
constexpr size_t OFF_P     = OFF_SSM  + D*D;               // E*1792*64  (L panels, compact)
constexpr size_t OFF_T     = OFF_P    + (size_t)E*1792*64; // E*65536    (D&C scratch)

__device__ __forceinline__ int prow(int k) { return k*(480 - 32*k); }  // row offset of panel k

// compact pair index helpers (a<=b)
__device__ __forceinline__ void pc2ab(int pc, int& a, int& b) {
    int aa = 0, t = pc;
    while (t >= E - aa) { t -= E - aa; ++aa; }
    a = aa; b = aa + t;
}

// ======== fast 64x64 Cholesky: column-split registers, 1 barrier/step, no spill ========
__device__ __forceinline__ void fact64(float a[16], float (*cb)[64], float* invd, int lane, int wv) {
    #pragma unroll
    for (int k = 0; k < 64; ++k) {
        const int kg = k >> 4, kj = k & 15;
        if (wv == kg) {
            float dkk = __shfl(a[kj], k);
            float dv = sqrtf(dkk);
            float iv = 1.0f / dv;
            float sc = a[kj] * iv;
            if (lane == k)      { a[kj] = dv; invd[k] = iv; }
            else if (lane > k)  a[kj] = sc;
            cb[k & 1][lane] = (lane > k) ? a[kj] : 0.0f;
        }
        __syncthreads();
        float lrk = cb[k & 1][lane];
        #pragma unroll
        for (int j = 0; j < 16; ++j)
            a[j] = fmaf(-lrk, cb[k & 1][wv*16 + j], a[j]);
    }
}

// ======== blocked in-LDS 64x64 triangular inverse: short critical path ========
__device__ __forceinline__ void binv64(const float (*Lsh)[65], float (*Xsh)[65],
                                       const float* invd, float (*Tsh)[16][17], int tid) {
    if (tid < 64) {
        int g = tid >> 4, c = tid & 15;
        int b = g*16;
        for (int r = 0; r < c; ++r) Xsh[b+r][b+c] = 0.f;
        for (int r = c; r < 16; ++r) {
            float acc = (r == c) ? 1.0f : 0.0f;
            for (int k = c; k < r; ++k)
                acc = fmaf(-Lsh[b+r][b+k], Xsh[b+k][b+c], acc);
            Xsh[b+r][b+c] = acc * invd[b+r];
        }
    } else {
        const int bis[6] = {0,0,0,1,1,2};
        const int bjs[6] = {1,2,3,2,3,3};
        for (int idx = tid - 64; idx < 1536; idx += 192) {
            int blk = idx >> 8, off = idx & 255;
            Xsh[bis[blk]*16 + (off >> 4)][bjs[blk]*16 + (off & 15)] = 0.f;
        }
    }
    __syncthreads();
    for (int d = 1; d <= 3; ++d) {
        int np = 4 - d;
        for (int idx = tid; idx < np*256; idx += 256) {
            int p = idx >> 8, off = idx & 255;
            int r = off >> 4, c = off & 15;
            int i = p + d, j = p;
            float acc = 0.f;
            for (int k = j; k < i; ++k)
                #pragma unroll
                for (int m = 0; m < 16; ++m)
                    acc = fmaf(Lsh[i*16+r][k*16+m], Xsh[k*16+m][j*16+c], acc);
            Tsh[p][r][c] = acc;
        }
        __syncthreads();
        for (int idx = tid; idx < np*256; idx += 256) {
            int p = idx >> 8, off = idx & 255;
            int r = off >> 4, c = off & 15;
            int i = p + d, j = p;
            float acc = 0.f;
            #pragma unroll
            for (int m = 0; m < 16; ++m)
                acc = fmaf(Xsh[i*16+r][i*16+m], Tsh[p][m][c], acc);
            Xsh[i*16+r][j*16+c] = -acc;
        }
        __syncthreads();
    }
}

// ======== vectorized 64x64 tile load ========
__device__ __forceinline__ void load_tile4(const float* __restrict__ g, size_t ldg,
                                           float (*S)[65], int tid) {
    #pragma unroll
    for (int j = 0; j < 4; ++j) {
        int idx = tid + j*256;
        int r = idx >> 4, c4 = idx & 15;
        float4 v = *(const float4*)&g[(size_t)r*ldg + c4*4];
        S[r][c4*4+0] = v.x; S[r][c4*4+1] = v.y; S[r][c4*4+2] = v.z; S[r][c4*4+3] = v.w;
    }
}

// ======== xs body: U/V for compact pair pc, point n ========
__device__ __forceinline__ void xs_body(float* __restrict__ ws, const float* __restrict__ ls,
                                        const float* __restrict__ os, int t, int tid) {
    int pc = t / N, n = t % N;
    int a, b;
    pc2ab(pc, a, b);
    int pairQ = a*E + b;
    __shared__ float Qs[16][17];
    __shared__ float i2a[16], i2b[16];
    Qs[tid >> 4][tid & 15] = ws[OFF_Q + (size_t)pairQ*D*D + tid];
    if (tid < 16) { float l = ls[a*D + tid]; i2a[tid] = 1.0f/(l*l); }
    else if (tid < 32) { int d = tid-16; float l = ls[b*D + d]; i2b[d] = 1.0f/(l*l); }
    __syncthreads();
    float x1[D], x2[D];
    float siNa = 0.f, siNb = 0.f;
    #pragma unroll
    for (int d = 0; d < D; ++d) {
        float ip = ws[OFF_INP + n*D + d];
        x1[d] = ip * i2a[d];
        x2[d] = ip * i2b[d];
        siNa = fmaf(ip*ip, i2a[d], siNa);
        siNb = fmaf(ip*ip, i2b[d], siNb);
    }
    float xs1 = 0.f, xs2 = 0.f;
    #pragma unroll
    for (int j = 0; j < D; ++j) {
        float t1 = 0.f, t2 = 0.f;
        #pragma unroll
        for (int i = 0; i < D; ++i) { t1 = fmaf(x1[i], Qs[i][j], t1); t2 = fmaf(x2[i], Qs[i][j], t2); }
        xs1 = fmaf(t1, x1[j], xs1);
        xs2 = fmaf(t2, x2[j], xs2);
    }
    float loa = logf(os[a]), lob = logf(os[b]);
    ws[OFF_U + (size_t)pc*N + n] = loa - 0.5f*siNa + xs1;
    ws[OFF_V + (size_t)pc*N + n] = lob - 0.5f*siNb + xs2;
}

// ======== point body: iN, t, lb, tiL for (e,n) ========
__device__ __forceinline__ void point_body(float* __restrict__ ws, const float* __restrict__ ls,
                                           int t) {
    int e = t >> 9, n = t & 511;
    float iN[D], tt[D], l[D];
    #pragma unroll
    for (int d = 0; d < D; ++d) { l[d] = ls[e*D + d]; iN[d] = ws[OFF_INP + n*D + d] / l[d]; }
    #pragma unroll
    for (int d = 0; d < D; ++d) {
        float acc = 0.f;
        #pragma unroll
        for (int j = 0; j < D; ++j) acc += ws[OFF_BINV + ((size_t)e*D + d)*D + j] * iN[j];
        tt[d] = acc;
    }
    float siNt = 0.f;
    #pragma unroll
    for (int d = 0; d < D; ++d) siNt += iN[d]*tt[d];
    float lbv = __expf(-0.5f * siNt) * ws[OFF_BETA + e*N + n];
    ws[OFF_LB + e*N + n] = lbv;
    #pragma unroll
    for (int d = 0; d < D; ++d) ws[OFF_TIL + ((size_t)e*N + n)*D + d] = tt[d] / l[d];
}

// ---------- 1. standardization ----------
__global__ __launch_bounds__(512) void k_prep(const float* __restrict__ X, const float* __restrict__ Y,
                                              const float* __restrict__ m, const float* __restrict__ s,
                                              float* __restrict__ ws) {
    int tid = threadIdx.x;
    int lane = tid & 63, wave = tid >> 6;
    __shared__ float meanX[D], stdX[D], meanY[E], stdY[E], mmsh[D];

    for (int col = wave; col < D + E; col += 8) {
        float s1 = 0.f, s2 = 0.f;
        if (col < D) {
            #pragma unroll
            for (int i = 0; i < 8; ++i) { float v = X[(i*64 + lane)*D + col]; s1 += v; s2 += v*v; }
        } else {
            int e = col - D;
            #pragma unroll
            for (int i = 0; i < 8; ++i) { float v = Y[(i*64 + lane)*E + e]; s1 += v; s2 += v*v; }
        }
        #pragma unroll
        for (int off = 32; off > 0; off >>= 1) { s1 += __shfl_xor(s1, off); s2 += __shfl_xor(s2, off); }
        if (lane == 0) {
            float mean = s1 * (1.0f/N);
            float var  = (s2 - (float)N*mean*mean) * (1.0f/(N-1));
            float sd   = sqrtf(var);
            if (col < D) { meanX[col] = mean; stdX[col] = sd; }
            else         { meanY[col-D] = mean; stdY[col-D] = sd; }
        }
    }
    __syncthreads();
    if (tid < D) {
        mmsh[tid] = (m[tid] - meanX[tid]) / stdX[tid];
        ws[OFF_XMEAN + tid] = meanX[tid];
        ws[OFF_XSTD  + tid] = stdX[tid];
    }
    if (tid < E) { ws[OFF_YMEAN + tid] = meanY[tid]; ws[OFF_YSTD + tid] = stdY[tid]; }
    __syncthreads();
    int n = tid;
    #pragma unroll
    for (int d = 0; d < D; ++d) {
        float xs = (X[n*D + d] - meanX[d]) / stdX[d];
        ws[OFF_XS  + n*D + d] = xs;
        ws[OFF_INP + n*D + d] = xs - mmsh[d];
    }
    #pragma unroll
    for (int e = 0; e < E; ++e)
        ws[OFF_YN + e*N + n] = (Y[n*E + e] - meanY[e]) / stdY[e];
    if (tid < D*D) {
        int i = tid / D, j = tid % D;
        ws[OFF_SSM + tid] = s[tid] / (stdX[i] * stdX[j]);
    }
}

// ---------- 2. A = K + noise I  +  appended B/R inverse blocks ----------
__global__ __launch_bounds__(256) void k_buildA(float* __restrict__ ws, const float* __restrict__ ls,
                                                const float* __restrict__ os, const float* __restrict__ noise) {
    int bid = blockIdx.x;
    int tid = threadIdx.x;
    if (bid < E*64) {
        int e  = bid >> 6;
        int t  = bid & 63;
        int bn = t >> 3, bm = t & 7;
        __shared__ float xn[64][17], xm[64][17];
        __shared__ float il2[16];
        for (int idx = tid; idx < 1024; idx += 256) {
            int r = idx >> 4, d0 = idx & 15;
            xn[r][d0] = ws[OFF_XS + (size_t)(bn*64 + r)*D + d0];
            xm[r][d0] = ws[OFF_XS + (size_t)(bm*64 + r)*D + d0];
        }
        if (tid < 16) { float l = ls[e*D + tid]; il2[tid] = 1.0f/(l*l); }
        __syncthreads();
        int tx = tid & 15, ty = tid >> 4;
        float osv = os[e], nsv = noise[e];
        float acc[4][4] = {};
        #pragma unroll
        for (int d = 0; d < 16; ++d) {
            float il = il2[d];
            float an[4], am[4];
            #pragma unroll
            for (int q = 0; q < 4; ++q) { an[q] = xn[ty + q*16][d]; am[q] = xm[tx + q*16][d]; }
            #pragma unroll
            for (int q = 0; q < 4; ++q)
                #pragma unroll
                for (int w = 0; w < 4; ++w) { float df = an[q] - am[w]; acc[q][w] = fmaf(df*df, il, acc[q][w]); }
        }
        float* A = ws + OFF_A + (size_t)e*N*N;
        #pragma unroll
        for (int q = 0; q < 4; ++q)
            #pragma unroll
            for (int w = 0; w < 4; ++w) {
                int nr = bn*64 + ty + q*16, mc = bm*64 + tx + w*16;
                float v = osv * __expf(-0.5f * acc[q][w]);
                if (nr == mc) v += nsv;
                A[(size_t)nr*N + mc] = v;
            }
        return;
    }
    int bidx = bid - E*64;
    int i = tid >> 4, j = tid & 15;
    if (bidx < E) {
        int e = bidx;
        __shared__ float Bm[16][17], BInv[16][17];
        float li = ls[e*D + i], lj = ls[e*D + j];
        Bm[i][j] = ws[OFF_SSM + i*D + j] / (li*lj) + ((i==j) ? 1.f : 0.f);
        BInv[i][j] = (i==j) ? 1.f : 0.f;
        __syncthreads();
        float det = 1.f;
        for (int k = 0; k < D; ++k) {
            float p   = Bm[k][k];
            float fik = Bm[i][k];
            float bkj = Bm[k][j];
            float ikj = BInv[k][j];
            __syncthreads();
            det *= p;
            if (i == k) { Bm[k][j] = bkj/p; BInv[k][j] = ikj/p; }
            else        { float f = fik/p; Bm[i][j] -= f*bkj; BInv[i][j] -= f*ikj; }
            __syncthreads();
        }
        ws[OFF_BINV + ((size_t)e*D + i)*D + j] = BInv[i][j];
        if (tid == 0) ws[OFF_C + e] = os[e] / sqrtf(det);
    } else {
        int pair = bidx - E;
        int a = pair / E, b = pair % E;
        __shared__ float Rm[16][17], RInv[16][17], ssl[16][17];
        float la = ls[a*D + j], lb2 = ls[b*D + j];
        float rj = 1.f/(la*la) + 1.f/(lb2*lb2);
        float ssv = ws[OFF_SSM + i*D + j];
        ssl[i][j] = ssv;
        Rm[i][j] = ssv * rj + ((i==j) ? 1.f : 0.f);
        RInv[i][j] = (i==j) ? 1.f : 0.f;
        __syncthreads();
        float det = 1.f;
        for (int k = 0; k < D; ++k) {
            float p   = Rm[k][k];
            float fik = Rm[i][k];
            float rkj = Rm[k][j];
            float ikj = RInv[k][j];
            __syncthreads();
            det *= p;
            if (i == k) { Rm[k][j] = rkj/p; RInv[k][j] = ikj/p; }
            else        { float f = fik/p; Rm[i][j] -= f*rkj; RInv[i][j] -= f*ikj; }
            __syncthreads();
        }
        float q = 0.f;
        #pragma unroll
        for (int k2 = 0; k2 < D; ++k2) q += RInv[i][k2] * ssl[k2][j];
        ws[OFF_Q + ((size_t)pair*D + i)*D + j] = 0.5f * q;
        if (tid == 0) ws[OFF_ISDR + pair] = 1.f / sqrtf(det);
    }
}

// ---------- 3a. first diag: fast factor + blocked inverse ----------
__global__ __launch_bounds__(256) void k_diag64(float* __restrict__ ws, int k0) {
    int e = blockIdx.x;
    int tid = threadIdx.x;
    int lane = tid & 63, wv = tid >> 6;
    const float* A = ws + OFF_A + (size_t)e*N*N;
    float* W = ws + OFF_IK + (size_t)e*N*N;
    __shared__ float Lsh[64][65], Xsh[64][65];
    __shared__ float cb[2][64];
    __shared__ float invd[64];
    __shared__ float Tsh[3][16][17];
    float a[16];
    #pragma unroll
    for (int j = 0; j < 16; ++j)
        a[j] = A[(size_t)(k0 + wv*16 + j)*N + k0 + lane];
    __syncthreads();
    fact64(a, cb, invd, lane, wv);
    #pragma unroll
    for (int j = 0; j < 16; ++j) Lsh[lane][wv*16 + j] = a[j];
    __syncthreads();
    binv64(Lsh, Xsh, invd, Tsh, tid);
    for (int idx = tid; idx < 4096; idx += 256) {
        int r = idx >> 6, c = idx & 63;
        W[(size_t)(k0 + r)*N + k0 + c] = Xsh[r][c];
    }
}

// ---------- 3b. panel TRSM as GEMM: P <- P * W_kk^T (writes A + compact OFF_P) ----------
__global__ __launch_bounds__(256) void k_panelmul(float* __restrict__ ws, int k0) {
    int kk = k0 >> 6;
    int nb = (N - k0 - 64) >> 6;
    int e  = blockIdx.x / nb;
    int bi = blockIdx.x % nb;
    float* A = ws + OFF_A + (size_t)e*N*N;
    const float* W = ws + OFF_IK + (size_t)e*N*N;
    int r0 = k0 + 64 + bi*64;
    __shared__ float Ps[64][65], Wsh[64][65];
    int tid = threadIdx.x;
    load_tile4(A + (size_t)r0*N + k0, N, Ps, tid);
    load_tile4(W + (size_t)k0*N + k0, N, Wsh, tid);
    __syncthreads();
    int tx = tid & 15, ty = tid >> 4;
    float acc[4][4] = {};
    #pragma unroll 8
    for (int j = 0; j < 64; ++j) {
        float pr[4], wr[4];
        #pragma unroll
        for (int q = 0; q < 4; ++q) { pr[q] = Ps[ty*4+q][j]; wr[q] = Wsh[tx*4+q][j]; }
        #pragma unroll
        for (int q = 0; q < 4; ++q)
            #pragma unroll
            for (int w = 0; w < 4; ++w) acc[q][w] = fmaf(pr[q], wr[w], acc[q][w]);
    }
    float* Pp = ws + OFF_P + ((size_t)e*1792 + prow(kk) + (size_t)bi*64)*64;
    #pragma unroll
    for (int q = 0; q < 4; ++q)
        #pragma unroll
        for (int w = 0; w < 4; ++w) {
            A[(size_t)(r0 + ty*4 + q)*N + k0 + tx*4 + w] = acc[q][w];
            Pp[(size_t)(ty*4 + q)*64 + tx*4 + w] = acc[q][w];
        }
}

// ---------- 3c. trailing SYRK + fused fast next-diag on (0,0) ----------
__global__ __launch_bounds__(256) void k_traild(float* __restrict__ ws, int k0) {
    int t0 = k0 + 64;
    int nb = (N - t0) >> 6;
    int ntiles = (nb*(nb+1)) >> 1;
    int e = blockIdx.x / ntiles;
    int t = blockIdx.x % ntiles;
    int bj = 0; while (t >= nb - bj) { t -= nb - bj; ++bj; }
    int bi = bj + t;
    bool same = (bi == bj);
    bool isdiag0 = (bi == 0) && (bj == 0);
    float* A = ws + OFF_A + (size_t)e*N*N;
    __shared__ float Sr[64][65], Sc[64][65];
    __shared__ float cb[2][64];
    __shared__ float invd[64];
    __shared__ float Tsh[3][16][17];
    int tid = threadIdx.x;
    int tx = tid & 15, ty = tid >> 4;
    load_tile4(A + (size_t)(t0 + bi*64)*N + k0, N, Sr, tid);
    if (!same) load_tile4(A + (size_t)(t0 + bj*64)*N + k0, N, Sc, tid);
    __syncthreads();
    float acc[4][4] = {};
    if (same) {
        #pragma unroll 8
        for (int p = 0; p < 64; ++p) {
            float ar[4], ac[4];
            #pragma unroll
            for (int q = 0; q < 4; ++q) { ar[q] = Sr[ty*4+q][p]; ac[q] = Sr[tx*4+q][p]; }
            #pragma unroll
            for (int q = 0; q < 4; ++q)
                #pragma unroll
                for (int w = 0; w < 4; ++w) acc[q][w] = fmaf(ar[q], ac[w], acc[q][w]);
        }
    } else {
        #pragma unroll 8
        for (int p = 0; p < 64; ++p) {
            float ar[4], ac[4];
            #pragma unroll
            for (int q = 0; q < 4; ++q) { ar[q] = Sr[ty*4+q][p]; ac[q] = Sc[tx*4+q][p]; }
            #pragma unroll
            for (int q = 0; q < 4; ++q)
                #pragma unroll
                for (int w = 0; w < 4; ++w) acc[q][w] = fmaf(ar[q], ac[w], acc[q][w]);
        }
    }
    float* Out = A + (size_t)(t0 + bi*64)*N + (t0 + bj*64);
    if (!isdiag0) {
        #pragma unroll
        for (int q = 0; q < 4; ++q)
            #pragma unroll
            for (int w = 0; w < 4; ++w)
                Out[(size_t)(ty*4+q)*N + tx*4+w] -= acc[q][w];
        return;
    }
    __syncthreads();
    #pragma unroll
    for (int q = 0; q < 4; ++q)
        #pragma unroll
        for (int w = 0; w < 4; ++w)
            Sc[ty*4+q][tx*4+w] = Out[(size_t)(ty*4+q)*N + tx*4+w] - acc[q][w];
    __syncthreads();
    int lane = tid & 63, wv = tid >> 6;
    float a[16];
    #pragma unroll
    for (int j = 0; j < 16; ++j) a[j] = Sc[lane][wv*16 + j];   // tile symmetric
    __syncthreads();
    fact64(a, cb, invd, lane, wv);
    #pragma unroll
    for (int j = 0; j < 16; ++j) Sc[lane][wv*16 + j] = a[j];   // Sc becomes Lsh
    __syncthreads();
    binv64(Sc, Sr, invd, Tsh, tid);                            // Sr becomes Xsh
    float* W = ws + OFF_IK + (size_t)e*N*N;
    for (int idx = tid; idx < 4096; idx += 256) {
        int r = idx >> 6, c = idx & 63;
        W[(size_t)(t0 + r)*N + t0 + c] = Sr[r][c];
    }
}

// ---------- 3d. D&C level 1 (H=1): W21 = -W22 L21 W11 ----------
__global__ __launch_bounds__(256) void k_dc1(float* __restrict__ ws) {
    int e = blockIdx.x >> 2, p = blockIdx.x & 3;
    float* W = ws + OFF_IK + (size_t)e*N*N;
    const float* Lt = ws + OFF_P + ((size_t)e*1792 + prow(2*p))*64;
    __shared__ float Sa[64][65], Sb[64][65], T[64][65];
    int tid = threadIdx.x;
    int tx = tid & 15, ty = tid >> 4;
    load_tile4(Lt, 64, Sa, tid);
    load_tile4(W + (size_t)(2*p*64)*N + 2*p*64, N, Sb, tid);
    __syncthreads();
    float acc[4][4] = {};
    #pragma unroll 8
    for (int pp = 0; pp < 64; ++pp) {
        float ar[4], bc[4];
        #pragma unroll
        for (int q = 0; q < 4; ++q) { ar[q] = Sa[ty*4+q][pp]; bc[q] = Sb[pp][tx*4+q]; }
        #pragma unroll
        for (int q = 0; q < 4; ++q)
            #pragma unroll
            for (int w = 0; w < 4; ++w) acc[q][w] = fmaf(ar[q], bc[w], acc[q][w]);
    }
    #pragma unroll
    for (int q = 0; q < 4; ++q)
        #pragma unroll
        for (int w = 0; w < 4; ++w) T[ty*4+q][tx*4+w] = acc[q][w];
    __syncthreads();
    load_tile4(W + (size_t)((2*p+1)*64)*N + (2*p+1)*64, N, Sa, tid);
    __syncthreads();
    float o[4][4] = {};
    #pragma unroll 8
    for (int pp = 0; pp < 64; ++pp) {
        float ar[4], bc[4];
        #pragma unroll
        for (int q = 0; q < 4; ++q) { ar[q] = Sa[ty*4+q][pp]; bc[q] = T[pp][tx*4+q]; }
        #pragma unroll
        for (int q = 0; q < 4; ++q)
            #pragma unroll
            for (int w = 0; w < 4; ++w) o[q][w] = fmaf(ar[q], bc[w], o[q][w]);
    }
    #pragma unroll
    for (int q = 0; q < 4; ++q)
        #pragma unroll
        for (int w = 0; w < 4; ++w)
            W[(size_t)((2*p+1)*64 + ty*4 + q)*N + 2*p*64 + tx*4 + w] = -o[q][w];
}

// ---------- 3e. D&C: T = L21 * W11 (levels H=2,4) ----------
__global__ __launch_bounds__(256) void k_dcT(float* __restrict__ ws, int H) {
    int per_e = 4*H;
    int e = blockIdx.x / per_e;
    int rem = blockIdx.x % per_e;
    int p  = rem / (H*H);
    int tt = rem % (H*H);
    int ti = tt / H, tj = tt % H;
    int C0 = 2*p*H;
    int I  = C0 + H + ti;
    const float* W = ws + OFF_IK + (size_t)e*N*N;
    float* Tt = ws + OFF_T + (size_t)e*65536 + (size_t)(p*H*H + ti*H + tj)*4096;
    __shared__ float Sa[64][65], Sb[64][65];
    int tid = threadIdx.x;
    int tx = tid & 15, ty = tid >> 4;
    float acc[4][4] = {};
    for (int k = tj; k < H; ++k) {
        int K = C0 + k;
        const float* Lt = ws + OFF_P + ((size_t)e*1792 + prow(K) + (size_t)(I - K - 1)*64)*64;
        __syncthreads();
        load_tile4(Lt, 64, Sa, tid);
        load_tile4(W + (size_t)(K*64)*N + (C0 + tj)*64, N, Sb, tid);
        __syncthreads();
        #pragma unroll 8
        for (int pp = 0; pp < 64; ++pp) {
            float ar[4], bc[4];
            #pragma unroll
            for (int q = 0; q < 4; ++q) { ar[q] = Sa[ty*4+q][pp]; bc[q] = Sb[pp][tx*4+q]; }
            #pragma unroll
            for (int q = 0; q < 4; ++q)
                #pragma unroll
                for (int w = 0; w < 4; ++w) acc[q][w] = fmaf(ar[q], bc[w], acc[q][w]);
        }
    }
    #pragma unroll
    for (int q = 0; q < 4; ++q)
        #pragma unroll
        for (int w = 0; w < 4; ++w)
            Tt[(size_t)(ty*4+q)*64 + tx*4 + w] = acc[q][w];
}

// ---------- 3f. D&C: W21 = -W22 * T ----------
__global__ __launch_bounds__(256) void k_dcW(float* __restrict__ ws, int H) {
    int per_e = 4*H;
    int e = blockIdx.x / per_e;
    int rem = blockIdx.x % per_e;
    int p  = rem / (H*H);
    int tt = rem % (H*H);
    int ti = tt / H, tj = tt % H;
    int C0 = 2*p*H, R0 = C0 + H;
    float* W = ws + OFF_IK + (size_t)e*N*N;
    const float* Tbase = ws + OFF_T + (size_t)e*65536 + (size_t)(p*H*H)*4096;
    __shared__ float Sa[64][65], Sb[64][65];
    int tid = threadIdx.x;
    int tx = tid & 15, ty = tid >> 4;
    float acc[4][4] = {};
    for (int tk = 0; tk <= ti; ++tk) {
        const float* Tt = Tbase + (size_t)(tk*H + tj)*4096;
        __syncthreads();
        load_tile4(W + (size_t)((R0 + ti)*64)*N + (R0 + tk)*64, N, Sa, tid);
        load_tile4(Tt, 64, Sb, tid);
        __syncthreads();
        #pragma unroll 8
        for (int pp = 0; pp < 64; ++pp) {
            float ar[4], bc[4];
            #pragma unroll
            for (int q = 0; q < 4; ++q) { ar[q] = Sa[ty*4+q][pp]; bc[q] = Sb[pp][tx*4+q]; }
            #pragma unroll
            for (int q = 0; q < 4; ++q)
                #pragma unroll
                for (int w = 0; w < 4; ++w) acc[q][w] = fmaf(ar[q], bc[w], acc[q][w]);
        }
    }
    #pragma unroll
    for (int q = 0; q < 4; ++q)
        #pragma unroll
        for (int w = 0; w < 4; ++w)
            W[(size_t)((R0 + ti)*64 + ty*4 + q)*N + (C0 + tj)*64 + tx*4 + w] = -acc[q][w];
}

// ---------- 3g. iK = W^T W  +  appended xs blocks (U/V precompute) ----------
__global__ __launch_bounds__(256) void k_syrk(float* __restrict__ ws, const float* __restrict__ ls,
                                              const float* __restrict__ os) {
    int tid = threadIdx.x;
    if (blockIdx.x >= E*36) {
        int t = (blockIdx.x - E*36)*256 + tid;
        xs_body(ws, ls, os, t, tid);
        return;
    }
    int e = blockIdx.x / 36;
    int t = blockIdx.x % 36;
    int bj = 0; while (t >= 8 - bj) { t -= 8 - bj; ++bj; }
    int bi = bj + t;
    bool same = (bi == bj);
    const float* W = ws + OFF_IK + (size_t)e*N*N;
    float*      IK = ws + OFF_A  + (size_t)e*N*N;
    __shared__ float Sa[64][65], Sb[64][65];
    int tx = tid & 15, ty = tid >> 4;

    float4 pa[4], pb[4];
    #pragma unroll
    for (int j = 0; j < 4; ++j) {
        int idx = tid + j*256;
        int r = idx >> 4, c4 = idx & 15;
        pa[j] = *(const float4*)&W[(size_t)(bi*64 + r)*N + bi*64 + c4*4];
        if (!same) pb[j] = *(const float4*)&W[(size_t)(bi*64 + r)*N + bj*64 + c4*4];
    }

    float acc[4][4] = {};
    for (int p = bi; p < 8; ++p) {
        __syncthreads();
        #pragma unroll
        for (int j = 0; j < 4; ++j) {
            int idx = tid + j*256;
            int r = idx >> 4, c4 = idx & 15;
            Sa[r][c4*4+0] = pa[j].x; Sa[r][c4*4+1] = pa[j].y; Sa[r][c4*4+2] = pa[j].z; Sa[r][c4*4+3] = pa[j].w;
            if (!same) { Sb[r][c4*4+0] = pb[j].x; Sb[r][c4*4+1] = pb[j].y; Sb[r][c4*4+2] = pb[j].z; Sb[r][c4*4+3] = pb[j].w; }
        }
        if (p < 7) {
            #pragma unroll
            for (int j = 0; j < 4; ++j) {
                int idx = tid + j*256;
                int r = idx >> 4, c4 = idx & 15;
                pa[j] = *(const float4*)&W[(size_t)((p+1)*64 + r)*N + bi*64 + c4*4];
                if (!same) pb[j] = *(const float4*)&W[(size_t)((p+1)*64 + r)*N + bj*64 + c4*4];
            }
        }
        __syncthreads();
        if (same) {
            #pragma unroll 8
            for (int pr2 = 0; pr2 < 64; ++pr2) {
                float ar[4], ac[4];
                #pragma unroll
                for (int q = 0; q < 4; ++q) { ar[q] = Sa[pr2][ty*4+q]; ac[q] = Sa[pr2][tx*4+q]; }
                #pragma unroll
                for (int q = 0; q < 4; ++q)
                    #pragma unroll
                    for (int w = 0; w < 4; ++w) acc[q][w] = fmaf(ar[q], ac[w], acc[q][w]);
            }
        } else {
            #pragma unroll 8
            for (int pr2 = 0; pr2 < 64; ++pr2) {
                float ar[4], ac[4];
                #pragma unroll
                for (int q = 0; q < 4; ++q) { ar[q] = Sa[pr2][ty*4+q]; ac[q] = Sb[pr2][tx*4+q]; }
                #pragma unroll
                for (int q = 0; q < 4; ++q)
                    #pragma unroll
                    for (int w = 0; w < 4; ++w) acc[q][w] = fmaf(ar[q], ac[w], acc[q][w]);
            }
        }
    }
    #pragma unroll
    for (int q = 0; q < 4; ++q)
        #pragma unroll
        for (int w = 0; w < 4; ++w) {
            int r = bi*64 + ty*4 + q, c = bj*64 + tx*4 + w;
            IK[(size_t)r*N + c] = acc[q][w];
            IK[(size_t)c*N + r] = acc[q][w];
        }
}

// ---------- 3h. beta = iK @ Yn ----------
__global__ __launch_bounds__(256) void k_beta(float* __restrict__ ws) {
    int e = blockIdx.x >> 2, qtr = blockIdx.x & 3;
    int tid = threadIdx.x;
    int half = tid >> 7;
    int nl = tid & 127;
    int n = qtr*128 + nl;
    __shared__ float yn[N];
    __shared__ float part[2][128];
    for (int i = tid; i < N; i += 256) yn[i] = ws[OFF_YN + (size_t)e*N + i];
    __syncthreads();
    const float* IK = ws + OFF_A + (size_t)e*N*N;
    int m0 = half*256;
    float a0 = 0.f, a1 = 0.f, a2 = 0.f, a3 = 0.f;
    for (int mm = m0; mm < m0 + 256; mm += 4) {
        a0 = fmaf(IK[(size_t)mm*N + n],     yn[mm],   a0);
        a1 = fmaf(IK[(size_t)(mm+1)*N + n], yn[mm+1], a1);
        a2 = fmaf(IK[(size_t)(mm+2)*N + n], yn[mm+2], a2);
        a3 = fmaf(IK[(size_t)(mm+3)*N + n], yn[mm+3], a3);
    }
    part[half][nl] = (a0 + a1) + (a2 + a3);
    __syncthreads();
    if (tid < 128)
        ws[OFF_BETA + e*N + qtr*128 + tid] = part[0][tid] + part[1][tid];
}

// ---------- 7. big cross-term (compact pairs) + appended point blocks ----------
__global__ __launch_bounds__(256) void k_S(float* __restrict__ ws, const float* __restrict__ ls,
                                           const float* __restrict__ os) {
    int tid = threadIdx.x;
    if (blockIdx.x >= NPAIR*8) {
        int t = (blockIdx.x - NPAIR*8)*256 + tid;
        point_body(ws, ls, t);
        return;
    }
    int bid = blockIdx.x;            // NPAIR * 8
    int pc = bid >> 3, ntile = bid & 7;
    int a, b;
    pc2ab(pc, a, b);
    int pairQ = a*E + b;
    int tx = tid & 15, ty = tid >> 4;
    __shared__ float Qs[16][17];
    __shared__ float i2a[16], i2b[16];
    __shared__ float __align__(16) bufAT[16][68];
    __shared__ float __align__(16) x1qT[16][68];
    __shared__ float __align__(16) bufBT[16][68];
    __shared__ float u_s[64], v_s[64], ba_s[64], bb_s[64];
    __shared__ float red[256];
    int n0 = ntile*64;
    Qs[tid >> 4][tid & 15] = ws[OFF_Q + (size_t)pairQ*D*D + tid];
    if (tid < 16) { float l = ls[a*D + tid]; i2a[tid] = 1.0f/(l*l); }
    else if (tid < 32) { int d = tid-16; float l = ls[b*D + d]; i2b[d] = 1.0f/(l*l); }
    __syncthreads();
    for (int idx = tid; idx < 1024; idx += 256) {
        int r = idx >> 4, d = idx & 15;
        bufAT[d][r] = ws[OFF_INP + (size_t)(n0 + r)*D + d] * i2a[d];
    }
    __syncthreads();
    for (int idx = tid; idx < 1024; idx += 256) {
        int r = idx >> 4, j = idx & 15;
        float s = 0.f;
        #pragma unroll
        for (int i = 0; i < 16; ++i) s = fmaf(bufAT[i][r], Qs[i][j], s);
        x1qT[j][r] = s;
    }
    if (tid < 64) {
        u_s[tid]  = ws[OFF_U + (size_t)pc*N + n0 + tid];
        ba_s[tid] = ws[OFF_BETA + a*N + n0 + tid];
    }
    __syncthreads();
    float4 av4[16];
    #pragma unroll
    for (int d = 0; d < 16; ++d) av4[d] = *(const float4*)&x1qT[d][ty*4];
    float uq[4], baq[4];
    #pragma unroll
    for (int q = 0; q < 4; ++q) { uq[q] = u_s[ty*4+q]; baq[q] = ba_s[ty*4+q]; }

    float pf[4];
    #pragma unroll
    for (int j = 0; j < 4; ++j) {
        int idx = tid + j*256;
        pf[j] = ws[OFF_INP + (size_t)((idx >> 4))*D + (idx & 15)];
    }
    float vpf = 0.f, bpf = 0.f;
    if (tid < 64) {
        vpf = ws[OFF_V + (size_t)pc*N + tid];
        bpf = ws[OFF_BETA + b*N + tid];
    }

    float sacc = 0.f, tacc = 0.f;
    for (int mt = 0; mt < 8; ++mt) {
        __syncthreads();
        #pragma unroll
        for (int j = 0; j < 4; ++j) {
            int idx = tid + j*256;
            bufBT[idx & 15][idx >> 4] = pf[j] * i2b[idx & 15];
        }
        if (tid < 64) { v_s[tid] = vpf; bb_s[tid] = bpf; }
        if (mt < 7) {
            #pragma unroll
            for (int j = 0; j < 4; ++j) {
                int idx = tid + j*256;
                pf[j] = ws[OFF_INP + (size_t)((mt+1)*64 + (idx >> 4))*D + (idx & 15)];
            }
            if (tid < 64) {
                vpf = ws[OFF_V + (size_t)pc*N + (mt+1)*64 + tid];
                bpf = ws[OFF_BETA + b*N + (mt+1)*64 + tid];
            }
        }
        __syncthreads();
        float dacc[4][4] = {};
        #pragma unroll
        for (int d = 0; d < 16; ++d) {
            float4 bv = *(const float4*)&bufBT[d][tx*4];
            float4 av = av4[d];
            dacc[0][0] = fmaf(av.x, bv.x, dacc[0][0]); dacc[0][1] = fmaf(av.x, bv.y, dacc[0][1]);
            dacc[0][2] = fmaf(av.x, bv.z, dacc[0][2]); dacc[0][3] = fmaf(av.x, bv.w, dacc[0][3]);
            dacc[1][0] = fmaf(av.y, bv.x, dacc[1][0]); dacc[1][1] = fmaf(av.y, bv.y, dacc[1][1]);
            dacc[1][2] = fmaf(av.y, bv.z, dacc[1][2]); dacc[1][3] = fmaf(av.y, bv.w, dacc[1][3]);
            dacc[2][0] = fmaf(av.z, bv.x, dacc[2][0]); dacc[2][1] = fmaf(av.z, bv.y, dacc[2][1]);
            dacc[2][2] = fmaf(av.z, bv.z, dacc[2][2]); dacc[2][3] = fmaf(av.z, bv.w, dacc[2][3]);
            dacc[3][0] = fmaf(av.w, bv.x, dacc[3][0]); dacc[3][1] = fmaf(av.w, bv.y, dacc[3][1]);
            dacc[3][2] = fmaf(av.w, bv.z, dacc[3][2]); dacc[3][3] = fmaf(av.w, bv.w, dacc[3][3]);
        }
        #pragma unroll
        for (int q = 0; q < 4; ++q) {
            float ikq[4];
            if (a == b)
                *(float4*)ikq = *(const float4*)&ws[OFF_A + ((size_t)a*N + n0 + ty*4 + q)*N + mt*64 + tx*4];
            #pragma unroll
            for (int w = 0; w < 4; ++w) {
                float Lv = __expf(2.f*dacc[q][w] + uq[q] + v_s[tx*4+w]);
                sacc = fmaf(baq[q] * bb_s[tx*4+w], Lv, sacc);
                if (a == b)
                    tacc = fmaf(ikq[w], Lv, tacc);
            }
        }
    }
    red[tid] = sacc; __syncthreads();
    for (int o = 128; o > 0; o >>= 1) { if (tid < o) red[tid] += red[tid+o]; __syncthreads(); }
    if (tid == 0) ws[OFF_SPART + bid] = red[0];
    if (a == b) {
        __syncthreads();
        red[tid] = tacc; __syncthreads();
        for (int o = 128; o > 0; o >>= 1) { if (tid < o) red[tid] += red[tid+o]; __syncthreads(); }
        if (tid == 0) ws[OFF_TPART + a*8 + ntile] = red[0];
    }
}

// ---------- 8. finalize ----------
__global__ __launch_bounds__(256) void k_final(float* __restrict__ ws, const float* __restrict__ s,
                                               const float* __restrict__ os, float* __restrict__ out) {
    int tid = threadIdx.x;
    __shared__ float Msh[E], Vsh[E][D], cov[D][E+1];
    __shared__ float Sm[16][17], Si[16][17];
    __shared__ float vred[16][17];

    {
        int wv = tid >> 6, lane = tid & 63;
        for (int e = wv; e < E; e += 4) {
            float sum = 0.f;
            #pragma unroll
            for (int i = 0; i < 8; ++i) sum += ws[OFF_LB + e*N + i*64 + lane];
            #pragma unroll
            for (int off = 32; off > 0; off >>= 1) sum += __shfl_xor(sum, off);
            if (lane == 0) Msh[e] = ws[OFF_C + e] * sum;
        }
    }
    for (int e = 0; e < E; ++e) {
        int d = tid & 15, sl = tid >> 4;
        float acc = 0.f;
        for (int i = 0; i < 32; ++i) {
            int n = sl*32 + i;
            acc = fmaf(ws[OFF_TIL + ((size_t)e*N + n)*D + d], ws[OFF_LB + e*N + n], acc);
        }
        vred[sl][d] = acc;
        __syncthreads();
        if (tid < 16) {
            float sum = 0.f;
            #pragma unroll
            for (int s2 = 0; s2 < 16; ++s2) sum += vred[s2][tid];
            Vsh[e][tid] = ws[OFF_C + e] * sum;
        }
        __syncthreads();
    }

    if (tid < E*E) {
        int a = tid / E, bb = tid % E;
        int amin = (a < bb) ? a : bb;
        int amax = (a < bb) ? bb : a;
        int pc = amin*E - (amin*(amin-1))/2 + (amax - amin);
        float acc = 0.f;
        for (int q = 0; q < 8; ++q) acc += ws[OFF_SPART + (size_t)pc*8 + q];
        if (a == bb) {
            float tr = 0.f;
            for (int q = 0; q < 8; ++q) tr += ws[OFF_TPART + a*8 + q];
            acc -= tr;
        }
        acc *= ws[OFF_ISDR + tid];
        if (a == bb) acc += os[a];
        float v = acc - Msh[a]*Msh[bb];
        v *= ws[OFF_YSTD + a] * ws[OFF_YSTD + bb];
        out[E + tid] = v;
    }
    if (tid < E) out[tid] = Msh[tid]*ws[OFF_YSTD + tid] + ws[OFF_YMEAN + tid];

    if (tid < D*E) {
        int d = tid / E, e = tid % E;
        float acc = 0.f;
        for (int k = 0; k < D; ++k) acc += ws[OFF_SSM + d*D + k] * Vsh[e][k];
        cov[d][e] = acc * ws[OFF_XSTD + d] * ws[OFF_YSTD + e];
    }
    int i = tid >> 4, j = tid & 15;
    Sm[i][j] = s[i*D + j];
    Si[i][j] = (i==j) ? 1.f : 0.f;
    __syncthreads();
    for (int k = 0; k < D; ++k) {
        float p   = Sm[k][k];
        float fik = Sm[i][k];
        float skj = Sm[k][j];
        float ikj = Si[k][j];
        __syncthreads();
        if (i == k) { Sm[k][j] = skj/p; Si[k][j] = ikj/p; }
        else        { float f = fik/p; Sm[i][j] -= f*skj; Si[i][j] -= f*ikj; }
        __syncthreads();
    }
    if (tid < D*E) {
        int d = tid / E, e = tid % E;
        float acc = 0.f;
        for (int k = 0; k < D; ++k) acc += Si[d][k] * cov[k][e];
        out[E + E*E + d*E + e] = acc;
    }
}

extern "C" void kernel_launch(void* const* d_in, const int* in_sizes, int n_in,
                              void* d_out, int out_size, void* d_ws, size_t ws_size,
                              hipStream_t stream) {
    const float* X     = (const float*)d_in[0];
    const float* Y     = (const float*)d_in[1];
    const float* m     = (const float*)d_in[2];
    const float* s     = (const float*)d_in[3];
    const float* ls    = (const float*)d_in[4];
    const float* os    = (const float*)d_in[5];
    const float* noise = (const float*)d_in[6];
    float* ws  = (float*)d_ws;
    float* out = (float*)d_out;

    k_prep   <<<1,              512, 0, stream>>>(X, Y, m, s, ws);
    k_buildA <<<E*64 + E + E*E, 256, 0, stream>>>(ws, ls, os, noise);
    k_diag64 <<<E,              256, 0, stream>>>(ws, 0);
    for (int kk = 0; kk < 7; ++kk) {
        int k0 = kk*64;
        int nb = 7 - kk;
        k_panelmul<<<E*nb,          256, 0, stream>>>(ws, k0);
        k_traild  <<<E*nb*(nb+1)/2, 256, 0, stream>>>(ws, k0);
    }
    k_dc1 <<<E*4,  256, 0, stream>>>(ws);
    k_dcT <<<E*8,  256, 0, stream>>>(ws, 2);
    k_dcW <<<E*8,  256, 0, stream>>>(ws, 2);
    k_dcT <<<E*16, 256, 0, stream>>>(ws, 4);
    k_dcW <<<E*16, 256, 0, stream>>>(ws, 4);
    k_syrk <<<E*36 + NPAIR*N/256,   256, 0, stream>>>(ws, ls, os);
    k_beta <<<E*4,                  256, 0, stream>>>(ws);
    k_S    <<<NPAIR*8 + E*N/256,    256, 0, stream>>>(ws, ls, os);
    k_final<<<1,                    256, 0, stream>>>(ws, s, os, out);
}

// Round 19
// 492.298 us; speedup vs baseline: 1.7335x; 1.0508x over previous
//
#include <hip/hip_runtime.h>
#include <math.h>

constexpr int N = 512;
constexpr int D = 16;
constexpr int E = 12;
constexpr int NPAIR = E*(E+1)/2;   // 78 compact pairs (a<=b)

// ---- workspace layout (float offsets) ----
constexpr size_t OFF_A     = 0;                            // E*N*N  A -> trail -> iK
constexpr size_t OFF_IK    = OFF_A    + (size_t)E*N*N;     // E*N*N  W = L^{-1}
constexpr size_t OFF_XS    = OFF_IK   + (size_t)E*N*N;     // N*D
constexpr size_t OFF_INP   = OFF_XS   + (size_t)N*D;       // N*D
constexpr size_t OFF_YN    = OFF_INP  + (size_t)N*D;       // E*N
constexpr size_t OFF_BETA  = OFF_YN   + (size_t)E*N;       // E*N
constexpr size_t OFF_KVEC  = OFF_BETA + (size_t)E*N;       // E*N (unused)
constexpr size_t OFF_LB    = OFF_KVEC + (size_t)E*N;       // E*N
constexpr size_t OFF_TIL   = OFF_LB   + (size_t)E*N;       // E*N*D
constexpr size_t OFF_U     = OFF_TIL  + (size_t)E*N*D;     // NPAIR*N (compact)
constexpr size_t OFF_V     = OFF_U    + (size_t)E*E*N;     // NPAIR*N (compact)
constexpr size_t OFF_Q     = OFF_V    + (size_t)E*E*N;     // E*E*D*D
constexpr size_t OFF_BINV  = OFF_Q    + (size_t)E*E*D*D;   // E*D*D
constexpr size_t OFF_C     = OFF_BINV + (size_t)E*D*D;     // E
constexpr size_t OFF_ISDR  = OFF_C    + E;                 // E*E
constexpr size_t OFF_SPART = OFF_ISDR + E*E;               // NPAIR*8
constexpr size_t OFF_TPART = OFF_SPART+ (size_t)E*E*8;     // E*8
constexpr size_t OFF_XMEAN = OFF_TPART+ (size_t)E*8;       // D
constexpr size_t OFF_XSTD  = OFF_XMEAN+ D;                 // D
constexpr size_t OFF_YMEAN = OFF_XSTD + D;                 // E
constexpr size_t OFF_YSTD  = OFF_YMEAN+ E;                 // E
constexpr size_t OFF_SSM   = OFF_YSTD + E;                 // D*D
constexpr size_t OFF_P     = OFF_SSM  + D*D;               // E*1792*64  (L panels, compact)
constexpr size_t OFF_T     = OFF_P    + (size_t)E*1792*64; // E*65536    (D&C scratch)

__device__ __forceinline__ int prow(int k) { return k*(480 - 32*k); }  // row offset of panel k

// compact pair index helpers (a<=b)
__device__ __forceinline__ void pc2ab(int pc, int& a, int& b) {
    int aa = 0, t = pc;
    while (t >= E - aa) { t -= E - aa; ++aa; }
    a = aa; b = aa + t;
}

// ======== fast 64x64 Cholesky: column-split registers, 1 barrier/step, no spill ========
__device__ __forceinline__ void fact64(float a[16], float (*cb)[64], float* invd, int lane, int wv) {
    #pragma unroll
    for (int k = 0; k < 64; ++k) {
        const int kg = k >> 4, kj = k & 15;
        if (wv == kg) {
            float dkk = __shfl(a[kj], k);
            float dv = sqrtf(dkk);
            float iv = 1.0f / dv;
            float sc = a[kj] * iv;
            if (lane == k)      { a[kj] = dv; invd[k] = iv; }
            else if (lane > k)  a[kj] = sc;
            cb[k & 1][lane] = (lane > k) ? a[kj] : 0.0f;
        }
        __syncthreads();
        float lrk = cb[k & 1][lane];
        #pragma unroll
        for (int j = 0; j < 16; ++j)
            a[j] = fmaf(-lrk, cb[k & 1][wv*16 + j], a[j]);
    }
}

// ======== blocked in-LDS 64x64 triangular inverse: short critical path ========
__device__ __forceinline__ void binv64(const float (*Lsh)[65], float (*Xsh)[65],
                                       const float* invd, float (*Tsh)[16][17], int tid) {
    if (tid < 64) {
        int g = tid >> 4, c = tid & 15;
        int b = g*16;
        for (int r = 0; r < c; ++r) Xsh[b+r][b+c] = 0.f;
        for (int r = c; r < 16; ++r) {
            float acc = (r == c) ? 1.0f : 0.0f;
            for (int k = c; k < r; ++k)
                acc = fmaf(-Lsh[b+r][b+k], Xsh[b+k][b+c], acc);
            Xsh[b+r][b+c] = acc * invd[b+r];
        }
    } else {
        const int bis[6] = {0,0,0,1,1,2};
        const int bjs[6] = {1,2,3,2,3,3};
        for (int idx = tid - 64; idx < 1536; idx += 192) {
            int blk = idx >> 8, off = idx & 255;
            Xsh[bis[blk]*16 + (off >> 4)][bjs[blk]*16 + (off & 15)] = 0.f;
        }
    }
    __syncthreads();
    for (int d = 1; d <= 3; ++d) {
        int np = 4 - d;
        for (int idx = tid; idx < np*256; idx += 256) {
            int p = idx >> 8, off = idx & 255;
            int r = off >> 4, c = off & 15;
            int i = p + d, j = p;
            float acc = 0.f;
            for (int k = j; k < i; ++k)
                #pragma unroll
                for (int m = 0; m < 16; ++m)
                    acc = fmaf(Lsh[i*16+r][k*16+m], Xsh[k*16+m][j*16+c], acc);
            Tsh[p][r][c] = acc;
        }
        __syncthreads();
        for (int idx = tid; idx < np*256; idx += 256) {
            int p = idx >> 8, off = idx & 255;
            int r = off >> 4, c = off & 15;
            int i = p + d, j = p;
            float acc = 0.f;
            #pragma unroll
            for (int m = 0; m < 16; ++m)
                acc = fmaf(Xsh[i*16+r][i*16+m], Tsh[p][m][c], acc);
            Xsh[i*16+r][j*16+c] = -acc;
        }
        __syncthreads();
    }
}

// ======== vectorized 64x64 tile load ========
__device__ __forceinline__ void load_tile4(const float* __restrict__ g, size_t ldg,
                                           float (*S)[65], int tid) {
    #pragma unroll
    for (int j = 0; j < 4; ++j) {
        int idx = tid + j*256;
        int r = idx >> 4, c4 = idx & 15;
        float4 v = *(const float4*)&g[(size_t)r*ldg + c4*4];
        S[r][c4*4+0] = v.x; S[r][c4*4+1] = v.y; S[r][c4*4+2] = v.z; S[r][c4*4+3] = v.w;
    }
}

// ======== xs body: U/V for compact pair pc, point n ========
__device__ __forceinline__ void xs_body(float* __restrict__ ws, const float* __restrict__ ls,
                                        const float* __restrict__ os, int t, int tid) {
    int pc = t / N, n = t % N;
    int a, b;
    pc2ab(pc, a, b);
    int pairQ = a*E + b;
    __shared__ float Qs[16][17];
    __shared__ float i2a[16], i2b[16];
    Qs[tid >> 4][tid & 15] = ws[OFF_Q + (size_t)pairQ*D*D + tid];
    if (tid < 16) { float l = ls[a*D + tid]; i2a[tid] = 1.0f/(l*l); }
    else if (tid < 32) { int d = tid-16; float l = ls[b*D + d]; i2b[d] = 1.0f/(l*l); }
    __syncthreads();
    float x1[D], x2[D];
    float siNa = 0.f, siNb = 0.f;
    #pragma unroll
    for (int d = 0; d < D; ++d) {
        float ip = ws[OFF_INP + n*D + d];
        x1[d] = ip * i2a[d];
        x2[d] = ip * i2b[d];
        siNa = fmaf(ip*ip, i2a[d], siNa);
        siNb = fmaf(ip*ip, i2b[d], siNb);
    }
    float xs1 = 0.f, xs2 = 0.f;
    #pragma unroll
    for (int j = 0; j < D; ++j) {
        float t1 = 0.f, t2 = 0.f;
        #pragma unroll
        for (int i = 0; i < D; ++i) { t1 = fmaf(x1[i], Qs[i][j], t1); t2 = fmaf(x2[i], Qs[i][j], t2); }
        xs1 = fmaf(t1, x1[j], xs1);
        xs2 = fmaf(t2, x2[j], xs2);
    }
    float loa = logf(os[a]), lob = logf(os[b]);
    ws[OFF_U + (size_t)pc*N + n] = loa - 0.5f*siNa + xs1;
    ws[OFF_V + (size_t)pc*N + n] = lob - 0.5f*siNb + xs2;
}

// ======== point body: iN, t, lb, tiL for (e,n) ========
__device__ __forceinline__ void point_body(float* __restrict__ ws, const float* __restrict__ ls,
                                           int t) {
    int e = t >> 9, n = t & 511;
    float iN[D], tt[D], l[D];
    #pragma unroll
    for (int d = 0; d < D; ++d) { l[d] = ls[e*D + d]; iN[d] = ws[OFF_INP + n*D + d] / l[d]; }
    #pragma unroll
    for (int d = 0; d < D; ++d) {
        float acc = 0.f;
        #pragma unroll
        for (int j = 0; j < D; ++j) acc += ws[OFF_BINV + ((size_t)e*D + d)*D + j] * iN[j];
        tt[d] = acc;
    }
    float siNt = 0.f;
    #pragma unroll
    for (int d = 0; d < D; ++d) siNt += iN[d]*tt[d];
    float lbv = __expf(-0.5f * siNt) * ws[OFF_BETA + e*N + n];
    ws[OFF_LB + e*N + n] = lbv;
    #pragma unroll
    for (int d = 0; d < D; ++d) ws[OFF_TIL + ((size_t)e*N + n)*D + d] = tt[d] / l[d];
}

// ---------- 1. standardization ----------
__global__ __launch_bounds__(512) void k_prep(const float* __restrict__ X, const float* __restrict__ Y,
                                              const float* __restrict__ m, const float* __restrict__ s,
                                              float* __restrict__ ws) {
    int tid = threadIdx.x;
    int lane = tid & 63, wave = tid >> 6;
    __shared__ float meanX[D], stdX[D], meanY[E], stdY[E], mmsh[D];

    for (int col = wave; col < D + E; col += 8) {
        float s1 = 0.f, s2 = 0.f;
        if (col < D) {
            #pragma unroll
            for (int i = 0; i < 8; ++i) { float v = X[(i*64 + lane)*D + col]; s1 += v; s2 += v*v; }
        } else {
            int e = col - D;
            #pragma unroll
            for (int i = 0; i < 8; ++i) { float v = Y[(i*64 + lane)*E + e]; s1 += v; s2 += v*v; }
        }
        #pragma unroll
        for (int off = 32; off > 0; off >>= 1) { s1 += __shfl_xor(s1, off); s2 += __shfl_xor(s2, off); }
        if (lane == 0) {
            float mean = s1 * (1.0f/N);
            float var  = (s2 - (float)N*mean*mean) * (1.0f/(N-1));
            float sd   = sqrtf(var);
            if (col < D) { meanX[col] = mean; stdX[col] = sd; }
            else         { meanY[col-D] = mean; stdY[col-D] = sd; }
        }
    }
    __syncthreads();
    if (tid < D) {
        mmsh[tid] = (m[tid] - meanX[tid]) / stdX[tid];
        ws[OFF_XMEAN + tid] = meanX[tid];
        ws[OFF_XSTD  + tid] = stdX[tid];
    }
    if (tid < E) { ws[OFF_YMEAN + tid] = meanY[tid]; ws[OFF_YSTD + tid] = stdY[tid]; }
    __syncthreads();
    int n = tid;
    #pragma unroll
    for (int d = 0; d < D; ++d) {
        float xs = (X[n*D + d] - meanX[d]) / stdX[d];
        ws[OFF_XS  + n*D + d] = xs;
        ws[OFF_INP + n*D + d] = xs - mmsh[d];
    }
    #pragma unroll
    for (int e = 0; e < E; ++e)
        ws[OFF_YN + e*N + n] = (Y[n*E + e] - meanY[e]) / stdY[e];
    if (tid < D*D) {
        int i = tid / D, j = tid % D;
        ws[OFF_SSM + tid] = s[tid] / (stdX[i] * stdX[j]);
    }
}

// ---------- 2. A = K + noise I  +  appended B/R inverse blocks ----------
__global__ __launch_bounds__(256) void k_buildA(float* __restrict__ ws, const float* __restrict__ ls,
                                                const float* __restrict__ os, const float* __restrict__ noise) {
    int bid = blockIdx.x;
    int tid = threadIdx.x;
    if (bid < E*64) {
        int e  = bid >> 6;
        int t  = bid & 63;
        int bn = t >> 3, bm = t & 7;
        __shared__ float xn[64][17], xm[64][17];
        __shared__ float il2[16];
        for (int idx = tid; idx < 1024; idx += 256) {
            int r = idx >> 4, d0 = idx & 15;
            xn[r][d0] = ws[OFF_XS + (size_t)(bn*64 + r)*D + d0];
            xm[r][d0] = ws[OFF_XS + (size_t)(bm*64 + r)*D + d0];
        }
        if (tid < 16) { float l = ls[e*D + tid]; il2[tid] = 1.0f/(l*l); }
        __syncthreads();
        int tx = tid & 15, ty = tid >> 4;
        float osv = os[e], nsv = noise[e];
        float acc[4][4] = {};
        #pragma unroll
        for (int d = 0; d < 16; ++d) {
            float il = il2[d];
            float an[4], am[4];
            #pragma unroll
            for (int q = 0; q < 4; ++q) { an[q] = xn[ty + q*16][d]; am[q] = xm[tx + q*16][d]; }
            #pragma unroll
            for (int q = 0; q < 4; ++q)
                #pragma unroll
                for (int w = 0; w < 4; ++w) { float df = an[q] - am[w]; acc[q][w] = fmaf(df*df, il, acc[q][w]); }
        }
        float* A = ws + OFF_A + (size_t)e*N*N;
        #pragma unroll
        for (int q = 0; q < 4; ++q)
            #pragma unroll
            for (int w = 0; w < 4; ++w) {
                int nr = bn*64 + ty + q*16, mc = bm*64 + tx + w*16;
                float v = osv * __expf(-0.5f * acc[q][w]);
                if (nr == mc) v += nsv;
                A[(size_t)nr*N + mc] = v;
            }
        return;
    }
    int bidx = bid - E*64;
    int i = tid >> 4, j = tid & 15;
    if (bidx < E) {
        int e = bidx;
        __shared__ float Bm[16][17], BInv[16][17];
        float li = ls[e*D + i], lj = ls[e*D + j];
        Bm[i][j] = ws[OFF_SSM + i*D + j] / (li*lj) + ((i==j) ? 1.f : 0.f);
        BInv[i][j] = (i==j) ? 1.f : 0.f;
        __syncthreads();
        float det = 1.f;
        for (int k = 0; k < D; ++k) {
            float p   = Bm[k][k];
            float fik = Bm[i][k];
            float bkj = Bm[k][j];
            float ikj = BInv[k][j];
            __syncthreads();
            det *= p;
            if (i == k) { Bm[k][j] = bkj/p; BInv[k][j] = ikj/p; }
            else        { float f = fik/p; Bm[i][j] -= f*bkj; BInv[i][j] -= f*ikj; }
            __syncthreads();
        }
        ws[OFF_BINV + ((size_t)e*D + i)*D + j] = BInv[i][j];
        if (tid == 0) ws[OFF_C + e] = os[e] / sqrtf(det);
    } else {
        int pair = bidx - E;
        int a = pair / E, b = pair % E;
        __shared__ float Rm[16][17], RInv[16][17], ssl[16][17];
        float la = ls[a*D + j], lb2 = ls[b*D + j];
        float rj = 1.f/(la*la) + 1.f/(lb2*lb2);
        float ssv = ws[OFF_SSM + i*D + j];
        ssl[i][j] = ssv;
        Rm[i][j] = ssv * rj + ((i==j) ? 1.f : 0.f);
        RInv[i][j] = (i==j) ? 1.f : 0.f;
        __syncthreads();
        float det = 1.f;
        for (int k = 0; k < D; ++k) {
            float p   = Rm[k][k];
            float fik = Rm[i][k];
            float rkj = Rm[k][j];
            float ikj = RInv[k][j];
            __syncthreads();
            det *= p;
            if (i == k) { Rm[k][j] = rkj/p; RInv[k][j] = ikj/p; }
            else        { float f = fik/p; Rm[i][j] -= f*rkj; RInv[i][j] -= f*ikj; }
            __syncthreads();
        }
        float q = 0.f;
        #pragma unroll
        for (int k2 = 0; k2 < D; ++k2) q += RInv[i][k2] * ssl[k2][j];
        ws[OFF_Q + ((size_t)pair*D + i)*D + j] = 0.5f * q;
        if (tid == 0) ws[OFF_ISDR + pair] = 1.f / sqrtf(det);
    }
}

// ---------- 3a. first diag: fast factor + blocked inverse ----------
__global__ __launch_bounds__(256) void k_diag64(float* __restrict__ ws, int k0) {
    int e = blockIdx.x;
    int tid = threadIdx.x;
    int lane = tid & 63, wv = tid >> 6;
    const float* A = ws + OFF_A + (size_t)e*N*N;
    float* W = ws + OFF_IK + (size_t)e*N*N;
    __shared__ float Lsh[64][65], Xsh[64][65];
    __shared__ float cb[2][64];
    __shared__ float invd[64];
    __shared__ float Tsh[3][16][17];
    float a[16];
    #pragma unroll
    for (int j = 0; j < 16; ++j)
        a[j] = A[(size_t)(k0 + wv*16 + j)*N + k0 + lane];
    __syncthreads();
    fact64(a, cb, invd, lane, wv);
    #pragma unroll
    for (int j = 0; j < 16; ++j) Lsh[lane][wv*16 + j] = a[j];
    __syncthreads();
    binv64(Lsh, Xsh, invd, Tsh, tid);
    for (int idx = tid; idx < 4096; idx += 256) {
        int r = idx >> 6, c = idx & 63;
        W[(size_t)(k0 + r)*N + k0 + c] = Xsh[r][c];
    }
}

// ---------- 3b. merged trailing step: panel TRSM recompute + SYRK + fused diag + OFF_P persist ----------
__global__ __launch_bounds__(256) void k_traild(float* __restrict__ ws, int k0) {
    int kk = k0 >> 6;
    int t0 = k0 + 64;
    int nb = (N - t0) >> 6;
    int ntiles = (nb*(nb+1)) >> 1;
    int e = blockIdx.x / ntiles;
    int t = blockIdx.x % ntiles;
    int bj = 0; while (t >= nb - bj) { t -= nb - bj; ++bj; }
    int bi = bj + t;
    bool same = (bi == bj);
    bool isdiag0 = (bi == 0) && (bj == 0);
    float* A = ws + OFF_A + (size_t)e*N*N;
    const float* Wd = ws + OFF_IK + (size_t)e*N*N;
    __shared__ float Wsh[64][65], Sr[64][65], Sc[64][65];
    __shared__ float cb[2][64];
    __shared__ float invd[64];
    __shared__ float Tsh[3][16][17];
    int tid = threadIdx.x;
    int tx = tid & 15, ty = tid >> 4;

    load_tile4(Wd + (size_t)k0*N + k0, N, Wsh, tid);
    load_tile4(A + (size_t)(t0 + bi*64)*N + k0, N, Sr, tid);
    if (!same) load_tile4(A + (size_t)(t0 + bj*64)*N + k0, N, Sc, tid);
    __syncthreads();
    // panel TRSM via GEMM with W_kk = L_kk^{-1}
    float pr[4][4] = {}, pc[4][4] = {};
    if (same) {
        #pragma unroll 8
        for (int j = 0; j < 64; ++j) {
            float w4[4], a4[4];
            #pragma unroll
            for (int q = 0; q < 4; ++q) { w4[q] = Wsh[tx*4+q][j]; a4[q] = Sr[ty*4+q][j]; }
            #pragma unroll
            for (int q = 0; q < 4; ++q)
                #pragma unroll
                for (int w = 0; w < 4; ++w) pr[q][w] = fmaf(a4[q], w4[w], pr[q][w]);
        }
    } else {
        #pragma unroll 4
        for (int j = 0; j < 64; ++j) {
            float w4[4], a4[4], c4[4];
            #pragma unroll
            for (int q = 0; q < 4; ++q) { w4[q] = Wsh[tx*4+q][j]; a4[q] = Sr[ty*4+q][j]; c4[q] = Sc[ty*4+q][j]; }
            #pragma unroll
            for (int q = 0; q < 4; ++q)
                #pragma unroll
                for (int w = 0; w < 4; ++w) {
                    pr[q][w] = fmaf(a4[q], w4[w], pr[q][w]);
                    pc[q][w] = fmaf(c4[q], w4[w], pc[q][w]);
                }
        }
    }
    __syncthreads();
    #pragma unroll
    for (int q = 0; q < 4; ++q)
        #pragma unroll
        for (int w = 0; w < 4; ++w) Sr[ty*4+q][tx*4+w] = pr[q][w];
    if (!same) {
        #pragma unroll
        for (int q = 0; q < 4; ++q)
            #pragma unroll
            for (int w = 0; w < 4; ++w) Sc[ty*4+q][tx*4+w] = pc[q][w];
    }
    __syncthreads();
    // designated writer: (bi, 0) persists final L-panel tile bi into OFF_P
    if (bj == 0) {
        float* Pp = ws + OFF_P + ((size_t)e*1792 + prow(kk) + (size_t)bi*64)*64;
        #pragma unroll
        for (int j = 0; j < 4; ++j) {
            int idx = tid + j*256;
            int r = idx >> 6, c = idx & 63;
            Pp[(size_t)r*64 + c] = Sr[r][c];
        }
    }
    // SYRK
    float acc[4][4] = {};
    if (same) {
        #pragma unroll 8
        for (int p = 0; p < 64; ++p) {
            float ar[4], ac[4];
            #pragma unroll
            for (int q = 0; q < 4; ++q) { ar[q] = Sr[ty*4+q][p]; ac[q] = Sr[tx*4+q][p]; }
            #pragma unroll
            for (int q = 0; q < 4; ++q)
                #pragma unroll
                for (int w = 0; w < 4; ++w) acc[q][w] = fmaf(ar[q], ac[w], acc[q][w]);
        }
    } else {
        #pragma unroll 8
        for (int p = 0; p < 64; ++p) {
            float ar[4], ac[4];
            #pragma unroll
            for (int q = 0; q < 4; ++q) { ar[q] = Sr[ty*4+q][p]; ac[q] = Sc[tx*4+q][p]; }
            #pragma unroll
            for (int q = 0; q < 4; ++q)
                #pragma unroll
                for (int w = 0; w < 4; ++w) acc[q][w] = fmaf(ar[q], ac[w], acc[q][w]);
        }
    }
    float* Out = A + (size_t)(t0 + bi*64)*N + (t0 + bj*64);
    if (!isdiag0) {
        #pragma unroll
        for (int q = 0; q < 4; ++q)
            #pragma unroll
            for (int w = 0; w < 4; ++w)
                Out[(size_t)(ty*4+q)*N + tx*4+w] -= acc[q][w];
        return;
    }
    // ---- fused: updated (t0,t0) tile -> fast factor + blocked invert -> W diag ----
    __syncthreads();
    #pragma unroll
    for (int q = 0; q < 4; ++q)
        #pragma unroll
        for (int w = 0; w < 4; ++w)
            Sc[ty*4+q][tx*4+w] = Out[(size_t)(ty*4+q)*N + tx*4+w] - acc[q][w];
    __syncthreads();
    int lane = tid & 63, wv = tid >> 6;
    float a[16];
    #pragma unroll
    for (int j = 0; j < 16; ++j) a[j] = Sc[lane][wv*16 + j];   // tile symmetric
    __syncthreads();
    fact64(a, cb, invd, lane, wv);
    #pragma unroll
    for (int j = 0; j < 16; ++j) Sc[lane][wv*16 + j] = a[j];   // Sc becomes Lsh
    __syncthreads();
    binv64(Sc, Sr, invd, Tsh, tid);                            // Sr becomes Xsh
    float* W = ws + OFF_IK + (size_t)e*N*N;
    for (int idx = tid; idx < 4096; idx += 256) {
        int r = idx >> 6, c = idx & 63;
        W[(size_t)(t0 + r)*N + t0 + c] = Sr[r][c];
    }
}

// ---------- 3d. D&C level 1 (H=1): W21 = -W22 L21 W11 ----------
__global__ __launch_bounds__(256) void k_dc1(float* __restrict__ ws) {
    int e = blockIdx.x >> 2, p = blockIdx.x & 3;
    float* W = ws + OFF_IK + (size_t)e*N*N;
    const float* Lt = ws + OFF_P + ((size_t)e*1792 + prow(2*p))*64;
    __shared__ float Sa[64][65], Sb[64][65], T[64][65];
    int tid = threadIdx.x;
    int tx = tid & 15, ty = tid >> 4;
    load_tile4(Lt, 64, Sa, tid);
    load_tile4(W + (size_t)(2*p*64)*N + 2*p*64, N, Sb, tid);
    __syncthreads();
    float acc[4][4] = {};
    #pragma unroll 8
    for (int pp = 0; pp < 64; ++pp) {
        float ar[4], bc[4];
        #pragma unroll
        for (int q = 0; q < 4; ++q) { ar[q] = Sa[ty*4+q][pp]; bc[q] = Sb[pp][tx*4+q]; }
        #pragma unroll
        for (int q = 0; q < 4; ++q)
            #pragma unroll
            for (int w = 0; w < 4; ++w) acc[q][w] = fmaf(ar[q], bc[w], acc[q][w]);
    }
    #pragma unroll
    for (int q = 0; q < 4; ++q)
        #pragma unroll
        for (int w = 0; w < 4; ++w) T[ty*4+q][tx*4+w] = acc[q][w];
    __syncthreads();
    load_tile4(W + (size_t)((2*p+1)*64)*N + (2*p+1)*64, N, Sa, tid);
    __syncthreads();
    float o[4][4] = {};
    #pragma unroll 8
    for (int pp = 0; pp < 64; ++pp) {
        float ar[4], bc[4];
        #pragma unroll
        for (int q = 0; q < 4; ++q) { ar[q] = Sa[ty*4+q][pp]; bc[q] = T[pp][tx*4+q]; }
        #pragma unroll
        for (int q = 0; q < 4; ++q)
            #pragma unroll
            for (int w = 0; w < 4; ++w) o[q][w] = fmaf(ar[q], bc[w], o[q][w]);
    }
    #pragma unroll
    for (int q = 0; q < 4; ++q)
        #pragma unroll
        for (int w = 0; w < 4; ++w)
            W[(size_t)((2*p+1)*64 + ty*4 + q)*N + 2*p*64 + tx*4 + w] = -o[q][w];
}

// ---------- 3e. D&C: T = L21 * W11 (levels H=2,4) ----------
__global__ __launch_bounds__(256) void k_dcT(float* __restrict__ ws, int H) {
    int per_e = 4*H;
    int e = blockIdx.x / per_e;
    int rem = blockIdx.x % per_e;
    int p  = rem / (H*H);
    int tt = rem % (H*H);
    int ti = tt / H, tj = tt % H;
    int C0 = 2*p*H;
    int I  = C0 + H + ti;
    const float* W = ws + OFF_IK + (size_t)e*N*N;
    float* Tt = ws + OFF_T + (size_t)e*65536 + (size_t)(p*H*H + ti*H + tj)*4096;
    __shared__ float Sa[64][65], Sb[64][65];
    int tid = threadIdx.x;
    int tx = tid & 15, ty = tid >> 4;
    float acc[4][4] = {};
    for (int k = tj; k < H; ++k) {
        int K = C0 + k;
        const float* Lt = ws + OFF_P + ((size_t)e*1792 + prow(K) + (size_t)(I - K - 1)*64)*64;
        __syncthreads();
        load_tile4(Lt, 64, Sa, tid);
        load_tile4(W + (size_t)(K*64)*N + (C0 + tj)*64, N, Sb, tid);
        __syncthreads();
        #pragma unroll 8
        for (int pp = 0; pp < 64; ++pp) {
            float ar[4], bc[4];
            #pragma unroll
            for (int q = 0; q < 4; ++q) { ar[q] = Sa[ty*4+q][pp]; bc[q] = Sb[pp][tx*4+q]; }
            #pragma unroll
            for (int q = 0; q < 4; ++q)
                #pragma unroll
                for (int w = 0; w < 4; ++w) acc[q][w] = fmaf(ar[q], bc[w], acc[q][w]);
        }
    }
    #pragma unroll
    for (int q = 0; q < 4; ++q)
        #pragma unroll
        for (int w = 0; w < 4; ++w)
            Tt[(size_t)(ty*4+q)*64 + tx*4 + w] = acc[q][w];
}

// ---------- 3f. D&C: W21 = -W22 * T ----------
__global__ __launch_bounds__(256) void k_dcW(float* __restrict__ ws, int H) {
    int per_e = 4*H;
    int e = blockIdx.x / per_e;
    int rem = blockIdx.x % per_e;
    int p  = rem / (H*H);
    int tt = rem % (H*H);
    int ti = tt / H, tj = tt % H;
    int C0 = 2*p*H, R0 = C0 + H;
    float* W = ws + OFF_IK + (size_t)e*N*N;
    const float* Tbase = ws + OFF_T + (size_t)e*65536 + (size_t)(p*H*H)*4096;
    __shared__ float Sa[64][65], Sb[64][65];
    int tid = threadIdx.x;
    int tx = tid & 15, ty = tid >> 4;
    float acc[4][4] = {};
    for (int tk = 0; tk <= ti; ++tk) {
        const float* Tt = Tbase + (size_t)(tk*H + tj)*4096;
        __syncthreads();
        load_tile4(W + (size_t)((R0 + ti)*64)*N + (R0 + tk)*64, N, Sa, tid);
        load_tile4(Tt, 64, Sb, tid);
        __syncthreads();
        #pragma unroll 8
        for (int pp = 0; pp < 64; ++pp) {
            float ar[4], bc[4];
            #pragma unroll
            for (int q = 0; q < 4; ++q) { ar[q] = Sa[ty*4+q][pp]; bc[q] = Sb[pp][tx*4+q]; }
            #pragma unroll
            for (int q = 0; q < 4; ++q)
                #pragma unroll
                for (int w = 0; w < 4; ++w) acc[q][w] = fmaf(ar[q], bc[w], acc[q][w]);
        }
    }
    #pragma unroll
    for (int q = 0; q < 4; ++q)
        #pragma unroll
        for (int w = 0; w < 4; ++w)
            W[(size_t)((R0 + ti)*64 + ty*4 + q)*N + (C0 + tj)*64 + tx*4 + w] = -acc[q][w];
}

// ---------- 3g. iK = W^T W  +  appended xs blocks (U/V precompute) ----------
__global__ __launch_bounds__(256) void k_syrk(float* __restrict__ ws, const float* __restrict__ ls,
                                              const float* __restrict__ os) {
    int tid = threadIdx.x;
    if (blockIdx.x >= E*36) {
        int t = (blockIdx.x - E*36)*256 + tid;
        xs_body(ws, ls, os, t, tid);
        return;
    }
    int e = blockIdx.x / 36;
    int t = blockIdx.x % 36;
    int bj = 0; while (t >= 8 - bj) { t -= 8 - bj; ++bj; }
    int bi = bj + t;
    bool same = (bi == bj);
    const float* W = ws + OFF_IK + (size_t)e*N*N;
    float*      IK = ws + OFF_A  + (size_t)e*N*N;
    __shared__ float Sa[64][65], Sb[64][65];
    int tx = tid & 15, ty = tid >> 4;

    float4 pa[4], pb[4];
    #pragma unroll
    for (int j = 0; j < 4; ++j) {
        int idx = tid + j*256;
        int r = idx >> 4, c4 = idx & 15;
        pa[j] = *(const float4*)&W[(size_t)(bi*64 + r)*N + bi*64 + c4*4];
        if (!same) pb[j] = *(const float4*)&W[(size_t)(bi*64 + r)*N + bj*64 + c4*4];
    }

    float acc[4][4] = {};
    for (int p = bi; p < 8; ++p) {
        __syncthreads();
        #pragma unroll
        for (int j = 0; j < 4; ++j) {
            int idx = tid + j*256;
            int r = idx >> 4, c4 = idx & 15;
            Sa[r][c4*4+0] = pa[j].x; Sa[r][c4*4+1] = pa[j].y; Sa[r][c4*4+2] = pa[j].z; Sa[r][c4*4+3] = pa[j].w;
            if (!same) { Sb[r][c4*4+0] = pb[j].x; Sb[r][c4*4+1] = pb[j].y; Sb[r][c4*4+2] = pb[j].z; Sb[r][c4*4+3] = pb[j].w; }
        }
        if (p < 7) {
            #pragma unroll
            for (int j = 0; j < 4; ++j) {
                int idx = tid + j*256;
                int r = idx >> 4, c4 = idx & 15;
                pa[j] = *(const float4*)&W[(size_t)((p+1)*64 + r)*N + bi*64 + c4*4];
                if (!same) pb[j] = *(const float4*)&W[(size_t)((p+1)*64 + r)*N + bj*64 + c4*4];
            }
        }
        __syncthreads();
        if (same) {
            #pragma unroll 8
            for (int pr2 = 0; pr2 < 64; ++pr2) {
                float ar[4], ac[4];
                #pragma unroll
                for (int q = 0; q < 4; ++q) { ar[q] = Sa[pr2][ty*4+q]; ac[q] = Sa[pr2][tx*4+q]; }
                #pragma unroll
                for (int q = 0; q < 4; ++q)
                    #pragma unroll
                    for (int w = 0; w < 4; ++w) acc[q][w] = fmaf(ar[q], ac[w], acc[q][w]);
            }
        } else {
            #pragma unroll 8
            for (int pr2 = 0; pr2 < 64; ++pr2) {
                float ar[4], ac[4];
                #pragma unroll
                for (int q = 0; q < 4; ++q) { ar[q] = Sa[pr2][ty*4+q]; ac[q] = Sb[pr2][tx*4+q]; }
                #pragma unroll
                for (int q = 0; q < 4; ++q)
                    #pragma unroll
                    for (int w = 0; w < 4; ++w) acc[q][w] = fmaf(ar[q], ac[w], acc[q][w]);
            }
        }
    }
    #pragma unroll
    for (int q = 0; q < 4; ++q)
        #pragma unroll
        for (int w = 0; w < 4; ++w) {
            int r = bi*64 + ty*4 + q, c = bj*64 + tx*4 + w;
            IK[(size_t)r*N + c] = acc[q][w];
            IK[(size_t)c*N + r] = acc[q][w];
        }
}

// ---------- 3h. beta = iK @ Yn ----------
__global__ __launch_bounds__(256) void k_beta(float* __restrict__ ws) {
    int e = blockIdx.x >> 2, qtr = blockIdx.x & 3;
    int tid = threadIdx.x;
    int half = tid >> 7;
    int nl = tid & 127;
    int n = qtr*128 + nl;
    __shared__ float yn[N];
    __shared__ float part[2][128];
    for (int i = tid; i < N; i += 256) yn[i] = ws[OFF_YN + (size_t)e*N + i];
    __syncthreads();
    const float* IK = ws + OFF_A + (size_t)e*N*N;
    int m0 = half*256;
    float a0 = 0.f, a1 = 0.f, a2 = 0.f, a3 = 0.f;
    for (int mm = m0; mm < m0 + 256; mm += 4) {
        a0 = fmaf(IK[(size_t)mm*N + n],     yn[mm],   a0);
        a1 = fmaf(IK[(size_t)(mm+1)*N + n], yn[mm+1], a1);
        a2 = fmaf(IK[(size_t)(mm+2)*N + n], yn[mm+2], a2);
        a3 = fmaf(IK[(size_t)(mm+3)*N + n], yn[mm+3], a3);
    }
    part[half][nl] = (a0 + a1) + (a2 + a3);
    __syncthreads();
    if (tid < 128)
        ws[OFF_BETA + e*N + qtr*128 + tid] = part[0][tid] + part[1][tid];
}

// ---------- 7. big cross-term (compact pairs) + appended point blocks ----------
__global__ __launch_bounds__(256) void k_S(float* __restrict__ ws, const float* __restrict__ ls,
                                           const float* __restrict__ os) {
    int tid = threadIdx.x;
    if (blockIdx.x >= NPAIR*8) {
        int t = (blockIdx.x - NPAIR*8)*256 + tid;
        point_body(ws, ls, t);
        return;
    }
    int bid = blockIdx.x;            // NPAIR * 8
    int pc = bid >> 3, ntile = bid & 7;
    int a, b;
    pc2ab(pc, a, b);
    int pairQ = a*E + b;
    int tx = tid & 15, ty = tid >> 4;
    __shared__ float Qs[16][17];
    __shared__ float i2a[16], i2b[16];
    __shared__ float __align__(16) bufAT[16][68];
    __shared__ float __align__(16) x1qT[16][68];
    __shared__ float __align__(16) bufBT[16][68];
    __shared__ float u_s[64], v_s[64], ba_s[64], bb_s[64];
    __shared__ float red[256];
    int n0 = ntile*64;
    Qs[tid >> 4][tid & 15] = ws[OFF_Q + (size_t)pairQ*D*D + tid];
    if (tid < 16) { float l = ls[a*D + tid]; i2a[tid] = 1.0f/(l*l); }
    else if (tid < 32) { int d = tid-16; float l = ls[b*D + d]; i2b[d] = 1.0f/(l*l); }
    __syncthreads();
    for (int idx = tid; idx < 1024; idx += 256) {
        int r = idx >> 4, d = idx & 15;
        bufAT[d][r] = ws[OFF_INP + (size_t)(n0 + r)*D + d] * i2a[d];
    }
    __syncthreads();
    for (int idx = tid; idx < 1024; idx += 256) {
        int r = idx >> 4, j = idx & 15;
        float s = 0.f;
        #pragma unroll
        for (int i = 0; i < 16; ++i) s = fmaf(bufAT[i][r], Qs[i][j], s);
        x1qT[j][r] = s;
    }
    if (tid < 64) {
        u_s[tid]  = ws[OFF_U + (size_t)pc*N + n0 + tid];
        ba_s[tid] = ws[OFF_BETA + a*N + n0 + tid];
    }
    __syncthreads();
    float4 av4[16];
    #pragma unroll
    for (int d = 0; d < 16; ++d) av4[d] = *(const float4*)&x1qT[d][ty*4];
    float uq[4], baq[4];
    #pragma unroll
    for (int q = 0; q < 4; ++q) { uq[q] = u_s[ty*4+q]; baq[q] = ba_s[ty*4+q]; }

    float pf[4];
    #pragma unroll
    for (int j = 0; j < 4; ++j) {
        int idx = tid + j*256;
        pf[j] = ws[OFF_INP + (size_t)((idx >> 4))*D + (idx & 15)];
    }
    float vpf = 0.f, bpf = 0.f;
    if (tid < 64) {
        vpf = ws[OFF_V + (size_t)pc*N + tid];
        bpf = ws[OFF_BETA + b*N + tid];
    }

    float sacc = 0.f, tacc = 0.f;
    for (int mt = 0; mt < 8; ++mt) {
        __syncthreads();
        #pragma unroll
        for (int j = 0; j < 4; ++j) {
            int idx = tid + j*256;
            bufBT[idx & 15][idx >> 4] = pf[j] * i2b[idx & 15];
        }
        if (tid < 64) { v_s[tid] = vpf; bb_s[tid] = bpf; }
        if (mt < 7) {
            #pragma unroll
            for (int j = 0; j < 4; ++j) {
                int idx = tid + j*256;
                pf[j] = ws[OFF_INP + (size_t)((mt+1)*64 + (idx >> 4))*D + (idx & 15)];
            }
            if (tid < 64) {
                vpf = ws[OFF_V + (size_t)pc*N + (mt+1)*64 + tid];
                bpf = ws[OFF_BETA + b*N + (mt+1)*64 + tid];
            }
        }
        __syncthreads();
        float dacc[4][4] = {};
        #pragma unroll
        for (int d = 0; d < 16; ++d) {
            float4 bv = *(const float4*)&bufBT[d][tx*4];
            float4 av = av4[d];
            dacc[0][0] = fmaf(av.x, bv.x, dacc[0][0]); dacc[0][1] = fmaf(av.x, bv.y, dacc[0][1]);
            dacc[0][2] = fmaf(av.x, bv.z, dacc[0][2]); dacc[0][3] = fmaf(av.x, bv.w, dacc[0][3]);
            dacc[1][0] = fmaf(av.y, bv.x, dacc[1][0]); dacc[1][1] = fmaf(av.y, bv.y, dacc[1][1]);
            dacc[1][2] = fmaf(av.y, bv.z, dacc[1][2]); dacc[1][3] = fmaf(av.y, bv.w, dacc[1][3]);
            dacc[2][0] = fmaf(av.z, bv.x, dacc[2][0]); dacc[2][1] = fmaf(av.z, bv.y, dacc[2][1]);
            dacc[2][2] = fmaf(av.z, bv.z, dacc[2][2]); dacc[2][3] = fmaf(av.z, bv.w, dacc[2][3]);
            dacc[3][0] = fmaf(av.w, bv.x, dacc[3][0]); dacc[3][1] = fmaf(av.w, bv.y, dacc[3][1]);
            dacc[3][2] = fmaf(av.w, bv.z, dacc[3][2]); dacc[3][3] = fmaf(av.w, bv.w, dacc[3][3]);
        }
        #pragma unroll
        for (int q = 0; q < 4; ++q) {
            float ikq[4];
            if (a == b)
                *(float4*)ikq = *(const float4*)&ws[OFF_A + ((size_t)a*N + n0 + ty*4 + q)*N + mt*64 + tx*4];
            #pragma unroll
            for (int w = 0; w < 4; ++w) {
                float Lv = __expf(2.f*dacc[q][w] + uq[q] + v_s[tx*4+w]);
                sacc = fmaf(baq[q] * bb_s[tx*4+w], Lv, sacc);
                if (a == b)
                    tacc = fmaf(ikq[w], Lv, tacc);
            }
        }
    }
    red[tid] = sacc; __syncthreads();
    for (int o = 128; o > 0; o >>= 1) { if (tid < o) red[tid] += red[tid+o]; __syncthreads(); }
    if (tid == 0) ws[OFF_SPART + bid] = red[0];
    if (a == b) {
        __syncthreads();
        red[tid] = tacc; __syncthreads();
        for (int o = 128; o > 0; o >>= 1) { if (tid < o) red[tid] += red[tid+o]; __syncthreads(); }
        if (tid == 0) ws[OFF_TPART + a*8 + ntile] = red[0];
    }
}

// ---------- 8. finalize ----------
__global__ __launch_bounds__(256) void k_final(float* __restrict__ ws, const float* __restrict__ s,
                                               const float* __restrict__ os, float* __restrict__ out) {
    int tid = threadIdx.x;
    __shared__ float Msh[E], Vsh[E][D], cov[D][E+1];
    __shared__ float Sm[16][17], Si[16][17];
    __shared__ float vred[16][17];

    {
        int wv = tid >> 6, lane = tid & 63;
        for (int e = wv; e < E; e += 4) {
            float sum = 0.f;
            #pragma unroll
            for (int i = 0; i < 8; ++i) sum += ws[OFF_LB + e*N + i*64 + lane];
            #pragma unroll
            for (int off = 32; off > 0; off >>= 1) sum += __shfl_xor(sum, off);
            if (lane == 0) Msh[e] = ws[OFF_C + e] * sum;
        }
    }
    for (int e = 0; e < E; ++e) {
        int d = tid & 15, sl = tid >> 4;
        float acc = 0.f;
        for (int i = 0; i < 32; ++i) {
            int n = sl*32 + i;
            acc = fmaf(ws[OFF_TIL + ((size_t)e*N + n)*D + d], ws[OFF_LB + e*N + n], acc);
        }
        vred[sl][d] = acc;
        __syncthreads();
        if (tid < 16) {
            float sum = 0.f;
            #pragma unroll
            for (int s2 = 0; s2 < 16; ++s2) sum += vred[s2][tid];
            Vsh[e][tid] = ws[OFF_C + e] * sum;
        }
        __syncthreads();
    }

    if (tid < E*E) {
        int a = tid / E, bb = tid % E;
        int amin = (a < bb) ? a : bb;
        int amax = (a < bb) ? bb : a;
        int pc = amin*E - (amin*(amin-1))/2 + (amax - amin);
        float acc = 0.f;
        for (int q = 0; q < 8; ++q) acc += ws[OFF_SPART + (size_t)pc*8 + q];
        if (a == bb) {
            float tr = 0.f;
            for (int q = 0; q < 8; ++q) tr += ws[OFF_TPART + a*8 + q];
            acc -= tr;
        }
        acc *= ws[OFF_ISDR + tid];
        if (a == bb) acc += os[a];
        float v = acc - Msh[a]*Msh[bb];
        v *= ws[OFF_YSTD + a] * ws[OFF_YSTD + bb];
        out[E + tid] = v;
    }
    if (tid < E) out[tid] = Msh[tid]*ws[OFF_YSTD + tid] + ws[OFF_YMEAN + tid];

    if (tid < D*E) {
        int d = tid / E, e = tid % E;
        float acc = 0.f;
        for (int k = 0; k < D; ++k) acc += ws[OFF_SSM + d*D + k] * Vsh[e][k];
        cov[d][e] = acc * ws[OFF_XSTD + d] * ws[OFF_YSTD + e];
    }
    int i = tid >> 4, j = tid & 15;
    Sm[i][j] = s[i*D + j];
    Si[i][j] = (i==j) ? 1.f : 0.f;
    __syncthreads();
    for (int k = 0; k < D; ++k) {
        float p   = Sm[k][k];
        float fik = Sm[i][k];
        float skj = Sm[k][j];
        float ikj = Si[k][j];
        __syncthreads();
        if (i == k) { Sm[k][j] = skj/p; Si[k][j] = ikj/p; }
        else        { float f = fik/p; Sm[i][j] -= f*skj; Si[i][j] -= f*ikj; }
        __syncthreads();
    }
    if (tid < D*E) {
        int d = tid / E, e = tid % E;
        float acc = 0.f;
        for (int k = 0; k < D; ++k) acc += Si[d][k] * cov[k][e];
        out[E + E*E + d*E + e] = acc;
    }
}

extern "C" void kernel_launch(void* const* d_in, const int* in_sizes, int n_in,
                              void* d_out, int out_size, void* d_ws, size_t ws_size,
                              hipStream_t stream) {
    const float* X     = (const float*)d_in[0];
    const float* Y     = (const float*)d_in[1];
    const float* m     = (const float*)d_in[2];
    const float* s     = (const float*)d_in[3];
    const float* ls    = (const float*)d_in[4];
    const float* os    = (const float*)d_in[5];
    const float* noise = (const float*)d_in[6];
    float* ws  = (float*)d_ws;
    float* out = (float*)d_out;

    k_prep   <<<1,              512, 0, stream>>>(X, Y, m, s, ws);
    k_buildA <<<E*64 + E + E*E, 256, 0, stream>>>(ws, ls, os, noise);
    k_diag64 <<<E,              256, 0, stream>>>(ws, 0);
    for (int kk = 0; kk < 7; ++kk) {
        int nb = 7 - kk;
        k_traild<<<E*nb*(nb+1)/2, 256, 0, stream>>>(ws, kk*64);
    }
    k_dc1 <<<E*4,  256, 0, stream>>>(ws);
    k_dcT <<<E*8,  256, 0, stream>>>(ws, 2);
    k_dcW <<<E*8,  256, 0, stream>>>(ws, 2);
    k_dcT <<<E*16, 256, 0, stream>>>(ws, 4);
    k_dcW <<<E*16, 256, 0, stream>>>(ws, 4);
    k_syrk <<<E*36 + NPAIR*N/256,   256, 0, stream>>>(ws, ls, os);
    k_beta <<<E*4,                  256, 0, stream>>>(ws);
    k_S    <<<NPAIR*8 + E*N/256,    256, 0, stream>>>(ws, ls, os);
    k_final<<<1,                    256, 0, stream>>>(ws, s, os, out);
}

// Round 20
// 482.192 us; speedup vs baseline: 1.7698x; 1.0210x over previous
//
#include <hip/hip_runtime.h>
#include <math.h>

constexpr int N = 512;
constexpr int D = 16;
constexpr int E = 12;
constexpr int NPAIR = E*(E+1)/2;   // 78 compact pairs (a<=b)

// ---- workspace layout (float offsets) ----
constexpr size_t OFF_A     = 0;                            // E*N*N  A -> trail -> iK
constexpr size_t OFF_IK    = OFF_A    + (size_t)E*N*N;     // E*N*N  W = L^{-1}
constexpr size_t OFF_XS    = OFF_IK   + (size_t)E*N*N;     // N*D
constexpr size_t OFF_INP   = OFF_XS   + (size_t)N*D;       // N*D
constexpr size_t OFF_YN    = OFF_INP  + (size_t)N*D;       // E*N
constexpr size_t OFF_BETA  = OFF_YN   + (size_t)E*N;       // E*N
constexpr size_t OFF_KVEC  = OFF_BETA + (size_t)E*N;       // E*N (unused)
constexpr size_t OFF_LB    = OFF_KVEC + (size_t)E*N;       // E*N
constexpr size_t OFF_TIL   = OFF_LB   + (size_t)E*N;       // E*N*D
constexpr size_t OFF_U     = OFF_TIL  + (size_t)E*N*D;     // NPAIR*N (compact)
constexpr size_t OFF_V     = OFF_U    + (size_t)E*E*N;     // NPAIR*N (compact)
constexpr size_t OFF_Q     = OFF_V    + (size_t)E*E*N;     // E*E*D*D
constexpr size_t OFF_BINV  = OFF_Q    + (size_t)E*E*D*D;   // E*D*D
constexpr size_t OFF_C     = OFF_BINV + (size_t)E*D*D;     // E
constexpr size_t OFF_ISDR  = OFF_C    + E;                 // E*E
constexpr size_t OFF_SPART = OFF_ISDR + E*E;               // NPAIR*8
constexpr size_t OFF_TPART = OFF_SPART+ (size_t)E*E*8;     // E*8
constexpr size_t OFF_XMEAN = OFF_TPART+ (size_t)E*8;       // D
constexpr size_t OFF_XSTD  = OFF_XMEAN+ D;                 // D
constexpr size_t OFF_YMEAN = OFF_XSTD + D;                 // E
constexpr size_t OFF_YSTD  = OFF_YMEAN+ E;                 // E
constexpr size_t OFF_SSM   = OFF_YSTD + E;                 // D*D
constexpr size_t OFF_P     = OFF_SSM  + D*D;               // E*1792*64  (L panels, compact)
constexpr size_t OFF_T     = OFF_P    + (size_t)E*1792*64; // E*65536    (D&C scratch)

__device__ __forceinline__ int prow(int k) { return k*(480 - 32*k); }  // row offset of panel k

// compact pair index helpers (a<=b)
__device__ __forceinline__ void pc2ab(int pc, int& a, int& b) {
    int aa = 0, t = pc;
    while (t >= E - aa) { t -= E - aa; ++aa; }
    a = aa; b = aa + t;
}

// ======== fast 64x64 Cholesky: column-split registers, 1 barrier/step, no spill ========
__device__ __forceinline__ void fact64(float a[16], float (*cb)[64], float* invd, int lane, int wv) {
    #pragma unroll
    for (int k = 0; k < 64; ++k) {
        const int kg = k >> 4, kj = k & 15;
        if (wv == kg) {
            float dkk = __shfl(a[kj], k);
            float dv = sqrtf(dkk);
            float iv = 1.0f / dv;
            float sc = a[kj] * iv;
            if (lane == k)      { a[kj] = dv; invd[k] = iv; }
            else if (lane > k)  a[kj] = sc;
            cb[k & 1][lane] = (lane > k) ? a[kj] : 0.0f;
        }
        __syncthreads();
        float lrk = cb[k & 1][lane];
        #pragma unroll
        for (int j = 0; j < 16; ++j)
            a[j] = fmaf(-lrk, cb[k & 1][wv*16 + j], a[j]);
    }
}

// ======== blocked in-LDS 64x64 triangular inverse: short critical path ========
__device__ __forceinline__ void binv64(const float (*Lsh)[65], float (*Xsh)[65],
                                       const float* invd, float (*Tsh)[16][17], int tid) {
    if (tid < 64) {
        int g = tid >> 4, c = tid & 15;
        int b = g*16;
        for (int r = 0; r < c; ++r) Xsh[b+r][b+c] = 0.f;
        for (int r = c; r < 16; ++r) {
            float acc = (r == c) ? 1.0f : 0.0f;
            for (int k = c; k < r; ++k)
                acc = fmaf(-Lsh[b+r][b+k], Xsh[b+k][b+c], acc);
            Xsh[b+r][b+c] = acc * invd[b+r];
        }
    } else {
        const int bis[6] = {0,0,0,1,1,2};
        const int bjs[6] = {1,2,3,2,3,3};
        for (int idx = tid - 64; idx < 1536; idx += 192) {
            int blk = idx >> 8, off = idx & 255;
            Xsh[bis[blk]*16 + (off >> 4)][bjs[blk]*16 + (off & 15)] = 0.f;
        }
    }
    __syncthreads();
    for (int d = 1; d <= 3; ++d) {
        int np = 4 - d;
        for (int idx = tid; idx < np*256; idx += 256) {
            int p = idx >> 8, off = idx & 255;
            int r = off >> 4, c = off & 15;
            int i = p + d, j = p;
            float acc = 0.f;
            for (int k = j; k < i; ++k)
                #pragma unroll
                for (int m = 0; m < 16; ++m)
                    acc = fmaf(Lsh[i*16+r][k*16+m], Xsh[k*16+m][j*16+c], acc);
            Tsh[p][r][c] = acc;
        }
        __syncthreads();
        for (int idx = tid; idx < np*256; idx += 256) {
            int p = idx >> 8, off = idx & 255;
            int r = off >> 4, c = off & 15;
            int i = p + d, j = p;
            float acc = 0.f;
            #pragma unroll
            for (int m = 0; m < 16; ++m)
                acc = fmaf(Xsh[i*16+r][i*16+m], Tsh[p][m][c], acc);
            Xsh[i*16+r][j*16+c] = -acc;
        }
        __syncthreads();
    }
}

// ======== vectorized 64x64 tile load ========
__device__ __forceinline__ void load_tile4(const float* __restrict__ g, size_t ldg,
                                           float (*S)[65], int tid) {
    #pragma unroll
    for (int j = 0; j < 4; ++j) {
        int idx = tid + j*256;
        int r = idx >> 4, c4 = idx & 15;
        float4 v = *(const float4*)&g[(size_t)r*ldg + c4*4];
        S[r][c4*4+0] = v.x; S[r][c4*4+1] = v.y; S[r][c4*4+2] = v.z; S[r][c4*4+3] = v.w;
    }
}

// ======== xs body: U/V for compact pair pc, point n ========
__device__ __forceinline__ void xs_body(float* __restrict__ ws, const float* __restrict__ ls,
                                        const float* __restrict__ os, int t, int tid) {
    int pc = t / N, n = t % N;
    int a, b;
    pc2ab(pc, a, b);
    int pairQ = a*E + b;
    __shared__ float Qs[16][17];
    __shared__ float i2a[16], i2b[16];
    Qs[tid >> 4][tid & 15] = ws[OFF_Q + (size_t)pairQ*D*D + tid];
    if (tid < 16) { float l = ls[a*D + tid]; i2a[tid] = 1.0f/(l*l); }
    else if (tid < 32) { int d = tid-16; float l = ls[b*D + d]; i2b[d] = 1.0f/(l*l); }
    __syncthreads();
    float x1[D], x2[D];
    float siNa = 0.f, siNb = 0.f;
    #pragma unroll
    for (int d = 0; d < D; ++d) {
        float ip = ws[OFF_INP + n*D + d];
        x1[d] = ip * i2a[d];
        x2[d] = ip * i2b[d];
        siNa = fmaf(ip*ip, i2a[d], siNa);
        siNb = fmaf(ip*ip, i2b[d], siNb);
    }
    float xs1 = 0.f, xs2 = 0.f;
    #pragma unroll
    for (int j = 0; j < D; ++j) {
        float t1 = 0.f, t2 = 0.f;
        #pragma unroll
        for (int i = 0; i < D; ++i) { t1 = fmaf(x1[i], Qs[i][j], t1); t2 = fmaf(x2[i], Qs[i][j], t2); }
        xs1 = fmaf(t1, x1[j], xs1);
        xs2 = fmaf(t2, x2[j], xs2);
    }
    float loa = logf(os[a]), lob = logf(os[b]);
    ws[OFF_U + (size_t)pc*N + n] = loa - 0.5f*siNa + xs1;
    ws[OFF_V + (size_t)pc*N + n] = lob - 0.5f*siNb + xs2;
}

// ======== point body: iN, t, lb, tiL for (e,n) ========
__device__ __forceinline__ void point_body(float* __restrict__ ws, const float* __restrict__ ls,
                                           int t) {
    int e = t >> 9, n = t & 511;
    float iN[D], tt[D], l[D];
    #pragma unroll
    for (int d = 0; d < D; ++d) { l[d] = ls[e*D + d]; iN[d] = ws[OFF_INP + n*D + d] / l[d]; }
    #pragma unroll
    for (int d = 0; d < D; ++d) {
        float acc = 0.f;
        #pragma unroll
        for (int j = 0; j < D; ++j) acc += ws[OFF_BINV + ((size_t)e*D + d)*D + j] * iN[j];
        tt[d] = acc;
    }
    float siNt = 0.f;
    #pragma unroll
    for (int d = 0; d < D; ++d) siNt += iN[d]*tt[d];
    float lbv = __expf(-0.5f * siNt) * ws[OFF_BETA + e*N + n];
    ws[OFF_LB + e*N + n] = lbv;
    #pragma unroll
    for (int d = 0; d < D; ++d) ws[OFF_TIL + ((size_t)e*N + n)*D + d] = tt[d] / l[d];
}

// ---------- 1. standardization ----------
__global__ __launch_bounds__(512) void k_prep(const float* __restrict__ X, const float* __restrict__ Y,
                                              const float* __restrict__ m, const float* __restrict__ s,
                                              float* __restrict__ ws) {
    int tid = threadIdx.x;
    int lane = tid & 63, wave = tid >> 6;
    __shared__ float meanX[D], stdX[D], meanY[E], stdY[E], mmsh[D];

    for (int col = wave; col < D + E; col += 8) {
        float s1 = 0.f, s2 = 0.f;
        if (col < D) {
            #pragma unroll
            for (int i = 0; i < 8; ++i) { float v = X[(i*64 + lane)*D + col]; s1 += v; s2 += v*v; }
        } else {
            int e = col - D;
            #pragma unroll
            for (int i = 0; i < 8; ++i) { float v = Y[(i*64 + lane)*E + e]; s1 += v; s2 += v*v; }
        }
        #pragma unroll
        for (int off = 32; off > 0; off >>= 1) { s1 += __shfl_xor(s1, off); s2 += __shfl_xor(s2, off); }
        if (lane == 0) {
            float mean = s1 * (1.0f/N);
            float var  = (s2 - (float)N*mean*mean) * (1.0f/(N-1));
            float sd   = sqrtf(var);
            if (col < D) { meanX[col] = mean; stdX[col] = sd; }
            else         { meanY[col-D] = mean; stdY[col-D] = sd; }
        }
    }
    __syncthreads();
    if (tid < D) {
        mmsh[tid] = (m[tid] - meanX[tid]) / stdX[tid];
        ws[OFF_XMEAN + tid] = meanX[tid];
        ws[OFF_XSTD  + tid] = stdX[tid];
    }
    if (tid < E) { ws[OFF_YMEAN + tid] = meanY[tid]; ws[OFF_YSTD + tid] = stdY[tid]; }
    __syncthreads();
    int n = tid;
    #pragma unroll
    for (int d = 0; d < D; ++d) {
        float xs = (X[n*D + d] - meanX[d]) / stdX[d];
        ws[OFF_XS  + n*D + d] = xs;
        ws[OFF_INP + n*D + d] = xs - mmsh[d];
    }
    #pragma unroll
    for (int e = 0; e < E; ++e)
        ws[OFF_YN + e*N + n] = (Y[n*E + e] - meanY[e]) / stdY[e];
    if (tid < D*D) {
        int i = tid / D, j = tid % D;
        ws[OFF_SSM + tid] = s[tid] / (stdX[i] * stdX[j]);
    }
}

// ---------- 2. A = K + noise I  +  appended B/R inverse blocks ----------
__global__ __launch_bounds__(256) void k_buildA(float* __restrict__ ws, const float* __restrict__ ls,
                                                const float* __restrict__ os, const float* __restrict__ noise) {
    int bid = blockIdx.x;
    int tid = threadIdx.x;
    if (bid < E*64) {
        int e  = bid >> 6;
        int t  = bid & 63;
        int bn = t >> 3, bm = t & 7;
        __shared__ float xn[64][17], xm[64][17];
        __shared__ float il2[16];
        for (int idx = tid; idx < 1024; idx += 256) {
            int r = idx >> 4, d0 = idx & 15;
            xn[r][d0] = ws[OFF_XS + (size_t)(bn*64 + r)*D + d0];
            xm[r][d0] = ws[OFF_XS + (size_t)(bm*64 + r)*D + d0];
        }
        if (tid < 16) { float l = ls[e*D + tid]; il2[tid] = 1.0f/(l*l); }
        __syncthreads();
        int tx = tid & 15, ty = tid >> 4;
        float osv = os[e], nsv = noise[e];
        float acc[4][4] = {};
        #pragma unroll
        for (int d = 0; d < 16; ++d) {
            float il = il2[d];
            float an[4], am[4];
            #pragma unroll
            for (int q = 0; q < 4; ++q) { an[q] = xn[ty + q*16][d]; am[q] = xm[tx + q*16][d]; }
            #pragma unroll
            for (int q = 0; q < 4; ++q)
                #pragma unroll
                for (int w = 0; w < 4; ++w) { float df = an[q] - am[w]; acc[q][w] = fmaf(df*df, il, acc[q][w]); }
        }
        float* A = ws + OFF_A + (size_t)e*N*N;
        #pragma unroll
        for (int q = 0; q < 4; ++q)
            #pragma unroll
            for (int w = 0; w < 4; ++w) {
                int nr = bn*64 + ty + q*16, mc = bm*64 + tx + w*16;
                float v = osv * __expf(-0.5f * acc[q][w]);
                if (nr == mc) v += nsv;
                A[(size_t)nr*N + mc] = v;
            }
        return;
    }
    int bidx = bid - E*64;
    int i = tid >> 4, j = tid & 15;
    if (bidx < E) {
        int e = bidx;
        __shared__ float Bm[16][17], BInv[16][17];
        float li = ls[e*D + i], lj = ls[e*D + j];
        Bm[i][j] = ws[OFF_SSM + i*D + j] / (li*lj) + ((i==j) ? 1.f : 0.f);
        BInv[i][j] = (i==j) ? 1.f : 0.f;
        __syncthreads();
        float det = 1.f;
        for (int k = 0; k < D; ++k) {
            float p   = Bm[k][k];
            float fik = Bm[i][k];
            float bkj = Bm[k][j];
            float ikj = BInv[k][j];
            __syncthreads();
            det *= p;
            if (i == k) { Bm[k][j] = bkj/p; BInv[k][j] = ikj/p; }
            else        { float f = fik/p; Bm[i][j] -= f*bkj; BInv[i][j] -= f*ikj; }
            __syncthreads();
        }
        ws[OFF_BINV + ((size_t)e*D + i)*D + j] = BInv[i][j];
        if (tid == 0) ws[OFF_C + e] = os[e] / sqrtf(det);
    } else {
        int pair = bidx - E;
        int a = pair / E, b = pair % E;
        __shared__ float Rm[16][17], RInv[16][17], ssl[16][17];
        float la = ls[a*D + j], lb2 = ls[b*D + j];
        float rj = 1.f/(la*la) + 1.f/(lb2*lb2);
        float ssv = ws[OFF_SSM + i*D + j];
        ssl[i][j] = ssv;
        Rm[i][j] = ssv * rj + ((i==j) ? 1.f : 0.f);
        RInv[i][j] = (i==j) ? 1.f : 0.f;
        __syncthreads();
        float det = 1.f;
        for (int k = 0; k < D; ++k) {
            float p   = Rm[k][k];
            float fik = Rm[i][k];
            float rkj = Rm[k][j];
            float ikj = RInv[k][j];
            __syncthreads();
            det *= p;
            if (i == k) { Rm[k][j] = rkj/p; RInv[k][j] = ikj/p; }
            else        { float f = fik/p; Rm[i][j] -= f*rkj; RInv[i][j] -= f*ikj; }
            __syncthreads();
        }
        float q = 0.f;
        #pragma unroll
        for (int k2 = 0; k2 < D; ++k2) q += RInv[i][k2] * ssl[k2][j];
        ws[OFF_Q + ((size_t)pair*D + i)*D + j] = 0.5f * q;
        if (tid == 0) ws[OFF_ISDR + pair] = 1.f / sqrtf(det);
    }
}

// ---------- 3a. first diag: fast factor + blocked inverse ----------
__global__ __launch_bounds__(256) void k_diag64(float* __restrict__ ws, int k0) {
    int e = blockIdx.x;
    int tid = threadIdx.x;
    int lane = tid & 63, wv = tid >> 6;
    const float* A = ws + OFF_A + (size_t)e*N*N;
    float* W = ws + OFF_IK + (size_t)e*N*N;
    __shared__ float Lsh[64][65], Xsh[64][65];
    __shared__ float cb[2][64];
    __shared__ float invd[64];
    __shared__ float Tsh[3][16][17];
    float a[16];
    #pragma unroll
    for (int j = 0; j < 16; ++j)
        a[j] = A[(size_t)(k0 + wv*16 + j)*N + k0 + lane];
    __syncthreads();
    fact64(a, cb, invd, lane, wv);
    #pragma unroll
    for (int j = 0; j < 16; ++j) Lsh[lane][wv*16 + j] = a[j];
    __syncthreads();
    binv64(Lsh, Xsh, invd, Tsh, tid);
    for (int idx = tid; idx < 4096; idx += 256) {
        int r = idx >> 6, c = idx & 63;
        W[(size_t)(k0 + r)*N + k0 + c] = Xsh[r][c];
    }
}

// ---------- 3b. merged trailing step: panel TRSM recompute + SYRK + fused diag + OFF_P persist ----------
__global__ __launch_bounds__(256) void k_traild(float* __restrict__ ws, int k0) {
    int kk = k0 >> 6;
    int t0 = k0 + 64;
    int nb = (N - t0) >> 6;
    int ntiles = (nb*(nb+1)) >> 1;
    int e = blockIdx.x / ntiles;
    int t = blockIdx.x % ntiles;
    int bj = 0; while (t >= nb - bj) { t -= nb - bj; ++bj; }
    int bi = bj + t;
    bool same = (bi == bj);
    bool isdiag0 = (bi == 0) && (bj == 0);
    float* A = ws + OFF_A + (size_t)e*N*N;
    const float* Wd = ws + OFF_IK + (size_t)e*N*N;
    __shared__ float Wsh[64][65], Sr[64][65], Sc[64][65];
    __shared__ float cb[2][64];
    __shared__ float invd[64];
    __shared__ float Tsh[3][16][17];
    int tid = threadIdx.x;
    int tx = tid & 15, ty = tid >> 4;

    load_tile4(Wd + (size_t)k0*N + k0, N, Wsh, tid);
    load_tile4(A + (size_t)(t0 + bi*64)*N + k0, N, Sr, tid);
    if (!same) load_tile4(A + (size_t)(t0 + bj*64)*N + k0, N, Sc, tid);
    __syncthreads();
    // panel TRSM via GEMM with W_kk = L_kk^{-1}
    float pr[4][4] = {}, pc[4][4] = {};
    if (same) {
        #pragma unroll 8
        for (int j = 0; j < 64; ++j) {
            float w4[4], a4[4];
            #pragma unroll
            for (int q = 0; q < 4; ++q) { w4[q] = Wsh[tx*4+q][j]; a4[q] = Sr[ty*4+q][j]; }
            #pragma unroll
            for (int q = 0; q < 4; ++q)
                #pragma unroll
                for (int w = 0; w < 4; ++w) pr[q][w] = fmaf(a4[q], w4[w], pr[q][w]);
        }
    } else {
        #pragma unroll 4
        for (int j = 0; j < 64; ++j) {
            float w4[4], a4[4], c4[4];
            #pragma unroll
            for (int q = 0; q < 4; ++q) { w4[q] = Wsh[tx*4+q][j]; a4[q] = Sr[ty*4+q][j]; c4[q] = Sc[ty*4+q][j]; }
            #pragma unroll
            for (int q = 0; q < 4; ++q)
                #pragma unroll
                for (int w = 0; w < 4; ++w) {
                    pr[q][w] = fmaf(a4[q], w4[w], pr[q][w]);
                    pc[q][w] = fmaf(c4[q], w4[w], pc[q][w]);
                }
        }
    }
    __syncthreads();
    #pragma unroll
    for (int q = 0; q < 4; ++q)
        #pragma unroll
        for (int w = 0; w < 4; ++w) Sr[ty*4+q][tx*4+w] = pr[q][w];
    if (!same) {
        #pragma unroll
        for (int q = 0; q < 4; ++q)
            #pragma unroll
            for (int w = 0; w < 4; ++w) Sc[ty*4+q][tx*4+w] = pc[q][w];
    }
    __syncthreads();
    // designated writer: (bi, 0) persists final L-panel tile bi into OFF_P
    if (bj == 0) {
        float* Pp = ws + OFF_P + ((size_t)e*1792 + prow(kk) + (size_t)bi*64)*64;
        #pragma unroll
        for (int j = 0; j < 4; ++j) {
            int idx = tid + j*256;
            int r = idx >> 6, c = idx & 63;
            Pp[(size_t)r*64 + c] = Sr[r][c];
        }
    }
    // SYRK
    float acc[4][4] = {};
    if (same) {
        #pragma unroll 8
        for (int p = 0; p < 64; ++p) {
            float ar[4], ac[4];
            #pragma unroll
            for (int q = 0; q < 4; ++q) { ar[q] = Sr[ty*4+q][p]; ac[q] = Sr[tx*4+q][p]; }
            #pragma unroll
            for (int q = 0; q < 4; ++q)
                #pragma unroll
                for (int w = 0; w < 4; ++w) acc[q][w] = fmaf(ar[q], ac[w], acc[q][w]);
        }
    } else {
        #pragma unroll 8
        for (int p = 0; p < 64; ++p) {
            float ar[4], ac[4];
            #pragma unroll
            for (int q = 0; q < 4; ++q) { ar[q] = Sr[ty*4+q][p]; ac[q] = Sc[tx*4+q][p]; }
            #pragma unroll
            for (int q = 0; q < 4; ++q)
                #pragma unroll
                for (int w = 0; w < 4; ++w) acc[q][w] = fmaf(ar[q], ac[w], acc[q][w]);
        }
    }
    float* Out = A + (size_t)(t0 + bi*64)*N + (t0 + bj*64);
    if (!isdiag0) {
        #pragma unroll
        for (int q = 0; q < 4; ++q)
            #pragma unroll
            for (int w = 0; w < 4; ++w)
                Out[(size_t)(ty*4+q)*N + tx*4+w] -= acc[q][w];
        return;
    }
    // ---- fused: updated (t0,t0) tile -> fast factor + blocked invert -> W diag ----
    __syncthreads();
    #pragma unroll
    for (int q = 0; q < 4; ++q)
        #pragma unroll
        for (int w = 0; w < 4; ++w)
            Sc[ty*4+q][tx*4+w] = Out[(size_t)(ty*4+q)*N + tx*4+w] - acc[q][w];
    __syncthreads();
    int lane = tid & 63, wv = tid >> 6;
    float a[16];
    #pragma unroll
    for (int j = 0; j < 16; ++j) a[j] = Sc[lane][wv*16 + j];   // tile symmetric
    __syncthreads();
    fact64(a, cb, invd, lane, wv);
    #pragma unroll
    for (int j = 0; j < 16; ++j) Sc[lane][wv*16 + j] = a[j];   // Sc becomes Lsh
    __syncthreads();
    binv64(Sc, Sr, invd, Tsh, tid);                            // Sr becomes Xsh
    float* W = ws + OFF_IK + (size_t)e*N*N;
    for (int idx = tid; idx < 4096; idx += 256) {
        int r = idx >> 6, c = idx & 63;
        W[(size_t)(t0 + r)*N + t0 + c] = Sr[r][c];
    }
}

// ---------- 3d. D&C level 1 (H=1): W21 = -W22 L21 W11 ----------
__global__ __launch_bounds__(256) void k_dc1(float* __restrict__ ws) {
    int e = blockIdx.x >> 2, p = blockIdx.x & 3;
    float* W = ws + OFF_IK + (size_t)e*N*N;
    const float* Lt = ws + OFF_P + ((size_t)e*1792 + prow(2*p))*64;
    __shared__ float Sa[64][65], Sb[64][65], T[64][65];
    int tid = threadIdx.x;
    int tx = tid & 15, ty = tid >> 4;
    load_tile4(Lt, 64, Sa, tid);
    load_tile4(W + (size_t)(2*p*64)*N + 2*p*64, N, Sb, tid);
    __syncthreads();
    float acc[4][4] = {};
    #pragma unroll 8
    for (int pp = 0; pp < 64; ++pp) {
        float ar[4], bc[4];
        #pragma unroll
        for (int q = 0; q < 4; ++q) { ar[q] = Sa[ty*4+q][pp]; bc[q] = Sb[pp][tx*4+q]; }
        #pragma unroll
        for (int q = 0; q < 4; ++q)
            #pragma unroll
            for (int w = 0; w < 4; ++w) acc[q][w] = fmaf(ar[q], bc[w], acc[q][w]);
    }
    #pragma unroll
    for (int q = 0; q < 4; ++q)
        #pragma unroll
        for (int w = 0; w < 4; ++w) T[ty*4+q][tx*4+w] = acc[q][w];
    __syncthreads();
    load_tile4(W + (size_t)((2*p+1)*64)*N + (2*p+1)*64, N, Sa, tid);
    __syncthreads();
    float o[4][4] = {};
    #pragma unroll 8
    for (int pp = 0; pp < 64; ++pp) {
        float ar[4], bc[4];
        #pragma unroll
        for (int q = 0; q < 4; ++q) { ar[q] = Sa[ty*4+q][pp]; bc[q] = T[pp][tx*4+q]; }
        #pragma unroll
        for (int q = 0; q < 4; ++q)
            #pragma unroll
            for (int w = 0; w < 4; ++w) o[q][w] = fmaf(ar[q], bc[w], o[q][w]);
    }
    #pragma unroll
    for (int q = 0; q < 4; ++q)
        #pragma unroll
        for (int w = 0; w < 4; ++w)
            W[(size_t)((2*p+1)*64 + ty*4 + q)*N + 2*p*64 + tx*4 + w] = -o[q][w];
}

// ---------- 3e. D&C: T = L21 * W11 (levels H=2,4) ----------
__global__ __launch_bounds__(256) void k_dcT(float* __restrict__ ws, int H) {
    int per_e = 4*H;
    int e = blockIdx.x / per_e;
    int rem = blockIdx.x % per_e;
    int p  = rem / (H*H);
    int tt = rem % (H*H);
    int ti = tt / H, tj = tt % H;
    int C0 = 2*p*H;
    int I  = C0 + H + ti;
    const float* W = ws + OFF_IK + (size_t)e*N*N;
    float* Tt = ws + OFF_T + (size_t)e*65536 + (size_t)(p*H*H + ti*H + tj)*4096;
    __shared__ float Sa[64][65], Sb[64][65];
    int tid = threadIdx.x;
    int tx = tid & 15, ty = tid >> 4;
    float acc[4][4] = {};
    for (int k = tj; k < H; ++k) {
        int K = C0 + k;
        const float* Lt = ws + OFF_P + ((size_t)e*1792 + prow(K) + (size_t)(I - K - 1)*64)*64;
        __syncthreads();
        load_tile4(Lt, 64, Sa, tid);
        load_tile4(W + (size_t)(K*64)*N + (C0 + tj)*64, N, Sb, tid);
        __syncthreads();
        #pragma unroll 8
        for (int pp = 0; pp < 64; ++pp) {
            float ar[4], bc[4];
            #pragma unroll
            for (int q = 0; q < 4; ++q) { ar[q] = Sa[ty*4+q][pp]; bc[q] = Sb[pp][tx*4+q]; }
            #pragma unroll
            for (int q = 0; q < 4; ++q)
                #pragma unroll
                for (int w = 0; w < 4; ++w) acc[q][w] = fmaf(ar[q], bc[w], acc[q][w]);
        }
    }
    #pragma unroll
    for (int q = 0; q < 4; ++q)
        #pragma unroll
        for (int w = 0; w < 4; ++w)
            Tt[(size_t)(ty*4+q)*64 + tx*4 + w] = acc[q][w];
}

// ---------- 3f. D&C: W21 = -W22 * T ----------
__global__ __launch_bounds__(256) void k_dcW(float* __restrict__ ws, int H) {
    int per_e = 4*H;
    int e = blockIdx.x / per_e;
    int rem = blockIdx.x % per_e;
    int p  = rem / (H*H);
    int tt = rem % (H*H);
    int ti = tt / H, tj = tt % H;
    int C0 = 2*p*H, R0 = C0 + H;
    float* W = ws + OFF_IK + (size_t)e*N*N;
    const float* Tbase = ws + OFF_T + (size_t)e*65536 + (size_t)(p*H*H)*4096;
    __shared__ float Sa[64][65], Sb[64][65];
    int tid = threadIdx.x;
    int tx = tid & 15, ty = tid >> 4;
    float acc[4][4] = {};
    for (int tk = 0; tk <= ti; ++tk) {
        const float* Tt = Tbase + (size_t)(tk*H + tj)*4096;
        __syncthreads();
        load_tile4(W + (size_t)((R0 + ti)*64)*N + (R0 + tk)*64, N, Sa, tid);
        load_tile4(Tt, 64, Sb, tid);
        __syncthreads();
        #pragma unroll 8
        for (int pp = 0; pp < 64; ++pp) {
            float ar[4], bc[4];
            #pragma unroll
            for (int q = 0; q < 4; ++q) { ar[q] = Sa[ty*4+q][pp]; bc[q] = Sb[pp][tx*4+q]; }
            #pragma unroll
            for (int q = 0; q < 4; ++q)
                #pragma unroll
                for (int w = 0; w < 4; ++w) acc[q][w] = fmaf(ar[q], bc[w], acc[q][w]);
        }
    }
    #pragma unroll
    for (int q = 0; q < 4; ++q)
        #pragma unroll
        for (int w = 0; w < 4; ++w)
            W[(size_t)((R0 + ti)*64 + ty*4 + q)*N + (C0 + tj)*64 + tx*4 + w] = -acc[q][w];
}

// ---------- 3g. iK = W^T W, column-split half-tiles (h=0/1)  +  appended xs blocks ----------
__global__ __launch_bounds__(256) void k_syrk(float* __restrict__ ws, const float* __restrict__ ls,
                                              const float* __restrict__ os) {
    int tid = threadIdx.x;
    if (blockIdx.x >= E*72) {
        int t = (blockIdx.x - E*72)*256 + tid;
        xs_body(ws, ls, os, t, tid);
        return;
    }
    int e = blockIdx.x / 72;
    int t2 = blockIdx.x % 72;
    int t = t2 >> 1, h = t2 & 1;
    int bj = 0; while (t >= 8 - bj) { t -= 8 - bj; ++bj; }
    int bi = bj + t;
    bool same = (bi == bj);
    const float* W = ws + OFF_IK + (size_t)e*N*N;
    float*      IK = ws + OFF_A  + (size_t)e*N*N;
    __shared__ float Sa[64][65], Sb[64][33];
    // thread -> 4 rows x 2 cols of the 64x32 half-tile
    int tx = tid & 15, ty = tid >> 4;   // cols: h*32 + tx*2 + w ; rows: ty*4 + q

    float4 pa[4];
    float4 pb[2];
    #pragma unroll
    for (int j = 0; j < 4; ++j) {
        int idx = tid + j*256;
        int r = idx >> 4, c4 = idx & 15;
        pa[j] = *(const float4*)&W[(size_t)(bi*64 + r)*N + bi*64 + c4*4];
    }
    if (!same) {
        #pragma unroll
        for (int j = 0; j < 2; ++j) {
            int idx = tid + j*256;     // 512 float4s = 64 rows x 8 float4
            int r = idx >> 3, c4 = idx & 7;
            pb[j] = *(const float4*)&W[(size_t)(bi*64 + r)*N + bj*64 + h*32 + c4*4];
        }
    }

    float acc[4][2] = {};
    for (int p = bi; p < 8; ++p) {
        __syncthreads();
        #pragma unroll
        for (int j = 0; j < 4; ++j) {
            int idx = tid + j*256;
            int r = idx >> 4, c4 = idx & 15;
            Sa[r][c4*4+0] = pa[j].x; Sa[r][c4*4+1] = pa[j].y; Sa[r][c4*4+2] = pa[j].z; Sa[r][c4*4+3] = pa[j].w;
        }
        if (!same) {
            #pragma unroll
            for (int j = 0; j < 2; ++j) {
                int idx = tid + j*256;
                int r = idx >> 3, c4 = idx & 7;
                Sb[r][c4*4+0] = pb[j].x; Sb[r][c4*4+1] = pb[j].y; Sb[r][c4*4+2] = pb[j].z; Sb[r][c4*4+3] = pb[j].w;
            }
        }
        if (p < 7) {
            #pragma unroll
            for (int j = 0; j < 4; ++j) {
                int idx = tid + j*256;
                int r = idx >> 4, c4 = idx & 15;
                pa[j] = *(const float4*)&W[(size_t)((p+1)*64 + r)*N + bi*64 + c4*4];
            }
            if (!same) {
                #pragma unroll
                for (int j = 0; j < 2; ++j) {
                    int idx = tid + j*256;
                    int r = idx >> 3, c4 = idx & 7;
                    pb[j] = *(const float4*)&W[(size_t)((p+1)*64 + r)*N + bj*64 + h*32 + c4*4];
                }
            }
        }
        __syncthreads();
        if (same) {
            #pragma unroll 8
            for (int pr2 = 0; pr2 < 64; ++pr2) {
                float ar[4], ac[2];
                #pragma unroll
                for (int q = 0; q < 4; ++q) ar[q] = Sa[pr2][ty*4+q];
                #pragma unroll
                for (int w = 0; w < 2; ++w) ac[w] = Sa[pr2][h*32 + tx*2 + w];
                #pragma unroll
                for (int q = 0; q < 4; ++q)
                    #pragma unroll
                    for (int w = 0; w < 2; ++w) acc[q][w] = fmaf(ar[q], ac[w], acc[q][w]);
            }
        } else {
            #pragma unroll 8
            for (int pr2 = 0; pr2 < 64; ++pr2) {
                float ar[4], ac[2];
                #pragma unroll
                for (int q = 0; q < 4; ++q) ar[q] = Sa[pr2][ty*4+q];
                #pragma unroll
                for (int w = 0; w < 2; ++w) ac[w] = Sb[pr2][tx*2 + w];
                #pragma unroll
                for (int q = 0; q < 4; ++q)
                    #pragma unroll
                    for (int w = 0; w < 2; ++w) acc[q][w] = fmaf(ar[q], ac[w], acc[q][w]);
            }
        }
    }
    #pragma unroll
    for (int q = 0; q < 4; ++q)
        #pragma unroll
        for (int w = 0; w < 2; ++w) {
            int r = bi*64 + ty*4 + q, c = bj*64 + h*32 + tx*2 + w;
            IK[(size_t)r*N + c] = acc[q][w];
            IK[(size_t)c*N + r] = acc[q][w];
        }
}

// ---------- 3h. beta = iK @ Yn ----------
__global__ __launch_bounds__(256) void k_beta(float* __restrict__ ws) {
    int e = blockIdx.x >> 2, qtr = blockIdx.x & 3;
    int tid = threadIdx.x;
    int half = tid >> 7;
    int nl = tid & 127;
    int n = qtr*128 + nl;
    __shared__ float yn[N];
    __shared__ float part[2][128];
    for (int i = tid; i < N; i += 256) yn[i] = ws[OFF_YN + (size_t)e*N + i];
    __syncthreads();
    const float* IK = ws + OFF_A + (size_t)e*N*N;
    int m0 = half*256;
    float a0 = 0.f, a1 = 0.f, a2 = 0.f, a3 = 0.f;
    for (int mm = m0; mm < m0 + 256; mm += 4) {
        a0 = fmaf(IK[(size_t)mm*N + n],     yn[mm],   a0);
        a1 = fmaf(IK[(size_t)(mm+1)*N + n], yn[mm+1], a1);
        a2 = fmaf(IK[(size_t)(mm+2)*N + n], yn[mm+2], a2);
        a3 = fmaf(IK[(size_t)(mm+3)*N + n], yn[mm+3], a3);
    }
    part[half][nl] = (a0 + a1) + (a2 + a3);
    __syncthreads();
    if (tid < 128)
        ws[OFF_BETA + e*N + qtr*128 + tid] = part[0][tid] + part[1][tid];
}

// ---------- 7. big cross-term (compact pairs) + appended point blocks ----------
__global__ __launch_bounds__(256) void k_S(float* __restrict__ ws, const float* __restrict__ ls,
                                           const float* __restrict__ os) {
    int tid = threadIdx.x;
    if (blockIdx.x >= NPAIR*8) {
        int t = (blockIdx.x - NPAIR*8)*256 + tid;
        point_body(ws, ls, t);
        return;
    }
    int bid = blockIdx.x;            // NPAIR * 8
    int pc = bid >> 3, ntile = bid & 7;
    int a, b;
    pc2ab(pc, a, b);
    int pairQ = a*E + b;
    int tx = tid & 15, ty = tid >> 4;
    __shared__ float Qs[16][17];
    __shared__ float i2a[16], i2b[16];
    __shared__ float __align__(16) bufAT[16][68];
    __shared__ float __align__(16) x1qT[16][68];
    __shared__ float __align__(16) bufBT[16][68];
    __shared__ float u_s[64], v_s[64], ba_s[64], bb_s[64];
    __shared__ float red[256];
    int n0 = ntile*64;
    Qs[tid >> 4][tid & 15] = ws[OFF_Q + (size_t)pairQ*D*D + tid];
    if (tid < 16) { float l = ls[a*D + tid]; i2a[tid] = 1.0f/(l*l); }
    else if (tid < 32) { int d = tid-16; float l = ls[b*D + d]; i2b[d] = 1.0f/(l*l); }
    __syncthreads();
    for (int idx = tid; idx < 1024; idx += 256) {
        int r = idx >> 4, d = idx & 15;
        bufAT[d][r] = ws[OFF_INP + (size_t)(n0 + r)*D + d] * i2a[d];
    }
    __syncthreads();
    for (int idx = tid; idx < 1024; idx += 256) {
        int r = idx >> 4, j = idx & 15;
        float s = 0.f;
        #pragma unroll
        for (int i = 0; i < 16; ++i) s = fmaf(bufAT[i][r], Qs[i][j], s);
        x1qT[j][r] = s;
    }
    if (tid < 64) {
        u_s[tid]  = ws[OFF_U + (size_t)pc*N + n0 + tid];
        ba_s[tid] = ws[OFF_BETA + a*N + n0 + tid];
    }
    __syncthreads();
    float4 av4[16];
    #pragma unroll
    for (int d = 0; d < 16; ++d) av4[d] = *(const float4*)&x1qT[d][ty*4];
    float uq[4], baq[4];
    #pragma unroll
    for (int q = 0; q < 4; ++q) { uq[q] = u_s[ty*4+q]; baq[q] = ba_s[ty*4+q]; }

    float pf[4];
    #pragma unroll
    for (int j = 0; j < 4; ++j) {
        int idx = tid + j*256;
        pf[j] = ws[OFF_INP + (size_t)((idx >> 4))*D + (idx & 15)];
    }
    float vpf = 0.f, bpf = 0.f;
    if (tid < 64) {
        vpf = ws[OFF_V + (size_t)pc*N + tid];
        bpf = ws[OFF_BETA + b*N + tid];
    }

    float sacc = 0.f, tacc = 0.f;
    for (int mt = 0; mt < 8; ++mt) {
        __syncthreads();
        #pragma unroll
        for (int j = 0; j < 4; ++j) {
            int idx = tid + j*256;
            bufBT[idx & 15][idx >> 4] = pf[j] * i2b[idx & 15];
        }
        if (tid < 64) { v_s[tid] = vpf; bb_s[tid] = bpf; }
        if (mt < 7) {
            #pragma unroll
            for (int j = 0; j < 4; ++j) {
                int idx = tid + j*256;
                pf[j] = ws[OFF_INP + (size_t)((mt+1)*64 + (idx >> 4))*D + (idx & 15)];
            }
            if (tid < 64) {
                vpf = ws[OFF_V + (size_t)pc*N + (mt+1)*64 + tid];
                bpf = ws[OFF_BETA + b*N + (mt+1)*64 + tid];
            }
        }
        __syncthreads();
        float dacc[4][4] = {};
        #pragma unroll
        for (int d = 0; d < 16; ++d) {
            float4 bv = *(const float4*)&bufBT[d][tx*4];
            float4 av = av4[d];
            dacc[0][0] = fmaf(av.x, bv.x, dacc[0][0]); dacc[0][1] = fmaf(av.x, bv.y, dacc[0][1]);
            dacc[0][2] = fmaf(av.x, bv.z, dacc[0][2]); dacc[0][3] = fmaf(av.x, bv.w, dacc[0][3]);
            dacc[1][0] = fmaf(av.y, bv.x, dacc[1][0]); dacc[1][1] = fmaf(av.y, bv.y, dacc[1][1]);
            dacc[1][2] = fmaf(av.y, bv.z, dacc[1][2]); dacc[1][3] = fmaf(av.y, bv.w, dacc[1][3]);
            dacc[2][0] = fmaf(av.z, bv.x, dacc[2][0]); dacc[2][1] = fmaf(av.z, bv.y, dacc[2][1]);
            dacc[2][2] = fmaf(av.z, bv.z, dacc[2][2]); dacc[2][3] = fmaf(av.z, bv.w, dacc[2][3]);
            dacc[3][0] = fmaf(av.w, bv.x, dacc[3][0]); dacc[3][1] = fmaf(av.w, bv.y, dacc[3][1]);
            dacc[3][2] = fmaf(av.w, bv.z, dacc[3][2]); dacc[3][3] = fmaf(av.w, bv.w, dacc[3][3]);
        }
        #pragma unroll
        for (int q = 0; q < 4; ++q) {
            float ikq[4];
            if (a == b)
                *(float4*)ikq = *(const float4*)&ws[OFF_A + ((size_t)a*N + n0 + ty*4 + q)*N + mt*64 + tx*4];
            #pragma unroll
            for (int w = 0; w < 4; ++w) {
                float Lv = __expf(2.f*dacc[q][w] + uq[q] + v_s[tx*4+w]);
                sacc = fmaf(baq[q] * bb_s[tx*4+w], Lv, sacc);
                if (a == b)
                    tacc = fmaf(ikq[w], Lv, tacc);
            }
        }
    }
    red[tid] = sacc; __syncthreads();
    for (int o = 128; o > 0; o >>= 1) { if (tid < o) red[tid] += red[tid+o]; __syncthreads(); }
    if (tid == 0) ws[OFF_SPART + bid] = red[0];
    if (a == b) {
        __syncthreads();
        red[tid] = tacc; __syncthreads();
        for (int o = 128; o > 0; o >>= 1) { if (tid < o) red[tid] += red[tid+o]; __syncthreads(); }
        if (tid == 0) ws[OFF_TPART + a*8 + ntile] = red[0];
    }
}

// ---------- 8. finalize ----------
__global__ __launch_bounds__(256) void k_final(float* __restrict__ ws, const float* __restrict__ s,
                                               const float* __restrict__ os, float* __restrict__ out) {
    int tid = threadIdx.x;
    __shared__ float Msh[E], Vsh[E][D], cov[D][E+1];
    __shared__ float Sm[16][17], Si[16][17];
    __shared__ float vred[16][17];

    {
        int wv = tid >> 6, lane = tid & 63;
        for (int e = wv; e < E; e += 4) {
            float sum = 0.f;
            #pragma unroll
            for (int i = 0; i < 8; ++i) sum += ws[OFF_LB + e*N + i*64 + lane];
            #pragma unroll
            for (int off = 32; off > 0; off >>= 1) sum += __shfl_xor(sum, off);
            if (lane == 0) Msh[e] = ws[OFF_C + e] * sum;
        }
    }
    for (int e = 0; e < E; ++e) {
        int d = tid & 15, sl = tid >> 4;
        float acc = 0.f;
        for (int i = 0; i < 32; ++i) {
            int n = sl*32 + i;
            acc = fmaf(ws[OFF_TIL + ((size_t)e*N + n)*D + d], ws[OFF_LB + e*N + n], acc);
        }
        vred[sl][d] = acc;
        __syncthreads();
        if (tid < 16) {
            float sum = 0.f;
            #pragma unroll
            for (int s2 = 0; s2 < 16; ++s2) sum += vred[s2][tid];
            Vsh[e][tid] = ws[OFF_C + e] * sum;
        }
        __syncthreads();
    }

    if (tid < E*E) {
        int a = tid / E, bb = tid % E;
        int amin = (a < bb) ? a : bb;
        int amax = (a < bb) ? bb : a;
        int pc = amin*E - (amin*(amin-1))/2 + (amax - amin);
        float acc = 0.f;
        for (int q = 0; q < 8; ++q) acc += ws[OFF_SPART + (size_t)pc*8 + q];
        if (a == bb) {
            float tr = 0.f;
            for (int q = 0; q < 8; ++q) tr += ws[OFF_TPART + a*8 + q];
            acc -= tr;
        }
        acc *= ws[OFF_ISDR + tid];
        if (a == bb) acc += os[a];
        float v = acc - Msh[a]*Msh[bb];
        v *= ws[OFF_YSTD + a] * ws[OFF_YSTD + bb];
        out[E + tid] = v;
    }
    if (tid < E) out[tid] = Msh[tid]*ws[OFF_YSTD + tid] + ws[OFF_YMEAN + tid];

    if (tid < D*E) {
        int d = tid / E, e = tid % E;
        float acc = 0.f;
        for (int k = 0; k < D; ++k) acc += ws[OFF_SSM + d*D + k] * Vsh[e][k];
        cov[d][e] = acc * ws[OFF_XSTD + d] * ws[OFF_YSTD + e];
    }
    int i = tid >> 4, j = tid & 15;
    Sm[i][j] = s[i*D + j];
    Si[i][j] = (i==j) ? 1.f : 0.f;
    __syncthreads();
    for (int k = 0; k < D; ++k) {
        float p   = Sm[k][k];
        float fik = Sm[i][k];
        float skj = Sm[k][j];
        float ikj = Si[k][j];
        __syncthreads();
        if (i == k) { Sm[k][j] = skj/p; Si[k][j] = ikj/p; }
        else        { float f = fik/p; Sm[i][j] -= f*skj; Si[i][j] -= f*ikj; }
        __syncthreads();
    }
    if (tid < D*E) {
        int d = tid / E, e = tid % E;
        float acc = 0.f;
        for (int k = 0; k < D; ++k) acc += Si[d][k] * cov[k][e];
        out[E + E*E + d*E + e] = acc;
    }
}

extern "C" void kernel_launch(void* const* d_in, const int* in_sizes, int n_in,
                              void* d_out, int out_size, void* d_ws, size_t ws_size,
                              hipStream_t stream) {
    const float* X     = (const float*)d_in[0];
    const float* Y     = (const float*)d_in[1];
    const float* m     = (const float*)d_in[2];
    const float* s     = (const float*)d_in[3];
    const float* ls    = (const float*)d_in[4];
    const float* os    = (const float*)d_in[5];
    const float* noise = (const float*)d_in[6];
    float* ws  = (float*)d_ws;
    float* out = (float*)d_out;

    k_prep   <<<1,              512, 0, stream>>>(X, Y, m, s, ws);
    k_buildA <<<E*64 + E + E*E, 256, 0, stream>>>(ws, ls, os, noise);
    k_diag64 <<<E,              256, 0, stream>>>(ws, 0);
    for (int kk = 0; kk < 7; ++kk) {
        int nb = 7 - kk;
        k_traild<<<E*nb*(nb+1)/2, 256, 0, stream>>>(ws, kk*64);
    }
    k_dc1 <<<E*4,  256, 0, stream>>>(ws);
    k_dcT <<<E*8,  256, 0, stream>>>(ws, 2);
    k_dcW <<<E*8,  256, 0, stream>>>(ws, 2);
    k_dcT <<<E*16, 256, 0, stream>>>(ws, 4);
    k_dcW <<<E*16, 256, 0, stream>>>(ws, 4);
    k_syrk <<<E*72 + NPAIR*N/256,   256, 0, stream>>>(ws, ls, os);
    k_beta <<<E*4,                  256, 0, stream>>>(ws);
    k_S    <<<NPAIR*8 + E*N/256,    256, 0, stream>>>(ws, ls, os);
    k_final<<<1,                    256, 0, stream>>>(ws, s, os, out);
}